// Round 11
// baseline (955.983 us; speedup 1.0000x reference)
//
#include <hip/hip_runtime.h>
#include <hip/hip_bf16.h>
#include <math.h>

// Problem constants
#define B_ 2
#define N_ 2048
#define NR_ 256
#define DA_ 256
#define E_ 768
#define H_ 12
#define DH_ 64
#define NB_ 2

typedef __attribute__((ext_vector_type(8))) __bf16 bf16x8;
typedef __attribute__((ext_vector_type(4))) float f32x4;

union U8 { bf16x8 v; __hip_bfloat16 e[8]; unsigned short u[8]; };
union U4 { __hip_bfloat16 e[4]; uint2 u2; };

__device__ __forceinline__ void gload16(const void* g, void* l) {
    __builtin_amdgcn_global_load_lds(
        (const __attribute__((address_space(1))) void*)g,
        (__attribute__((address_space(3))) void*)l, 16, 0, 0);
}

// ---------------------------------------------------------------------------
// build feats[B*N, 1024] (bf16) and coordsF[B*N, 512] (bf16) + rope tables
// ---------------------------------------------------------------------------
__global__ __launch_bounds__(128) void build_feats_kernel(
    const float* __restrict__ atom_coords, const float* __restrict__ ref_pos,
    const int* __restrict__ res_id, const float* __restrict__ res_type,
    const float* __restrict__ charge, const float* __restrict__ atomic_number,
    const float* __restrict__ atom_name, const int* __restrict__ rope_pos,
    __hip_bfloat16* __restrict__ feats, __hip_bfloat16* __restrict__ coordsF,
    float* __restrict__ ropeC, float* __restrict__ ropeS)
{
    int a = blockIdx.x;            // atom index over B*N
    int tid = threadIdx.x;
    __hip_bfloat16* f  = feats   + (size_t)a * 1024;
    __hip_bfloat16* cf = coordsF + (size_t)a * 512;

    float rp[3], cc[3];
    #pragma unroll
    for (int i = 0; i < 3; ++i) { rp[i] = ref_pos[(size_t)a*3 + i]; cc[i] = atom_coords[(size_t)a*3 + i]; }

    if (tid < 3) { f[tid] = __float2bfloat16(rp[tid]); cf[tid] = __float2bfloat16(cc[tid]); }

    if (tid >= 64 && tid < 96) {
        int dd = tid - 64;
        float rpos = (float)rope_pos[a];
        float ang = rpos * expf(-0.28782313662425574f * (float)dd);  // ln(1e4)/32
        float sn, cs; sincosf(ang, &sn, &cs);
        ropeC[a*32 + dd] = cs; ropeS[a*32 + dd] = sn;
    }

    for (int s = tid; s < 192; s += 128) {
        int fi = s / 3, ci = s % 3;
        float freq = exp2f(12.f * (float)fi / 63.f);
        float ar = rp[ci] * freq;
        float ac = cc[ci] * freq;
        float snr, csr, snc, csc_;
        sincosf(ar, &snr, &csr);
        sincosf(ac, &snc, &csc_);
        f[3 + s]    = __float2bfloat16(snr);  f[195 + s]  = __float2bfloat16(csr);
        cf[3 + s]   = __float2bfloat16(snc);  cf[195 + s] = __float2bfloat16(csc_);
    }
    if (tid < 23) f[387 + tid] = __float2bfloat16(res_type[(size_t)a*23 + tid]);

    float pos = (float)res_id[a];
    if (tid == 0) f[410] = __float2bfloat16(pos);
    if (tid < 64) {
        float div = expf(-9.210340371976184f / 128.f * (float)(2 * tid));
        float ang = pos * div;
        float sn, cs; sincosf(ang, &sn, &cs);
        f[411 + tid] = __float2bfloat16(sn);
        f[475 + tid] = __float2bfloat16(cs);
    }
    if (tid == 0) f[539] = __float2bfloat16(charge[a]);
    if (tid < 128) f[540 + tid] = __float2bfloat16(atomic_number[(size_t)a*128 + tid]);
    for (int s = tid; s < 256; s += 128) f[668 + s] = __float2bfloat16(atom_name[(size_t)a*256 + s]);
    if (tid < 100) f[924 + tid] = __float2bfloat16(0.f);
    if (tid < 125) cf[387 + tid] = __float2bfloat16(0.f);
}

// ---------------------------------------------------------------------------
// Transpose + fp32->bf16 + K-pad: W[Ksrc][Nn] -> WT[Nn][Kdst], zeros k>=Ksrc
// ---------------------------------------------------------------------------
__global__ __launch_bounds__(256) void transconv_kernel(
    const float* __restrict__ W, __hip_bfloat16* __restrict__ WT,
    int Ksrc, int Kdst, int Nn, size_t wstride, size_t tstride)
{
    __shared__ float t[32][33];
    W  += (size_t)blockIdx.z * wstride;
    WT += (size_t)blockIdx.z * tstride;
    int n0 = blockIdx.x * 32, k0 = blockIdx.y * 32;
    int tid = threadIdx.x;
    int tx = tid & 31, ty = tid >> 5;           // ty 0..7
    #pragma unroll
    for (int i = 0; i < 4; ++i) {
        int k = k0 + ty + i*8;
        t[ty + i*8][tx] = (k < Ksrc) ? W[(size_t)k * Nn + n0 + tx] : 0.f;
    }
    __syncthreads();
    #pragma unroll
    for (int i = 0; i < 4; ++i) {
        int row = ty + i*8;                      // n within tile
        WT[(size_t)(n0 + row) * Kdst + k0 + tx] = __float2bfloat16(t[tx][row]);
    }
}

// ---------------------------------------------------------------------------
// shared epilogue.  mode 0 none; 1 gelu; 2 X + gate[b][col]*v; 3 v*gate[row]
// ---------------------------------------------------------------------------
__device__ __forceinline__ float epi_apply(float v, int grow, int gcol,
    const float* bias, int mode, const float* X, int ldx,
    const float* gate, int gstride)
{
    if (bias) v += bias[gcol];
    if (mode == 1) {
        float u = 1.5957691216057308f * (v + 0.044715f * v * v * v);
        v = v / (1.f + __expf(-u));
    } else if (mode == 2) {
        int b = grow >> 11;                      // /N_
        v = X[(size_t)grow * ldx + gcol] + gate[(size_t)b * gstride + gcol] * v;
    } else if (mode == 3) {
        v = v * gate[grow];
    }
    return v;
}

// ---------------------------------------------------------------------------
// DIRECT bf16 MFMA GEMM: no LDS, no barriers.  Tile 128x128, 4 waves, 64x64
// per wave.  Fragments loaded straight from global (L1/L2-resident operands;
// lanes (lr,lg) read 16 rows x 64B contiguous = fully coalesced).  Software-
// pipelined 1 K-step ahead with two register sets (hand-unrolled, static
// indexing).  Compiler tracks all register deps (auto s_waitcnt).
// Bijective XCD swizzle.  nz>1 -> raw fp32 partials to P.
// ---------------------------------------------------------------------------
__global__ __launch_bounds__(256) void gemm_bf16_direct_kernel(
    const __hip_bfloat16* __restrict__ A, int lda,
    const __hip_bfloat16* __restrict__ BT, int ldb,
    const float* __restrict__ bias,
    void* __restrict__ C, int ldc,
    int K, int mode, int obf,
    const float* __restrict__ X, int ldx,
    const float* __restrict__ gate, int gstride,
    float* __restrict__ P)
{
    int gx = gridDim.x;
    int nwg = gx * gridDim.y;
    int fo = blockIdx.y * gx + blockIdx.x;
    int ft = (fo & 7) * (nwg >> 3) + (fo >> 3);
    int bx = ft % gx, by = ft / gx;

    int m0 = by * 128, n0 = bx * 128;
    int nz = gridDim.z;
    int Kh = K / nz;
    int kb = blockIdx.z * Kh;
    int nIter = Kh >> 5;                         // even for all call sites
    int tid = threadIdx.x;
    int w = tid >> 6, l = tid & 63;
    int wr = (w >> 1) * 64, wc = (w & 1) * 64;
    int lr = l & 15, lg = l >> 4;

    const __hip_bfloat16* pA[4];
    const __hip_bfloat16* pB[4];
    #pragma unroll
    for (int i = 0; i < 4; ++i) {
        pA[i] = A  + (size_t)(m0 + wr + i*16 + lr) * lda + kb + lg*8;
        pB[i] = BT + (size_t)(n0 + wc + i*16 + lr) * ldb + kb + lg*8;
    }

    f32x4 acc[4][4];
    #pragma unroll
    for (int i = 0; i < 4; ++i)
        #pragma unroll
        for (int j = 0; j < 4; ++j)
            acc[i][j] = f32x4{0.f, 0.f, 0.f, 0.f};

    bf16x8 a0[4], b0[4], a1[4], b1[4];
    #pragma unroll
    for (int i = 0; i < 4; ++i) { a0[i] = *(const bf16x8*)(pA[i]); b0[i] = *(const bf16x8*)(pB[i]); }

    for (int it = 0; it < nIter; it += 2) {
        int k1 = (it + 1) * 32, k2 = (it + 2) * 32;
        if (it + 1 < nIter) {
            #pragma unroll
            for (int i = 0; i < 4; ++i) { a1[i] = *(const bf16x8*)(pA[i] + k1); b1[i] = *(const bf16x8*)(pB[i] + k1); }
        }
        #pragma unroll
        for (int i = 0; i < 4; ++i)
            #pragma unroll
            for (int j = 0; j < 4; ++j)
                acc[i][j] = __builtin_amdgcn_mfma_f32_16x16x32_bf16(a0[i], b0[j], acc[i][j], 0, 0, 0);
        if (it + 2 < nIter) {
            #pragma unroll
            for (int i = 0; i < 4; ++i) { a0[i] = *(const bf16x8*)(pA[i] + k2); b0[i] = *(const bf16x8*)(pB[i] + k2); }
        }
        if (it + 1 < nIter) {
            #pragma unroll
            for (int i = 0; i < 4; ++i)
                #pragma unroll
                for (int j = 0; j < 4; ++j)
                    acc[i][j] = __builtin_amdgcn_mfma_f32_16x16x32_bf16(a1[i], b1[j], acc[i][j], 0, 0, 0);
        }
    }

    if (nz > 1) {
        int Nw = gridDim.x * 128;
        size_t pstride = (size_t)Nw * (gridDim.y * 128);
        float* Pz = P + (size_t)blockIdx.z * pstride;
        #pragma unroll
        for (int i = 0; i < 4; ++i)
            #pragma unroll
            for (int j = 0; j < 4; ++j)
                #pragma unroll
                for (int r = 0; r < 4; ++r) {
                    int grow = m0 + wr + i*16 + lg*4 + r;
                    int gcol = n0 + wc + j*16 + lr;
                    Pz[(size_t)grow * Nw + gcol] = acc[i][j][r];
                }
        return;
    }

    #pragma unroll
    for (int i = 0; i < 4; ++i)
        #pragma unroll
        for (int j = 0; j < 4; ++j)
            #pragma unroll
            for (int r = 0; r < 4; ++r) {
                int grow = m0 + wr + i*16 + lg*4 + r;
                int gcol = n0 + wc + j*16 + lr;
                float v = epi_apply(acc[i][j][r], grow, gcol, bias, mode, X, ldx, gate, gstride);
                if (obf)
                    ((__hip_bfloat16*)C)[(size_t)grow * ldc + gcol] = __float2bfloat16(v);
                else
                    ((float*)C)[(size_t)grow * ldc + gcol] = v;
            }
}

// ---------------------------------------------------------------------------
// bf16 MFMA GEMM (LDS path, phase A + residue): tile 128x128, BK=32, 4 waves,
// ring-3 + counted vmcnt, both-sides swizzle, XCD swizzle. (round-8 proven)
// ---------------------------------------------------------------------------
__global__ __launch_bounds__(256) void gemm_bf16_kernel(
    const __hip_bfloat16* __restrict__ A, int lda,
    const __hip_bfloat16* __restrict__ BT, int ldb,
    const float* __restrict__ bias,
    void* __restrict__ C, int ldc,
    int K, int mode, int obf,
    const float* __restrict__ X, int ldx,
    const float* __restrict__ gate, int gstride,
    float* __restrict__ P,
    int mtiles, size_t bstrideA, size_t bstrideB)
{
    __shared__ __hip_bfloat16 As[3][128 * 32];
    __shared__ __hip_bfloat16 Bs[3][128 * 32];

    int gx = gridDim.x;
    int nwg = gx * gridDim.y;
    int fo = blockIdx.y * gx + blockIdx.x;
    int ft = (fo & 7) * (nwg >> 3) + (fo >> 3);
    int bx = ft % gx, by = ft / gx;

    int bb  = by / mtiles;
    int m0l = (by % mtiles) * 128;
    int m0g = by * 128;
    int n0 = bx * 128;
    const __hip_bfloat16* Ab  = A  + (size_t)bb * bstrideA;
    const __hip_bfloat16* BTb = BT + (size_t)bb * bstrideB;
    int nz = gridDim.z;
    int Kh = K / nz;
    int kb = blockIdx.z * Kh;
    int nIter = Kh >> 5;
    int tid = threadIdx.x;
    int w = tid >> 6, l = tid & 63;
    int wr = (w >> 1) * 64, wc = (w & 1) * 64;
    int lr = l & 15, lg = l >> 4;
    int slot = ((lg ^ ((lr >> 1) & 3)) & 3) * 8;

    int seg0 = tid,        row0s = seg0 >> 2, g0 = (seg0 & 3) ^ ((row0s >> 1) & 3);
    int seg1 = 256 + tid,  row1s = seg1 >> 2, g1 = (seg1 & 3) ^ ((row1s >> 1) & 3);

    f32x4 acc[4][4];
    #pragma unroll
    for (int i = 0; i < 4; ++i)
        #pragma unroll
        for (int j = 0; j < 4; ++j)
            acc[i][j] = f32x4{0.f, 0.f, 0.f, 0.f};

    {
        gload16(Ab  + (size_t)(m0l + row0s) * lda + kb + g0 * 8, (char*)As[0] + seg0 * 16);
        gload16(BTb + (size_t)(n0 + row0s) * ldb + kb + g0 * 8, (char*)Bs[0] + seg0 * 16);
        gload16(Ab  + (size_t)(m0l + row1s) * lda + kb + g1 * 8, (char*)As[0] + seg1 * 16);
        gload16(BTb + (size_t)(n0 + row1s) * ldb + kb + g1 * 8, (char*)Bs[0] + seg1 * 16);
        if (nIter > 1) {
            int k1 = kb + 32;
            gload16(Ab  + (size_t)(m0l + row0s) * lda + k1 + g0 * 8, (char*)As[1] + seg0 * 16);
            gload16(BTb + (size_t)(n0 + row0s) * ldb + k1 + g0 * 8, (char*)Bs[1] + seg0 * 16);
            gload16(Ab  + (size_t)(m0l + row1s) * lda + k1 + g1 * 8, (char*)As[1] + seg1 * 16);
            gload16(BTb + (size_t)(n0 + row1s) * ldb + k1 + g1 * 8, (char*)Bs[1] + seg1 * 16);
        }
    }

    int cur = 0;
    for (int it = 0; it < nIter; ++it) {
        if (it + 1 < nIter) asm volatile("s_waitcnt vmcnt(4)" ::: "memory");
        else                asm volatile("s_waitcnt vmcnt(0)" ::: "memory");
        __builtin_amdgcn_s_barrier();
        __builtin_amdgcn_sched_barrier(0);
        if (it + 2 < nIter) {
            int nb = cur + 2; if (nb >= 3) nb -= 3;
            int kn = kb + (it + 2) * 32;
            gload16(Ab  + (size_t)(m0l + row0s) * lda + kn + g0 * 8, (char*)As[nb] + seg0 * 16);
            gload16(BTb + (size_t)(n0 + row0s) * ldb + kn + g0 * 8, (char*)Bs[nb] + seg0 * 16);
            gload16(Ab  + (size_t)(m0l + row1s) * lda + kn + g1 * 8, (char*)As[nb] + seg1 * 16);
            gload16(BTb + (size_t)(n0 + row1s) * ldb + kn + g1 * 8, (char*)Bs[nb] + seg1 * 16);
        }
        bf16x8 af[4], bfr[4];
        #pragma unroll
        for (int i = 0; i < 4; ++i) {
            af[i]  = *(bf16x8*)(As[cur] + (wr + i*16 + lr) * 32 + slot);
            bfr[i] = *(bf16x8*)(Bs[cur] + (wc + i*16 + lr) * 32 + slot);
        }
        #pragma unroll
        for (int i = 0; i < 4; ++i)
            #pragma unroll
            for (int j = 0; j < 4; ++j)
                acc[i][j] = __builtin_amdgcn_mfma_f32_16x16x32_bf16(af[i], bfr[j], acc[i][j], 0, 0, 0);
        cur = (cur == 2) ? 0 : cur + 1;
    }

    if (nz > 1) {
        int Nw = gridDim.x * 128;
        size_t pstride = (size_t)Nw * (gridDim.y * 128);
        float* Pz = P + (size_t)blockIdx.z * pstride;
        #pragma unroll
        for (int i = 0; i < 4; ++i)
            #pragma unroll
            for (int j = 0; j < 4; ++j)
                #pragma unroll
                for (int r = 0; r < 4; ++r) {
                    int grow = m0g + wr + i*16 + lg*4 + r;
                    int gcol = n0 + wc + j*16 + lr;
                    Pz[(size_t)grow * Nw + gcol] = acc[i][j][r];
                }
        return;
    }

    #pragma unroll
    for (int i = 0; i < 4; ++i)
        #pragma unroll
        for (int j = 0; j < 4; ++j)
            #pragma unroll
            for (int r = 0; r < 4; ++r) {
                int grow = m0g + wr + i*16 + lg*4 + r;
                int gcol = n0 + wc + j*16 + lr;
                float v = epi_apply(acc[i][j][r], grow, gcol, bias, mode, X, ldx, gate, gstride);
                if (obf)
                    ((__hip_bfloat16*)C)[(size_t)grow * ldc + gcol] = __float2bfloat16(v);
                else
                    ((float*)C)[(size_t)grow * ldc + gcol] = v;
            }
}

// ---------------------------------------------------------------------------
// combine split-K partials + epilogue. 4 elems/thread. optional C2 bf16 out.
// ---------------------------------------------------------------------------
__global__ __launch_bounds__(256) void gcomb_kernel(
    const float* __restrict__ P, size_t pstride, int nz, int Nw,
    const float* __restrict__ bias,
    void* __restrict__ C, int ldc, int mode, int obf,
    const float* __restrict__ X, int ldx,
    const float* __restrict__ gate, int gstride,
    __hip_bfloat16* __restrict__ C2, int ldc2)
{
    int idx = blockIdx.x * 256 + threadIdx.x;
    int e0 = idx * 4;
    int grow = e0 / Nw, gc0 = e0 % Nw;
    float4 v = *(const float4*)(P + (size_t)grow * Nw + gc0);
    for (int z = 1; z < nz; ++z) {
        float4 t = *(const float4*)(P + (size_t)z * pstride + (size_t)grow * Nw + gc0);
        v.x += t.x; v.y += t.y; v.z += t.z; v.w += t.w;
    }
    float e[4] = {v.x, v.y, v.z, v.w};
    #pragma unroll
    for (int r = 0; r < 4; ++r)
        e[r] = epi_apply(e[r], grow, gc0 + r, bias, mode, X, ldx, gate, gstride);
    if (obf) {
        U4 o4;
        #pragma unroll
        for (int r = 0; r < 4; ++r) o4.e[r] = __float2bfloat16(e[r]);
        *(uint2*)((__hip_bfloat16*)C + (size_t)grow * ldc + gc0) = o4.u2;
    } else {
        *(float4*)((float*)C + (size_t)grow * ldc + gc0) = make_float4(e[0], e[1], e[2], e[3]);
    }
    if (C2) {
        U4 o4;
        #pragma unroll
        for (int r = 0; r < 4; ++r) o4.e[r] = __float2bfloat16(e[r]);
        *(uint2*)(C2 + (size_t)grow * ldc2 + gc0) = o4.u2;
    }
}

// ---------------------------------------------------------------------------
// fused: combine split-K (nz, D=256) + bias + LayerNorm(g,b) [+silu] -> out
// ---------------------------------------------------------------------------
__global__ __launch_bounds__(256) void combln256_kernel(
    const float* __restrict__ P, size_t pstride, int nz,
    const float* __restrict__ bias,
    const float* __restrict__ g, const float* __restrict__ bv,
    int do_silu, int obf,
    void* __restrict__ out, int ldout)
{
    int row = blockIdx.x, d = threadIdx.x;
    __shared__ float red[256];
    float v = P[(size_t)row*256 + d];
    for (int z = 1; z < nz; ++z) v += P[(size_t)z*pstride + (size_t)row*256 + d];
    v += bias[d];
    red[d] = v; __syncthreads();
    for (int off = 128; off > 0; off >>= 1) { if (d < off) red[d] += red[d+off]; __syncthreads(); }
    float mu = red[0] * (1.f/256.f);
    __syncthreads();
    float dv = v - mu;
    red[d] = dv*dv; __syncthreads();
    for (int off = 128; off > 0; off >>= 1) { if (d < off) red[d] += red[d+off]; __syncthreads(); }
    float rstd = rsqrtf(red[0] * (1.f/256.f) + 1e-5f);
    float y = dv * rstd * g[d] + bv[d];
    if (do_silu) y = y / (1.f + __expf(-y));
    if (obf) ((__hip_bfloat16*)out)[(size_t)row * ldout + d] = __float2bfloat16(y);
    else     ((float*)out)[(size_t)row * ldout + d] = y;
}

// ---------------------------------------------------------------------------
// fused: combine split-K (nz) + bias + residual-gate into X, then
// Hb = bf16( LN(xnew)*(1+scm[b]) + shm[b] ).  block per row, D=768.
// ---------------------------------------------------------------------------
__global__ __launch_bounds__(256) void gcombln_kernel(
    const float* __restrict__ P, size_t pstride, int nz,
    const float* __restrict__ bias,
    float* __restrict__ X,
    const float* __restrict__ gate,
    const float* __restrict__ scm, const float* __restrict__ shm,
    __hip_bfloat16* __restrict__ Hb)
{
    int row = blockIdx.x, tid = threadIdx.x;
    int b = row >> 11;
    __shared__ float red[256];
    float xv[3];
    float s = 0.f;
    #pragma unroll
    for (int q = 0; q < 3; ++q) {
        int d = tid + q*256;
        float v = P[(size_t)row*768 + d];
        for (int z = 1; z < nz; ++z) v += P[(size_t)z*pstride + (size_t)row*768 + d];
        v += bias[d];
        v = X[(size_t)row*768 + d] + gate[(size_t)b*4608 + d] * v;
        X[(size_t)row*768 + d] = v;
        xv[q] = v; s += v;
    }
    red[tid] = s; __syncthreads();
    for (int off = 128; off > 0; off >>= 1) { if (tid < off) red[tid] += red[tid+off]; __syncthreads(); }
    float mu = red[0] * (1.f/768.f);
    __syncthreads();
    float s2 = 0.f;
    #pragma unroll
    for (int q = 0; q < 3; ++q) { float dv = xv[q] - mu; s2 += dv*dv; }
    red[tid] = s2; __syncthreads();
    for (int off = 128; off > 0; off >>= 1) { if (tid < off) red[tid] += red[tid+off]; __syncthreads(); }
    float rstd = rsqrtf(red[0] * (1.f/768.f) + 1e-5f);
    #pragma unroll
    for (int q = 0; q < 3; ++q) {
        int d = tid + q*256;
        float y = (xv[q] - mu) * rstd * (1.f + scm[(size_t)b*4608 + d]) + shm[(size_t)b*4608 + d];
        Hb[(size_t)row*768 + d] = __float2bfloat16(y);
    }
}

// ---------------------------------------------------------------------------
// Row LayerNorm. mode bit0: *g+b ; bit1: *(1+scm[b])+shm[b] ; bit2: silu
// ---------------------------------------------------------------------------
__global__ __launch_bounds__(256) void rownorm_kernel(
    const float* __restrict__ in, int ldin,
    void* __restrict__ out, int ldout,
    int D, int mode, int obf,
    const float* __restrict__ gvec, const float* __restrict__ bvec,
    const float* __restrict__ scm, const float* __restrict__ shm, int mstride)
{
    int row = blockIdx.x;
    int tid = threadIdx.x;
    __shared__ float red[256];
    const float* pin = in + (size_t)row * ldin;
    float vals[3];
    float s = 0.f;
    #pragma unroll
    for (int q = 0; q < 3; ++q) {
        int d = tid + q*256;
        float v = (d < D) ? pin[d] : 0.f;
        vals[q] = v; s += v;
    }
    red[tid] = s; __syncthreads();
    for (int off = 128; off > 0; off >>= 1) { if (tid < off) red[tid] += red[tid+off]; __syncthreads(); }
    float mu = red[0] / (float)D;
    __syncthreads();
    float s2 = 0.f;
    #pragma unroll
    for (int q = 0; q < 3; ++q) { int d = tid + q*256; if (d < D) { float dv = vals[q] - mu; s2 += dv*dv; } }
    red[tid] = s2; __syncthreads();
    for (int off = 128; off > 0; off >>= 1) { if (tid < off) red[tid] += red[tid+off]; __syncthreads(); }
    float rstd = rsqrtf(red[0] / (float)D + 1e-5f);
    int b = row / N_;
    #pragma unroll
    for (int q = 0; q < 3; ++q) {
        int d = tid + q*256;
        if (d >= D) continue;
        float y = (vals[q] - mu) * rstd;
        if (mode & 1) y = y * gvec[d] + bvec[d];
        if (mode & 2) y = y * (1.f + scm[(size_t)b*mstride + d]) + shm[(size_t)b*mstride + d];
        if (mode & 4) y = y / (1.f + expf(-y));
        if (obf) ((__hip_bfloat16*)out)[(size_t)row * ldout + d] = __float2bfloat16(y);
        else     ((float*)out)[(size_t)row * ldout + d] = y;
    }
}

// ---------------------------------------------------------------------------
// c = LN(adaLN_emb @ ada_W + ada_b; g,b); c_silu = silu(c). 2 blocks.
// ---------------------------------------------------------------------------
__global__ __launch_bounds__(256) void ada_kernel(
    const float* __restrict__ emb, const float* __restrict__ W,
    const float* __restrict__ bias,
    const float* __restrict__ g, const float* __restrict__ bb,
    float* __restrict__ c, float* __restrict__ c_silu)
{
    int b = blockIdx.x, tid = threadIdx.x;
    __shared__ float emb_s[256];
    __shared__ float t[768];
    __shared__ float red[256];
    emb_s[tid] = emb[b*256 + tid];
    __syncthreads();
    for (int q = 0; q < 3; ++q) {
        int e = tid + q*256;
        float acc = bias[e];
        for (int k = 0; k < 256; ++k) acc += emb_s[k] * W[(size_t)k*768 + e];
        t[e] = acc;
    }
    __syncthreads();
    float s = 0.f; for (int q = 0; q < 3; ++q) s += t[tid + q*256];
    red[tid] = s; __syncthreads();
    for (int off = 128; off > 0; off >>= 1) { if (tid < off) red[tid] += red[tid+off]; __syncthreads(); }
    float mu = red[0] / 768.f; __syncthreads();
    float s2 = 0.f; for (int q = 0; q < 3; ++q) { float d = t[tid + q*256] - mu; s2 += d*d; }
    red[tid] = s2; __syncthreads();
    for (int off = 128; off > 0; off >>= 1) { if (tid < off) red[tid] += red[tid+off]; __syncthreads(); }
    float rstd = rsqrtf(red[0] / 768.f + 1e-5f);
    for (int q = 0; q < 3; ++q) {
        int e = tid + q*256;
        float y = (t[e] - mu) * rstd * g[e] + bb[e];
        c[b*768 + e] = y;
        c_silu[b*768 + e] = y / (1.f + expf(-y));
    }
}

// ---------------------------------------------------------------------------
// mod for BOTH layers, K-split 4: part[z][l][b][4608] ; grid (72, 4)
// ---------------------------------------------------------------------------
__global__ __launch_bounds__(256) void mod2_kernel(
    const float* __restrict__ c_silu, const float* __restrict__ mod_W,
    float* __restrict__ part)
{
    int idx = blockIdx.x * 256 + threadIdx.x;   // < 18432
    int z = blockIdx.y;
    int lyr = idx / 9216, b = (idx / 4608) & 1, j = idx % 4608;
    const float* Wl = mod_W + (size_t)lyr * 768 * 4608;
    const float* cs = c_silu + b * 768;
    float acc = 0.f;
    int k0 = z * 192;
    for (int k = k0; k < k0 + 192; ++k) acc += cs[k] * Wl[(size_t)k * 4608 + j];
    part[(size_t)z * 18432 + idx] = acc;
}

__global__ __launch_bounds__(256) void modc_kernel(
    const float* __restrict__ part, const float* __restrict__ mod_b,
    float* __restrict__ m2buf)
{
    int idx = blockIdx.x * 256 + threadIdx.x;
    int lyr = idx / 9216, j = idx % 4608;
    float acc = mod_b[(size_t)lyr * 4608 + j];
    #pragma unroll
    for (int z = 0; z < 4; ++z) acc += part[(size_t)z * 18432 + idx];
    m2buf[idx] = acc;
}

// ---------------------------------------------------------------------------
// MFMA local-window attention. 1 wave per (b, h, qblock of 32).
// ---------------------------------------------------------------------------
__global__ __launch_bounds__(64) void attn_mfma_kernel(
    const __hip_bfloat16* __restrict__ qkv,   // [B*N, 2304]
    const float* __restrict__ ropeC,          // [B*N, 32]
    const float* __restrict__ ropeS,
    __hip_bfloat16* __restrict__ o)           // [B*N, 768]
{
    int bid = blockIdx.x;
    int qb = bid & 63;
    int h  = (bid >> 6) % 12;
    int b  = bid / 768;
    int l  = threadIdx.x;
    int lr = l & 15, lg = l >> 4;
    int lo = max(0, 32*qb - 48);
    int hi = min(N_, 32*qb + 80);
    int wlen = hi - lo;

    __shared__ __hip_bfloat16 Vl[128 * 72];
    __shared__ __hip_bfloat16 Pl[32 * 144];

    {
        int vr0 = l >> 3;
        int c0  = (l & 7) * 8;
        #pragma unroll
        for (int it = 0; it < 16; ++it) {
            int vr = it*8 + vr0;
            int n = lo + vr;
            U8 v;
            if (n < hi) {
                v.v = *(const bf16x8*)(qkv + ((size_t)(b*N_ + n))*2304 + 1536 + h*64 + c0);
            } else {
                #pragma unroll
                for (int j = 0; j < 8; ++j) v.u[j] = 0;
            }
            *(bf16x8*)(Vl + vr*72 + c0) = v.v;
        }
    }

    bf16x8 aq0[2], aq1[2];
    #pragma unroll
    for (int i = 0; i < 2; ++i) {
        int n = qb*32 + i*16 + lr;
        const __hip_bfloat16* qrow = qkv + ((size_t)(b*N_ + n))*2304 + h*64;
        U8 xlo, xhi;
        xlo.v = *(const bf16x8*)(qrow + lg*8);
        xhi.v = *(const bf16x8*)(qrow + 32 + lg*8);
        const float* pc = ropeC + ((size_t)(b*N_ + n))*32 + lg*8;
        const float* ps = ropeS + ((size_t)(b*N_ + n))*32 + lg*8;
        float4 c0 = *(const float4*)(pc), c1 = *(const float4*)(pc + 4);
        float4 s0 = *(const float4*)(ps), s1 = *(const float4*)(ps + 4);
        float cv[8] = {c0.x,c0.y,c0.z,c0.w,c1.x,c1.y,c1.z,c1.w};
        float sv[8] = {s0.x,s0.y,s0.z,s0.w,s1.x,s1.y,s1.z,s1.w};
        U8 f0, f1;
        #pragma unroll
        for (int j = 0; j < 8; ++j) {
            float x1 = __bfloat162float(xlo.e[j]);
            float x2 = __bfloat162float(xhi.e[j]);
            f0.e[j] = __float2bfloat16(x1*cv[j] - x2*sv[j]);
            f1.e[j] = __float2bfloat16(x1*sv[j] + x2*cv[j]);
        }
        aq0[i] = f0.v; aq1[i] = f1.v;
    }

    f32x4 S[2][8];
    #pragma unroll
    for (int i = 0; i < 2; ++i)
        #pragma unroll
        for (int jt = 0; jt < 8; ++jt)
            S[i][jt] = f32x4{0.f, 0.f, 0.f, 0.f};

    #pragma unroll
    for (int jt = 0; jt < 8; ++jt) {
        int n = lo + jt*16 + lr;
        U8 f0, f1;
        if (n < hi) {
            const __hip_bfloat16* krow = qkv + ((size_t)(b*N_ + n))*2304 + 768 + h*64;
            U8 xlo, xhi;
            xlo.v = *(const bf16x8*)(krow + lg*8);
            xhi.v = *(const bf16x8*)(krow + 32 + lg*8);
            const float* pc = ropeC + ((size_t)(b*N_ + n))*32 + lg*8;
            const float* ps = ropeS + ((size_t)(b*N_ + n))*32 + lg*8;
            float4 c0 = *(const float4*)(pc), c1 = *(const float4*)(pc + 4);
            float4 s0 = *(const float4*)(ps), s1 = *(const float4*)(ps + 4);
            float cv[8] = {c0.x,c0.y,c0.z,c0.w,c1.x,c1.y,c1.z,c1.w};
            float sv[8] = {s0.x,s0.y,s0.z,s0.w,s1.x,s1.y,s1.z,s1.w};
            #pragma unroll
            for (int j = 0; j < 8; ++j) {
                float x1 = __bfloat162float(xlo.e[j]);
                float x2 = __bfloat162float(xhi.e[j]);
                f0.e[j] = __float2bfloat16(x1*cv[j] - x2*sv[j]);
                f1.e[j] = __float2bfloat16(x1*sv[j] + x2*cv[j]);
            }
        } else {
            #pragma unroll
            for (int j = 0; j < 8; ++j) { f0.u[j] = 0; f1.u[j] = 0; }
        }
        #pragma unroll
        for (int i = 0; i < 2; ++i) {
            S[i][jt] = __builtin_amdgcn_mfma_f32_16x16x32_bf16(aq0[i], f0.v, S[i][jt], 0, 0, 0);
            S[i][jt] = __builtin_amdgcn_mfma_f32_16x16x32_bf16(aq1[i], f1.v, S[i][jt], 0, 0, 0);
        }
    }

    #pragma unroll
    for (int jt = 0; jt < 8; ++jt) {
        bool oob = (jt*16 + lr) >= wlen;
        #pragma unroll
        for (int i = 0; i < 2; ++i)
            #pragma unroll
            for (int r = 0; r < 4; ++r)
                S[i][jt][r] = oob ? -1e30f : S[i][jt][r] * 0.125f;
    }

    float rinv[2][4];
    #pragma unroll
    for (int i = 0; i < 2; ++i) {
        #pragma unroll
        for (int r = 0; r < 4; ++r) {
            float m = -1e30f;
            #pragma unroll
            for (int jt = 0; jt < 8; ++jt) m = fmaxf(m, S[i][jt][r]);
            #pragma unroll
            for (int mask = 8; mask > 0; mask >>= 1) m = fmaxf(m, __shfl_xor(m, mask, 16));
            float sum = 0.f;
            #pragma unroll
            for (int jt = 0; jt < 8; ++jt) {
                float e = __expf(S[i][jt][r] - m);
                S[i][jt][r] = e;
                sum += e;
            }
            #pragma unroll
            for (int mask = 8; mask > 0; mask >>= 1) sum += __shfl_xor(sum, mask, 16);
            rinv[i][r] = 1.f / sum;
        }
    }

    #pragma unroll
    for (int i = 0; i < 2; ++i)
        #pragma unroll
        for (int jt = 0; jt < 8; ++jt)
            #pragma unroll
            for (int r = 0; r < 4; ++r) {
                int row = i*16 + lg*4 + r;
                int colp = (jt*16 + lr) ^ (lg << 3);
                Pl[row*144 + colp] = __float2bfloat16(S[i][jt][r]);
            }

    __syncthreads();

    f32x4 O_[2][4];
    #pragma unroll
    for (int i = 0; i < 2; ++i)
        #pragma unroll
        for (int ct = 0; ct < 4; ++ct)
            O_[i][ct] = f32x4{0.f, 0.f, 0.f, 0.f};

    int key = (lr >> 2) & 3;
    #pragma unroll
    for (int kt = 0; kt < 4; ++kt) {
        bf16x8 pa[2];
        #pragma unroll
        for (int i = 0; i < 2; ++i) {
            int row = i*16 + lr;
            int colp = (kt*32 + lg*8) ^ (key << 3);
            pa[i] = *(bf16x8*)(Pl + row*144 + colp);
        }
        #pragma unroll
        for (int ct = 0; ct < 4; ++ct) {
            U8 bv;
            #pragma unroll
            for (int j = 0; j < 8; ++j)
                bv.e[j] = Vl[(kt*32 + lg*8 + j)*72 + ct*16 + lr];
            O_[0][ct] = __builtin_amdgcn_mfma_f32_16x16x32_bf16(pa[0], bv.v, O_[0][ct], 0, 0, 0);
            O_[1][ct] = __builtin_amdgcn_mfma_f32_16x16x32_bf16(pa[1], bv.v, O_[1][ct], 0, 0, 0);
        }
    }

    #pragma unroll
    for (int i = 0; i < 2; ++i)
        #pragma unroll
        for (int ct = 0; ct < 4; ++ct)
            #pragma unroll
            for (int r = 0; r < 4; ++r) {
                int row = qb*32 + i*16 + lg*4 + r;
                o[((size_t)(b*N_ + row))*768 + h*64 + ct*16 + lr] =
                    __float2bfloat16(O_[i][ct][r] * rinv[i][r]);
            }
}

// ---------------------------------------------------------------------------
// a2t [B,N,NR] fp32 -> a2tTb [B,NR,N] bf16   grid (NR/32, N/32, B)
// ---------------------------------------------------------------------------
__global__ __launch_bounds__(256) void a2t_transpose_kernel(
    const float* __restrict__ a2t, __hip_bfloat16* __restrict__ a2tTb)
{
    __shared__ float t[32][33];
    int r0 = blockIdx.x * 32, n0 = blockIdx.y * 32, b = blockIdx.z;
    int tid = threadIdx.x;
    int tx = tid & 31, ty = tid >> 5;
    #pragma unroll
    for (int i = 0; i < 4; ++i) {
        int row = ty + i*8;
        t[row][tx] = a2t[((size_t)b*N_ + n0 + row) * 256 + r0 + tx];
    }
    __syncthreads();
    #pragma unroll
    for (int i = 0; i < 4; ++i) {
        int row = ty + i*8;
        a2tTb[((size_t)b*256 + r0 + row) * N_ + n0 + tx] = __float2bfloat16(t[tx][row]);
    }
}

// ---------------------------------------------------------------------------
// recip[row] = 1/(sum of a2tTb row + 1e-6).  block per row (512 rows).
// ---------------------------------------------------------------------------
__global__ __launch_bounds__(256) void rowrecip_kernel(
    const __hip_bfloat16* __restrict__ a2tTb, float* __restrict__ recip)
{
    int row = blockIdx.x;
    int tid = threadIdx.x;
    __shared__ float red[256];
    U8 v; v.v = *(const bf16x8*)(a2tTb + (size_t)row*2048 + tid*8);
    float s = 0.f;
    #pragma unroll
    for (int j = 0; j < 8; ++j) s += __bfloat162float(v.e[j]);
    red[tid] = s; __syncthreads();
    for (int off = 128; off > 0; off >>= 1) { if (tid < off) red[tid] += red[tid+off]; __syncthreads(); }
    if (tid == 0) recip[row] = 1.f / (red[0] + 1e-6f);
}

// ---------------------------------------------------------------------------
extern "C" void kernel_launch(void* const* d_in, const int* in_sizes, int n_in,
                              void* d_out, int out_size, void* d_ws, size_t ws_size,
                              hipStream_t stream) {
    const float* atom_coords  = (const float*)d_in[0];
    const float* ref_pos      = (const float*)d_in[1];
    const int*   res_id       = (const int*)  d_in[2];
    const float* res_type     = (const float*)d_in[3];
    const float* charge       = (const float*)d_in[4];
    const float* atomic_num   = (const float*)d_in[5];
    const float* atom_name    = (const float*)d_in[6];
    const float* adaLN_emb    = (const float*)d_in[7];
    const int*   rope_pos     = (const int*)  d_in[8];
    const float* atom_to_tok  = (const float*)d_in[9];
    const float* feat_W       = (const float*)d_in[10];
    const float* feat_b       = (const float*)d_in[11];
    const float* feat_ln_g    = (const float*)d_in[12];
    const float* feat_ln_b    = (const float*)d_in[13];
    const float* pos_W        = (const float*)d_in[14];
    const float* in_W         = (const float*)d_in[15];
    const float* tin_W        = (const float*)d_in[16];
    const float* tin_b        = (const float*)d_in[17];
    const float* tin_ln_g     = (const float*)d_in[18];
    const float* tin_ln_b     = (const float*)d_in[19];
    const float* ada_W        = (const float*)d_in[20];
    const float* ada_b        = (const float*)d_in[21];
    const float* ada_ln_g     = (const float*)d_in[22];
    const float* ada_ln_b     = (const float*)d_in[23];
    const float* blk_mod_W    = (const float*)d_in[24];
    const float* blk_mod_b    = (const float*)d_in[25];
    const float* blk_qkv_W    = (const float*)d_in[26];
    const float* blk_qkv_b    = (const float*)d_in[27];
    const float* blk_o_W      = (const float*)d_in[28];
    const float* blk_o_b      = (const float*)d_in[29];
    const float* blk_m1_W     = (const float*)d_in[30];
    const float* blk_m1_b     = (const float*)d_in[31];
    const float* blk_m2_W     = (const float*)d_in[32];
    const float* blk_m2_b     = (const float*)d_in[33];
    const float* tout_W       = (const float*)d_in[34];
    const float* tout_b       = (const float*)d_in[35];
    const float* tout_ln_g    = (const float*)d_in[36];
    const float* tout_ln_b    = (const float*)d_in[37];

    const int BN = B_ * N_;                          // 4096
    float* ws = (float*)d_ws;

    // layout (float units)
    const size_t OFF_X    = 0;                                // fp32 [4096][768]
    const size_t OFF_HB   = OFF_X    + (size_t)BN*768;        // bf16 [4096][768]
    const size_t OFF_QKVB = OFF_HB   + (size_t)BN*768/2;      // bf16 [4096][2304]
    const size_t OFF_OB   = OFF_QKVB + (size_t)BN*2304/2;     // bf16 [4096][768]
    const size_t OFF_UB   = OFF_OB   + (size_t)BN*768/2;      // bf16 [4096][3072]
    const size_t OFF_WT   = OFF_UB   + (size_t)BN*3072/2;     // bf16 up to 3072*768
    const size_t OFF_RC   = OFF_WT   + (size_t)3072*768/2;    // fp32 BN*32
    const size_t OFF_RS   = OFF_RC   + (size_t)BN*32;
    const size_t OFF_SM   = OFF_RS   + (size_t)BN*32;

    float* X = ws + OFF_X;
    __hip_bfloat16* Hb   = (__hip_bfloat16*)(ws + OFF_HB);
    __hip_bfloat16* QKVb = (__hip_bfloat16*)(ws + OFF_QKVB);
    __hip_bfloat16* Ob   = (__hip_bfloat16*)(ws + OFF_OB);
    __hip_bfloat16* Ub   = (__hip_bfloat16*)(ws + OFF_UB);
    __hip_bfloat16* WT   = (__hip_bfloat16*)(ws + OFF_WT);
    float* ropeC  = ws + OFF_RC;
    float* ropeS  = ws + OFF_RS;
    float* cbuf   = ws + OFF_SM;                     // 1536
    float* c_silu = cbuf + 1536;                     // 1536
    float* mbuf2  = c_silu + 1536;                   // 18432  [2][2][4608]
    float* modpart= mbuf2 + 18432;                   // 73728

    // phase-A aliases
    __hip_bfloat16* featsB  = QKVb;                           // [4096][1024] bf16
    __hip_bfloat16* coordsB = QKVb + (size_t)BN*1024;         // [4096][512] bf16
    float* t1               = ws + OFF_UB;                    // scratch
    __hip_bfloat16* concatB = (__hip_bfloat16*)(t1 + (size_t)BN*256);  // [4096][512] bf16
    __hip_bfloat16* atom_inB= Ob;                             // [4096][256] bf16

    // residue-phase aliases (Ob/Ub regions dead by then)
    __hip_bfloat16* a2tTb   = Ob;                             // [2][256][2048] bf16
    __hip_bfloat16* latTb   = Ob + (size_t)2*256*2048;        // [2][256][2048] bf16
    float* recip            = modpart;                        // 512 fp32

    // split-K / raw partial buffers (aliases of dead regions)
    float* P_pa   = ws + OFF_X;       // phase A (feat/pos/in)
    float* P_tin  = ws + OFF_UB;
    float* P_o    = ws + OFF_UB;
    float* P_m2   = ws + OFF_QKVB;
    float* P_tout = ws + OFF_UB;
    float* P_res  = ws + OFF_UB;

    float* out_res = (float*)d_out;                           // B*NR*DA
    float* out_lat = out_res + (size_t)B_*NR_*DA_;            // B*N*DA

    // ---- featurization (bf16) + rope table (fused) ----
    build_feats_kernel<<<BN, 128, 0, stream>>>(atom_coords, ref_pos, res_id,
        res_type, charge, atomic_num, atom_name, rope_pos, featsB, coordsB,
        ropeC, ropeS);

    // t1 = feats @ feat_W + feat_b   (K padded 924->1024, split 4)
    transconv_kernel<<<dim3(8, 32), 256, 0, stream>>>(feat_W, WT, 924, 1024, 256, 0, 0);
    gemm_bf16_kernel<<<dim3(2, 32, 4), 256, 0, stream>>>(featsB, 1024, WT, 1024, nullptr,
        nullptr, 0, 1024, 0, 0, nullptr, 0, nullptr, 0, P_pa, 32, 0, 0);
    combln256_kernel<<<BN, 256, 0, stream>>>(P_pa, (size_t)BN*256, 4, feat_b,
        feat_ln_g, feat_ln_b, 1, 1, concatB, 512);
    // concat[:,256:512] = coordsF @ pos_W  (K 387->512, split 4)
    transconv_kernel<<<dim3(8, 16), 256, 0, stream>>>(pos_W, WT, 387, 512, 256, 0, 0);
    gemm_bf16_kernel<<<dim3(2, 32, 4), 256, 0, stream>>>(coordsB, 512, WT, 512, nullptr,
        nullptr, 0, 512, 0, 0, nullptr, 0, nullptr, 0, P_pa, 32, 0, 0);
    gcomb_kernel<<<1024, 256, 0, stream>>>(P_pa, (size_t)BN*256, 4, 256, nullptr,
        concatB + 256, 512, 0, 1, nullptr, 0, nullptr, 0, nullptr, 0);
    // atom_in = concat @ in_W -> bf16 (split 4)
    transconv_kernel<<<dim3(8, 16), 256, 0, stream>>>(in_W, WT, 512, 512, 256, 0, 0);
    gemm_bf16_kernel<<<dim3(2, 32, 4), 256, 0, stream>>>(concatB, 512, WT, 512, nullptr,
        nullptr, 0, 512, 0, 0, nullptr, 0, nullptr, 0, P_pa, 32, 0, 0);
    gcomb_kernel<<<1024, 256, 0, stream>>>(P_pa, (size_t)BN*256, 4, 256, nullptr,
        atom_inB, 256, 0, 1, nullptr, 0, nullptr, 0, nullptr, 0);
    // X = atom_in @ tin_W + tin_b  (split 2), then LN in place
    transconv_kernel<<<dim3(24, 8), 256, 0, stream>>>(tin_W, WT, 256, 256, 768, 0, 0);
    gemm_bf16_kernel<<<dim3(6, 32, 2), 256, 0, stream>>>(atom_inB, 256, WT, 256, nullptr,
        nullptr, 0, 256, 0, 0, nullptr, 0, nullptr, 0, P_tin, 32, 0, 0);
    gcomb_kernel<<<3072, 256, 0, stream>>>(P_tin, (size_t)BN*768, 2, 768, tin_b,
        X, 768, 0, 0, nullptr, 0, nullptr, 0, nullptr, 0);
    rownorm_kernel<<<BN, 256, 0, stream>>>(X, 768, X, 768, 768, 1, 0,
        tin_ln_g, tin_ln_b, nullptr, nullptr, 0);

    // ---- adaLN + modulation for both layers ----
    ada_kernel<<<2, 256, 0, stream>>>(adaLN_emb, ada_W, ada_b, ada_ln_g, ada_ln_b,
        cbuf, c_silu);
    mod2_kernel<<<dim3(72, 4), 256, 0, stream>>>(c_silu, blk_mod_W, modpart);
    modc_kernel<<<72, 256, 0, stream>>>(modpart, blk_mod_b, mbuf2);

    for (int l = 0; l < NB_; ++l) {
        const float* qkvW = blk_qkv_W + (size_t)l*768*2304;
        const float* qkvB = blk_qkv_b + (size_t)l*2304;
        const float* oW   = blk_o_W   + (size_t)l*768*768;
        const float* oB   = blk_o_b   + (size_t)l*768;
        const float* m1W  = blk_m1_W  + (size_t)l*768*3072;
        const float* m1B  = blk_m1_b  + (size_t)l*3072;
        const float* m2W  = blk_m2_W  + (size_t)l*3072*768;
        const float* m2B  = blk_m2_b  + (size_t)l*768;

        float* mptr = mbuf2 + (size_t)l*9216;        // [b][4608]
        float* sh1 = mptr + 0,    *sc1 = mptr + 768,  *g1 = mptr + 1536;
        float* sh2 = mptr + 2304, *sc2 = mptr + 3072, *g2 = mptr + 3840;

        // h = LN(x)*(1+sc1)+sh1 -> bf16 (layer 0 only)
        if (l == 0)
            rownorm_kernel<<<BN, 256, 0, stream>>>(X, 768, Hb, 768, 768, 2, 1,
                nullptr, nullptr, sc1, sh1, 4608);
        // qkv = h @ qkv_W + b -> bf16   (DIRECT, no LDS)
        transconv_kernel<<<dim3(72, 24), 256, 0, stream>>>(qkvW, WT, 768, 768, 2304, 0, 0);
        gemm_bf16_direct_kernel<<<dim3(18, 32, 1), 256, 0, stream>>>(Hb, 768, WT, 768, qkvB,
            QKVb, 2304, 768, 0, 1, nullptr, 0, nullptr, 0, nullptr);
        // attention
        attn_mfma_kernel<<<B_*H_*64, 64, 0, stream>>>(QKVb, ropeC, ropeS, Ob);
        // o-proj: raw fp32 to P_o (DIRECT), fused comb+residual+LN
        transconv_kernel<<<dim3(24, 24), 256, 0, stream>>>(oW, WT, 768, 768, 768, 0, 0);
        gemm_bf16_direct_kernel<<<dim3(6, 32, 1), 256, 0, stream>>>(Ob, 768, WT, 768, nullptr,
            P_o, 768, 768, 0, 0, nullptr, 0, nullptr, 0, nullptr);
        gcombln_kernel<<<BN, 256, 0, stream>>>(P_o, (size_t)BN*768, 1, oB,
            X, g1, sc2, sh2, Hb);
        // u = gelu(h2 @ m1_W + b) -> bf16   (DIRECT)
        transconv_kernel<<<dim3(96, 24), 256, 0, stream>>>(m1W, WT, 768, 768, 3072, 0, 0);
        gemm_bf16_direct_kernel<<<dim3(24, 32, 1), 256, 0, stream>>>(Hb, 768, WT, 768, m1B,
            Ub, 3072, 768, 1, 1, nullptr, 0, nullptr, 0, nullptr);
        // x = x + g2*(u @ m2_W + b)  (DIRECT, split 2)
        transconv_kernel<<<dim3(24, 96), 256, 0, stream>>>(m2W, WT, 3072, 3072, 768, 0, 0);
        gemm_bf16_direct_kernel<<<dim3(6, 32, 2), 256, 0, stream>>>(Ub, 3072, WT, 3072, nullptr,
            nullptr, 0, 3072, 0, 0, nullptr, 0, nullptr, 0, P_m2);
        if (l < NB_ - 1) {
            float* mnext = mbuf2 + (size_t)(l+1)*9216;
            gcombln_kernel<<<BN, 256, 0, stream>>>(P_m2, (size_t)BN*768, 2, m2B,
                X, g2, mnext + 768, mnext + 0, Hb);
        } else {
            gcomb_kernel<<<3072, 256, 0, stream>>>(P_m2, (size_t)BN*768, 2, 768, m2B,
                X, 768, 2, 0, X, 768, g2, 4608, Hb, 768);
        }
    }

    // atom_latent = LN(x @ tout_W + tout_b)  (split 4, fused combine+LN)
    transconv_kernel<<<dim3(8, 24), 256, 0, stream>>>(tout_W, WT, 768, 768, 256, 0, 0);
    gemm_bf16_kernel<<<dim3(2, 32, 4), 256, 0, stream>>>(Hb, 768, WT, 768, nullptr,
        nullptr, 0, 768, 0, 0, nullptr, 0, nullptr, 0, P_tout, 32, 0, 0);
    combln256_kernel<<<BN, 256, 0, stream>>>(P_tout, (size_t)BN*256, 4, tout_b,
        tout_ln_g, tout_ln_b, 0, 0, out_lat, 256);

    // ---- residue pooling as MFMA GEMM ----
    a2t_transpose_kernel<<<dim3(8, 64, 2), 256, 0, stream>>>(atom_to_tok, a2tTb);
    rowrecip_kernel<<<512, 256, 0, stream>>>(a2tTb, recip);
    transconv_kernel<<<dim3(8, 64, 2), 256, 0, stream>>>(out_lat, latTb, 2048, 2048, 256,
        (size_t)2048*256, (size_t)256*2048);
    gemm_bf16_kernel<<<dim3(2, 4, 8), 256, 0, stream>>>(a2tTb, 2048, latTb, 2048, nullptr,
        nullptr, 0, 2048, 0, 0, nullptr, 0, nullptr, 0, P_res,
        2, (size_t)256*2048, (size_t)256*2048);
    gcomb_kernel<<<128, 256, 0, stream>>>(P_res, (size_t)512*256, 8, 256, nullptr,
        out_res, 256, 3, 0, nullptr, 0, recip, 0, nullptr, 0);
}

// Round 12
// 598.513 us; speedup vs baseline: 1.5973x; 1.5973x over previous
//
#include <hip/hip_runtime.h>
#include <hip/hip_bf16.h>
#include <math.h>

// Problem constants
#define B_ 2
#define N_ 2048
#define NR_ 256
#define DA_ 256
#define E_ 768
#define H_ 12
#define DH_ 64
#define NB_ 2

typedef __attribute__((ext_vector_type(8))) __bf16 bf16x8;
typedef __attribute__((ext_vector_type(4))) float f32x4;

union U8 { bf16x8 v; __hip_bfloat16 e[8]; unsigned short u[8]; };
union U4 { __hip_bfloat16 e[4]; uint2 u2; };

__device__ __forceinline__ void gload16(const void* g, void* l) {
    __builtin_amdgcn_global_load_lds(
        (const __attribute__((address_space(1))) void*)g,
        (__attribute__((address_space(3))) void*)l, 16, 0, 0);
}

// ---------------------------------------------------------------------------
// build feats[B*N, 1024] (bf16) and coordsF[B*N, 512] (bf16) + rope tables
// ---------------------------------------------------------------------------
__global__ __launch_bounds__(128) void build_feats_kernel(
    const float* __restrict__ atom_coords, const float* __restrict__ ref_pos,
    const int* __restrict__ res_id, const float* __restrict__ res_type,
    const float* __restrict__ charge, const float* __restrict__ atomic_number,
    const float* __restrict__ atom_name, const int* __restrict__ rope_pos,
    __hip_bfloat16* __restrict__ feats, __hip_bfloat16* __restrict__ coordsF,
    float* __restrict__ ropeC, float* __restrict__ ropeS)
{
    int a = blockIdx.x;            // atom index over B*N
    int tid = threadIdx.x;
    __hip_bfloat16* f  = feats   + (size_t)a * 1024;
    __hip_bfloat16* cf = coordsF + (size_t)a * 512;

    float rp[3], cc[3];
    #pragma unroll
    for (int i = 0; i < 3; ++i) { rp[i] = ref_pos[(size_t)a*3 + i]; cc[i] = atom_coords[(size_t)a*3 + i]; }

    if (tid < 3) { f[tid] = __float2bfloat16(rp[tid]); cf[tid] = __float2bfloat16(cc[tid]); }

    if (tid >= 64 && tid < 96) {
        int dd = tid - 64;
        float rpos = (float)rope_pos[a];
        float ang = rpos * expf(-0.28782313662425574f * (float)dd);  // ln(1e4)/32
        float sn, cs; sincosf(ang, &sn, &cs);
        ropeC[a*32 + dd] = cs; ropeS[a*32 + dd] = sn;
    }

    for (int s = tid; s < 192; s += 128) {
        int fi = s / 3, ci = s % 3;
        float freq = exp2f(12.f * (float)fi / 63.f);
        float ar = rp[ci] * freq;
        float ac = cc[ci] * freq;
        float snr, csr, snc, csc_;
        sincosf(ar, &snr, &csr);
        sincosf(ac, &snc, &csc_);
        f[3 + s]    = __float2bfloat16(snr);  f[195 + s]  = __float2bfloat16(csr);
        cf[3 + s]   = __float2bfloat16(snc);  cf[195 + s] = __float2bfloat16(csc_);
    }
    if (tid < 23) f[387 + tid] = __float2bfloat16(res_type[(size_t)a*23 + tid]);

    float pos = (float)res_id[a];
    if (tid == 0) f[410] = __float2bfloat16(pos);
    if (tid < 64) {
        float div = expf(-9.210340371976184f / 128.f * (float)(2 * tid));
        float ang = pos * div;
        float sn, cs; sincosf(ang, &sn, &cs);
        f[411 + tid] = __float2bfloat16(sn);
        f[475 + tid] = __float2bfloat16(cs);
    }
    if (tid == 0) f[539] = __float2bfloat16(charge[a]);
    if (tid < 128) f[540 + tid] = __float2bfloat16(atomic_number[(size_t)a*128 + tid]);
    for (int s = tid; s < 256; s += 128) f[668 + s] = __float2bfloat16(atom_name[(size_t)a*256 + s]);
    if (tid < 100) f[924 + tid] = __float2bfloat16(0.f);
    if (tid < 125) cf[387 + tid] = __float2bfloat16(0.f);
}

// ---------------------------------------------------------------------------
// Transpose + fp32->bf16 + K-pad: W[Ksrc][Nn] -> WT[Nn][Kdst], zeros k>=Ksrc
// ---------------------------------------------------------------------------
__global__ __launch_bounds__(256) void transconv_kernel(
    const float* __restrict__ W, __hip_bfloat16* __restrict__ WT,
    int Ksrc, int Kdst, int Nn, size_t wstride, size_t tstride)
{
    __shared__ float t[32][33];
    W  += (size_t)blockIdx.z * wstride;
    WT += (size_t)blockIdx.z * tstride;
    int n0 = blockIdx.x * 32, k0 = blockIdx.y * 32;
    int tid = threadIdx.x;
    int tx = tid & 31, ty = tid >> 5;           // ty 0..7
    #pragma unroll
    for (int i = 0; i < 4; ++i) {
        int k = k0 + ty + i*8;
        t[ty + i*8][tx] = (k < Ksrc) ? W[(size_t)k * Nn + n0 + tx] : 0.f;
    }
    __syncthreads();
    #pragma unroll
    for (int i = 0; i < 4; ++i) {
        int row = ty + i*8;                      // n within tile
        WT[(size_t)(n0 + row) * Kdst + k0 + tx] = __float2bfloat16(t[tx][row]);
    }
}

// ---------------------------------------------------------------------------
// shared epilogue.  mode 0 none; 1 gelu; 2 X + gate[b][col]*v; 3 v*gate[row]
// ---------------------------------------------------------------------------
__device__ __forceinline__ float epi_apply(float v, int grow, int gcol,
    const float* bias, int mode, const float* X, int ldx,
    const float* gate, int gstride)
{
    if (bias) v += bias[gcol];
    if (mode == 1) {
        float u = 1.5957691216057308f * (v + 0.044715f * v * v * v);
        v = v / (1.f + __expf(-u));
    } else if (mode == 2) {
        int b = grow >> 11;                      // /N_
        v = X[(size_t)grow * ldx + gcol] + gate[(size_t)b * gstride + gcol] * v;
    } else if (mode == 3) {
        v = v * gate[grow];
    }
    return v;
}

// ---------------------------------------------------------------------------
// bf16 MFMA GEMM: tile 128x128, BK=32, 4 waves.  Ring-3 LDS + counted vmcnt.
// XOR-swizzle both sides: key(row)=(row>>1)&3.  Bijective XCD swizzle.
// (round-10 proven structure)
// ---------------------------------------------------------------------------
__global__ __launch_bounds__(256) void gemm_bf16_kernel(
    const __hip_bfloat16* __restrict__ A, int lda,
    const __hip_bfloat16* __restrict__ BT, int ldb,
    const float* __restrict__ bias,
    void* __restrict__ C, int ldc,
    int K, int mode, int obf,
    const float* __restrict__ X, int ldx,
    const float* __restrict__ gate, int gstride,
    float* __restrict__ P,
    int mtiles, size_t bstrideA, size_t bstrideB)
{
    __shared__ __hip_bfloat16 As[3][128 * 32];
    __shared__ __hip_bfloat16 Bs[3][128 * 32];

    int gx = gridDim.x;
    int nwg = gx * gridDim.y;
    int fo = blockIdx.y * gx + blockIdx.x;
    int ft = (fo & 7) * (nwg >> 3) + (fo >> 3);
    int bx = ft % gx, by = ft / gx;

    int bb  = by / mtiles;
    int m0l = (by % mtiles) * 128;
    int m0g = by * 128;
    int n0 = bx * 128;
    const __hip_bfloat16* Ab  = A  + (size_t)bb * bstrideA;
    const __hip_bfloat16* BTb = BT + (size_t)bb * bstrideB;
    int nz = gridDim.z;
    int Kh = K / nz;
    int kb = blockIdx.z * Kh;
    int nIter = Kh >> 5;
    int tid = threadIdx.x;
    int w = tid >> 6, l = tid & 63;
    int wr = (w >> 1) * 64, wc = (w & 1) * 64;
    int lr = l & 15, lg = l >> 4;
    int slot = ((lg ^ ((lr >> 1) & 3)) & 3) * 8;

    int seg0 = tid,        row0s = seg0 >> 2, g0 = (seg0 & 3) ^ ((row0s >> 1) & 3);
    int seg1 = 256 + tid,  row1s = seg1 >> 2, g1 = (seg1 & 3) ^ ((row1s >> 1) & 3);

    f32x4 acc[4][4];
    #pragma unroll
    for (int i = 0; i < 4; ++i)
        #pragma unroll
        for (int j = 0; j < 4; ++j)
            acc[i][j] = f32x4{0.f, 0.f, 0.f, 0.f};

    {
        gload16(Ab  + (size_t)(m0l + row0s) * lda + kb + g0 * 8, (char*)As[0] + seg0 * 16);
        gload16(BTb + (size_t)(n0 + row0s) * ldb + kb + g0 * 8, (char*)Bs[0] + seg0 * 16);
        gload16(Ab  + (size_t)(m0l + row1s) * lda + kb + g1 * 8, (char*)As[0] + seg1 * 16);
        gload16(BTb + (size_t)(n0 + row1s) * ldb + kb + g1 * 8, (char*)Bs[0] + seg1 * 16);
        if (nIter > 1) {
            int k1 = kb + 32;
            gload16(Ab  + (size_t)(m0l + row0s) * lda + k1 + g0 * 8, (char*)As[1] + seg0 * 16);
            gload16(BTb + (size_t)(n0 + row0s) * ldb + k1 + g0 * 8, (char*)Bs[1] + seg0 * 16);
            gload16(Ab  + (size_t)(m0l + row1s) * lda + k1 + g1 * 8, (char*)As[1] + seg1 * 16);
            gload16(BTb + (size_t)(n0 + row1s) * ldb + k1 + g1 * 8, (char*)Bs[1] + seg1 * 16);
        }
    }

    int cur = 0;
    for (int it = 0; it < nIter; ++it) {
        if (it + 1 < nIter) asm volatile("s_waitcnt vmcnt(4)" ::: "memory");
        else                asm volatile("s_waitcnt vmcnt(0)" ::: "memory");
        __builtin_amdgcn_s_barrier();
        __builtin_amdgcn_sched_barrier(0);
        if (it + 2 < nIter) {
            int nb = cur + 2; if (nb >= 3) nb -= 3;
            int kn = kb + (it + 2) * 32;
            gload16(Ab  + (size_t)(m0l + row0s) * lda + kn + g0 * 8, (char*)As[nb] + seg0 * 16);
            gload16(BTb + (size_t)(n0 + row0s) * ldb + kn + g0 * 8, (char*)Bs[nb] + seg0 * 16);
            gload16(Ab  + (size_t)(m0l + row1s) * lda + kn + g1 * 8, (char*)As[nb] + seg1 * 16);
            gload16(BTb + (size_t)(n0 + row1s) * ldb + kn + g1 * 8, (char*)Bs[nb] + seg1 * 16);
        }
        bf16x8 af[4], bfr[4];
        #pragma unroll
        for (int i = 0; i < 4; ++i) {
            af[i]  = *(bf16x8*)(As[cur] + (wr + i*16 + lr) * 32 + slot);
            bfr[i] = *(bf16x8*)(Bs[cur] + (wc + i*16 + lr) * 32 + slot);
        }
        #pragma unroll
        for (int i = 0; i < 4; ++i)
            #pragma unroll
            for (int j = 0; j < 4; ++j)
                acc[i][j] = __builtin_amdgcn_mfma_f32_16x16x32_bf16(af[i], bfr[j], acc[i][j], 0, 0, 0);
        cur = (cur == 2) ? 0 : cur + 1;
    }

    if (nz > 1) {
        int Nw = gridDim.x * 128;
        size_t pstride = (size_t)Nw * (gridDim.y * 128);
        float* Pz = P + (size_t)blockIdx.z * pstride;
        #pragma unroll
        for (int i = 0; i < 4; ++i)
            #pragma unroll
            for (int j = 0; j < 4; ++j)
                #pragma unroll
                for (int r = 0; r < 4; ++r) {
                    int grow = m0g + wr + i*16 + lg*4 + r;
                    int gcol = n0 + wc + j*16 + lr;
                    Pz[(size_t)grow * Nw + gcol] = acc[i][j][r];
                }
        return;
    }

    #pragma unroll
    for (int i = 0; i < 4; ++i)
        #pragma unroll
        for (int j = 0; j < 4; ++j)
            #pragma unroll
            for (int r = 0; r < 4; ++r) {
                int grow = m0g + wr + i*16 + lg*4 + r;
                int gcol = n0 + wc + j*16 + lr;
                float v = epi_apply(acc[i][j][r], grow, gcol, bias, mode, X, ldx, gate, gstride);
                if (obf)
                    ((__hip_bfloat16*)C)[(size_t)grow * ldc + gcol] = __float2bfloat16(v);
                else
                    ((float*)C)[(size_t)grow * ldc + gcol] = v;
            }
}

// ---------------------------------------------------------------------------
// combine split-K partials + epilogue. 4 elems/thread. optional C2 bf16 out.
// ---------------------------------------------------------------------------
__global__ __launch_bounds__(256) void gcomb_kernel(
    const float* __restrict__ P, size_t pstride, int nz, int Nw,
    const float* __restrict__ bias,
    void* __restrict__ C, int ldc, int mode, int obf,
    const float* __restrict__ X, int ldx,
    const float* __restrict__ gate, int gstride,
    __hip_bfloat16* __restrict__ C2, int ldc2)
{
    int idx = blockIdx.x * 256 + threadIdx.x;
    int e0 = idx * 4;
    int grow = e0 / Nw, gc0 = e0 % Nw;
    float4 v = *(const float4*)(P + (size_t)grow * Nw + gc0);
    for (int z = 1; z < nz; ++z) {
        float4 t = *(const float4*)(P + (size_t)z * pstride + (size_t)grow * Nw + gc0);
        v.x += t.x; v.y += t.y; v.z += t.z; v.w += t.w;
    }
    float e[4] = {v.x, v.y, v.z, v.w};
    #pragma unroll
    for (int r = 0; r < 4; ++r)
        e[r] = epi_apply(e[r], grow, gc0 + r, bias, mode, X, ldx, gate, gstride);
    if (obf) {
        U4 o4;
        #pragma unroll
        for (int r = 0; r < 4; ++r) o4.e[r] = __float2bfloat16(e[r]);
        *(uint2*)((__hip_bfloat16*)C + (size_t)grow * ldc + gc0) = o4.u2;
    } else {
        *(float4*)((float*)C + (size_t)grow * ldc + gc0) = make_float4(e[0], e[1], e[2], e[3]);
    }
    if (C2) {
        U4 o4;
        #pragma unroll
        for (int r = 0; r < 4; ++r) o4.e[r] = __float2bfloat16(e[r]);
        *(uint2*)(C2 + (size_t)grow * ldc2 + gc0) = o4.u2;
    }
}

// ---------------------------------------------------------------------------
// fused: combine split-K (nz, D=256) + bias + LayerNorm(g,b) [+silu] -> out
// ---------------------------------------------------------------------------
__global__ __launch_bounds__(256) void combln256_kernel(
    const float* __restrict__ P, size_t pstride, int nz,
    const float* __restrict__ bias,
    const float* __restrict__ g, const float* __restrict__ bv,
    int do_silu, int obf,
    void* __restrict__ out, int ldout)
{
    int row = blockIdx.x, d = threadIdx.x;
    __shared__ float red[256];
    float v = P[(size_t)row*256 + d];
    for (int z = 1; z < nz; ++z) v += P[(size_t)z*pstride + (size_t)row*256 + d];
    v += bias[d];
    red[d] = v; __syncthreads();
    for (int off = 128; off > 0; off >>= 1) { if (d < off) red[d] += red[d+off]; __syncthreads(); }
    float mu = red[0] * (1.f/256.f);
    __syncthreads();
    float dv = v - mu;
    red[d] = dv*dv; __syncthreads();
    for (int off = 128; off > 0; off >>= 1) { if (d < off) red[d] += red[d+off]; __syncthreads(); }
    float rstd = rsqrtf(red[0] * (1.f/256.f) + 1e-5f);
    float y = dv * rstd * g[d] + bv[d];
    if (do_silu) y = y / (1.f + __expf(-y));
    if (obf) ((__hip_bfloat16*)out)[(size_t)row * ldout + d] = __float2bfloat16(y);
    else     ((float*)out)[(size_t)row * ldout + d] = y;
}

// ---------------------------------------------------------------------------
// tin-chain fusion: combine split-K (nz, D=768) + bias ->
//   X = LN(t; g,b)  (write fp32) ; Hb = bf16( LN2(X)*(1+scm[b]) + shm[b] )
// ---------------------------------------------------------------------------
__global__ __launch_bounds__(256) void tinfuse_kernel(
    const float* __restrict__ P, size_t pstride, int nz,
    const float* __restrict__ bias,
    const float* __restrict__ g, const float* __restrict__ bb,
    const float* __restrict__ scm, const float* __restrict__ shm,
    float* __restrict__ X, __hip_bfloat16* __restrict__ Hb)
{
    int row = blockIdx.x, tid = threadIdx.x;
    int b = row >> 11;
    __shared__ float red[256];
    float tv[3];
    float s = 0.f;
    #pragma unroll
    for (int q = 0; q < 3; ++q) {
        int d = tid + q*256;
        float v = P[(size_t)row*768 + d];
        for (int z = 1; z < nz; ++z) v += P[(size_t)z*pstride + (size_t)row*768 + d];
        v += bias[d];
        tv[q] = v; s += v;
    }
    red[tid] = s; __syncthreads();
    for (int off = 128; off > 0; off >>= 1) { if (tid < off) red[tid] += red[tid+off]; __syncthreads(); }
    float mu1 = red[0] * (1.f/768.f);
    __syncthreads();
    float s2 = 0.f;
    #pragma unroll
    for (int q = 0; q < 3; ++q) { float dv = tv[q] - mu1; s2 += dv*dv; }
    red[tid] = s2; __syncthreads();
    for (int off = 128; off > 0; off >>= 1) { if (tid < off) red[tid] += red[tid+off]; __syncthreads(); }
    float rstd1 = rsqrtf(red[0] * (1.f/768.f) + 1e-5f);
    __syncthreads();
    float xv[3];
    float s3 = 0.f;
    #pragma unroll
    for (int q = 0; q < 3; ++q) {
        int d = tid + q*256;
        float y = (tv[q] - mu1) * rstd1 * g[d] + bb[d];
        X[(size_t)row*768 + d] = y;
        xv[q] = y; s3 += y;
    }
    red[tid] = s3; __syncthreads();
    for (int off = 128; off > 0; off >>= 1) { if (tid < off) red[tid] += red[tid+off]; __syncthreads(); }
    float mu2 = red[0] * (1.f/768.f);
    __syncthreads();
    float s4 = 0.f;
    #pragma unroll
    for (int q = 0; q < 3; ++q) { float dv = xv[q] - mu2; s4 += dv*dv; }
    red[tid] = s4; __syncthreads();
    for (int off = 128; off > 0; off >>= 1) { if (tid < off) red[tid] += red[tid+off]; __syncthreads(); }
    float rstd2 = rsqrtf(red[0] * (1.f/768.f) + 1e-5f);
    #pragma unroll
    for (int q = 0; q < 3; ++q) {
        int d = tid + q*256;
        float h = (xv[q] - mu2) * rstd2 * (1.f + scm[(size_t)b*4608 + d]) + shm[(size_t)b*4608 + d];
        Hb[(size_t)row*768 + d] = __float2bfloat16(h);
    }
}

// ---------------------------------------------------------------------------
// fused: combine split-K (nz) + bias + residual-gate into X, then
// Hb = bf16( LN(xnew)*(1+scm[b]) + shm[b] ).  block per row, D=768.
// ---------------------------------------------------------------------------
__global__ __launch_bounds__(256) void gcombln_kernel(
    const float* __restrict__ P, size_t pstride, int nz,
    const float* __restrict__ bias,
    float* __restrict__ X,
    const float* __restrict__ gate,
    const float* __restrict__ scm, const float* __restrict__ shm,
    __hip_bfloat16* __restrict__ Hb)
{
    int row = blockIdx.x, tid = threadIdx.x;
    int b = row >> 11;
    __shared__ float red[256];
    float xv[3];
    float s = 0.f;
    #pragma unroll
    for (int q = 0; q < 3; ++q) {
        int d = tid + q*256;
        float v = P[(size_t)row*768 + d];
        for (int z = 1; z < nz; ++z) v += P[(size_t)z*pstride + (size_t)row*768 + d];
        v += bias[d];
        v = X[(size_t)row*768 + d] + gate[(size_t)b*4608 + d] * v;
        X[(size_t)row*768 + d] = v;
        xv[q] = v; s += v;
    }
    red[tid] = s; __syncthreads();
    for (int off = 128; off > 0; off >>= 1) { if (tid < off) red[tid] += red[tid+off]; __syncthreads(); }
    float mu = red[0] * (1.f/768.f);
    __syncthreads();
    float s2 = 0.f;
    #pragma unroll
    for (int q = 0; q < 3; ++q) { float dv = xv[q] - mu; s2 += dv*dv; }
    red[tid] = s2; __syncthreads();
    for (int off = 128; off > 0; off >>= 1) { if (tid < off) red[tid] += red[tid+off]; __syncthreads(); }
    float rstd = rsqrtf(red[0] * (1.f/768.f) + 1e-5f);
    #pragma unroll
    for (int q = 0; q < 3; ++q) {
        int d = tid + q*256;
        float y = (xv[q] - mu) * rstd * (1.f + scm[(size_t)b*4608 + d]) + shm[(size_t)b*4608 + d];
        Hb[(size_t)row*768 + d] = __float2bfloat16(y);
    }
}

// ---------------------------------------------------------------------------
// Row LayerNorm. mode bit0: *g+b ; bit1: *(1+scm[b])+shm[b] ; bit2: silu
// ---------------------------------------------------------------------------
__global__ __launch_bounds__(256) void rownorm_kernel(
    const float* __restrict__ in, int ldin,
    void* __restrict__ out, int ldout,
    int D, int mode, int obf,
    const float* __restrict__ gvec, const float* __restrict__ bvec,
    const float* __restrict__ scm, const float* __restrict__ shm, int mstride)
{
    int row = blockIdx.x;
    int tid = threadIdx.x;
    __shared__ float red[256];
    const float* pin = in + (size_t)row * ldin;
    float vals[3];
    float s = 0.f;
    #pragma unroll
    for (int q = 0; q < 3; ++q) {
        int d = tid + q*256;
        float v = (d < D) ? pin[d] : 0.f;
        vals[q] = v; s += v;
    }
    red[tid] = s; __syncthreads();
    for (int off = 128; off > 0; off >>= 1) { if (tid < off) red[tid] += red[tid+off]; __syncthreads(); }
    float mu = red[0] / (float)D;
    __syncthreads();
    float s2 = 0.f;
    #pragma unroll
    for (int q = 0; q < 3; ++q) { int d = tid + q*256; if (d < D) { float dv = vals[q] - mu; s2 += dv*dv; } }
    red[tid] = s2; __syncthreads();
    for (int off = 128; off > 0; off >>= 1) { if (tid < off) red[tid] += red[tid+off]; __syncthreads(); }
    float rstd = rsqrtf(red[0] / (float)D + 1e-5f);
    int b = row / N_;
    #pragma unroll
    for (int q = 0; q < 3; ++q) {
        int d = tid + q*256;
        if (d >= D) continue;
        float y = (vals[q] - mu) * rstd;
        if (mode & 1) y = y * gvec[d] + bvec[d];
        if (mode & 2) y = y * (1.f + scm[(size_t)b*mstride + d]) + shm[(size_t)b*mstride + d];
        if (mode & 4) y = y / (1.f + expf(-y));
        if (obf) ((__hip_bfloat16*)out)[(size_t)row * ldout + d] = __float2bfloat16(y);
        else     ((float*)out)[(size_t)row * ldout + d] = y;
    }
}

// ---------------------------------------------------------------------------
// c = LN(adaLN_emb @ ada_W + ada_b; g,b); c_silu = silu(c). 2 blocks.
// ---------------------------------------------------------------------------
__global__ __launch_bounds__(256) void ada_kernel(
    const float* __restrict__ emb, const float* __restrict__ W,
    const float* __restrict__ bias,
    const float* __restrict__ g, const float* __restrict__ bb,
    float* __restrict__ c, float* __restrict__ c_silu)
{
    int b = blockIdx.x, tid = threadIdx.x;
    __shared__ float emb_s[256];
    __shared__ float t[768];
    __shared__ float red[256];
    emb_s[tid] = emb[b*256 + tid];
    __syncthreads();
    for (int q = 0; q < 3; ++q) {
        int e = tid + q*256;
        float acc = bias[e];
        for (int k = 0; k < 256; ++k) acc += emb_s[k] * W[(size_t)k*768 + e];
        t[e] = acc;
    }
    __syncthreads();
    float s = 0.f; for (int q = 0; q < 3; ++q) s += t[tid + q*256];
    red[tid] = s; __syncthreads();
    for (int off = 128; off > 0; off >>= 1) { if (tid < off) red[tid] += red[tid+off]; __syncthreads(); }
    float mu = red[0] / 768.f; __syncthreads();
    float s2 = 0.f; for (int q = 0; q < 3; ++q) { float d = t[tid + q*256] - mu; s2 += d*d; }
    red[tid] = s2; __syncthreads();
    for (int off = 128; off > 0; off >>= 1) { if (tid < off) red[tid] += red[tid+off]; __syncthreads(); }
    float rstd = rsqrtf(red[0] / 768.f + 1e-5f);
    for (int q = 0; q < 3; ++q) {
        int e = tid + q*256;
        float y = (t[e] - mu) * rstd * g[e] + bb[e];
        c[b*768 + e] = y;
        c_silu[b*768 + e] = y / (1.f + expf(-y));
    }
}

// ---------------------------------------------------------------------------
// mod for BOTH layers, K-split 4: part[z][l][b][4608] ; grid (72, 4)
// ---------------------------------------------------------------------------
__global__ __launch_bounds__(256) void mod2_kernel(
    const float* __restrict__ c_silu, const float* __restrict__ mod_W,
    float* __restrict__ part)
{
    int idx = blockIdx.x * 256 + threadIdx.x;   // < 18432
    int z = blockIdx.y;
    int lyr = idx / 9216, b = (idx / 4608) & 1, j = idx % 4608;
    const float* Wl = mod_W + (size_t)lyr * 768 * 4608;
    const float* cs = c_silu + b * 768;
    float acc = 0.f;
    int k0 = z * 192;
    for (int k = k0; k < k0 + 192; ++k) acc += cs[k] * Wl[(size_t)k * 4608 + j];
    part[(size_t)z * 18432 + idx] = acc;
}

__global__ __launch_bounds__(256) void modc_kernel(
    const float* __restrict__ part, const float* __restrict__ mod_b,
    float* __restrict__ m2buf)
{
    int idx = blockIdx.x * 256 + threadIdx.x;
    int lyr = idx / 9216, j = idx % 4608;
    float acc = mod_b[(size_t)lyr * 4608 + j];
    #pragma unroll
    for (int z = 0; z < 4; ++z) acc += part[(size_t)z * 18432 + idx];
    m2buf[idx] = acc;
}

// ---------------------------------------------------------------------------
// MFMA local-window attention. 1 wave per (b, h, qblock of 32).
// ---------------------------------------------------------------------------
__global__ __launch_bounds__(64) void attn_mfma_kernel(
    const __hip_bfloat16* __restrict__ qkv,   // [B*N, 2304]
    const float* __restrict__ ropeC,          // [B*N, 32]
    const float* __restrict__ ropeS,
    __hip_bfloat16* __restrict__ o)           // [B*N, 768]
{
    int bid = blockIdx.x;
    int qb = bid & 63;
    int h  = (bid >> 6) % 12;
    int b  = bid / 768;
    int l  = threadIdx.x;
    int lr = l & 15, lg = l >> 4;
    int lo = max(0, 32*qb - 48);
    int hi = min(N_, 32*qb + 80);
    int wlen = hi - lo;

    __shared__ __hip_bfloat16 Vl[128 * 72];
    __shared__ __hip_bfloat16 Pl[32 * 144];

    {
        int vr0 = l >> 3;
        int c0  = (l & 7) * 8;
        #pragma unroll
        for (int it = 0; it < 16; ++it) {
            int vr = it*8 + vr0;
            int n = lo + vr;
            U8 v;
            if (n < hi) {
                v.v = *(const bf16x8*)(qkv + ((size_t)(b*N_ + n))*2304 + 1536 + h*64 + c0);
            } else {
                #pragma unroll
                for (int j = 0; j < 8; ++j) v.u[j] = 0;
            }
            *(bf16x8*)(Vl + vr*72 + c0) = v.v;
        }
    }

    bf16x8 aq0[2], aq1[2];
    #pragma unroll
    for (int i = 0; i < 2; ++i) {
        int n = qb*32 + i*16 + lr;
        const __hip_bfloat16* qrow = qkv + ((size_t)(b*N_ + n))*2304 + h*64;
        U8 xlo, xhi;
        xlo.v = *(const bf16x8*)(qrow + lg*8);
        xhi.v = *(const bf16x8*)(qrow + 32 + lg*8);
        const float* pc = ropeC + ((size_t)(b*N_ + n))*32 + lg*8;
        const float* ps = ropeS + ((size_t)(b*N_ + n))*32 + lg*8;
        float4 c0 = *(const float4*)(pc), c1 = *(const float4*)(pc + 4);
        float4 s0 = *(const float4*)(ps), s1 = *(const float4*)(ps + 4);
        float cv[8] = {c0.x,c0.y,c0.z,c0.w,c1.x,c1.y,c1.z,c1.w};
        float sv[8] = {s0.x,s0.y,s0.z,s0.w,s1.x,s1.y,s1.z,s1.w};
        U8 f0, f1;
        #pragma unroll
        for (int j = 0; j < 8; ++j) {
            float x1 = __bfloat162float(xlo.e[j]);
            float x2 = __bfloat162float(xhi.e[j]);
            f0.e[j] = __float2bfloat16(x1*cv[j] - x2*sv[j]);
            f1.e[j] = __float2bfloat16(x1*sv[j] + x2*cv[j]);
        }
        aq0[i] = f0.v; aq1[i] = f1.v;
    }

    f32x4 S[2][8];
    #pragma unroll
    for (int i = 0; i < 2; ++i)
        #pragma unroll
        for (int jt = 0; jt < 8; ++jt)
            S[i][jt] = f32x4{0.f, 0.f, 0.f, 0.f};

    #pragma unroll
    for (int jt = 0; jt < 8; ++jt) {
        int n = lo + jt*16 + lr;
        U8 f0, f1;
        if (n < hi) {
            const __hip_bfloat16* krow = qkv + ((size_t)(b*N_ + n))*2304 + 768 + h*64;
            U8 xlo, xhi;
            xlo.v = *(const bf16x8*)(krow + lg*8);
            xhi.v = *(const bf16x8*)(krow + 32 + lg*8);
            const float* pc = ropeC + ((size_t)(b*N_ + n))*32 + lg*8;
            const float* ps = ropeS + ((size_t)(b*N_ + n))*32 + lg*8;
            float4 c0 = *(const float4*)(pc), c1 = *(const float4*)(pc + 4);
            float4 s0 = *(const float4*)(ps), s1 = *(const float4*)(ps + 4);
            float cv[8] = {c0.x,c0.y,c0.z,c0.w,c1.x,c1.y,c1.z,c1.w};
            float sv[8] = {s0.x,s0.y,s0.z,s0.w,s1.x,s1.y,s1.z,s1.w};
            #pragma unroll
            for (int j = 0; j < 8; ++j) {
                float x1 = __bfloat162float(xlo.e[j]);
                float x2 = __bfloat162float(xhi.e[j]);
                f0.e[j] = __float2bfloat16(x1*cv[j] - x2*sv[j]);
                f1.e[j] = __float2bfloat16(x1*sv[j] + x2*cv[j]);
            }
        } else {
            #pragma unroll
            for (int j = 0; j < 8; ++j) { f0.u[j] = 0; f1.u[j] = 0; }
        }
        #pragma unroll
        for (int i = 0; i < 2; ++i) {
            S[i][jt] = __builtin_amdgcn_mfma_f32_16x16x32_bf16(aq0[i], f0.v, S[i][jt], 0, 0, 0);
            S[i][jt] = __builtin_amdgcn_mfma_f32_16x16x32_bf16(aq1[i], f1.v, S[i][jt], 0, 0, 0);
        }
    }

    #pragma unroll
    for (int jt = 0; jt < 8; ++jt) {
        bool oob = (jt*16 + lr) >= wlen;
        #pragma unroll
        for (int i = 0; i < 2; ++i)
            #pragma unroll
            for (int r = 0; r < 4; ++r)
                S[i][jt][r] = oob ? -1e30f : S[i][jt][r] * 0.125f;
    }

    float rinv[2][4];
    #pragma unroll
    for (int i = 0; i < 2; ++i) {
        #pragma unroll
        for (int r = 0; r < 4; ++r) {
            float m = -1e30f;
            #pragma unroll
            for (int jt = 0; jt < 8; ++jt) m = fmaxf(m, S[i][jt][r]);
            #pragma unroll
            for (int mask = 8; mask > 0; mask >>= 1) m = fmaxf(m, __shfl_xor(m, mask, 16));
            float sum = 0.f;
            #pragma unroll
            for (int jt = 0; jt < 8; ++jt) {
                float e = __expf(S[i][jt][r] - m);
                S[i][jt][r] = e;
                sum += e;
            }
            #pragma unroll
            for (int mask = 8; mask > 0; mask >>= 1) sum += __shfl_xor(sum, mask, 16);
            rinv[i][r] = 1.f / sum;
        }
    }

    #pragma unroll
    for (int i = 0; i < 2; ++i)
        #pragma unroll
        for (int jt = 0; jt < 8; ++jt)
            #pragma unroll
            for (int r = 0; r < 4; ++r) {
                int row = i*16 + lg*4 + r;
                int colp = (jt*16 + lr) ^ (lg << 3);
                Pl[row*144 + colp] = __float2bfloat16(S[i][jt][r]);
            }

    __syncthreads();

    f32x4 O_[2][4];
    #pragma unroll
    for (int i = 0; i < 2; ++i)
        #pragma unroll
        for (int ct = 0; ct < 4; ++ct)
            O_[i][ct] = f32x4{0.f, 0.f, 0.f, 0.f};

    int key = (lr >> 2) & 3;
    #pragma unroll
    for (int kt = 0; kt < 4; ++kt) {
        bf16x8 pa[2];
        #pragma unroll
        for (int i = 0; i < 2; ++i) {
            int row = i*16 + lr;
            int colp = (kt*32 + lg*8) ^ (key << 3);
            pa[i] = *(bf16x8*)(Pl + row*144 + colp);
        }
        #pragma unroll
        for (int ct = 0; ct < 4; ++ct) {
            U8 bv;
            #pragma unroll
            for (int j = 0; j < 8; ++j)
                bv.e[j] = Vl[(kt*32 + lg*8 + j)*72 + ct*16 + lr];
            O_[0][ct] = __builtin_amdgcn_mfma_f32_16x16x32_bf16(pa[0], bv.v, O_[0][ct], 0, 0, 0);
            O_[1][ct] = __builtin_amdgcn_mfma_f32_16x16x32_bf16(pa[1], bv.v, O_[1][ct], 0, 0, 0);
        }
    }

    #pragma unroll
    for (int i = 0; i < 2; ++i)
        #pragma unroll
        for (int ct = 0; ct < 4; ++ct)
            #pragma unroll
            for (int r = 0; r < 4; ++r) {
                int row = qb*32 + i*16 + lg*4 + r;
                o[((size_t)(b*N_ + row))*768 + h*64 + ct*16 + lr] =
                    __float2bfloat16(O_[i][ct][r] * rinv[i][r]);
            }
}

// ---------------------------------------------------------------------------
// a2t [B,N,NR] fp32 -> a2tTb [B,NR,N] bf16   grid (NR/32, N/32, B)
// ---------------------------------------------------------------------------
__global__ __launch_bounds__(256) void a2t_transpose_kernel(
    const float* __restrict__ a2t, __hip_bfloat16* __restrict__ a2tTb)
{
    __shared__ float t[32][33];
    int r0 = blockIdx.x * 32, n0 = blockIdx.y * 32, b = blockIdx.z;
    int tid = threadIdx.x;
    int tx = tid & 31, ty = tid >> 5;
    #pragma unroll
    for (int i = 0; i < 4; ++i) {
        int row = ty + i*8;
        t[row][tx] = a2t[((size_t)b*N_ + n0 + row) * 256 + r0 + tx];
    }
    __syncthreads();
    #pragma unroll
    for (int i = 0; i < 4; ++i) {
        int row = ty + i*8;
        a2tTb[((size_t)b*256 + r0 + row) * N_ + n0 + tx] = __float2bfloat16(t[tx][row]);
    }
}

// ---------------------------------------------------------------------------
// recip[row] = 1/(sum of a2tTb row + 1e-6).  block per row (512 rows).
// ---------------------------------------------------------------------------
__global__ __launch_bounds__(256) void rowrecip_kernel(
    const __hip_bfloat16* __restrict__ a2tTb, float* __restrict__ recip)
{
    int row = blockIdx.x;
    int tid = threadIdx.x;
    __shared__ float red[256];
    U8 v; v.v = *(const bf16x8*)(a2tTb + (size_t)row*2048 + tid*8);
    float s = 0.f;
    #pragma unroll
    for (int j = 0; j < 8; ++j) s += __bfloat162float(v.e[j]);
    red[tid] = s; __syncthreads();
    for (int off = 128; off > 0; off >>= 1) { if (tid < off) red[tid] += red[tid+off]; __syncthreads(); }
    if (tid == 0) recip[row] = 1.f / (red[0] + 1e-6f);
}

// ---------------------------------------------------------------------------
extern "C" void kernel_launch(void* const* d_in, const int* in_sizes, int n_in,
                              void* d_out, int out_size, void* d_ws, size_t ws_size,
                              hipStream_t stream) {
    const float* atom_coords  = (const float*)d_in[0];
    const float* ref_pos      = (const float*)d_in[1];
    const int*   res_id       = (const int*)  d_in[2];
    const float* res_type     = (const float*)d_in[3];
    const float* charge       = (const float*)d_in[4];
    const float* atomic_num   = (const float*)d_in[5];
    const float* atom_name    = (const float*)d_in[6];
    const float* adaLN_emb    = (const float*)d_in[7];
    const int*   rope_pos     = (const int*)  d_in[8];
    const float* atom_to_tok  = (const float*)d_in[9];
    const float* feat_W       = (const float*)d_in[10];
    const float* feat_b       = (const float*)d_in[11];
    const float* feat_ln_g    = (const float*)d_in[12];
    const float* feat_ln_b    = (const float*)d_in[13];
    const float* pos_W        = (const float*)d_in[14];
    const float* in_W         = (const float*)d_in[15];
    const float* tin_W        = (const float*)d_in[16];
    const float* tin_b        = (const float*)d_in[17];
    const float* tin_ln_g     = (const float*)d_in[18];
    const float* tin_ln_b     = (const float*)d_in[19];
    const float* ada_W        = (const float*)d_in[20];
    const float* ada_b        = (const float*)d_in[21];
    const float* ada_ln_g     = (const float*)d_in[22];
    const float* ada_ln_b     = (const float*)d_in[23];
    const float* blk_mod_W    = (const float*)d_in[24];
    const float* blk_mod_b    = (const float*)d_in[25];
    const float* blk_qkv_W    = (const float*)d_in[26];
    const float* blk_qkv_b    = (const float*)d_in[27];
    const float* blk_o_W      = (const float*)d_in[28];
    const float* blk_o_b      = (const float*)d_in[29];
    const float* blk_m1_W     = (const float*)d_in[30];
    const float* blk_m1_b     = (const float*)d_in[31];
    const float* blk_m2_W     = (const float*)d_in[32];
    const float* blk_m2_b     = (const float*)d_in[33];
    const float* tout_W       = (const float*)d_in[34];
    const float* tout_b       = (const float*)d_in[35];
    const float* tout_ln_g    = (const float*)d_in[36];
    const float* tout_ln_b    = (const float*)d_in[37];

    const int BN = B_ * N_;                          // 4096
    float* ws = (float*)d_ws;

    // layout (float units)
    const size_t OFF_X    = 0;                                // fp32 [4096][768]
    const size_t OFF_HB   = OFF_X    + (size_t)BN*768;        // bf16 [4096][768]
    const size_t OFF_QKVB = OFF_HB   + (size_t)BN*768/2;      // bf16 [4096][2304]
    const size_t OFF_OB   = OFF_QKVB + (size_t)BN*2304/2;     // bf16 [4096][768]
    const size_t OFF_UB   = OFF_OB   + (size_t)BN*768/2;      // bf16 [4096][3072]
    const size_t OFF_WT   = OFF_UB   + (size_t)BN*3072/2;     // bf16 up to 3072*768
    const size_t OFF_RC   = OFF_WT   + (size_t)3072*768/2;    // fp32 BN*32
    const size_t OFF_RS   = OFF_RC   + (size_t)BN*32;
    const size_t OFF_SM   = OFF_RS   + (size_t)BN*32;

    float* X = ws + OFF_X;
    __hip_bfloat16* Hb   = (__hip_bfloat16*)(ws + OFF_HB);
    __hip_bfloat16* QKVb = (__hip_bfloat16*)(ws + OFF_QKVB);
    __hip_bfloat16* Ob   = (__hip_bfloat16*)(ws + OFF_OB);
    __hip_bfloat16* Ub   = (__hip_bfloat16*)(ws + OFF_UB);
    __hip_bfloat16* WT   = (__hip_bfloat16*)(ws + OFF_WT);
    float* ropeC  = ws + OFF_RC;
    float* ropeS  = ws + OFF_RS;
    float* cbuf   = ws + OFF_SM;                     // 1536
    float* c_silu = cbuf + 1536;                     // 1536
    float* mbuf2  = c_silu + 1536;                   // 18432  [2][2][4608]
    float* modpart= mbuf2 + 18432;                   // 73728

    // phase-A aliases
    __hip_bfloat16* featsB  = QKVb;                           // [4096][1024] bf16
    __hip_bfloat16* coordsB = QKVb + (size_t)BN*1024;         // [4096][512] bf16
    float* t1               = ws + OFF_UB;                    // scratch
    __hip_bfloat16* concatB = (__hip_bfloat16*)(t1 + (size_t)BN*256);  // [4096][512] bf16
    __hip_bfloat16* atom_inB= Ob;                             // [4096][256] bf16

    // residue-phase aliases (Ob/Ub regions dead by then)
    __hip_bfloat16* a2tTb   = Ob;                             // [2][256][2048] bf16
    __hip_bfloat16* latTb   = Ob + (size_t)2*256*2048;        // [2][256][2048] bf16
    float* recip            = modpart;                        // 512 fp32

    // split-K partial buffers (aliases of dead regions)
    float* P_pa   = ws + OFF_X;       // phase A (feat/pos/in)
    float* P_tin  = ws + OFF_UB;
    float* P_o    = ws + OFF_UB;
    float* P_m2   = ws + OFF_QKVB;
    float* P_tout = ws + OFF_UB;
    float* P_res  = ws + OFF_UB;

    float* out_res = (float*)d_out;                           // B*NR*DA
    float* out_lat = out_res + (size_t)B_*NR_*DA_;            // B*N*DA

    // ---- adaLN + modulation for both layers (input-only; run first) ----
    ada_kernel<<<2, 256, 0, stream>>>(adaLN_emb, ada_W, ada_b, ada_ln_g, ada_ln_b,
        cbuf, c_silu);
    mod2_kernel<<<dim3(72, 4), 256, 0, stream>>>(c_silu, blk_mod_W, modpart);
    modc_kernel<<<72, 256, 0, stream>>>(modpart, blk_mod_b, mbuf2);

    // ---- featurization (bf16) + rope table (fused) ----
    build_feats_kernel<<<BN, 128, 0, stream>>>(atom_coords, ref_pos, res_id,
        res_type, charge, atomic_num, atom_name, rope_pos, featsB, coordsB,
        ropeC, ropeS);

    // t1 = feats @ feat_W + feat_b   (K padded 924->1024, split 4)
    transconv_kernel<<<dim3(8, 32), 256, 0, stream>>>(feat_W, WT, 924, 1024, 256, 0, 0);
    gemm_bf16_kernel<<<dim3(2, 32, 4), 256, 0, stream>>>(featsB, 1024, WT, 1024, nullptr,
        nullptr, 0, 1024, 0, 0, nullptr, 0, nullptr, 0, P_pa, 32, 0, 0);
    combln256_kernel<<<BN, 256, 0, stream>>>(P_pa, (size_t)BN*256, 4, feat_b,
        feat_ln_g, feat_ln_b, 1, 1, concatB, 512);
    // concat[:,256:512] = coordsF @ pos_W  (K 387->512, split 4)
    transconv_kernel<<<dim3(8, 16), 256, 0, stream>>>(pos_W, WT, 387, 512, 256, 0, 0);
    gemm_bf16_kernel<<<dim3(2, 32, 4), 256, 0, stream>>>(coordsB, 512, WT, 512, nullptr,
        nullptr, 0, 512, 0, 0, nullptr, 0, nullptr, 0, P_pa, 32, 0, 0);
    gcomb_kernel<<<1024, 256, 0, stream>>>(P_pa, (size_t)BN*256, 4, 256, nullptr,
        concatB + 256, 512, 0, 1, nullptr, 0, nullptr, 0, nullptr, 0);
    // atom_in = concat @ in_W -> bf16 (split 4)
    transconv_kernel<<<dim3(8, 16), 256, 0, stream>>>(in_W, WT, 512, 512, 256, 0, 0);
    gemm_bf16_kernel<<<dim3(2, 32, 4), 256, 0, stream>>>(concatB, 512, WT, 512, nullptr,
        nullptr, 0, 512, 0, 0, nullptr, 0, nullptr, 0, P_pa, 32, 0, 0);
    gcomb_kernel<<<1024, 256, 0, stream>>>(P_pa, (size_t)BN*256, 4, 256, nullptr,
        atom_inB, 256, 0, 1, nullptr, 0, nullptr, 0, nullptr, 0);
    // X = LN(atom_in @ tin_W + tin_b) ; Hb = LN(X)*(1+sc1)+sh1  (fused)
    transconv_kernel<<<dim3(24, 8), 256, 0, stream>>>(tin_W, WT, 256, 256, 768, 0, 0);
    gemm_bf16_kernel<<<dim3(6, 32, 2), 256, 0, stream>>>(atom_inB, 256, WT, 256, nullptr,
        nullptr, 0, 256, 0, 0, nullptr, 0, nullptr, 0, P_tin, 32, 0, 0);
    tinfuse_kernel<<<BN, 256, 0, stream>>>(P_tin, (size_t)BN*768, 2, tin_b,
        tin_ln_g, tin_ln_b, mbuf2 + 768, mbuf2 + 0, X, Hb);

    for (int l = 0; l < NB_; ++l) {
        const float* qkvW = blk_qkv_W + (size_t)l*768*2304;
        const float* qkvB = blk_qkv_b + (size_t)l*2304;
        const float* oW   = blk_o_W   + (size_t)l*768*768;
        const float* oB   = blk_o_b   + (size_t)l*768;
        const float* m1W  = blk_m1_W  + (size_t)l*768*3072;
        const float* m1B  = blk_m1_b  + (size_t)l*3072;
        const float* m2W  = blk_m2_W  + (size_t)l*3072*768;
        const float* m2B  = blk_m2_b  + (size_t)l*768;

        float* mptr = mbuf2 + (size_t)l*9216;        // [b][4608]
        float* sh2 = mptr + 2304, *sc2 = mptr + 3072;
        float* g1  = mptr + 1536, *g2 = mptr + 3840;

        // qkv = h @ qkv_W + b -> bf16
        transconv_kernel<<<dim3(72, 24), 256, 0, stream>>>(qkvW, WT, 768, 768, 2304, 0, 0);
        gemm_bf16_kernel<<<dim3(18, 32, 1), 256, 0, stream>>>(Hb, 768, WT, 768, qkvB,
            QKVb, 2304, 768, 0, 1, nullptr, 0, nullptr, 0, nullptr, 32, 0, 0);
        // attention
        attn_mfma_kernel<<<B_*H_*64, 64, 0, stream>>>(QKVb, ropeC, ropeS, Ob);
        // x = x + g1*(o @ o_W + o_b)  (split 2) ; fused -> Hb = h2
        transconv_kernel<<<dim3(24, 24), 256, 0, stream>>>(oW, WT, 768, 768, 768, 0, 0);
        gemm_bf16_kernel<<<dim3(6, 32, 2), 256, 0, stream>>>(Ob, 768, WT, 768, nullptr,
            nullptr, 0, 768, 0, 0, nullptr, 0, nullptr, 0, P_o, 32, 0, 0);
        gcombln_kernel<<<BN, 256, 0, stream>>>(P_o, (size_t)BN*768, 2, oB,
            X, g1, sc2, sh2, Hb);
        // u = gelu(h2 @ m1_W + b) -> bf16
        transconv_kernel<<<dim3(96, 24), 256, 0, stream>>>(m1W, WT, 768, 768, 3072, 0, 0);
        gemm_bf16_kernel<<<dim3(24, 32, 1), 256, 0, stream>>>(Hb, 768, WT, 768, m1B,
            Ub, 3072, 768, 1, 1, nullptr, 0, nullptr, 0, nullptr, 32, 0, 0);
        // x = x + g2*(u @ m2_W + b)  (split 2)
        transconv_kernel<<<dim3(24, 96), 256, 0, stream>>>(m2W, WT, 3072, 3072, 768, 0, 0);
        gemm_bf16_kernel<<<dim3(6, 32, 2), 256, 0, stream>>>(Ub, 3072, WT, 3072, nullptr,
            nullptr, 0, 3072, 0, 0, nullptr, 0, nullptr, 0, P_m2, 32, 0, 0);
        if (l < NB_ - 1) {
            float* mnext = mbuf2 + (size_t)(l+1)*9216;
            gcombln_kernel<<<BN, 256, 0, stream>>>(P_m2, (size_t)BN*768, 2, m2B,
                X, g2, mnext + 768, mnext + 0, Hb);
        } else {
            gcomb_kernel<<<3072, 256, 0, stream>>>(P_m2, (size_t)BN*768, 2, 768, m2B,
                X, 768, 2, 0, X, 768, g2, 4608, Hb, 768);
        }
    }

    // atom_latent = LN(x @ tout_W + tout_b)  (split 4, fused combine+LN)
    transconv_kernel<<<dim3(8, 24), 256, 0, stream>>>(tout_W, WT, 768, 768, 256, 0, 0);
    gemm_bf16_kernel<<<dim3(2, 32, 4), 256, 0, stream>>>(Hb, 768, WT, 768, nullptr,
        nullptr, 0, 768, 0, 0, nullptr, 0, nullptr, 0, P_tout, 32, 0, 0);
    combln256_kernel<<<BN, 256, 0, stream>>>(P_tout, (size_t)BN*256, 4, tout_b,
        tout_ln_g, tout_ln_b, 0, 0, out_lat, 256);

    // ---- residue pooling as MFMA GEMM ----
    a2t_transpose_kernel<<<dim3(8, 64, 2), 256, 0, stream>>>(atom_to_tok, a2tTb);
    rowrecip_kernel<<<512, 256, 0, stream>>>(a2tTb, recip);
    transconv_kernel<<<dim3(8, 64, 2), 256, 0, stream>>>(out_lat, latTb, 2048, 2048, 256,
        (size_t)2048*256, (size_t)256*2048);
    gemm_bf16_kernel<<<dim3(2, 4, 8), 256, 0, stream>>>(a2tTb, 2048, latTb, 2048, nullptr,
        nullptr, 0, 2048, 0, 0, nullptr, 0, nullptr, 0, P_res,
        2, (size_t)256*2048, (size_t)256*2048);
    gcomb_kernel<<<128, 256, 0, stream>>>(P_res, (size_t)512*256, 8, 256, nullptr,
        out_res, 256, 3, 0, nullptr, 0, recip, 0, nullptr, 0);
}

// Round 13
// 590.700 us; speedup vs baseline: 1.6184x; 1.0132x over previous
//
#include <hip/hip_runtime.h>
#include <hip/hip_bf16.h>
#include <math.h>

// Problem constants
#define B_ 2
#define N_ 2048
#define NR_ 256
#define DA_ 256
#define E_ 768
#define H_ 12
#define DH_ 64
#define NB_ 2

typedef __attribute__((ext_vector_type(8))) __bf16 bf16x8;
typedef __attribute__((ext_vector_type(4))) float f32x4;

union U8 { bf16x8 v; __hip_bfloat16 e[8]; unsigned short u[8]; };
union U4 { __hip_bfloat16 e[4]; uint2 u2; };

__device__ __forceinline__ void gload16(const void* g, void* l) {
    __builtin_amdgcn_global_load_lds(
        (const __attribute__((address_space(1))) void*)g,
        (__attribute__((address_space(3))) void*)l, 16, 0, 0);
}

// 256-thread block sum: wave shuffle + 4-slot LDS combine (2 barriers).
__device__ __forceinline__ float bsum256(float v, float* red4, int tid) {
    #pragma unroll
    for (int m = 32; m > 0; m >>= 1) v += __shfl_xor(v, m, 64);
    __syncthreads();
    if ((tid & 63) == 0) red4[tid >> 6] = v;
    __syncthreads();
    return red4[0] + red4[1] + red4[2] + red4[3];
}

// ---------------------------------------------------------------------------
// build feats[B*N, 1024] (bf16) and coordsF[B*N, 512] (bf16) + rope tables
// ---------------------------------------------------------------------------
__global__ __launch_bounds__(128) void build_feats_kernel(
    const float* __restrict__ atom_coords, const float* __restrict__ ref_pos,
    const int* __restrict__ res_id, const float* __restrict__ res_type,
    const float* __restrict__ charge, const float* __restrict__ atomic_number,
    const float* __restrict__ atom_name, const int* __restrict__ rope_pos,
    __hip_bfloat16* __restrict__ feats, __hip_bfloat16* __restrict__ coordsF,
    float* __restrict__ ropeC, float* __restrict__ ropeS)
{
    int a = blockIdx.x;            // atom index over B*N
    int tid = threadIdx.x;
    __hip_bfloat16* f  = feats   + (size_t)a * 1024;
    __hip_bfloat16* cf = coordsF + (size_t)a * 512;

    float rp[3], cc[3];
    #pragma unroll
    for (int i = 0; i < 3; ++i) { rp[i] = ref_pos[(size_t)a*3 + i]; cc[i] = atom_coords[(size_t)a*3 + i]; }

    if (tid < 3) { f[tid] = __float2bfloat16(rp[tid]); cf[tid] = __float2bfloat16(cc[tid]); }

    if (tid >= 64 && tid < 96) {
        int dd = tid - 64;
        float rpos = (float)rope_pos[a];
        float ang = rpos * expf(-0.28782313662425574f * (float)dd);  // ln(1e4)/32
        float sn, cs; sincosf(ang, &sn, &cs);
        ropeC[a*32 + dd] = cs; ropeS[a*32 + dd] = sn;
    }

    for (int s = tid; s < 192; s += 128) {
        int fi = s / 3, ci = s % 3;
        float freq = exp2f(12.f * (float)fi / 63.f);
        float ar = rp[ci] * freq;
        float ac = cc[ci] * freq;
        float snr, csr, snc, csc_;
        sincosf(ar, &snr, &csr);
        sincosf(ac, &snc, &csc_);
        f[3 + s]    = __float2bfloat16(snr);  f[195 + s]  = __float2bfloat16(csr);
        cf[3 + s]   = __float2bfloat16(snc);  cf[195 + s] = __float2bfloat16(csc_);
    }
    if (tid < 23) f[387 + tid] = __float2bfloat16(res_type[(size_t)a*23 + tid]);

    float pos = (float)res_id[a];
    if (tid == 0) f[410] = __float2bfloat16(pos);
    if (tid < 64) {
        float div = expf(-9.210340371976184f / 128.f * (float)(2 * tid));
        float ang = pos * div;
        float sn, cs; sincosf(ang, &sn, &cs);
        f[411 + tid] = __float2bfloat16(sn);
        f[475 + tid] = __float2bfloat16(cs);
    }
    if (tid == 0) f[539] = __float2bfloat16(charge[a]);
    if (tid < 128) f[540 + tid] = __float2bfloat16(atomic_number[(size_t)a*128 + tid]);
    for (int s = tid; s < 256; s += 128) f[668 + s] = __float2bfloat16(atom_name[(size_t)a*256 + s]);
    if (tid < 100) f[924 + tid] = __float2bfloat16(0.f);
    if (tid < 125) cf[387 + tid] = __float2bfloat16(0.f);
}

// ---------------------------------------------------------------------------
// Transpose + fp32->bf16 + K-pad: W[Ksrc][Nn] -> WT[Nn][Kdst], zeros k>=Ksrc
// ---------------------------------------------------------------------------
__global__ __launch_bounds__(256) void transconv_kernel(
    const float* __restrict__ W, __hip_bfloat16* __restrict__ WT,
    int Ksrc, int Kdst, int Nn, size_t wstride, size_t tstride)
{
    __shared__ float t[32][33];
    W  += (size_t)blockIdx.z * wstride;
    WT += (size_t)blockIdx.z * tstride;
    int n0 = blockIdx.x * 32, k0 = blockIdx.y * 32;
    int tid = threadIdx.x;
    int tx = tid & 31, ty = tid >> 5;           // ty 0..7
    #pragma unroll
    for (int i = 0; i < 4; ++i) {
        int k = k0 + ty + i*8;
        t[ty + i*8][tx] = (k < Ksrc) ? W[(size_t)k * Nn + n0 + tx] : 0.f;
    }
    __syncthreads();
    #pragma unroll
    for (int i = 0; i < 4; ++i) {
        int row = ty + i*8;                      // n within tile
        WT[(size_t)(n0 + row) * Kdst + k0 + tx] = __float2bfloat16(t[tx][row]);
    }
}

// ---------------------------------------------------------------------------
// shared epilogue.  mode 0 none; 1 gelu; 2 X + gate[b][col]*v; 3 v*gate[row]
// ---------------------------------------------------------------------------
__device__ __forceinline__ float epi_apply(float v, int grow, int gcol,
    const float* bias, int mode, const float* X, int ldx,
    const float* gate, int gstride)
{
    if (bias) v += bias[gcol];
    if (mode == 1) {
        float u = 1.5957691216057308f * (v + 0.044715f * v * v * v);
        v = v / (1.f + __expf(-u));
    } else if (mode == 2) {
        int b = grow >> 11;                      // /N_
        v = X[(size_t)grow * ldx + gcol] + gate[(size_t)b * gstride + gcol] * v;
    } else if (mode == 3) {
        v = v * gate[grow];
    }
    return v;
}

// ---------------------------------------------------------------------------
// bf16 MFMA GEMM: tile 128x128, BK=32, 4 waves.  Ring-3 LDS + counted vmcnt.
// XOR-swizzle both sides: key(row)=(row>>1)&3.  Bijective XCD swizzle.
// ---------------------------------------------------------------------------
__global__ __launch_bounds__(256) void gemm_bf16_kernel(
    const __hip_bfloat16* __restrict__ A, int lda,
    const __hip_bfloat16* __restrict__ BT, int ldb,
    const float* __restrict__ bias,
    void* __restrict__ C, int ldc,
    int K, int mode, int obf,
    const float* __restrict__ X, int ldx,
    const float* __restrict__ gate, int gstride,
    float* __restrict__ P,
    int mtiles, size_t bstrideA, size_t bstrideB)
{
    __shared__ __hip_bfloat16 As[3][128 * 32];
    __shared__ __hip_bfloat16 Bs[3][128 * 32];

    int gx = gridDim.x;
    int nwg = gx * gridDim.y;
    int fo = blockIdx.y * gx + blockIdx.x;
    int ft = (fo & 7) * (nwg >> 3) + (fo >> 3);
    int bx = ft % gx, by = ft / gx;

    int bb  = by / mtiles;
    int m0l = (by % mtiles) * 128;
    int m0g = by * 128;
    int n0 = bx * 128;
    const __hip_bfloat16* Ab  = A  + (size_t)bb * bstrideA;
    const __hip_bfloat16* BTb = BT + (size_t)bb * bstrideB;
    int nz = gridDim.z;
    int Kh = K / nz;
    int kb = blockIdx.z * Kh;
    int nIter = Kh >> 5;
    int tid = threadIdx.x;
    int w = tid >> 6, l = tid & 63;
    int wr = (w >> 1) * 64, wc = (w & 1) * 64;
    int lr = l & 15, lg = l >> 4;
    int slot = ((lg ^ ((lr >> 1) & 3)) & 3) * 8;

    int seg0 = tid,        row0s = seg0 >> 2, g0 = (seg0 & 3) ^ ((row0s >> 1) & 3);
    int seg1 = 256 + tid,  row1s = seg1 >> 2, g1 = (seg1 & 3) ^ ((row1s >> 1) & 3);

    f32x4 acc[4][4];
    #pragma unroll
    for (int i = 0; i < 4; ++i)
        #pragma unroll
        for (int j = 0; j < 4; ++j)
            acc[i][j] = f32x4{0.f, 0.f, 0.f, 0.f};

    {
        gload16(Ab  + (size_t)(m0l + row0s) * lda + kb + g0 * 8, (char*)As[0] + seg0 * 16);
        gload16(BTb + (size_t)(n0 + row0s) * ldb + kb + g0 * 8, (char*)Bs[0] + seg0 * 16);
        gload16(Ab  + (size_t)(m0l + row1s) * lda + kb + g1 * 8, (char*)As[0] + seg1 * 16);
        gload16(BTb + (size_t)(n0 + row1s) * ldb + kb + g1 * 8, (char*)Bs[0] + seg1 * 16);
        if (nIter > 1) {
            int k1 = kb + 32;
            gload16(Ab  + (size_t)(m0l + row0s) * lda + k1 + g0 * 8, (char*)As[1] + seg0 * 16);
            gload16(BTb + (size_t)(n0 + row0s) * ldb + k1 + g0 * 8, (char*)Bs[1] + seg0 * 16);
            gload16(Ab  + (size_t)(m0l + row1s) * lda + k1 + g1 * 8, (char*)As[1] + seg1 * 16);
            gload16(BTb + (size_t)(n0 + row1s) * ldb + k1 + g1 * 8, (char*)Bs[1] + seg1 * 16);
        }
    }

    int cur = 0;
    for (int it = 0; it < nIter; ++it) {
        if (it + 1 < nIter) asm volatile("s_waitcnt vmcnt(4)" ::: "memory");
        else                asm volatile("s_waitcnt vmcnt(0)" ::: "memory");
        __builtin_amdgcn_s_barrier();
        __builtin_amdgcn_sched_barrier(0);
        if (it + 2 < nIter) {
            int nb = cur + 2; if (nb >= 3) nb -= 3;
            int kn = kb + (it + 2) * 32;
            gload16(Ab  + (size_t)(m0l + row0s) * lda + kn + g0 * 8, (char*)As[nb] + seg0 * 16);
            gload16(BTb + (size_t)(n0 + row0s) * ldb + kn + g0 * 8, (char*)Bs[nb] + seg0 * 16);
            gload16(Ab  + (size_t)(m0l + row1s) * lda + kn + g1 * 8, (char*)As[nb] + seg1 * 16);
            gload16(BTb + (size_t)(n0 + row1s) * ldb + kn + g1 * 8, (char*)Bs[nb] + seg1 * 16);
        }
        bf16x8 af[4], bfr[4];
        #pragma unroll
        for (int i = 0; i < 4; ++i) {
            af[i]  = *(bf16x8*)(As[cur] + (wr + i*16 + lr) * 32 + slot);
            bfr[i] = *(bf16x8*)(Bs[cur] + (wc + i*16 + lr) * 32 + slot);
        }
        #pragma unroll
        for (int i = 0; i < 4; ++i)
            #pragma unroll
            for (int j = 0; j < 4; ++j)
                acc[i][j] = __builtin_amdgcn_mfma_f32_16x16x32_bf16(af[i], bfr[j], acc[i][j], 0, 0, 0);
        cur = (cur == 2) ? 0 : cur + 1;
    }

    if (nz > 1) {
        int Nw = gridDim.x * 128;
        size_t pstride = (size_t)Nw * (gridDim.y * 128);
        float* Pz = P + (size_t)blockIdx.z * pstride;
        #pragma unroll
        for (int i = 0; i < 4; ++i)
            #pragma unroll
            for (int j = 0; j < 4; ++j)
                #pragma unroll
                for (int r = 0; r < 4; ++r) {
                    int grow = m0g + wr + i*16 + lg*4 + r;
                    int gcol = n0 + wc + j*16 + lr;
                    Pz[(size_t)grow * Nw + gcol] = acc[i][j][r];
                }
        return;
    }

    #pragma unroll
    for (int i = 0; i < 4; ++i)
        #pragma unroll
        for (int j = 0; j < 4; ++j)
            #pragma unroll
            for (int r = 0; r < 4; ++r) {
                int grow = m0g + wr + i*16 + lg*4 + r;
                int gcol = n0 + wc + j*16 + lr;
                float v = epi_apply(acc[i][j][r], grow, gcol, bias, mode, X, ldx, gate, gstride);
                if (obf)
                    ((__hip_bfloat16*)C)[(size_t)grow * ldc + gcol] = __float2bfloat16(v);
                else
                    ((float*)C)[(size_t)grow * ldc + gcol] = v;
            }
}

// ---------------------------------------------------------------------------
// combine split-K partials + epilogue. 4 elems/thread. optional C2 bf16 out.
// ---------------------------------------------------------------------------
__global__ __launch_bounds__(256) void gcomb_kernel(
    const float* __restrict__ P, size_t pstride, int nz, int Nw,
    const float* __restrict__ bias,
    void* __restrict__ C, int ldc, int mode, int obf,
    const float* __restrict__ X, int ldx,
    const float* __restrict__ gate, int gstride,
    __hip_bfloat16* __restrict__ C2, int ldc2)
{
    int idx = blockIdx.x * 256 + threadIdx.x;
    int e0 = idx * 4;
    int grow = e0 / Nw, gc0 = e0 % Nw;
    float4 v = *(const float4*)(P + (size_t)grow * Nw + gc0);
    for (int z = 1; z < nz; ++z) {
        float4 t = *(const float4*)(P + (size_t)z * pstride + (size_t)grow * Nw + gc0);
        v.x += t.x; v.y += t.y; v.z += t.z; v.w += t.w;
    }
    float e[4] = {v.x, v.y, v.z, v.w};
    #pragma unroll
    for (int r = 0; r < 4; ++r)
        e[r] = epi_apply(e[r], grow, gc0 + r, bias, mode, X, ldx, gate, gstride);
    if (obf) {
        U4 o4;
        #pragma unroll
        for (int r = 0; r < 4; ++r) o4.e[r] = __float2bfloat16(e[r]);
        *(uint2*)((__hip_bfloat16*)C + (size_t)grow * ldc + gc0) = o4.u2;
    } else {
        *(float4*)((float*)C + (size_t)grow * ldc + gc0) = make_float4(e[0], e[1], e[2], e[3]);
    }
    if (C2) {
        U4 o4;
        #pragma unroll
        for (int r = 0; r < 4; ++r) o4.e[r] = __float2bfloat16(e[r]);
        *(uint2*)(C2 + (size_t)grow * ldc2 + gc0) = o4.u2;
    }
}

// ---------------------------------------------------------------------------
// fused: combine split-K (nz, D=256) + bias + LayerNorm(g,b) [+silu] -> out
// ---------------------------------------------------------------------------
__global__ __launch_bounds__(256) void combln256_kernel(
    const float* __restrict__ P, size_t pstride, int nz,
    const float* __restrict__ bias,
    const float* __restrict__ g, const float* __restrict__ bv,
    int do_silu, int obf,
    void* __restrict__ out, int ldout)
{
    int row = blockIdx.x, d = threadIdx.x;
    __shared__ float red4[4];
    float v = P[(size_t)row*256 + d];
    for (int z = 1; z < nz; ++z) v += P[(size_t)z*pstride + (size_t)row*256 + d];
    v += bias[d];
    float mu = bsum256(v, red4, d) * (1.f/256.f);
    float dv = v - mu;
    float rstd = rsqrtf(bsum256(dv*dv, red4, d) * (1.f/256.f) + 1e-5f);
    float y = dv * rstd * g[d] + bv[d];
    if (do_silu) y = y / (1.f + __expf(-y));
    if (obf) ((__hip_bfloat16*)out)[(size_t)row * ldout + d] = __float2bfloat16(y);
    else     ((float*)out)[(size_t)row * ldout + d] = y;
}

// ---------------------------------------------------------------------------
// tin-chain fusion: combine split-K (nz, D=768) + bias ->
//   X = LN(t; g,b)  (write fp32) ; Hb = bf16( LN2(X)*(1+scm[b]) + shm[b] )
// ---------------------------------------------------------------------------
__global__ __launch_bounds__(256) void tinfuse_kernel(
    const float* __restrict__ P, size_t pstride, int nz,
    const float* __restrict__ bias,
    const float* __restrict__ g, const float* __restrict__ bb,
    const float* __restrict__ scm, const float* __restrict__ shm,
    float* __restrict__ X, __hip_bfloat16* __restrict__ Hb)
{
    int row = blockIdx.x, tid = threadIdx.x;
    int b = row >> 11;
    __shared__ float red4[4];
    float tv[3];
    float s = 0.f;
    #pragma unroll
    for (int q = 0; q < 3; ++q) {
        int d = tid + q*256;
        float v = P[(size_t)row*768 + d];
        for (int z = 1; z < nz; ++z) v += P[(size_t)z*pstride + (size_t)row*768 + d];
        v += bias[d];
        tv[q] = v; s += v;
    }
    float mu1 = bsum256(s, red4, tid) * (1.f/768.f);
    float s2 = 0.f;
    #pragma unroll
    for (int q = 0; q < 3; ++q) { float dv = tv[q] - mu1; s2 += dv*dv; }
    float rstd1 = rsqrtf(bsum256(s2, red4, tid) * (1.f/768.f) + 1e-5f);
    float xv[3];
    float s3 = 0.f;
    #pragma unroll
    for (int q = 0; q < 3; ++q) {
        int d = tid + q*256;
        float y = (tv[q] - mu1) * rstd1 * g[d] + bb[d];
        X[(size_t)row*768 + d] = y;
        xv[q] = y; s3 += y;
    }
    float mu2 = bsum256(s3, red4, tid) * (1.f/768.f);
    float s4 = 0.f;
    #pragma unroll
    for (int q = 0; q < 3; ++q) { float dv = xv[q] - mu2; s4 += dv*dv; }
    float rstd2 = rsqrtf(bsum256(s4, red4, tid) * (1.f/768.f) + 1e-5f);
    #pragma unroll
    for (int q = 0; q < 3; ++q) {
        int d = tid + q*256;
        float h = (xv[q] - mu2) * rstd2 * (1.f + scm[(size_t)b*4608 + d]) + shm[(size_t)b*4608 + d];
        Hb[(size_t)row*768 + d] = __float2bfloat16(h);
    }
}

// ---------------------------------------------------------------------------
// fused: combine split-K (nz) + bias + residual-gate into X, then
// Hb = bf16( LN(xnew)*(1+scm[b]) + shm[b] ).  block per row, D=768.
// ---------------------------------------------------------------------------
__global__ __launch_bounds__(256) void gcombln_kernel(
    const float* __restrict__ P, size_t pstride, int nz,
    const float* __restrict__ bias,
    float* __restrict__ X,
    const float* __restrict__ gate,
    const float* __restrict__ scm, const float* __restrict__ shm,
    __hip_bfloat16* __restrict__ Hb)
{
    int row = blockIdx.x, tid = threadIdx.x;
    int b = row >> 11;
    __shared__ float red4[4];
    float xv[3];
    float s = 0.f;
    #pragma unroll
    for (int q = 0; q < 3; ++q) {
        int d = tid + q*256;
        float v = P[(size_t)row*768 + d];
        for (int z = 1; z < nz; ++z) v += P[(size_t)z*pstride + (size_t)row*768 + d];
        v += bias[d];
        v = X[(size_t)row*768 + d] + gate[(size_t)b*4608 + d] * v;
        X[(size_t)row*768 + d] = v;
        xv[q] = v; s += v;
    }
    float mu = bsum256(s, red4, tid) * (1.f/768.f);
    float s2 = 0.f;
    #pragma unroll
    for (int q = 0; q < 3; ++q) { float dv = xv[q] - mu; s2 += dv*dv; }
    float rstd = rsqrtf(bsum256(s2, red4, tid) * (1.f/768.f) + 1e-5f);
    #pragma unroll
    for (int q = 0; q < 3; ++q) {
        int d = tid + q*256;
        float y = (xv[q] - mu) * rstd * (1.f + scm[(size_t)b*4608 + d]) + shm[(size_t)b*4608 + d];
        Hb[(size_t)row*768 + d] = __float2bfloat16(y);
    }
}

// ---------------------------------------------------------------------------
// c = LN(adaLN_emb @ ada_W + ada_b; g,b); c_silu = silu(c). 2 blocks.
// ---------------------------------------------------------------------------
__global__ __launch_bounds__(256) void ada_kernel(
    const float* __restrict__ emb, const float* __restrict__ W,
    const float* __restrict__ bias,
    const float* __restrict__ g, const float* __restrict__ bb,
    float* __restrict__ c, float* __restrict__ c_silu)
{
    int b = blockIdx.x, tid = threadIdx.x;
    __shared__ float emb_s[256];
    __shared__ float t[768];
    __shared__ float red[256];
    emb_s[tid] = emb[b*256 + tid];
    __syncthreads();
    for (int q = 0; q < 3; ++q) {
        int e = tid + q*256;
        float acc = bias[e];
        for (int k = 0; k < 256; ++k) acc += emb_s[k] * W[(size_t)k*768 + e];
        t[e] = acc;
    }
    __syncthreads();
    float s = 0.f; for (int q = 0; q < 3; ++q) s += t[tid + q*256];
    red[tid] = s; __syncthreads();
    for (int off = 128; off > 0; off >>= 1) { if (tid < off) red[tid] += red[tid+off]; __syncthreads(); }
    float mu = red[0] / 768.f; __syncthreads();
    float s2 = 0.f; for (int q = 0; q < 3; ++q) { float d = t[tid + q*256] - mu; s2 += d*d; }
    red[tid] = s2; __syncthreads();
    for (int off = 128; off > 0; off >>= 1) { if (tid < off) red[tid] += red[tid+off]; __syncthreads(); }
    float rstd = rsqrtf(red[0] / 768.f + 1e-5f);
    for (int q = 0; q < 3; ++q) {
        int e = tid + q*256;
        float y = (t[e] - mu) * rstd * g[e] + bb[e];
        c[b*768 + e] = y;
        c_silu[b*768 + e] = y / (1.f + expf(-y));
    }
}

// ---------------------------------------------------------------------------
// mod for BOTH layers, K-split 4: part[z][l][b][4608] ; grid (72, 4)
// ---------------------------------------------------------------------------
__global__ __launch_bounds__(256) void mod2_kernel(
    const float* __restrict__ c_silu, const float* __restrict__ mod_W,
    float* __restrict__ part)
{
    int idx = blockIdx.x * 256 + threadIdx.x;   // < 18432
    int z = blockIdx.y;
    int lyr = idx / 9216, b = (idx / 4608) & 1, j = idx % 4608;
    const float* Wl = mod_W + (size_t)lyr * 768 * 4608;
    const float* cs = c_silu + b * 768;
    float acc = 0.f;
    int k0 = z * 192;
    for (int k = k0; k < k0 + 192; ++k) acc += cs[k] * Wl[(size_t)k * 4608 + j];
    part[(size_t)z * 18432 + idx] = acc;
}

__global__ __launch_bounds__(256) void modc_kernel(
    const float* __restrict__ part, const float* __restrict__ mod_b,
    float* __restrict__ m2buf)
{
    int idx = blockIdx.x * 256 + threadIdx.x;
    int lyr = idx / 9216, j = idx % 4608;
    float acc = mod_b[(size_t)lyr * 4608 + j];
    #pragma unroll
    for (int z = 0; z < 4; ++z) acc += part[(size_t)z * 18432 + idx];
    m2buf[idx] = acc;
}

// ---------------------------------------------------------------------------
// MFMA local-window attention. 1 wave per (b, h, qblock of 32).
// ---------------------------------------------------------------------------
__global__ __launch_bounds__(64) void attn_mfma_kernel(
    const __hip_bfloat16* __restrict__ qkv,   // [B*N, 2304]
    const float* __restrict__ ropeC,          // [B*N, 32]
    const float* __restrict__ ropeS,
    __hip_bfloat16* __restrict__ o)           // [B*N, 768]
{
    int bid = blockIdx.x;
    int qb = bid & 63;
    int h  = (bid >> 6) % 12;
    int b  = bid / 768;
    int l  = threadIdx.x;
    int lr = l & 15, lg = l >> 4;
    int lo = max(0, 32*qb - 48);
    int hi = min(N_, 32*qb + 80);
    int wlen = hi - lo;

    __shared__ __hip_bfloat16 Vl[128 * 72];
    __shared__ __hip_bfloat16 Pl[32 * 144];

    {
        int vr0 = l >> 3;
        int c0  = (l & 7) * 8;
        #pragma unroll
        for (int it = 0; it < 16; ++it) {
            int vr = it*8 + vr0;
            int n = lo + vr;
            U8 v;
            if (n < hi) {
                v.v = *(const bf16x8*)(qkv + ((size_t)(b*N_ + n))*2304 + 1536 + h*64 + c0);
            } else {
                #pragma unroll
                for (int j = 0; j < 8; ++j) v.u[j] = 0;
            }
            *(bf16x8*)(Vl + vr*72 + c0) = v.v;
        }
    }

    bf16x8 aq0[2], aq1[2];
    #pragma unroll
    for (int i = 0; i < 2; ++i) {
        int n = qb*32 + i*16 + lr;
        const __hip_bfloat16* qrow = qkv + ((size_t)(b*N_ + n))*2304 + h*64;
        U8 xlo, xhi;
        xlo.v = *(const bf16x8*)(qrow + lg*8);
        xhi.v = *(const bf16x8*)(qrow + 32 + lg*8);
        const float* pc = ropeC + ((size_t)(b*N_ + n))*32 + lg*8;
        const float* ps = ropeS + ((size_t)(b*N_ + n))*32 + lg*8;
        float4 c0 = *(const float4*)(pc), c1 = *(const float4*)(pc + 4);
        float4 s0 = *(const float4*)(ps), s1 = *(const float4*)(ps + 4);
        float cv[8] = {c0.x,c0.y,c0.z,c0.w,c1.x,c1.y,c1.z,c1.w};
        float sv[8] = {s0.x,s0.y,s0.z,s0.w,s1.x,s1.y,s1.z,s1.w};
        U8 f0, f1;
        #pragma unroll
        for (int j = 0; j < 8; ++j) {
            float x1 = __bfloat162float(xlo.e[j]);
            float x2 = __bfloat162float(xhi.e[j]);
            f0.e[j] = __float2bfloat16(x1*cv[j] - x2*sv[j]);
            f1.e[j] = __float2bfloat16(x1*sv[j] + x2*cv[j]);
        }
        aq0[i] = f0.v; aq1[i] = f1.v;
    }

    f32x4 S[2][8];
    #pragma unroll
    for (int i = 0; i < 2; ++i)
        #pragma unroll
        for (int jt = 0; jt < 8; ++jt)
            S[i][jt] = f32x4{0.f, 0.f, 0.f, 0.f};

    #pragma unroll
    for (int jt = 0; jt < 8; ++jt) {
        int n = lo + jt*16 + lr;
        U8 f0, f1;
        if (n < hi) {
            const __hip_bfloat16* krow = qkv + ((size_t)(b*N_ + n))*2304 + 768 + h*64;
            U8 xlo, xhi;
            xlo.v = *(const bf16x8*)(krow + lg*8);
            xhi.v = *(const bf16x8*)(krow + 32 + lg*8);
            const float* pc = ropeC + ((size_t)(b*N_ + n))*32 + lg*8;
            const float* ps = ropeS + ((size_t)(b*N_ + n))*32 + lg*8;
            float4 c0 = *(const float4*)(pc), c1 = *(const float4*)(pc + 4);
            float4 s0 = *(const float4*)(ps), s1 = *(const float4*)(ps + 4);
            float cv[8] = {c0.x,c0.y,c0.z,c0.w,c1.x,c1.y,c1.z,c1.w};
            float sv[8] = {s0.x,s0.y,s0.z,s0.w,s1.x,s1.y,s1.z,s1.w};
            #pragma unroll
            for (int j = 0; j < 8; ++j) {
                float x1 = __bfloat162float(xlo.e[j]);
                float x2 = __bfloat162float(xhi.e[j]);
                f0.e[j] = __float2bfloat16(x1*cv[j] - x2*sv[j]);
                f1.e[j] = __float2bfloat16(x1*sv[j] + x2*cv[j]);
            }
        } else {
            #pragma unroll
            for (int j = 0; j < 8; ++j) { f0.u[j] = 0; f1.u[j] = 0; }
        }
        #pragma unroll
        for (int i = 0; i < 2; ++i) {
            S[i][jt] = __builtin_amdgcn_mfma_f32_16x16x32_bf16(aq0[i], f0.v, S[i][jt], 0, 0, 0);
            S[i][jt] = __builtin_amdgcn_mfma_f32_16x16x32_bf16(aq1[i], f1.v, S[i][jt], 0, 0, 0);
        }
    }

    #pragma unroll
    for (int jt = 0; jt < 8; ++jt) {
        bool oob = (jt*16 + lr) >= wlen;
        #pragma unroll
        for (int i = 0; i < 2; ++i)
            #pragma unroll
            for (int r = 0; r < 4; ++r)
                S[i][jt][r] = oob ? -1e30f : S[i][jt][r] * 0.125f;
    }

    float rinv[2][4];
    #pragma unroll
    for (int i = 0; i < 2; ++i) {
        #pragma unroll
        for (int r = 0; r < 4; ++r) {
            float m = -1e30f;
            #pragma unroll
            for (int jt = 0; jt < 8; ++jt) m = fmaxf(m, S[i][jt][r]);
            #pragma unroll
            for (int mask = 8; mask > 0; mask >>= 1) m = fmaxf(m, __shfl_xor(m, mask, 16));
            float sum = 0.f;
            #pragma unroll
            for (int jt = 0; jt < 8; ++jt) {
                float e = __expf(S[i][jt][r] - m);
                S[i][jt][r] = e;
                sum += e;
            }
            #pragma unroll
            for (int mask = 8; mask > 0; mask >>= 1) sum += __shfl_xor(sum, mask, 16);
            rinv[i][r] = 1.f / sum;
        }
    }

    #pragma unroll
    for (int i = 0; i < 2; ++i)
        #pragma unroll
        for (int jt = 0; jt < 8; ++jt)
            #pragma unroll
            for (int r = 0; r < 4; ++r) {
                int row = i*16 + lg*4 + r;
                int colp = (jt*16 + lr) ^ (lg << 3);
                Pl[row*144 + colp] = __float2bfloat16(S[i][jt][r]);
            }

    __syncthreads();

    f32x4 O_[2][4];
    #pragma unroll
    for (int i = 0; i < 2; ++i)
        #pragma unroll
        for (int ct = 0; ct < 4; ++ct)
            O_[i][ct] = f32x4{0.f, 0.f, 0.f, 0.f};

    int key = (lr >> 2) & 3;
    #pragma unroll
    for (int kt = 0; kt < 4; ++kt) {
        bf16x8 pa[2];
        #pragma unroll
        for (int i = 0; i < 2; ++i) {
            int row = i*16 + lr;
            int colp = (kt*32 + lg*8) ^ (key << 3);
            pa[i] = *(bf16x8*)(Pl + row*144 + colp);
        }
        #pragma unroll
        for (int ct = 0; ct < 4; ++ct) {
            U8 bv;
            #pragma unroll
            for (int j = 0; j < 8; ++j)
                bv.e[j] = Vl[(kt*32 + lg*8 + j)*72 + ct*16 + lr];
            O_[0][ct] = __builtin_amdgcn_mfma_f32_16x16x32_bf16(pa[0], bv.v, O_[0][ct], 0, 0, 0);
            O_[1][ct] = __builtin_amdgcn_mfma_f32_16x16x32_bf16(pa[1], bv.v, O_[1][ct], 0, 0, 0);
        }
    }

    #pragma unroll
    for (int i = 0; i < 2; ++i)
        #pragma unroll
        for (int ct = 0; ct < 4; ++ct)
            #pragma unroll
            for (int r = 0; r < 4; ++r) {
                int row = qb*32 + i*16 + lg*4 + r;
                o[((size_t)(b*N_ + row))*768 + h*64 + ct*16 + lr] =
                    __float2bfloat16(O_[i][ct][r] * rinv[i][r]);
            }
}

// ---------------------------------------------------------------------------
// a2t [B,N,NR] fp32 -> a2tTb [B,NR,N] bf16   grid (NR/32, N/32, B)
// ---------------------------------------------------------------------------
__global__ __launch_bounds__(256) void a2t_transpose_kernel(
    const float* __restrict__ a2t, __hip_bfloat16* __restrict__ a2tTb)
{
    __shared__ float t[32][33];
    int r0 = blockIdx.x * 32, n0 = blockIdx.y * 32, b = blockIdx.z;
    int tid = threadIdx.x;
    int tx = tid & 31, ty = tid >> 5;
    #pragma unroll
    for (int i = 0; i < 4; ++i) {
        int row = ty + i*8;
        t[row][tx] = a2t[((size_t)b*N_ + n0 + row) * 256 + r0 + tx];
    }
    __syncthreads();
    #pragma unroll
    for (int i = 0; i < 4; ++i) {
        int row = ty + i*8;
        a2tTb[((size_t)b*256 + r0 + row) * N_ + n0 + tx] = __float2bfloat16(t[tx][row]);
    }
}

// ---------------------------------------------------------------------------
// recip[row] = 1/(sum of a2tTb row + 1e-6).  block per row (512 rows).
// ---------------------------------------------------------------------------
__global__ __launch_bounds__(256) void rowrecip_kernel(
    const __hip_bfloat16* __restrict__ a2tTb, float* __restrict__ recip)
{
    int row = blockIdx.x;
    int tid = threadIdx.x;
    __shared__ float red4[4];
    U8 v; v.v = *(const bf16x8*)(a2tTb + (size_t)row*2048 + tid*8);
    float s = 0.f;
    #pragma unroll
    for (int j = 0; j < 8; ++j) s += __bfloat162float(v.e[j]);
    float tot = bsum256(s, red4, tid);
    if (tid == 0) recip[row] = 1.f / (tot + 1e-6f);
}

// ---------------------------------------------------------------------------
extern "C" void kernel_launch(void* const* d_in, const int* in_sizes, int n_in,
                              void* d_out, int out_size, void* d_ws, size_t ws_size,
                              hipStream_t stream) {
    const float* atom_coords  = (const float*)d_in[0];
    const float* ref_pos      = (const float*)d_in[1];
    const int*   res_id       = (const int*)  d_in[2];
    const float* res_type     = (const float*)d_in[3];
    const float* charge       = (const float*)d_in[4];
    const float* atomic_num   = (const float*)d_in[5];
    const float* atom_name    = (const float*)d_in[6];
    const float* adaLN_emb    = (const float*)d_in[7];
    const int*   rope_pos     = (const int*)  d_in[8];
    const float* atom_to_tok  = (const float*)d_in[9];
    const float* feat_W       = (const float*)d_in[10];
    const float* feat_b       = (const float*)d_in[11];
    const float* feat_ln_g    = (const float*)d_in[12];
    const float* feat_ln_b    = (const float*)d_in[13];
    const float* pos_W        = (const float*)d_in[14];
    const float* in_W         = (const float*)d_in[15];
    const float* tin_W        = (const float*)d_in[16];
    const float* tin_b        = (const float*)d_in[17];
    const float* tin_ln_g     = (const float*)d_in[18];
    const float* tin_ln_b     = (const float*)d_in[19];
    const float* ada_W        = (const float*)d_in[20];
    const float* ada_b        = (const float*)d_in[21];
    const float* ada_ln_g     = (const float*)d_in[22];
    const float* ada_ln_b     = (const float*)d_in[23];
    const float* blk_mod_W    = (const float*)d_in[24];
    const float* blk_mod_b    = (const float*)d_in[25];
    const float* blk_qkv_W    = (const float*)d_in[26];
    const float* blk_qkv_b    = (const float*)d_in[27];
    const float* blk_o_W      = (const float*)d_in[28];
    const float* blk_o_b      = (const float*)d_in[29];
    const float* blk_m1_W     = (const float*)d_in[30];
    const float* blk_m1_b     = (const float*)d_in[31];
    const float* blk_m2_W     = (const float*)d_in[32];
    const float* blk_m2_b     = (const float*)d_in[33];
    const float* tout_W       = (const float*)d_in[34];
    const float* tout_b       = (const float*)d_in[35];
    const float* tout_ln_g    = (const float*)d_in[36];
    const float* tout_ln_b    = (const float*)d_in[37];

    const int BN = B_ * N_;                          // 4096
    float* ws = (float*)d_ws;

    // layout (float units)
    const size_t OFF_X    = 0;                                // fp32 [4096][768]
    const size_t OFF_HB   = OFF_X    + (size_t)BN*768;        // bf16 [4096][768]
    const size_t OFF_QKVB = OFF_HB   + (size_t)BN*768/2;      // bf16 [4096][2304]
    const size_t OFF_OB   = OFF_QKVB + (size_t)BN*2304/2;     // bf16 [4096][768]
    const size_t OFF_UB   = OFF_OB   + (size_t)BN*768/2;      // bf16 [4096][3072]
    const size_t OFF_WT   = OFF_UB   + (size_t)BN*3072/2;     // bf16 up to 3072*768
    const size_t OFF_RC   = OFF_WT   + (size_t)3072*768/2;    // fp32 BN*32
    const size_t OFF_RS   = OFF_RC   + (size_t)BN*32;
    const size_t OFF_SM   = OFF_RS   + (size_t)BN*32;

    float* X = ws + OFF_X;
    __hip_bfloat16* Hb   = (__hip_bfloat16*)(ws + OFF_HB);
    __hip_bfloat16* QKVb = (__hip_bfloat16*)(ws + OFF_QKVB);
    __hip_bfloat16* Ob   = (__hip_bfloat16*)(ws + OFF_OB);
    __hip_bfloat16* Ub   = (__hip_bfloat16*)(ws + OFF_UB);
    __hip_bfloat16* WT   = (__hip_bfloat16*)(ws + OFF_WT);
    float* ropeC  = ws + OFF_RC;
    float* ropeS  = ws + OFF_RS;
    float* cbuf   = ws + OFF_SM;                     // 1536
    float* c_silu = cbuf + 1536;                     // 1536
    float* mbuf2  = c_silu + 1536;                   // 18432  [2][2][4608]
    float* modpart= mbuf2 + 18432;                   // 73728

    // phase-A aliases
    __hip_bfloat16* featsB  = QKVb;                           // [4096][1024] bf16
    __hip_bfloat16* coordsB = QKVb + (size_t)BN*1024;         // [4096][512] bf16
    float* t1               = ws + OFF_UB;                    // scratch
    __hip_bfloat16* concatB = (__hip_bfloat16*)(t1 + (size_t)BN*256);  // [4096][512] bf16
    __hip_bfloat16* atom_inB= Ob;                             // [4096][256] bf16

    // residue-phase aliases (Ob/Ub regions dead by then)
    __hip_bfloat16* a2tTb   = Ob;                             // [2][256][2048] bf16
    __hip_bfloat16* latTb   = Ob + (size_t)2*256*2048;        // [2][256][2048] bf16
    float* recip            = modpart;                        // 512 fp32

    // split-K partial buffers (aliases of dead regions)
    float* P_pa   = ws + OFF_X;       // phase A (feat/pos/in)
    float* P_tin  = ws + OFF_UB;
    float* P_o    = ws + OFF_UB;
    float* P_m2   = ws + OFF_QKVB;
    float* P_tout = ws + OFF_UB;
    float* P_res  = ws + OFF_UB;

    float* out_res = (float*)d_out;                           // B*NR*DA
    float* out_lat = out_res + (size_t)B_*NR_*DA_;            // B*N*DA

    // ---- adaLN + modulation for both layers (input-only; run first) ----
    ada_kernel<<<2, 256, 0, stream>>>(adaLN_emb, ada_W, ada_b, ada_ln_g, ada_ln_b,
        cbuf, c_silu);
    mod2_kernel<<<dim3(72, 4), 256, 0, stream>>>(c_silu, blk_mod_W, modpart);
    modc_kernel<<<72, 256, 0, stream>>>(modpart, blk_mod_b, mbuf2);

    // ---- featurization (bf16) + rope table (fused) ----
    build_feats_kernel<<<BN, 128, 0, stream>>>(atom_coords, ref_pos, res_id,
        res_type, charge, atomic_num, atom_name, rope_pos, featsB, coordsB,
        ropeC, ropeS);

    // t1 = feats @ feat_W + feat_b   (K padded 924->1024, split 4)
    transconv_kernel<<<dim3(8, 32), 256, 0, stream>>>(feat_W, WT, 924, 1024, 256, 0, 0);
    gemm_bf16_kernel<<<dim3(2, 32, 4), 256, 0, stream>>>(featsB, 1024, WT, 1024, nullptr,
        nullptr, 0, 1024, 0, 0, nullptr, 0, nullptr, 0, P_pa, 32, 0, 0);
    combln256_kernel<<<BN, 256, 0, stream>>>(P_pa, (size_t)BN*256, 4, feat_b,
        feat_ln_g, feat_ln_b, 1, 1, concatB, 512);
    // concat[:,256:512] = coordsF @ pos_W  (K 387->512, split 4)
    transconv_kernel<<<dim3(8, 16), 256, 0, stream>>>(pos_W, WT, 387, 512, 256, 0, 0);
    gemm_bf16_kernel<<<dim3(2, 32, 4), 256, 0, stream>>>(coordsB, 512, WT, 512, nullptr,
        nullptr, 0, 512, 0, 0, nullptr, 0, nullptr, 0, P_pa, 32, 0, 0);
    gcomb_kernel<<<1024, 256, 0, stream>>>(P_pa, (size_t)BN*256, 4, 256, nullptr,
        concatB + 256, 512, 0, 1, nullptr, 0, nullptr, 0, nullptr, 0);
    // atom_in = concat @ in_W -> bf16 (split 4)
    transconv_kernel<<<dim3(8, 16), 256, 0, stream>>>(in_W, WT, 512, 512, 256, 0, 0);
    gemm_bf16_kernel<<<dim3(2, 32, 4), 256, 0, stream>>>(concatB, 512, WT, 512, nullptr,
        nullptr, 0, 512, 0, 0, nullptr, 0, nullptr, 0, P_pa, 32, 0, 0);
    gcomb_kernel<<<1024, 256, 0, stream>>>(P_pa, (size_t)BN*256, 4, 256, nullptr,
        atom_inB, 256, 0, 1, nullptr, 0, nullptr, 0, nullptr, 0);
    // X = LN(atom_in @ tin_W + tin_b) ; Hb = LN(X)*(1+sc1)+sh1  (fused)
    transconv_kernel<<<dim3(24, 8), 256, 0, stream>>>(tin_W, WT, 256, 256, 768, 0, 0);
    gemm_bf16_kernel<<<dim3(6, 32, 2), 256, 0, stream>>>(atom_inB, 256, WT, 256, nullptr,
        nullptr, 0, 256, 0, 0, nullptr, 0, nullptr, 0, P_tin, 32, 0, 0);
    tinfuse_kernel<<<BN, 256, 0, stream>>>(P_tin, (size_t)BN*768, 2, tin_b,
        tin_ln_g, tin_ln_b, mbuf2 + 768, mbuf2 + 0, X, Hb);

    for (int l = 0; l < NB_; ++l) {
        const float* qkvW = blk_qkv_W + (size_t)l*768*2304;
        const float* qkvB = blk_qkv_b + (size_t)l*2304;
        const float* oW   = blk_o_W   + (size_t)l*768*768;
        const float* oB   = blk_o_b   + (size_t)l*768;
        const float* m1W  = blk_m1_W  + (size_t)l*768*3072;
        const float* m1B  = blk_m1_b  + (size_t)l*3072;
        const float* m2W  = blk_m2_W  + (size_t)l*3072*768;
        const float* m2B  = blk_m2_b  + (size_t)l*768;

        float* mptr = mbuf2 + (size_t)l*9216;        // [b][4608]
        float* sh2 = mptr + 2304, *sc2 = mptr + 3072;
        float* g1  = mptr + 1536, *g2 = mptr + 3840;

        // qkv = h @ qkv_W + b -> bf16
        transconv_kernel<<<dim3(72, 24), 256, 0, stream>>>(qkvW, WT, 768, 768, 2304, 0, 0);
        gemm_bf16_kernel<<<dim3(18, 32, 1), 256, 0, stream>>>(Hb, 768, WT, 768, qkvB,
            QKVb, 2304, 768, 0, 1, nullptr, 0, nullptr, 0, nullptr, 32, 0, 0);
        // attention
        attn_mfma_kernel<<<B_*H_*64, 64, 0, stream>>>(QKVb, ropeC, ropeS, Ob);
        // x = x + g1*(o @ o_W + o_b)  (split 2) ; fused -> Hb = h2
        transconv_kernel<<<dim3(24, 24), 256, 0, stream>>>(oW, WT, 768, 768, 768, 0, 0);
        gemm_bf16_kernel<<<dim3(6, 32, 2), 256, 0, stream>>>(Ob, 768, WT, 768, nullptr,
            nullptr, 0, 768, 0, 0, nullptr, 0, nullptr, 0, P_o, 32, 0, 0);
        gcombln_kernel<<<BN, 256, 0, stream>>>(P_o, (size_t)BN*768, 2, oB,
            X, g1, sc2, sh2, Hb);
        // u = gelu(h2 @ m1_W + b) -> bf16
        transconv_kernel<<<dim3(96, 24), 256, 0, stream>>>(m1W, WT, 768, 768, 3072, 0, 0);
        gemm_bf16_kernel<<<dim3(24, 32, 1), 256, 0, stream>>>(Hb, 768, WT, 768, m1B,
            Ub, 3072, 768, 1, 1, nullptr, 0, nullptr, 0, nullptr, 32, 0, 0);
        // x = x + g2*(u @ m2_W + b)  (split 2)
        transconv_kernel<<<dim3(24, 96), 256, 0, stream>>>(m2W, WT, 3072, 3072, 768, 0, 0);
        gemm_bf16_kernel<<<dim3(6, 32, 2), 256, 0, stream>>>(Ub, 3072, WT, 3072, nullptr,
            nullptr, 0, 3072, 0, 0, nullptr, 0, nullptr, 0, P_m2, 32, 0, 0);
        if (l < NB_ - 1) {
            float* mnext = mbuf2 + (size_t)(l+1)*9216;
            gcombln_kernel<<<BN, 256, 0, stream>>>(P_m2, (size_t)BN*768, 2, m2B,
                X, g2, mnext + 768, mnext + 0, Hb);
        } else {
            // final layer: X is dead afterward -> write Hb (bf16) directly
            gcomb_kernel<<<3072, 256, 0, stream>>>(P_m2, (size_t)BN*768, 2, 768, m2B,
                Hb, 768, 2, 1, X, 768, g2, 4608, nullptr, 0);
        }
    }

    // atom_latent = LN(x @ tout_W + tout_b)  (split 4, fused combine+LN)
    transconv_kernel<<<dim3(8, 24), 256, 0, stream>>>(tout_W, WT, 768, 768, 256, 0, 0);
    gemm_bf16_kernel<<<dim3(2, 32, 4), 256, 0, stream>>>(Hb, 768, WT, 768, nullptr,
        nullptr, 0, 768, 0, 0, nullptr, 0, nullptr, 0, P_tout, 32, 0, 0);
    combln256_kernel<<<BN, 256, 0, stream>>>(P_tout, (size_t)BN*256, 4, tout_b,
        tout_ln_g, tout_ln_b, 0, 0, out_lat, 256);

    // ---- residue pooling as MFMA GEMM ----
    a2t_transpose_kernel<<<dim3(8, 64, 2), 256, 0, stream>>>(atom_to_tok, a2tTb);
    rowrecip_kernel<<<512, 256, 0, stream>>>(a2tTb, recip);
    transconv_kernel<<<dim3(8, 64, 2), 256, 0, stream>>>(out_lat, latTb, 2048, 2048, 256,
        (size_t)2048*256, (size_t)256*2048);
    gemm_bf16_kernel<<<dim3(2, 4, 8), 256, 0, stream>>>(a2tTb, 2048, latTb, 2048, nullptr,
        nullptr, 0, 2048, 0, 0, nullptr, 0, nullptr, 0, P_res,
        2, (size_t)256*2048, (size_t)256*2048);
    gcomb_kernel<<<128, 256, 0, stream>>>(P_res, (size_t)512*256, 8, 256, nullptr,
        out_res, 256, 3, 0, nullptr, 0, recip, 0, nullptr, 0);
}

// Round 14
// 560.005 us; speedup vs baseline: 1.7071x; 1.0548x over previous
//
#include <hip/hip_runtime.h>
#include <hip/hip_bf16.h>
#include <math.h>

// Problem constants
#define B_ 2
#define N_ 2048
#define NR_ 256
#define DA_ 256
#define E_ 768
#define H_ 12
#define DH_ 64
#define NB_ 2

typedef __attribute__((ext_vector_type(8))) __bf16 bf16x8;
typedef __attribute__((ext_vector_type(4))) float f32x4;

union U8 { bf16x8 v; __hip_bfloat16 e[8]; unsigned short u[8]; };
union U4 { __hip_bfloat16 e[4]; uint2 u2; };

__device__ __forceinline__ void gload16(const void* g, void* l) {
    __builtin_amdgcn_global_load_lds(
        (const __attribute__((address_space(1))) void*)g,
        (__attribute__((address_space(3))) void*)l, 16, 0, 0);
}

// 256-thread block sum: wave shuffle + 4-slot LDS combine (2 barriers).
__device__ __forceinline__ float bsum256(float v, float* red4, int tid) {
    #pragma unroll
    for (int m = 32; m > 0; m >>= 1) v += __shfl_xor(v, m, 64);
    __syncthreads();
    if ((tid & 63) == 0) red4[tid >> 6] = v;
    __syncthreads();
    return red4[0] + red4[1] + red4[2] + red4[3];
}

// ---------------------------------------------------------------------------
// build feats[B*N, 1024] (bf16) and coordsF[B*N, 512] (bf16) + rope tables
// ---------------------------------------------------------------------------
__global__ __launch_bounds__(128) void build_feats_kernel(
    const float* __restrict__ atom_coords, const float* __restrict__ ref_pos,
    const int* __restrict__ res_id, const float* __restrict__ res_type,
    const float* __restrict__ charge, const float* __restrict__ atomic_number,
    const float* __restrict__ atom_name, const int* __restrict__ rope_pos,
    __hip_bfloat16* __restrict__ feats, __hip_bfloat16* __restrict__ coordsF,
    float* __restrict__ ropeC, float* __restrict__ ropeS)
{
    int a = blockIdx.x;            // atom index over B*N
    int tid = threadIdx.x;
    __hip_bfloat16* f  = feats   + (size_t)a * 1024;
    __hip_bfloat16* cf = coordsF + (size_t)a * 512;

    float rp[3], cc[3];
    #pragma unroll
    for (int i = 0; i < 3; ++i) { rp[i] = ref_pos[(size_t)a*3 + i]; cc[i] = atom_coords[(size_t)a*3 + i]; }

    if (tid < 3) { f[tid] = __float2bfloat16(rp[tid]); cf[tid] = __float2bfloat16(cc[tid]); }

    if (tid >= 64 && tid < 96) {
        int dd = tid - 64;
        float rpos = (float)rope_pos[a];
        float ang = rpos * expf(-0.28782313662425574f * (float)dd);  // ln(1e4)/32
        float sn, cs; sincosf(ang, &sn, &cs);
        ropeC[a*32 + dd] = cs; ropeS[a*32 + dd] = sn;
    }

    for (int s = tid; s < 192; s += 128) {
        int fi = s / 3, ci = s % 3;
        float freq = exp2f(12.f * (float)fi / 63.f);
        float ar = rp[ci] * freq;
        float ac = cc[ci] * freq;
        float snr, csr, snc, csc_;
        sincosf(ar, &snr, &csr);
        sincosf(ac, &snc, &csc_);
        f[3 + s]    = __float2bfloat16(snr);  f[195 + s]  = __float2bfloat16(csr);
        cf[3 + s]   = __float2bfloat16(snc);  cf[195 + s] = __float2bfloat16(csc_);
    }
    if (tid < 23) f[387 + tid] = __float2bfloat16(res_type[(size_t)a*23 + tid]);

    float pos = (float)res_id[a];
    if (tid == 0) f[410] = __float2bfloat16(pos);
    if (tid < 64) {
        float div = expf(-9.210340371976184f / 128.f * (float)(2 * tid));
        float ang = pos * div;
        float sn, cs; sincosf(ang, &sn, &cs);
        f[411 + tid] = __float2bfloat16(sn);
        f[475 + tid] = __float2bfloat16(cs);
    }
    if (tid == 0) f[539] = __float2bfloat16(charge[a]);
    if (tid < 128) f[540 + tid] = __float2bfloat16(atomic_number[(size_t)a*128 + tid]);
    for (int s = tid; s < 256; s += 128) f[668 + s] = __float2bfloat16(atom_name[(size_t)a*256 + s]);
    if (tid < 100) f[924 + tid] = __float2bfloat16(0.f);
    if (tid < 125) cf[387 + tid] = __float2bfloat16(0.f);
}

// ---------------------------------------------------------------------------
// Transpose + fp32->bf16 + K-pad: W[Ksrc][Nn] -> WT[Nn][Kdst], zeros k>=Ksrc
// ---------------------------------------------------------------------------
__global__ __launch_bounds__(256) void transconv_kernel(
    const float* __restrict__ W, __hip_bfloat16* __restrict__ WT,
    int Ksrc, int Kdst, int Nn, size_t wstride, size_t tstride)
{
    __shared__ float t[32][33];
    W  += (size_t)blockIdx.z * wstride;
    WT += (size_t)blockIdx.z * tstride;
    int n0 = blockIdx.x * 32, k0 = blockIdx.y * 32;
    int tid = threadIdx.x;
    int tx = tid & 31, ty = tid >> 5;           // ty 0..7
    #pragma unroll
    for (int i = 0; i < 4; ++i) {
        int k = k0 + ty + i*8;
        t[ty + i*8][tx] = (k < Ksrc) ? W[(size_t)k * Nn + n0 + tx] : 0.f;
    }
    __syncthreads();
    #pragma unroll
    for (int i = 0; i < 4; ++i) {
        int row = ty + i*8;                      // n within tile
        WT[(size_t)(n0 + row) * Kdst + k0 + tx] = __float2bfloat16(t[tx][row]);
    }
}

// ---------------------------------------------------------------------------
// shared epilogue.  mode 0 none; 1 gelu; 2 X + gate[b][col]*v; 3 v*gate[row]
// ---------------------------------------------------------------------------
__device__ __forceinline__ float epi_apply(float v, int grow, int gcol,
    const float* bias, int mode, const float* X, int ldx,
    const float* gate, int gstride)
{
    if (bias) v += bias[gcol];
    if (mode == 1) {
        float u = 1.5957691216057308f * (v + 0.044715f * v * v * v);
        v = v / (1.f + __expf(-u));
    } else if (mode == 2) {
        int b = grow >> 11;                      // /N_
        v = X[(size_t)grow * ldx + gcol] + gate[(size_t)b * gstride + gcol] * v;
    } else if (mode == 3) {
        v = v * gate[grow];
    }
    return v;
}

// ---------------------------------------------------------------------------
// bf16 MFMA GEMM: tile 128x128, BK=32, **8 waves (512 thr), 64x32 per wave**.
// dbuf-2 LDS (32 KB -> up to 4 blocks/CU = 32 waves/CU): barrier -> issue
// STAGE(next) -> ds_read+MFMA(current).  (round-6-proven data path, only the
// wave decomposition changed: more TLP, less work per wave.)
// XOR-swizzle both sides: key(row)=(row>>1)&3.  Bijective XCD swizzle.
// gridDim.z = nz splits K; nz>1 -> raw fp32 partials to P.
// ---------------------------------------------------------------------------
__global__ __launch_bounds__(512) void gemm_bf16_kernel(
    const __hip_bfloat16* __restrict__ A, int lda,
    const __hip_bfloat16* __restrict__ BT, int ldb,
    const float* __restrict__ bias,
    void* __restrict__ C, int ldc,
    int K, int mode, int obf,
    const float* __restrict__ X, int ldx,
    const float* __restrict__ gate, int gstride,
    float* __restrict__ P,
    int mtiles, size_t bstrideA, size_t bstrideB)
{
    __shared__ __hip_bfloat16 As[2][128 * 32];
    __shared__ __hip_bfloat16 Bs[2][128 * 32];

    int gx = gridDim.x;
    int nwg = gx * gridDim.y;
    int fo = blockIdx.y * gx + blockIdx.x;
    int ft = (fo & 7) * (nwg >> 3) + (fo >> 3);
    int bx = ft % gx, by = ft / gx;

    int bb  = by / mtiles;
    int m0l = (by % mtiles) * 128;
    int m0g = by * 128;
    int n0 = bx * 128;
    const __hip_bfloat16* Ab  = A  + (size_t)bb * bstrideA;
    const __hip_bfloat16* BTb = BT + (size_t)bb * bstrideB;
    int nz = gridDim.z;
    int Kh = K / nz;
    int kb = blockIdx.z * Kh;
    int tid = threadIdx.x;
    int w = tid >> 6, l = tid & 63;
    int wr = (w >> 2) * 64, wc = (w & 3) * 32;   // 2 wave-rows x 4 wave-cols
    int lr = l & 15, lg = l >> 4;
    int slot = ((lg ^ ((lr >> 1) & 3)) & 3) * 8;

    // staging: exactly 1 seg per thread per operand (512 segs = 128 rows x 4)
    int seg  = tid;
    int rowS = seg >> 2;
    int gS   = (seg & 3) ^ ((rowS >> 1) & 3);

    f32x4 acc[4][2];
    #pragma unroll
    for (int i = 0; i < 4; ++i)
        #pragma unroll
        for (int j = 0; j < 2; ++j)
            acc[i][j] = f32x4{0.f, 0.f, 0.f, 0.f};

    // prologue: stage first tile into buf 0
    gload16(Ab  + (size_t)(m0l + rowS) * lda + kb + gS * 8, (char*)As[0] + seg * 16);
    gload16(BTb + (size_t)(n0 + rowS) * ldb + kb + gS * 8, (char*)Bs[0] + seg * 16);

    int cur = 0;
    for (int k0 = kb; k0 < kb + Kh; k0 += 32) {
        __syncthreads();                         // vmcnt(0): buf[cur] ready
        int kn = k0 + 32;
        if (kn < kb + Kh) {
            int nb = cur ^ 1;
            gload16(Ab  + (size_t)(m0l + rowS) * lda + kn + gS * 8, (char*)As[nb] + seg * 16);
            gload16(BTb + (size_t)(n0 + rowS) * ldb + kn + gS * 8, (char*)Bs[nb] + seg * 16);
        }
        bf16x8 af[4], bfr[2];
        #pragma unroll
        for (int i = 0; i < 4; ++i)
            af[i]  = *(bf16x8*)(As[cur] + (wr + i*16 + lr) * 32 + slot);
        #pragma unroll
        for (int j = 0; j < 2; ++j)
            bfr[j] = *(bf16x8*)(Bs[cur] + (wc + j*16 + lr) * 32 + slot);
        #pragma unroll
        for (int i = 0; i < 4; ++i)
            #pragma unroll
            for (int j = 0; j < 2; ++j)
                acc[i][j] = __builtin_amdgcn_mfma_f32_16x16x32_bf16(af[i], bfr[j], acc[i][j], 0, 0, 0);
        cur ^= 1;
    }

    if (nz > 1) {
        int Nw = gridDim.x * 128;
        size_t pstride = (size_t)Nw * (gridDim.y * 128);
        float* Pz = P + (size_t)blockIdx.z * pstride;
        #pragma unroll
        for (int i = 0; i < 4; ++i)
            #pragma unroll
            for (int j = 0; j < 2; ++j)
                #pragma unroll
                for (int r = 0; r < 4; ++r) {
                    int grow = m0g + wr + i*16 + lg*4 + r;
                    int gcol = n0 + wc + j*16 + lr;
                    Pz[(size_t)grow * Nw + gcol] = acc[i][j][r];
                }
        return;
    }

    #pragma unroll
    for (int i = 0; i < 4; ++i)
        #pragma unroll
        for (int j = 0; j < 2; ++j)
            #pragma unroll
            for (int r = 0; r < 4; ++r) {
                int grow = m0g + wr + i*16 + lg*4 + r;
                int gcol = n0 + wc + j*16 + lr;
                float v = epi_apply(acc[i][j][r], grow, gcol, bias, mode, X, ldx, gate, gstride);
                if (obf)
                    ((__hip_bfloat16*)C)[(size_t)grow * ldc + gcol] = __float2bfloat16(v);
                else
                    ((float*)C)[(size_t)grow * ldc + gcol] = v;
            }
}

// ---------------------------------------------------------------------------
// combine split-K partials + epilogue. 4 elems/thread. optional C2 bf16 out.
// ---------------------------------------------------------------------------
__global__ __launch_bounds__(256) void gcomb_kernel(
    const float* __restrict__ P, size_t pstride, int nz, int Nw,
    const float* __restrict__ bias,
    void* __restrict__ C, int ldc, int mode, int obf,
    const float* __restrict__ X, int ldx,
    const float* __restrict__ gate, int gstride,
    __hip_bfloat16* __restrict__ C2, int ldc2)
{
    int idx = blockIdx.x * 256 + threadIdx.x;
    int e0 = idx * 4;
    int grow = e0 / Nw, gc0 = e0 % Nw;
    float4 v = *(const float4*)(P + (size_t)grow * Nw + gc0);
    for (int z = 1; z < nz; ++z) {
        float4 t = *(const float4*)(P + (size_t)z * pstride + (size_t)grow * Nw + gc0);
        v.x += t.x; v.y += t.y; v.z += t.z; v.w += t.w;
    }
    float e[4] = {v.x, v.y, v.z, v.w};
    #pragma unroll
    for (int r = 0; r < 4; ++r)
        e[r] = epi_apply(e[r], grow, gc0 + r, bias, mode, X, ldx, gate, gstride);
    if (obf) {
        U4 o4;
        #pragma unroll
        for (int r = 0; r < 4; ++r) o4.e[r] = __float2bfloat16(e[r]);
        *(uint2*)((__hip_bfloat16*)C + (size_t)grow * ldc + gc0) = o4.u2;
    } else {
        *(float4*)((float*)C + (size_t)grow * ldc + gc0) = make_float4(e[0], e[1], e[2], e[3]);
    }
    if (C2) {
        U4 o4;
        #pragma unroll
        for (int r = 0; r < 4; ++r) o4.e[r] = __float2bfloat16(e[r]);
        *(uint2*)(C2 + (size_t)grow * ldc2 + gc0) = o4.u2;
    }
}

// ---------------------------------------------------------------------------
// fused: combine split-K (nz, D=256) + bias + LayerNorm(g,b) [+silu] -> out
// ---------------------------------------------------------------------------
__global__ __launch_bounds__(256) void combln256_kernel(
    const float* __restrict__ P, size_t pstride, int nz,
    const float* __restrict__ bias,
    const float* __restrict__ g, const float* __restrict__ bv,
    int do_silu, int obf,
    void* __restrict__ out, int ldout)
{
    int row = blockIdx.x, d = threadIdx.x;
    __shared__ float red4[4];
    float v = P[(size_t)row*256 + d];
    for (int z = 1; z < nz; ++z) v += P[(size_t)z*pstride + (size_t)row*256 + d];
    v += bias[d];
    float mu = bsum256(v, red4, d) * (1.f/256.f);
    float dv = v - mu;
    float rstd = rsqrtf(bsum256(dv*dv, red4, d) * (1.f/256.f) + 1e-5f);
    float y = dv * rstd * g[d] + bv[d];
    if (do_silu) y = y / (1.f + __expf(-y));
    if (obf) ((__hip_bfloat16*)out)[(size_t)row * ldout + d] = __float2bfloat16(y);
    else     ((float*)out)[(size_t)row * ldout + d] = y;
}

// ---------------------------------------------------------------------------
// tin-chain fusion: combine split-K (nz, D=768) + bias ->
//   X = LN(t; g,b)  (write fp32) ; Hb = bf16( LN2(X)*(1+scm[b]) + shm[b] )
// ---------------------------------------------------------------------------
__global__ __launch_bounds__(256) void tinfuse_kernel(
    const float* __restrict__ P, size_t pstride, int nz,
    const float* __restrict__ bias,
    const float* __restrict__ g, const float* __restrict__ bb,
    const float* __restrict__ scm, const float* __restrict__ shm,
    float* __restrict__ X, __hip_bfloat16* __restrict__ Hb)
{
    int row = blockIdx.x, tid = threadIdx.x;
    int b = row >> 11;
    __shared__ float red4[4];
    float tv[3];
    float s = 0.f;
    #pragma unroll
    for (int q = 0; q < 3; ++q) {
        int d = tid + q*256;
        float v = P[(size_t)row*768 + d];
        for (int z = 1; z < nz; ++z) v += P[(size_t)z*pstride + (size_t)row*768 + d];
        v += bias[d];
        tv[q] = v; s += v;
    }
    float mu1 = bsum256(s, red4, tid) * (1.f/768.f);
    float s2 = 0.f;
    #pragma unroll
    for (int q = 0; q < 3; ++q) { float dv = tv[q] - mu1; s2 += dv*dv; }
    float rstd1 = rsqrtf(bsum256(s2, red4, tid) * (1.f/768.f) + 1e-5f);
    float xv[3];
    float s3 = 0.f;
    #pragma unroll
    for (int q = 0; q < 3; ++q) {
        int d = tid + q*256;
        float y = (tv[q] - mu1) * rstd1 * g[d] + bb[d];
        X[(size_t)row*768 + d] = y;
        xv[q] = y; s3 += y;
    }
    float mu2 = bsum256(s3, red4, tid) * (1.f/768.f);
    float s4 = 0.f;
    #pragma unroll
    for (int q = 0; q < 3; ++q) { float dv = xv[q] - mu2; s4 += dv*dv; }
    float rstd2 = rsqrtf(bsum256(s4, red4, tid) * (1.f/768.f) + 1e-5f);
    #pragma unroll
    for (int q = 0; q < 3; ++q) {
        int d = tid + q*256;
        float h = (xv[q] - mu2) * rstd2 * (1.f + scm[(size_t)b*4608 + d]) + shm[(size_t)b*4608 + d];
        Hb[(size_t)row*768 + d] = __float2bfloat16(h);
    }
}

// ---------------------------------------------------------------------------
// fused: combine split-K (nz) + bias + residual-gate into X, then
// Hb = bf16( LN(xnew)*(1+scm[b]) + shm[b] ).  block per row, D=768.
// ---------------------------------------------------------------------------
__global__ __launch_bounds__(256) void gcombln_kernel(
    const float* __restrict__ P, size_t pstride, int nz,
    const float* __restrict__ bias,
    float* __restrict__ X,
    const float* __restrict__ gate,
    const float* __restrict__ scm, const float* __restrict__ shm,
    __hip_bfloat16* __restrict__ Hb)
{
    int row = blockIdx.x, tid = threadIdx.x;
    int b = row >> 11;
    __shared__ float red4[4];
    float xv[3];
    float s = 0.f;
    #pragma unroll
    for (int q = 0; q < 3; ++q) {
        int d = tid + q*256;
        float v = P[(size_t)row*768 + d];
        for (int z = 1; z < nz; ++z) v += P[(size_t)z*pstride + (size_t)row*768 + d];
        v += bias[d];
        v = X[(size_t)row*768 + d] + gate[(size_t)b*4608 + d] * v;
        X[(size_t)row*768 + d] = v;
        xv[q] = v; s += v;
    }
    float mu = bsum256(s, red4, tid) * (1.f/768.f);
    float s2 = 0.f;
    #pragma unroll
    for (int q = 0; q < 3; ++q) { float dv = xv[q] - mu; s2 += dv*dv; }
    float rstd = rsqrtf(bsum256(s2, red4, tid) * (1.f/768.f) + 1e-5f);
    #pragma unroll
    for (int q = 0; q < 3; ++q) {
        int d = tid + q*256;
        float y = (xv[q] - mu) * rstd * (1.f + scm[(size_t)b*4608 + d]) + shm[(size_t)b*4608 + d];
        Hb[(size_t)row*768 + d] = __float2bfloat16(y);
    }
}

// ---------------------------------------------------------------------------
// c = LN(adaLN_emb @ ada_W + ada_b; g,b); c_silu = silu(c). 2 blocks.
// ---------------------------------------------------------------------------
__global__ __launch_bounds__(256) void ada_kernel(
    const float* __restrict__ emb, const float* __restrict__ W,
    const float* __restrict__ bias,
    const float* __restrict__ g, const float* __restrict__ bb,
    float* __restrict__ c, float* __restrict__ c_silu)
{
    int b = blockIdx.x, tid = threadIdx.x;
    __shared__ float emb_s[256];
    __shared__ float t[768];
    __shared__ float red[256];
    emb_s[tid] = emb[b*256 + tid];
    __syncthreads();
    for (int q = 0; q < 3; ++q) {
        int e = tid + q*256;
        float acc = bias[e];
        for (int k = 0; k < 256; ++k) acc += emb_s[k] * W[(size_t)k*768 + e];
        t[e] = acc;
    }
    __syncthreads();
    float s = 0.f; for (int q = 0; q < 3; ++q) s += t[tid + q*256];
    red[tid] = s; __syncthreads();
    for (int off = 128; off > 0; off >>= 1) { if (tid < off) red[tid] += red[tid+off]; __syncthreads(); }
    float mu = red[0] / 768.f; __syncthreads();
    float s2 = 0.f; for (int q = 0; q < 3; ++q) { float d = t[tid + q*256] - mu; s2 += d*d; }
    red[tid] = s2; __syncthreads();
    for (int off = 128; off > 0; off >>= 1) { if (tid < off) red[tid] += red[tid+off]; __syncthreads(); }
    float rstd = rsqrtf(red[0] / 768.f + 1e-5f);
    for (int q = 0; q < 3; ++q) {
        int e = tid + q*256;
        float y = (t[e] - mu) * rstd * g[e] + bb[e];
        c[b*768 + e] = y;
        c_silu[b*768 + e] = y / (1.f + expf(-y));
    }
}

// ---------------------------------------------------------------------------
// mod for BOTH layers, K-split 4: part[z][l][b][4608] ; grid (72, 4)
// ---------------------------------------------------------------------------
__global__ __launch_bounds__(256) void mod2_kernel(
    const float* __restrict__ c_silu, const float* __restrict__ mod_W,
    float* __restrict__ part)
{
    int idx = blockIdx.x * 256 + threadIdx.x;   // < 18432
    int z = blockIdx.y;
    int lyr = idx / 9216, b = (idx / 4608) & 1, j = idx % 4608;
    const float* Wl = mod_W + (size_t)lyr * 768 * 4608;
    const float* cs = c_silu + b * 768;
    float acc = 0.f;
    int k0 = z * 192;
    for (int k = k0; k < k0 + 192; ++k) acc += cs[k] * Wl[(size_t)k * 4608 + j];
    part[(size_t)z * 18432 + idx] = acc;
}

__global__ __launch_bounds__(256) void modc_kernel(
    const float* __restrict__ part, const float* __restrict__ mod_b,
    float* __restrict__ m2buf)
{
    int idx = blockIdx.x * 256 + threadIdx.x;
    int lyr = idx / 9216, j = idx % 4608;
    float acc = mod_b[(size_t)lyr * 4608 + j];
    #pragma unroll
    for (int z = 0; z < 4; ++z) acc += part[(size_t)z * 18432 + idx];
    m2buf[idx] = acc;
}

// ---------------------------------------------------------------------------
// MFMA local-window attention. 1 wave per (b, h, qblock of 32).
// ---------------------------------------------------------------------------
__global__ __launch_bounds__(64) void attn_mfma_kernel(
    const __hip_bfloat16* __restrict__ qkv,   // [B*N, 2304]
    const float* __restrict__ ropeC,          // [B*N, 32]
    const float* __restrict__ ropeS,
    __hip_bfloat16* __restrict__ o)           // [B*N, 768]
{
    int bid = blockIdx.x;
    int qb = bid & 63;
    int h  = (bid >> 6) % 12;
    int b  = bid / 768;
    int l  = threadIdx.x;
    int lr = l & 15, lg = l >> 4;
    int lo = max(0, 32*qb - 48);
    int hi = min(N_, 32*qb + 80);
    int wlen = hi - lo;

    __shared__ __hip_bfloat16 Vl[128 * 72];
    __shared__ __hip_bfloat16 Pl[32 * 144];

    {
        int vr0 = l >> 3;
        int c0  = (l & 7) * 8;
        #pragma unroll
        for (int it = 0; it < 16; ++it) {
            int vr = it*8 + vr0;
            int n = lo + vr;
            U8 v;
            if (n < hi) {
                v.v = *(const bf16x8*)(qkv + ((size_t)(b*N_ + n))*2304 + 1536 + h*64 + c0);
            } else {
                #pragma unroll
                for (int j = 0; j < 8; ++j) v.u[j] = 0;
            }
            *(bf16x8*)(Vl + vr*72 + c0) = v.v;
        }
    }

    bf16x8 aq0[2], aq1[2];
    #pragma unroll
    for (int i = 0; i < 2; ++i) {
        int n = qb*32 + i*16 + lr;
        const __hip_bfloat16* qrow = qkv + ((size_t)(b*N_ + n))*2304 + h*64;
        U8 xlo, xhi;
        xlo.v = *(const bf16x8*)(qrow + lg*8);
        xhi.v = *(const bf16x8*)(qrow + 32 + lg*8);
        const float* pc = ropeC + ((size_t)(b*N_ + n))*32 + lg*8;
        const float* ps = ropeS + ((size_t)(b*N_ + n))*32 + lg*8;
        float4 c0 = *(const float4*)(pc), c1 = *(const float4*)(pc + 4);
        float4 s0 = *(const float4*)(ps), s1 = *(const float4*)(ps + 4);
        float cv[8] = {c0.x,c0.y,c0.z,c0.w,c1.x,c1.y,c1.z,c1.w};
        float sv[8] = {s0.x,s0.y,s0.z,s0.w,s1.x,s1.y,s1.z,s1.w};
        U8 f0, f1;
        #pragma unroll
        for (int j = 0; j < 8; ++j) {
            float x1 = __bfloat162float(xlo.e[j]);
            float x2 = __bfloat162float(xhi.e[j]);
            f0.e[j] = __float2bfloat16(x1*cv[j] - x2*sv[j]);
            f1.e[j] = __float2bfloat16(x1*sv[j] + x2*cv[j]);
        }
        aq0[i] = f0.v; aq1[i] = f1.v;
    }

    f32x4 S[2][8];
    #pragma unroll
    for (int i = 0; i < 2; ++i)
        #pragma unroll
        for (int jt = 0; jt < 8; ++jt)
            S[i][jt] = f32x4{0.f, 0.f, 0.f, 0.f};

    #pragma unroll
    for (int jt = 0; jt < 8; ++jt) {
        int n = lo + jt*16 + lr;
        U8 f0, f1;
        if (n < hi) {
            const __hip_bfloat16* krow = qkv + ((size_t)(b*N_ + n))*2304 + 768 + h*64;
            U8 xlo, xhi;
            xlo.v = *(const bf16x8*)(krow + lg*8);
            xhi.v = *(const bf16x8*)(krow + 32 + lg*8);
            const float* pc = ropeC + ((size_t)(b*N_ + n))*32 + lg*8;
            const float* ps = ropeS + ((size_t)(b*N_ + n))*32 + lg*8;
            float4 c0 = *(const float4*)(pc), c1 = *(const float4*)(pc + 4);
            float4 s0 = *(const float4*)(ps), s1 = *(const float4*)(ps + 4);
            float cv[8] = {c0.x,c0.y,c0.z,c0.w,c1.x,c1.y,c1.z,c1.w};
            float sv[8] = {s0.x,s0.y,s0.z,s0.w,s1.x,s1.y,s1.z,s1.w};
            #pragma unroll
            for (int j = 0; j < 8; ++j) {
                float x1 = __bfloat162float(xlo.e[j]);
                float x2 = __bfloat162float(xhi.e[j]);
                f0.e[j] = __float2bfloat16(x1*cv[j] - x2*sv[j]);
                f1.e[j] = __float2bfloat16(x1*sv[j] + x2*cv[j]);
            }
        } else {
            #pragma unroll
            for (int j = 0; j < 8; ++j) { f0.u[j] = 0; f1.u[j] = 0; }
        }
        #pragma unroll
        for (int i = 0; i < 2; ++i) {
            S[i][jt] = __builtin_amdgcn_mfma_f32_16x16x32_bf16(aq0[i], f0.v, S[i][jt], 0, 0, 0);
            S[i][jt] = __builtin_amdgcn_mfma_f32_16x16x32_bf16(aq1[i], f1.v, S[i][jt], 0, 0, 0);
        }
    }

    #pragma unroll
    for (int jt = 0; jt < 8; ++jt) {
        bool oob = (jt*16 + lr) >= wlen;
        #pragma unroll
        for (int i = 0; i < 2; ++i)
            #pragma unroll
            for (int r = 0; r < 4; ++r)
                S[i][jt][r] = oob ? -1e30f : S[i][jt][r] * 0.125f;
    }

    float rinv[2][4];
    #pragma unroll
    for (int i = 0; i < 2; ++i) {
        #pragma unroll
        for (int r = 0; r < 4; ++r) {
            float m = -1e30f;
            #pragma unroll
            for (int jt = 0; jt < 8; ++jt) m = fmaxf(m, S[i][jt][r]);
            #pragma unroll
            for (int mask = 8; mask > 0; mask >>= 1) m = fmaxf(m, __shfl_xor(m, mask, 16));
            float sum = 0.f;
            #pragma unroll
            for (int jt = 0; jt < 8; ++jt) {
                float e = __expf(S[i][jt][r] - m);
                S[i][jt][r] = e;
                sum += e;
            }
            #pragma unroll
            for (int mask = 8; mask > 0; mask >>= 1) sum += __shfl_xor(sum, mask, 16);
            rinv[i][r] = 1.f / sum;
        }
    }

    #pragma unroll
    for (int i = 0; i < 2; ++i)
        #pragma unroll
        for (int jt = 0; jt < 8; ++jt)
            #pragma unroll
            for (int r = 0; r < 4; ++r) {
                int row = i*16 + lg*4 + r;
                int colp = (jt*16 + lr) ^ (lg << 3);
                Pl[row*144 + colp] = __float2bfloat16(S[i][jt][r]);
            }

    __syncthreads();

    f32x4 O_[2][4];
    #pragma unroll
    for (int i = 0; i < 2; ++i)
        #pragma unroll
        for (int ct = 0; ct < 4; ++ct)
            O_[i][ct] = f32x4{0.f, 0.f, 0.f, 0.f};

    int key = (lr >> 2) & 3;
    #pragma unroll
    for (int kt = 0; kt < 4; ++kt) {
        bf16x8 pa[2];
        #pragma unroll
        for (int i = 0; i < 2; ++i) {
            int row = i*16 + lr;
            int colp = (kt*32 + lg*8) ^ (key << 3);
            pa[i] = *(bf16x8*)(Pl + row*144 + colp);
        }
        #pragma unroll
        for (int ct = 0; ct < 4; ++ct) {
            U8 bv;
            #pragma unroll
            for (int j = 0; j < 8; ++j)
                bv.e[j] = Vl[(kt*32 + lg*8 + j)*72 + ct*16 + lr];
            O_[0][ct] = __builtin_amdgcn_mfma_f32_16x16x32_bf16(pa[0], bv.v, O_[0][ct], 0, 0, 0);
            O_[1][ct] = __builtin_amdgcn_mfma_f32_16x16x32_bf16(pa[1], bv.v, O_[1][ct], 0, 0, 0);
        }
    }

    #pragma unroll
    for (int i = 0; i < 2; ++i)
        #pragma unroll
        for (int ct = 0; ct < 4; ++ct)
            #pragma unroll
            for (int r = 0; r < 4; ++r) {
                int row = qb*32 + i*16 + lg*4 + r;
                o[((size_t)(b*N_ + row))*768 + h*64 + ct*16 + lr] =
                    __float2bfloat16(O_[i][ct][r] * rinv[i][r]);
            }
}

// ---------------------------------------------------------------------------
// a2t [B,N,NR] fp32 -> a2tTb [B,NR,N] bf16   grid (NR/32, N/32, B)
// ---------------------------------------------------------------------------
__global__ __launch_bounds__(256) void a2t_transpose_kernel(
    const float* __restrict__ a2t, __hip_bfloat16* __restrict__ a2tTb)
{
    __shared__ float t[32][33];
    int r0 = blockIdx.x * 32, n0 = blockIdx.y * 32, b = blockIdx.z;
    int tid = threadIdx.x;
    int tx = tid & 31, ty = tid >> 5;
    #pragma unroll
    for (int i = 0; i < 4; ++i) {
        int row = ty + i*8;
        t[row][tx] = a2t[((size_t)b*N_ + n0 + row) * 256 + r0 + tx];
    }
    __syncthreads();
    #pragma unroll
    for (int i = 0; i < 4; ++i) {
        int row = ty + i*8;
        a2tTb[((size_t)b*256 + r0 + row) * N_ + n0 + tx] = __float2bfloat16(t[tx][row]);
    }
}

// ---------------------------------------------------------------------------
// recip[row] = 1/(sum of a2tTb row + 1e-6).  block per row (512 rows).
// ---------------------------------------------------------------------------
__global__ __launch_bounds__(256) void rowrecip_kernel(
    const __hip_bfloat16* __restrict__ a2tTb, float* __restrict__ recip)
{
    int row = blockIdx.x;
    int tid = threadIdx.x;
    __shared__ float red4[4];
    U8 v; v.v = *(const bf16x8*)(a2tTb + (size_t)row*2048 + tid*8);
    float s = 0.f;
    #pragma unroll
    for (int j = 0; j < 8; ++j) s += __bfloat162float(v.e[j]);
    float tot = bsum256(s, red4, tid);
    if (tid == 0) recip[row] = 1.f / (tot + 1e-6f);
}

// ---------------------------------------------------------------------------
extern "C" void kernel_launch(void* const* d_in, const int* in_sizes, int n_in,
                              void* d_out, int out_size, void* d_ws, size_t ws_size,
                              hipStream_t stream) {
    const float* atom_coords  = (const float*)d_in[0];
    const float* ref_pos      = (const float*)d_in[1];
    const int*   res_id       = (const int*)  d_in[2];
    const float* res_type     = (const float*)d_in[3];
    const float* charge       = (const float*)d_in[4];
    const float* atomic_num   = (const float*)d_in[5];
    const float* atom_name    = (const float*)d_in[6];
    const float* adaLN_emb    = (const float*)d_in[7];
    const int*   rope_pos     = (const int*)  d_in[8];
    const float* atom_to_tok  = (const float*)d_in[9];
    const float* feat_W       = (const float*)d_in[10];
    const float* feat_b       = (const float*)d_in[11];
    const float* feat_ln_g    = (const float*)d_in[12];
    const float* feat_ln_b    = (const float*)d_in[13];
    const float* pos_W        = (const float*)d_in[14];
    const float* in_W         = (const float*)d_in[15];
    const float* tin_W        = (const float*)d_in[16];
    const float* tin_b        = (const float*)d_in[17];
    const float* tin_ln_g     = (const float*)d_in[18];
    const float* tin_ln_b     = (const float*)d_in[19];
    const float* ada_W        = (const float*)d_in[20];
    const float* ada_b        = (const float*)d_in[21];
    const float* ada_ln_g     = (const float*)d_in[22];
    const float* ada_ln_b     = (const float*)d_in[23];
    const float* blk_mod_W    = (const float*)d_in[24];
    const float* blk_mod_b    = (const float*)d_in[25];
    const float* blk_qkv_W    = (const float*)d_in[26];
    const float* blk_qkv_b    = (const float*)d_in[27];
    const float* blk_o_W      = (const float*)d_in[28];
    const float* blk_o_b      = (const float*)d_in[29];
    const float* blk_m1_W     = (const float*)d_in[30];
    const float* blk_m1_b     = (const float*)d_in[31];
    const float* blk_m2_W     = (const float*)d_in[32];
    const float* blk_m2_b     = (const float*)d_in[33];
    const float* tout_W       = (const float*)d_in[34];
    const float* tout_b       = (const float*)d_in[35];
    const float* tout_ln_g    = (const float*)d_in[36];
    const float* tout_ln_b    = (const float*)d_in[37];

    const int BN = B_ * N_;                          // 4096
    float* ws = (float*)d_ws;

    // layout (float units)
    const size_t OFF_X    = 0;                                // fp32 [4096][768]
    const size_t OFF_HB   = OFF_X    + (size_t)BN*768;        // bf16 [4096][768]
    const size_t OFF_QKVB = OFF_HB   + (size_t)BN*768/2;      // bf16 [4096][2304]
    const size_t OFF_OB   = OFF_QKVB + (size_t)BN*2304/2;     // bf16 [4096][768]
    const size_t OFF_UB   = OFF_OB   + (size_t)BN*768/2;      // bf16 [4096][3072]
    const size_t OFF_WT   = OFF_UB   + (size_t)BN*3072/2;     // bf16 up to 3072*768
    const size_t OFF_RC   = OFF_WT   + (size_t)3072*768/2;    // fp32 BN*32
    const size_t OFF_RS   = OFF_RC   + (size_t)BN*32;
    const size_t OFF_SM   = OFF_RS   + (size_t)BN*32;

    float* X = ws + OFF_X;
    __hip_bfloat16* Hb   = (__hip_bfloat16*)(ws + OFF_HB);
    __hip_bfloat16* QKVb = (__hip_bfloat16*)(ws + OFF_QKVB);
    __hip_bfloat16* Ob   = (__hip_bfloat16*)(ws + OFF_OB);
    __hip_bfloat16* Ub   = (__hip_bfloat16*)(ws + OFF_UB);
    __hip_bfloat16* WT   = (__hip_bfloat16*)(ws + OFF_WT);
    float* ropeC  = ws + OFF_RC;
    float* ropeS  = ws + OFF_RS;
    float* cbuf   = ws + OFF_SM;                     // 1536
    float* c_silu = cbuf + 1536;                     // 1536
    float* mbuf2  = c_silu + 1536;                   // 18432  [2][2][4608]
    float* modpart= mbuf2 + 18432;                   // 73728

    // phase-A aliases
    __hip_bfloat16* featsB  = QKVb;                           // [4096][1024] bf16
    __hip_bfloat16* coordsB = QKVb + (size_t)BN*1024;         // [4096][512] bf16
    float* t1               = ws + OFF_UB;                    // scratch
    __hip_bfloat16* concatB = (__hip_bfloat16*)(t1 + (size_t)BN*256);  // [4096][512] bf16
    __hip_bfloat16* atom_inB= Ob;                             // [4096][256] bf16

    // residue-phase aliases (Ob/Ub regions dead by then)
    __hip_bfloat16* a2tTb   = Ob;                             // [2][256][2048] bf16
    __hip_bfloat16* latTb   = Ob + (size_t)2*256*2048;        // [2][256][2048] bf16
    float* recip            = modpart;                        // 512 fp32

    // split-K partial buffers (aliases of dead regions)
    float* P_pa   = ws + OFF_X;       // phase A (feat/pos/in)
    float* P_tin  = ws + OFF_UB;
    float* P_o    = ws + OFF_UB;
    float* P_m2   = ws + OFF_QKVB;
    float* P_tout = ws + OFF_UB;
    float* P_res  = ws + OFF_UB;

    float* out_res = (float*)d_out;                           // B*NR*DA
    float* out_lat = out_res + (size_t)B_*NR_*DA_;            // B*N*DA

    // ---- adaLN + modulation for both layers (input-only; run first) ----
    ada_kernel<<<2, 256, 0, stream>>>(adaLN_emb, ada_W, ada_b, ada_ln_g, ada_ln_b,
        cbuf, c_silu);
    mod2_kernel<<<dim3(72, 4), 256, 0, stream>>>(c_silu, blk_mod_W, modpart);
    modc_kernel<<<72, 256, 0, stream>>>(modpart, blk_mod_b, mbuf2);

    // ---- featurization (bf16) + rope table (fused) ----
    build_feats_kernel<<<BN, 128, 0, stream>>>(atom_coords, ref_pos, res_id,
        res_type, charge, atomic_num, atom_name, rope_pos, featsB, coordsB,
        ropeC, ropeS);

    // t1 = feats @ feat_W + feat_b   (K padded 924->1024, split 4)
    transconv_kernel<<<dim3(8, 32), 256, 0, stream>>>(feat_W, WT, 924, 1024, 256, 0, 0);
    gemm_bf16_kernel<<<dim3(2, 32, 4), 512, 0, stream>>>(featsB, 1024, WT, 1024, nullptr,
        nullptr, 0, 1024, 0, 0, nullptr, 0, nullptr, 0, P_pa, 32, 0, 0);
    combln256_kernel<<<BN, 256, 0, stream>>>(P_pa, (size_t)BN*256, 4, feat_b,
        feat_ln_g, feat_ln_b, 1, 1, concatB, 512);
    // concat[:,256:512] = coordsF @ pos_W  (K 387->512, split 4)
    transconv_kernel<<<dim3(8, 16), 256, 0, stream>>>(pos_W, WT, 387, 512, 256, 0, 0);
    gemm_bf16_kernel<<<dim3(2, 32, 4), 512, 0, stream>>>(coordsB, 512, WT, 512, nullptr,
        nullptr, 0, 512, 0, 0, nullptr, 0, nullptr, 0, P_pa, 32, 0, 0);
    gcomb_kernel<<<1024, 256, 0, stream>>>(P_pa, (size_t)BN*256, 4, 256, nullptr,
        concatB + 256, 512, 0, 1, nullptr, 0, nullptr, 0, nullptr, 0);
    // atom_in = concat @ in_W -> bf16 (split 4)
    transconv_kernel<<<dim3(8, 16), 256, 0, stream>>>(in_W, WT, 512, 512, 256, 0, 0);
    gemm_bf16_kernel<<<dim3(2, 32, 4), 512, 0, stream>>>(concatB, 512, WT, 512, nullptr,
        nullptr, 0, 512, 0, 0, nullptr, 0, nullptr, 0, P_pa, 32, 0, 0);
    gcomb_kernel<<<1024, 256, 0, stream>>>(P_pa, (size_t)BN*256, 4, 256, nullptr,
        atom_inB, 256, 0, 1, nullptr, 0, nullptr, 0, nullptr, 0);
    // X = LN(atom_in @ tin_W + tin_b) ; Hb = LN(X)*(1+sc1)+sh1  (fused)
    transconv_kernel<<<dim3(24, 8), 256, 0, stream>>>(tin_W, WT, 256, 256, 768, 0, 0);
    gemm_bf16_kernel<<<dim3(6, 32, 2), 512, 0, stream>>>(atom_inB, 256, WT, 256, nullptr,
        nullptr, 0, 256, 0, 0, nullptr, 0, nullptr, 0, P_tin, 32, 0, 0);
    tinfuse_kernel<<<BN, 256, 0, stream>>>(P_tin, (size_t)BN*768, 2, tin_b,
        tin_ln_g, tin_ln_b, mbuf2 + 768, mbuf2 + 0, X, Hb);

    for (int l = 0; l < NB_; ++l) {
        const float* qkvW = blk_qkv_W + (size_t)l*768*2304;
        const float* qkvB = blk_qkv_b + (size_t)l*2304;
        const float* oW   = blk_o_W   + (size_t)l*768*768;
        const float* oB   = blk_o_b   + (size_t)l*768;
        const float* m1W  = blk_m1_W  + (size_t)l*768*3072;
        const float* m1B  = blk_m1_b  + (size_t)l*3072;
        const float* m2W  = blk_m2_W  + (size_t)l*3072*768;
        const float* m2B  = blk_m2_b  + (size_t)l*768;

        float* mptr = mbuf2 + (size_t)l*9216;        // [b][4608]
        float* sh2 = mptr + 2304, *sc2 = mptr + 3072;
        float* g1  = mptr + 1536, *g2 = mptr + 3840;

        // qkv = h @ qkv_W + b -> bf16
        transconv_kernel<<<dim3(72, 24), 256, 0, stream>>>(qkvW, WT, 768, 768, 2304, 0, 0);
        gemm_bf16_kernel<<<dim3(18, 32, 1), 512, 0, stream>>>(Hb, 768, WT, 768, qkvB,
            QKVb, 2304, 768, 0, 1, nullptr, 0, nullptr, 0, nullptr, 32, 0, 0);
        // attention
        attn_mfma_kernel<<<B_*H_*64, 64, 0, stream>>>(QKVb, ropeC, ropeS, Ob);
        // x = x + g1*(o @ o_W + o_b)  (split 2) ; fused -> Hb = h2
        transconv_kernel<<<dim3(24, 24), 256, 0, stream>>>(oW, WT, 768, 768, 768, 0, 0);
        gemm_bf16_kernel<<<dim3(6, 32, 2), 512, 0, stream>>>(Ob, 768, WT, 768, nullptr,
            nullptr, 0, 768, 0, 0, nullptr, 0, nullptr, 0, P_o, 32, 0, 0);
        gcombln_kernel<<<BN, 256, 0, stream>>>(P_o, (size_t)BN*768, 2, oB,
            X, g1, sc2, sh2, Hb);
        // u = gelu(h2 @ m1_W + b) -> bf16
        transconv_kernel<<<dim3(96, 24), 256, 0, stream>>>(m1W, WT, 768, 768, 3072, 0, 0);
        gemm_bf16_kernel<<<dim3(24, 32, 1), 512, 0, stream>>>(Hb, 768, WT, 768, m1B,
            Ub, 3072, 768, 1, 1, nullptr, 0, nullptr, 0, nullptr, 32, 0, 0);
        // x = x + g2*(u @ m2_W + b)  (split 2)
        transconv_kernel<<<dim3(24, 96), 256, 0, stream>>>(m2W, WT, 3072, 3072, 768, 0, 0);
        gemm_bf16_kernel<<<dim3(6, 32, 2), 512, 0, stream>>>(Ub, 3072, WT, 3072, nullptr,
            nullptr, 0, 3072, 0, 0, nullptr, 0, nullptr, 0, P_m2, 32, 0, 0);
        if (l < NB_ - 1) {
            float* mnext = mbuf2 + (size_t)(l+1)*9216;
            gcombln_kernel<<<BN, 256, 0, stream>>>(P_m2, (size_t)BN*768, 2, m2B,
                X, g2, mnext + 768, mnext + 0, Hb);
        } else {
            // final layer: X is dead afterward -> write Hb (bf16) directly
            gcomb_kernel<<<3072, 256, 0, stream>>>(P_m2, (size_t)BN*768, 2, 768, m2B,
                Hb, 768, 2, 1, X, 768, g2, 4608, nullptr, 0);
        }
    }

    // atom_latent = LN(x @ tout_W + tout_b)  (split 4, fused combine+LN)
    transconv_kernel<<<dim3(8, 24), 256, 0, stream>>>(tout_W, WT, 768, 768, 256, 0, 0);
    gemm_bf16_kernel<<<dim3(2, 32, 4), 512, 0, stream>>>(Hb, 768, WT, 768, nullptr,
        nullptr, 0, 768, 0, 0, nullptr, 0, nullptr, 0, P_tout, 32, 0, 0);
    combln256_kernel<<<BN, 256, 0, stream>>>(P_tout, (size_t)BN*256, 4, tout_b,
        tout_ln_g, tout_ln_b, 0, 0, out_lat, 256);

    // ---- residue pooling as MFMA GEMM ----
    a2t_transpose_kernel<<<dim3(8, 64, 2), 256, 0, stream>>>(atom_to_tok, a2tTb);
    rowrecip_kernel<<<512, 256, 0, stream>>>(a2tTb, recip);
    transconv_kernel<<<dim3(8, 64, 2), 256, 0, stream>>>(out_lat, latTb, 2048, 2048, 256,
        (size_t)2048*256, (size_t)256*2048);
    gemm_bf16_kernel<<<dim3(2, 4, 8), 512, 0, stream>>>(a2tTb, 2048, latTb, 2048, nullptr,
        nullptr, 0, 2048, 0, 0, nullptr, 0, nullptr, 0, P_res,
        2, (size_t)256*2048, (size_t)256*2048);
    gcomb_kernel<<<128, 256, 0, stream>>>(P_res, (size_t)512*256, 8, 256, nullptr,
        out_res, 256, 3, 0, nullptr, 0, recip, 0, nullptr, 0);
}

// Round 15
// 553.719 us; speedup vs baseline: 1.7265x; 1.0114x over previous
//
#include <hip/hip_runtime.h>
#include <hip/hip_bf16.h>
#include <math.h>

// Problem constants
#define B_ 2
#define N_ 2048
#define NR_ 256
#define DA_ 256
#define E_ 768
#define H_ 12
#define DH_ 64
#define NB_ 2

typedef __attribute__((ext_vector_type(8))) __bf16 bf16x8;
typedef __attribute__((ext_vector_type(4))) float f32x4;

union U8 { bf16x8 v; __hip_bfloat16 e[8]; unsigned short u[8]; };
union U4 { __hip_bfloat16 e[4]; uint2 u2; };

__device__ __forceinline__ void gload16(const void* g, void* l) {
    __builtin_amdgcn_global_load_lds(
        (const __attribute__((address_space(1))) void*)g,
        (__attribute__((address_space(3))) void*)l, 16, 0, 0);
}

// 256-thread block sum: wave shuffle + 4-slot LDS combine (2 barriers).
__device__ __forceinline__ float bsum256(float v, float* red4, int tid) {
    #pragma unroll
    for (int m = 32; m > 0; m >>= 1) v += __shfl_xor(v, m, 64);
    __syncthreads();
    if ((tid & 63) == 0) red4[tid >> 6] = v;
    __syncthreads();
    return red4[0] + red4[1] + red4[2] + red4[3];
}

// ---------------------------------------------------------------------------
// build feats[B*N, 1024] (bf16) and coordsF[B*N, 512] (bf16) + rope tables
// ---------------------------------------------------------------------------
__global__ __launch_bounds__(128) void build_feats_kernel(
    const float* __restrict__ atom_coords, const float* __restrict__ ref_pos,
    const int* __restrict__ res_id, const float* __restrict__ res_type,
    const float* __restrict__ charge, const float* __restrict__ atomic_number,
    const float* __restrict__ atom_name, const int* __restrict__ rope_pos,
    __hip_bfloat16* __restrict__ feats, __hip_bfloat16* __restrict__ coordsF,
    float* __restrict__ ropeC, float* __restrict__ ropeS)
{
    int a = blockIdx.x;            // atom index over B*N
    int tid = threadIdx.x;
    __hip_bfloat16* f  = feats   + (size_t)a * 1024;
    __hip_bfloat16* cf = coordsF + (size_t)a * 512;

    float rp[3], cc[3];
    #pragma unroll
    for (int i = 0; i < 3; ++i) { rp[i] = ref_pos[(size_t)a*3 + i]; cc[i] = atom_coords[(size_t)a*3 + i]; }

    if (tid < 3) { f[tid] = __float2bfloat16(rp[tid]); cf[tid] = __float2bfloat16(cc[tid]); }

    if (tid >= 64 && tid < 96) {
        int dd = tid - 64;
        float rpos = (float)rope_pos[a];
        float ang = rpos * expf(-0.28782313662425574f * (float)dd);  // ln(1e4)/32
        float sn, cs; sincosf(ang, &sn, &cs);
        ropeC[a*32 + dd] = cs; ropeS[a*32 + dd] = sn;
    }

    for (int s = tid; s < 192; s += 128) {
        int fi = s / 3, ci = s % 3;
        float freq = exp2f(12.f * (float)fi / 63.f);
        float ar = rp[ci] * freq;
        float ac = cc[ci] * freq;
        float snr, csr, snc, csc_;
        sincosf(ar, &snr, &csr);
        sincosf(ac, &snc, &csc_);
        f[3 + s]    = __float2bfloat16(snr);  f[195 + s]  = __float2bfloat16(csr);
        cf[3 + s]   = __float2bfloat16(snc);  cf[195 + s] = __float2bfloat16(csc_);
    }
    if (tid < 23) f[387 + tid] = __float2bfloat16(res_type[(size_t)a*23 + tid]);

    float pos = (float)res_id[a];
    if (tid == 0) f[410] = __float2bfloat16(pos);
    if (tid < 64) {
        float div = expf(-9.210340371976184f / 128.f * (float)(2 * tid));
        float ang = pos * div;
        float sn, cs; sincosf(ang, &sn, &cs);
        f[411 + tid] = __float2bfloat16(sn);
        f[475 + tid] = __float2bfloat16(cs);
    }
    if (tid == 0) f[539] = __float2bfloat16(charge[a]);
    if (tid < 128) f[540 + tid] = __float2bfloat16(atomic_number[(size_t)a*128 + tid]);
    for (int s = tid; s < 256; s += 128) f[668 + s] = __float2bfloat16(atom_name[(size_t)a*256 + s]);
    if (tid < 100) f[924 + tid] = __float2bfloat16(0.f);
    if (tid < 125) cf[387 + tid] = __float2bfloat16(0.f);
}

// ---------------------------------------------------------------------------
// Transpose + fp32->bf16 + K-pad: W[Ksrc][Nn] -> WT[Nn][Kdst], zeros k>=Ksrc
// ---------------------------------------------------------------------------
__global__ __launch_bounds__(256) void transconv_kernel(
    const float* __restrict__ W, __hip_bfloat16* __restrict__ WT,
    int Ksrc, int Kdst, int Nn, size_t wstride, size_t tstride)
{
    __shared__ float t[32][33];
    W  += (size_t)blockIdx.z * wstride;
    WT += (size_t)blockIdx.z * tstride;
    int n0 = blockIdx.x * 32, k0 = blockIdx.y * 32;
    int tid = threadIdx.x;
    int tx = tid & 31, ty = tid >> 5;           // ty 0..7
    #pragma unroll
    for (int i = 0; i < 4; ++i) {
        int k = k0 + ty + i*8;
        t[ty + i*8][tx] = (k < Ksrc) ? W[(size_t)k * Nn + n0 + tx] : 0.f;
    }
    __syncthreads();
    #pragma unroll
    for (int i = 0; i < 4; ++i) {
        int row = ty + i*8;                      // n within tile
        WT[(size_t)(n0 + row) * Kdst + k0 + tx] = __float2bfloat16(t[tx][row]);
    }
}

// ---------------------------------------------------------------------------
// shared epilogue.  mode 0 none; 1 gelu; 2 X + gate[b][col]*v; 3 v*gate[row]
// ---------------------------------------------------------------------------
__device__ __forceinline__ float epi_apply(float v, int grow, int gcol,
    const float* bias, int mode, const float* X, int ldx,
    const float* gate, int gstride)
{
    if (bias) v += bias[gcol];
    if (mode == 1) {
        float u = 1.5957691216057308f * (v + 0.044715f * v * v * v);
        v = v / (1.f + __expf(-u));
    } else if (mode == 2) {
        int b = grow >> 11;                      // /N_
        v = X[(size_t)grow * ldx + gcol] + gate[(size_t)b * gstride + gcol] * v;
    } else if (mode == 3) {
        v = v * gate[grow];
    }
    return v;
}

// ---------------------------------------------------------------------------
// bf16 MFMA GEMM: tile 128x128, BK=32, **16 waves (1024 thr), 32x32 per wave**
// dbuf-2 LDS (32 KB; 2 blocks/CU = 32 waves/CU):
//   barrier -> issue STAGE(next) -> ds_read+MFMA(current).
// Staging: 1 gload16/thread; waves 0-7 stage A, waves 8-15 stage B (uniform).
// XOR-swizzle both sides: key(row)=(row>>1)&3.  Bijective XCD swizzle.
// gridDim.z = nz splits K; nz>1 -> raw fp32 partials to P.
// ---------------------------------------------------------------------------
__global__ __launch_bounds__(1024) void gemm_bf16_kernel(
    const __hip_bfloat16* __restrict__ A, int lda,
    const __hip_bfloat16* __restrict__ BT, int ldb,
    const float* __restrict__ bias,
    void* __restrict__ C, int ldc,
    int K, int mode, int obf,
    const float* __restrict__ X, int ldx,
    const float* __restrict__ gate, int gstride,
    float* __restrict__ P,
    int mtiles, size_t bstrideA, size_t bstrideB)
{
    __shared__ __hip_bfloat16 As[2][128 * 32];
    __shared__ __hip_bfloat16 Bs[2][128 * 32];

    int gx = gridDim.x;
    int nwg = gx * gridDim.y;
    int fo = blockIdx.y * gx + blockIdx.x;
    int ft = (fo & 7) * (nwg >> 3) + (fo >> 3);
    int bx = ft % gx, by = ft / gx;

    int bb  = by / mtiles;
    int m0l = (by % mtiles) * 128;
    int m0g = by * 128;
    int n0 = bx * 128;
    const __hip_bfloat16* Ab  = A  + (size_t)bb * bstrideA;
    const __hip_bfloat16* BTb = BT + (size_t)bb * bstrideB;
    int nz = gridDim.z;
    int Kh = K / nz;
    int kb = blockIdx.z * Kh;
    int tid = threadIdx.x;
    int w = tid >> 6, l = tid & 63;
    int wr = (w >> 2) * 32, wc = (w & 3) * 32;   // 4 wave-rows x 4 wave-cols
    int lr = l & 15, lg = l >> 4;
    int slot = ((lg ^ ((lr >> 1) & 3)) & 3) * 8;

    // staging: 1 seg/thread; low 8 waves -> A, high 8 waves -> B
    int sop  = tid >> 9;                         // 0 = A, 1 = B (wave-uniform)
    int seg  = tid & 511;
    int rowS = seg >> 2;
    int gS   = (seg & 3) ^ ((rowS >> 1) & 3);
    const __hip_bfloat16* srcBase = sop ? (BTb + (size_t)(n0 + rowS) * ldb)
                                        : (Ab  + (size_t)(m0l + rowS) * lda);
    __hip_bfloat16* dst0 = (sop ? Bs[0] : As[0]);
    __hip_bfloat16* dst1 = (sop ? Bs[1] : As[1]);

    f32x4 acc[2][2];
    #pragma unroll
    for (int i = 0; i < 2; ++i)
        #pragma unroll
        for (int j = 0; j < 2; ++j)
            acc[i][j] = f32x4{0.f, 0.f, 0.f, 0.f};

    // prologue: stage first tile into buf 0
    gload16(srcBase + kb + gS * 8, (char*)dst0 + seg * 16);

    int cur = 0;
    for (int k0 = kb; k0 < kb + Kh; k0 += 32) {
        __syncthreads();                         // vmcnt(0): buf[cur] ready
        int kn = k0 + 32;
        if (kn < kb + Kh) {
            gload16(srcBase + kn + gS * 8, (char*)(cur ? dst0 : dst1) + seg * 16);
        }
        bf16x8 af[2], bfr[2];
        #pragma unroll
        for (int i = 0; i < 2; ++i)
            af[i]  = *(bf16x8*)(As[cur] + (wr + i*16 + lr) * 32 + slot);
        #pragma unroll
        for (int j = 0; j < 2; ++j)
            bfr[j] = *(bf16x8*)(Bs[cur] + (wc + j*16 + lr) * 32 + slot);
        #pragma unroll
        for (int i = 0; i < 2; ++i)
            #pragma unroll
            for (int j = 0; j < 2; ++j)
                acc[i][j] = __builtin_amdgcn_mfma_f32_16x16x32_bf16(af[i], bfr[j], acc[i][j], 0, 0, 0);
        cur ^= 1;
    }

    if (nz > 1) {
        int Nw = gridDim.x * 128;
        size_t pstride = (size_t)Nw * (gridDim.y * 128);
        float* Pz = P + (size_t)blockIdx.z * pstride;
        #pragma unroll
        for (int i = 0; i < 2; ++i)
            #pragma unroll
            for (int j = 0; j < 2; ++j)
                #pragma unroll
                for (int r = 0; r < 4; ++r) {
                    int grow = m0g + wr + i*16 + lg*4 + r;
                    int gcol = n0 + wc + j*16 + lr;
                    Pz[(size_t)grow * Nw + gcol] = acc[i][j][r];
                }
        return;
    }

    #pragma unroll
    for (int i = 0; i < 2; ++i)
        #pragma unroll
        for (int j = 0; j < 2; ++j)
            #pragma unroll
            for (int r = 0; r < 4; ++r) {
                int grow = m0g + wr + i*16 + lg*4 + r;
                int gcol = n0 + wc + j*16 + lr;
                float v = epi_apply(acc[i][j][r], grow, gcol, bias, mode, X, ldx, gate, gstride);
                if (obf)
                    ((__hip_bfloat16*)C)[(size_t)grow * ldc + gcol] = __float2bfloat16(v);
                else
                    ((float*)C)[(size_t)grow * ldc + gcol] = v;
            }
}

// ---------------------------------------------------------------------------
// combine split-K partials + epilogue. 4 elems/thread. optional C2 bf16 out.
// ---------------------------------------------------------------------------
__global__ __launch_bounds__(256) void gcomb_kernel(
    const float* __restrict__ P, size_t pstride, int nz, int Nw,
    const float* __restrict__ bias,
    void* __restrict__ C, int ldc, int mode, int obf,
    const float* __restrict__ X, int ldx,
    const float* __restrict__ gate, int gstride,
    __hip_bfloat16* __restrict__ C2, int ldc2)
{
    int idx = blockIdx.x * 256 + threadIdx.x;
    int e0 = idx * 4;
    int grow = e0 / Nw, gc0 = e0 % Nw;
    float4 v = *(const float4*)(P + (size_t)grow * Nw + gc0);
    for (int z = 1; z < nz; ++z) {
        float4 t = *(const float4*)(P + (size_t)z * pstride + (size_t)grow * Nw + gc0);
        v.x += t.x; v.y += t.y; v.z += t.z; v.w += t.w;
    }
    float e[4] = {v.x, v.y, v.z, v.w};
    #pragma unroll
    for (int r = 0; r < 4; ++r)
        e[r] = epi_apply(e[r], grow, gc0 + r, bias, mode, X, ldx, gate, gstride);
    if (obf) {
        U4 o4;
        #pragma unroll
        for (int r = 0; r < 4; ++r) o4.e[r] = __float2bfloat16(e[r]);
        *(uint2*)((__hip_bfloat16*)C + (size_t)grow * ldc + gc0) = o4.u2;
    } else {
        *(float4*)((float*)C + (size_t)grow * ldc + gc0) = make_float4(e[0], e[1], e[2], e[3]);
    }
    if (C2) {
        U4 o4;
        #pragma unroll
        for (int r = 0; r < 4; ++r) o4.e[r] = __float2bfloat16(e[r]);
        *(uint2*)(C2 + (size_t)grow * ldc2 + gc0) = o4.u2;
    }
}

// ---------------------------------------------------------------------------
// fused: combine split-K (nz, D=256) + bias + LayerNorm(g,b) [+silu] -> out
// ---------------------------------------------------------------------------
__global__ __launch_bounds__(256) void combln256_kernel(
    const float* __restrict__ P, size_t pstride, int nz,
    const float* __restrict__ bias,
    const float* __restrict__ g, const float* __restrict__ bv,
    int do_silu, int obf,
    void* __restrict__ out, int ldout)
{
    int row = blockIdx.x, d = threadIdx.x;
    __shared__ float red4[4];
    float v = P[(size_t)row*256 + d];
    for (int z = 1; z < nz; ++z) v += P[(size_t)z*pstride + (size_t)row*256 + d];
    v += bias[d];
    float mu = bsum256(v, red4, d) * (1.f/256.f);
    float dv = v - mu;
    float rstd = rsqrtf(bsum256(dv*dv, red4, d) * (1.f/256.f) + 1e-5f);
    float y = dv * rstd * g[d] + bv[d];
    if (do_silu) y = y / (1.f + __expf(-y));
    if (obf) ((__hip_bfloat16*)out)[(size_t)row * ldout + d] = __float2bfloat16(y);
    else     ((float*)out)[(size_t)row * ldout + d] = y;
}

// ---------------------------------------------------------------------------
// tin-chain fusion: combine split-K (nz, D=768) + bias ->
//   X = LN(t; g,b)  (write fp32) ; Hb = bf16( LN2(X)*(1+scm[b]) + shm[b] )
// ---------------------------------------------------------------------------
__global__ __launch_bounds__(256) void tinfuse_kernel(
    const float* __restrict__ P, size_t pstride, int nz,
    const float* __restrict__ bias,
    const float* __restrict__ g, const float* __restrict__ bb,
    const float* __restrict__ scm, const float* __restrict__ shm,
    float* __restrict__ X, __hip_bfloat16* __restrict__ Hb)
{
    int row = blockIdx.x, tid = threadIdx.x;
    int b = row >> 11;
    __shared__ float red4[4];
    float tv[3];
    float s = 0.f;
    #pragma unroll
    for (int q = 0; q < 3; ++q) {
        int d = tid + q*256;
        float v = P[(size_t)row*768 + d];
        for (int z = 1; z < nz; ++z) v += P[(size_t)z*pstride + (size_t)row*768 + d];
        v += bias[d];
        tv[q] = v; s += v;
    }
    float mu1 = bsum256(s, red4, tid) * (1.f/768.f);
    float s2 = 0.f;
    #pragma unroll
    for (int q = 0; q < 3; ++q) { float dv = tv[q] - mu1; s2 += dv*dv; }
    float rstd1 = rsqrtf(bsum256(s2, red4, tid) * (1.f/768.f) + 1e-5f);
    float xv[3];
    float s3 = 0.f;
    #pragma unroll
    for (int q = 0; q < 3; ++q) {
        int d = tid + q*256;
        float y = (tv[q] - mu1) * rstd1 * g[d] + bb[d];
        X[(size_t)row*768 + d] = y;
        xv[q] = y; s3 += y;
    }
    float mu2 = bsum256(s3, red4, tid) * (1.f/768.f);
    float s4 = 0.f;
    #pragma unroll
    for (int q = 0; q < 3; ++q) { float dv = xv[q] - mu2; s4 += dv*dv; }
    float rstd2 = rsqrtf(bsum256(s4, red4, tid) * (1.f/768.f) + 1e-5f);
    #pragma unroll
    for (int q = 0; q < 3; ++q) {
        int d = tid + q*256;
        float h = (xv[q] - mu2) * rstd2 * (1.f + scm[(size_t)b*4608 + d]) + shm[(size_t)b*4608 + d];
        Hb[(size_t)row*768 + d] = __float2bfloat16(h);
    }
}

// ---------------------------------------------------------------------------
// fused: combine split-K (nz) + bias + residual-gate into X, then
// Hb = bf16( LN(xnew)*(1+scm[b]) + shm[b] ).  block per row, D=768.
// ---------------------------------------------------------------------------
__global__ __launch_bounds__(256) void gcombln_kernel(
    const float* __restrict__ P, size_t pstride, int nz,
    const float* __restrict__ bias,
    float* __restrict__ X,
    const float* __restrict__ gate,
    const float* __restrict__ scm, const float* __restrict__ shm,
    __hip_bfloat16* __restrict__ Hb)
{
    int row = blockIdx.x, tid = threadIdx.x;
    int b = row >> 11;
    __shared__ float red4[4];
    float xv[3];
    float s = 0.f;
    #pragma unroll
    for (int q = 0; q < 3; ++q) {
        int d = tid + q*256;
        float v = P[(size_t)row*768 + d];
        for (int z = 1; z < nz; ++z) v += P[(size_t)z*pstride + (size_t)row*768 + d];
        v += bias[d];
        v = X[(size_t)row*768 + d] + gate[(size_t)b*4608 + d] * v;
        X[(size_t)row*768 + d] = v;
        xv[q] = v; s += v;
    }
    float mu = bsum256(s, red4, tid) * (1.f/768.f);
    float s2 = 0.f;
    #pragma unroll
    for (int q = 0; q < 3; ++q) { float dv = xv[q] - mu; s2 += dv*dv; }
    float rstd = rsqrtf(bsum256(s2, red4, tid) * (1.f/768.f) + 1e-5f);
    #pragma unroll
    for (int q = 0; q < 3; ++q) {
        int d = tid + q*256;
        float y = (xv[q] - mu) * rstd * (1.f + scm[(size_t)b*4608 + d]) + shm[(size_t)b*4608 + d];
        Hb[(size_t)row*768 + d] = __float2bfloat16(y);
    }
}

// ---------------------------------------------------------------------------
// c = LN(adaLN_emb @ ada_W + ada_b; g,b); c_silu = silu(c). 2 blocks.
// ---------------------------------------------------------------------------
__global__ __launch_bounds__(256) void ada_kernel(
    const float* __restrict__ emb, const float* __restrict__ W,
    const float* __restrict__ bias,
    const float* __restrict__ g, const float* __restrict__ bb,
    float* __restrict__ c, float* __restrict__ c_silu)
{
    int b = blockIdx.x, tid = threadIdx.x;
    __shared__ float emb_s[256];
    __shared__ float t[768];
    __shared__ float red[256];
    emb_s[tid] = emb[b*256 + tid];
    __syncthreads();
    for (int q = 0; q < 3; ++q) {
        int e = tid + q*256;
        float acc = bias[e];
        for (int k = 0; k < 256; ++k) acc += emb_s[k] * W[(size_t)k*768 + e];
        t[e] = acc;
    }
    __syncthreads();
    float s = 0.f; for (int q = 0; q < 3; ++q) s += t[tid + q*256];
    red[tid] = s; __syncthreads();
    for (int off = 128; off > 0; off >>= 1) { if (tid < off) red[tid] += red[tid+off]; __syncthreads(); }
    float mu = red[0] / 768.f; __syncthreads();
    float s2 = 0.f; for (int q = 0; q < 3; ++q) { float d = t[tid + q*256] - mu; s2 += d*d; }
    red[tid] = s2; __syncthreads();
    for (int off = 128; off > 0; off >>= 1) { if (tid < off) red[tid] += red[tid+off]; __syncthreads(); }
    float rstd = rsqrtf(red[0] / 768.f + 1e-5f);
    for (int q = 0; q < 3; ++q) {
        int e = tid + q*256;
        float y = (t[e] - mu) * rstd * g[e] + bb[e];
        c[b*768 + e] = y;
        c_silu[b*768 + e] = y / (1.f + expf(-y));
    }
}

// ---------------------------------------------------------------------------
// mod for BOTH layers, K-split 4: part[z][l][b][4608] ; grid (72, 4)
// ---------------------------------------------------------------------------
__global__ __launch_bounds__(256) void mod2_kernel(
    const float* __restrict__ c_silu, const float* __restrict__ mod_W,
    float* __restrict__ part)
{
    int idx = blockIdx.x * 256 + threadIdx.x;   // < 18432
    int z = blockIdx.y;
    int lyr = idx / 9216, b = (idx / 4608) & 1, j = idx % 4608;
    const float* Wl = mod_W + (size_t)lyr * 768 * 4608;
    const float* cs = c_silu + b * 768;
    float acc = 0.f;
    int k0 = z * 192;
    for (int k = k0; k < k0 + 192; ++k) acc += cs[k] * Wl[(size_t)k * 4608 + j];
    part[(size_t)z * 18432 + idx] = acc;
}

__global__ __launch_bounds__(256) void modc_kernel(
    const float* __restrict__ part, const float* __restrict__ mod_b,
    float* __restrict__ m2buf)
{
    int idx = blockIdx.x * 256 + threadIdx.x;
    int lyr = idx / 9216, j = idx % 4608;
    float acc = mod_b[(size_t)lyr * 4608 + j];
    #pragma unroll
    for (int z = 0; z < 4; ++z) acc += part[(size_t)z * 18432 + idx];
    m2buf[idx] = acc;
}

// ---------------------------------------------------------------------------
// MFMA local-window attention. 1 wave per (b, h, qblock of 32).
// ---------------------------------------------------------------------------
__global__ __launch_bounds__(64) void attn_mfma_kernel(
    const __hip_bfloat16* __restrict__ qkv,   // [B*N, 2304]
    const float* __restrict__ ropeC,          // [B*N, 32]
    const float* __restrict__ ropeS,
    __hip_bfloat16* __restrict__ o)           // [B*N, 768]
{
    int bid = blockIdx.x;
    int qb = bid & 63;
    int h  = (bid >> 6) % 12;
    int b  = bid / 768;
    int l  = threadIdx.x;
    int lr = l & 15, lg = l >> 4;
    int lo = max(0, 32*qb - 48);
    int hi = min(N_, 32*qb + 80);
    int wlen = hi - lo;

    __shared__ __hip_bfloat16 Vl[128 * 72];
    __shared__ __hip_bfloat16 Pl[32 * 144];

    {
        int vr0 = l >> 3;
        int c0  = (l & 7) * 8;
        #pragma unroll
        for (int it = 0; it < 16; ++it) {
            int vr = it*8 + vr0;
            int n = lo + vr;
            U8 v;
            if (n < hi) {
                v.v = *(const bf16x8*)(qkv + ((size_t)(b*N_ + n))*2304 + 1536 + h*64 + c0);
            } else {
                #pragma unroll
                for (int j = 0; j < 8; ++j) v.u[j] = 0;
            }
            *(bf16x8*)(Vl + vr*72 + c0) = v.v;
        }
    }

    bf16x8 aq0[2], aq1[2];
    #pragma unroll
    for (int i = 0; i < 2; ++i) {
        int n = qb*32 + i*16 + lr;
        const __hip_bfloat16* qrow = qkv + ((size_t)(b*N_ + n))*2304 + h*64;
        U8 xlo, xhi;
        xlo.v = *(const bf16x8*)(qrow + lg*8);
        xhi.v = *(const bf16x8*)(qrow + 32 + lg*8);
        const float* pc = ropeC + ((size_t)(b*N_ + n))*32 + lg*8;
        const float* ps = ropeS + ((size_t)(b*N_ + n))*32 + lg*8;
        float4 c0 = *(const float4*)(pc), c1 = *(const float4*)(pc + 4);
        float4 s0 = *(const float4*)(ps), s1 = *(const float4*)(ps + 4);
        float cv[8] = {c0.x,c0.y,c0.z,c0.w,c1.x,c1.y,c1.z,c1.w};
        float sv[8] = {s0.x,s0.y,s0.z,s0.w,s1.x,s1.y,s1.z,s1.w};
        U8 f0, f1;
        #pragma unroll
        for (int j = 0; j < 8; ++j) {
            float x1 = __bfloat162float(xlo.e[j]);
            float x2 = __bfloat162float(xhi.e[j]);
            f0.e[j] = __float2bfloat16(x1*cv[j] - x2*sv[j]);
            f1.e[j] = __float2bfloat16(x1*sv[j] + x2*cv[j]);
        }
        aq0[i] = f0.v; aq1[i] = f1.v;
    }

    f32x4 S[2][8];
    #pragma unroll
    for (int i = 0; i < 2; ++i)
        #pragma unroll
        for (int jt = 0; jt < 8; ++jt)
            S[i][jt] = f32x4{0.f, 0.f, 0.f, 0.f};

    #pragma unroll
    for (int jt = 0; jt < 8; ++jt) {
        int n = lo + jt*16 + lr;
        U8 f0, f1;
        if (n < hi) {
            const __hip_bfloat16* krow = qkv + ((size_t)(b*N_ + n))*2304 + 768 + h*64;
            U8 xlo, xhi;
            xlo.v = *(const bf16x8*)(krow + lg*8);
            xhi.v = *(const bf16x8*)(krow + 32 + lg*8);
            const float* pc = ropeC + ((size_t)(b*N_ + n))*32 + lg*8;
            const float* ps = ropeS + ((size_t)(b*N_ + n))*32 + lg*8;
            float4 c0 = *(const float4*)(pc), c1 = *(const float4*)(pc + 4);
            float4 s0 = *(const float4*)(ps), s1 = *(const float4*)(ps + 4);
            float cv[8] = {c0.x,c0.y,c0.z,c0.w,c1.x,c1.y,c1.z,c1.w};
            float sv[8] = {s0.x,s0.y,s0.z,s0.w,s1.x,s1.y,s1.z,s1.w};
            #pragma unroll
            for (int j = 0; j < 8; ++j) {
                float x1 = __bfloat162float(xlo.e[j]);
                float x2 = __bfloat162float(xhi.e[j]);
                f0.e[j] = __float2bfloat16(x1*cv[j] - x2*sv[j]);
                f1.e[j] = __float2bfloat16(x1*sv[j] + x2*cv[j]);
            }
        } else {
            #pragma unroll
            for (int j = 0; j < 8; ++j) { f0.u[j] = 0; f1.u[j] = 0; }
        }
        #pragma unroll
        for (int i = 0; i < 2; ++i) {
            S[i][jt] = __builtin_amdgcn_mfma_f32_16x16x32_bf16(aq0[i], f0.v, S[i][jt], 0, 0, 0);
            S[i][jt] = __builtin_amdgcn_mfma_f32_16x16x32_bf16(aq1[i], f1.v, S[i][jt], 0, 0, 0);
        }
    }

    #pragma unroll
    for (int jt = 0; jt < 8; ++jt) {
        bool oob = (jt*16 + lr) >= wlen;
        #pragma unroll
        for (int i = 0; i < 2; ++i)
            #pragma unroll
            for (int r = 0; r < 4; ++r)
                S[i][jt][r] = oob ? -1e30f : S[i][jt][r] * 0.125f;
    }

    float rinv[2][4];
    #pragma unroll
    for (int i = 0; i < 2; ++i) {
        #pragma unroll
        for (int r = 0; r < 4; ++r) {
            float m = -1e30f;
            #pragma unroll
            for (int jt = 0; jt < 8; ++jt) m = fmaxf(m, S[i][jt][r]);
            #pragma unroll
            for (int mask = 8; mask > 0; mask >>= 1) m = fmaxf(m, __shfl_xor(m, mask, 16));
            float sum = 0.f;
            #pragma unroll
            for (int jt = 0; jt < 8; ++jt) {
                float e = __expf(S[i][jt][r] - m);
                S[i][jt][r] = e;
                sum += e;
            }
            #pragma unroll
            for (int mask = 8; mask > 0; mask >>= 1) sum += __shfl_xor(sum, mask, 16);
            rinv[i][r] = 1.f / sum;
        }
    }

    #pragma unroll
    for (int i = 0; i < 2; ++i)
        #pragma unroll
        for (int jt = 0; jt < 8; ++jt)
            #pragma unroll
            for (int r = 0; r < 4; ++r) {
                int row = i*16 + lg*4 + r;
                int colp = (jt*16 + lr) ^ (lg << 3);
                Pl[row*144 + colp] = __float2bfloat16(S[i][jt][r]);
            }

    __syncthreads();

    f32x4 O_[2][4];
    #pragma unroll
    for (int i = 0; i < 2; ++i)
        #pragma unroll
        for (int ct = 0; ct < 4; ++ct)
            O_[i][ct] = f32x4{0.f, 0.f, 0.f, 0.f};

    int key = (lr >> 2) & 3;
    #pragma unroll
    for (int kt = 0; kt < 4; ++kt) {
        bf16x8 pa[2];
        #pragma unroll
        for (int i = 0; i < 2; ++i) {
            int row = i*16 + lr;
            int colp = (kt*32 + lg*8) ^ (key << 3);
            pa[i] = *(bf16x8*)(Pl + row*144 + colp);
        }
        #pragma unroll
        for (int ct = 0; ct < 4; ++ct) {
            U8 bv;
            #pragma unroll
            for (int j = 0; j < 8; ++j)
                bv.e[j] = Vl[(kt*32 + lg*8 + j)*72 + ct*16 + lr];
            O_[0][ct] = __builtin_amdgcn_mfma_f32_16x16x32_bf16(pa[0], bv.v, O_[0][ct], 0, 0, 0);
            O_[1][ct] = __builtin_amdgcn_mfma_f32_16x16x32_bf16(pa[1], bv.v, O_[1][ct], 0, 0, 0);
        }
    }

    #pragma unroll
    for (int i = 0; i < 2; ++i)
        #pragma unroll
        for (int ct = 0; ct < 4; ++ct)
            #pragma unroll
            for (int r = 0; r < 4; ++r) {
                int row = qb*32 + i*16 + lg*4 + r;
                o[((size_t)(b*N_ + row))*768 + h*64 + ct*16 + lr] =
                    __float2bfloat16(O_[i][ct][r] * rinv[i][r]);
            }
}

// ---------------------------------------------------------------------------
// a2t [B,N,NR] fp32 -> a2tTb [B,NR,N] bf16   grid (NR/32, N/32, B)
// ---------------------------------------------------------------------------
__global__ __launch_bounds__(256) void a2t_transpose_kernel(
    const float* __restrict__ a2t, __hip_bfloat16* __restrict__ a2tTb)
{
    __shared__ float t[32][33];
    int r0 = blockIdx.x * 32, n0 = blockIdx.y * 32, b = blockIdx.z;
    int tid = threadIdx.x;
    int tx = tid & 31, ty = tid >> 5;
    #pragma unroll
    for (int i = 0; i < 4; ++i) {
        int row = ty + i*8;
        t[row][tx] = a2t[((size_t)b*N_ + n0 + row) * 256 + r0 + tx];
    }
    __syncthreads();
    #pragma unroll
    for (int i = 0; i < 4; ++i) {
        int row = ty + i*8;
        a2tTb[((size_t)b*256 + r0 + row) * N_ + n0 + tx] = __float2bfloat16(t[tx][row]);
    }
}

// ---------------------------------------------------------------------------
// recip[row] = 1/(sum of a2tTb row + 1e-6).  block per row (512 rows).
// ---------------------------------------------------------------------------
__global__ __launch_bounds__(256) void rowrecip_kernel(
    const __hip_bfloat16* __restrict__ a2tTb, float* __restrict__ recip)
{
    int row = blockIdx.x;
    int tid = threadIdx.x;
    __shared__ float red4[4];
    U8 v; v.v = *(const bf16x8*)(a2tTb + (size_t)row*2048 + tid*8);
    float s = 0.f;
    #pragma unroll
    for (int j = 0; j < 8; ++j) s += __bfloat162float(v.e[j]);
    float tot = bsum256(s, red4, tid);
    if (tid == 0) recip[row] = 1.f / (tot + 1e-6f);
}

// ---------------------------------------------------------------------------
extern "C" void kernel_launch(void* const* d_in, const int* in_sizes, int n_in,
                              void* d_out, int out_size, void* d_ws, size_t ws_size,
                              hipStream_t stream) {
    const float* atom_coords  = (const float*)d_in[0];
    const float* ref_pos      = (const float*)d_in[1];
    const int*   res_id       = (const int*)  d_in[2];
    const float* res_type     = (const float*)d_in[3];
    const float* charge       = (const float*)d_in[4];
    const float* atomic_num   = (const float*)d_in[5];
    const float* atom_name    = (const float*)d_in[6];
    const float* adaLN_emb    = (const float*)d_in[7];
    const int*   rope_pos     = (const int*)  d_in[8];
    const float* atom_to_tok  = (const float*)d_in[9];
    const float* feat_W       = (const float*)d_in[10];
    const float* feat_b       = (const float*)d_in[11];
    const float* feat_ln_g    = (const float*)d_in[12];
    const float* feat_ln_b    = (const float*)d_in[13];
    const float* pos_W        = (const float*)d_in[14];
    const float* in_W         = (const float*)d_in[15];
    const float* tin_W        = (const float*)d_in[16];
    const float* tin_b        = (const float*)d_in[17];
    const float* tin_ln_g     = (const float*)d_in[18];
    const float* tin_ln_b     = (const float*)d_in[19];
    const float* ada_W        = (const float*)d_in[20];
    const float* ada_b        = (const float*)d_in[21];
    const float* ada_ln_g     = (const float*)d_in[22];
    const float* ada_ln_b     = (const float*)d_in[23];
    const float* blk_mod_W    = (const float*)d_in[24];
    const float* blk_mod_b    = (const float*)d_in[25];
    const float* blk_qkv_W    = (const float*)d_in[26];
    const float* blk_qkv_b    = (const float*)d_in[27];
    const float* blk_o_W      = (const float*)d_in[28];
    const float* blk_o_b      = (const float*)d_in[29];
    const float* blk_m1_W     = (const float*)d_in[30];
    const float* blk_m1_b     = (const float*)d_in[31];
    const float* blk_m2_W     = (const float*)d_in[32];
    const float* blk_m2_b     = (const float*)d_in[33];
    const float* tout_W       = (const float*)d_in[34];
    const float* tout_b       = (const float*)d_in[35];
    const float* tout_ln_g    = (const float*)d_in[36];
    const float* tout_ln_b    = (const float*)d_in[37];

    const int BN = B_ * N_;                          // 4096
    float* ws = (float*)d_ws;

    // layout (float units)
    const size_t OFF_X    = 0;                                // fp32 [4096][768]
    const size_t OFF_HB   = OFF_X    + (size_t)BN*768;        // bf16 [4096][768]
    const size_t OFF_QKVB = OFF_HB   + (size_t)BN*768/2;      // bf16 [4096][2304]
    const size_t OFF_OB   = OFF_QKVB + (size_t)BN*2304/2;     // bf16 [4096][768]
    const size_t OFF_UB   = OFF_OB   + (size_t)BN*768/2;      // bf16 [4096][3072]
    const size_t OFF_WT   = OFF_UB   + (size_t)BN*3072/2;     // bf16 up to 3072*768
    const size_t OFF_RC   = OFF_WT   + (size_t)3072*768/2;    // fp32 BN*32
    const size_t OFF_RS   = OFF_RC   + (size_t)BN*32;
    const size_t OFF_SM   = OFF_RS   + (size_t)BN*32;

    float* X = ws + OFF_X;
    __hip_bfloat16* Hb   = (__hip_bfloat16*)(ws + OFF_HB);
    __hip_bfloat16* QKVb = (__hip_bfloat16*)(ws + OFF_QKVB);
    __hip_bfloat16* Ob   = (__hip_bfloat16*)(ws + OFF_OB);
    __hip_bfloat16* Ub   = (__hip_bfloat16*)(ws + OFF_UB);
    __hip_bfloat16* WT   = (__hip_bfloat16*)(ws + OFF_WT);
    float* ropeC  = ws + OFF_RC;
    float* ropeS  = ws + OFF_RS;
    float* cbuf   = ws + OFF_SM;                     // 1536
    float* c_silu = cbuf + 1536;                     // 1536
    float* mbuf2  = c_silu + 1536;                   // 18432  [2][2][4608]
    float* modpart= mbuf2 + 18432;                   // 73728

    // phase-A aliases
    __hip_bfloat16* featsB  = QKVb;                           // [4096][1024] bf16
    __hip_bfloat16* coordsB = QKVb + (size_t)BN*1024;         // [4096][512] bf16
    float* t1               = ws + OFF_UB;                    // scratch
    __hip_bfloat16* concatB = (__hip_bfloat16*)(t1 + (size_t)BN*256);  // [4096][512] bf16
    __hip_bfloat16* atom_inB= Ob;                             // [4096][256] bf16

    // residue-phase aliases (Ob/Ub regions dead by then)
    __hip_bfloat16* a2tTb   = Ob;                             // [2][256][2048] bf16
    __hip_bfloat16* latTb   = Ob + (size_t)2*256*2048;        // [2][256][2048] bf16
    float* recip            = modpart;                        // 512 fp32

    // split-K partial buffers (aliases of dead regions)
    float* P_pa   = ws + OFF_X;       // phase A (feat/pos/in)
    float* P_tin  = ws + OFF_UB;
    float* P_o    = ws + OFF_UB;
    float* P_m2   = ws + OFF_QKVB;
    float* P_tout = ws + OFF_UB;
    float* P_res  = ws + OFF_UB;

    float* out_res = (float*)d_out;                           // B*NR*DA
    float* out_lat = out_res + (size_t)B_*NR_*DA_;            // B*N*DA

    // ---- adaLN + modulation for both layers (input-only; run first) ----
    ada_kernel<<<2, 256, 0, stream>>>(adaLN_emb, ada_W, ada_b, ada_ln_g, ada_ln_b,
        cbuf, c_silu);
    mod2_kernel<<<dim3(72, 4), 256, 0, stream>>>(c_silu, blk_mod_W, modpart);
    modc_kernel<<<72, 256, 0, stream>>>(modpart, blk_mod_b, mbuf2);

    // ---- featurization (bf16) + rope table (fused) ----
    build_feats_kernel<<<BN, 128, 0, stream>>>(atom_coords, ref_pos, res_id,
        res_type, charge, atomic_num, atom_name, rope_pos, featsB, coordsB,
        ropeC, ropeS);

    // t1 = feats @ feat_W + feat_b   (K padded 924->1024, split 4)
    transconv_kernel<<<dim3(8, 32), 256, 0, stream>>>(feat_W, WT, 924, 1024, 256, 0, 0);
    gemm_bf16_kernel<<<dim3(2, 32, 4), 1024, 0, stream>>>(featsB, 1024, WT, 1024, nullptr,
        nullptr, 0, 1024, 0, 0, nullptr, 0, nullptr, 0, P_pa, 32, 0, 0);
    combln256_kernel<<<BN, 256, 0, stream>>>(P_pa, (size_t)BN*256, 4, feat_b,
        feat_ln_g, feat_ln_b, 1, 1, concatB, 512);
    // concat[:,256:512] = coordsF @ pos_W  (K 387->512, split 4)
    transconv_kernel<<<dim3(8, 16), 256, 0, stream>>>(pos_W, WT, 387, 512, 256, 0, 0);
    gemm_bf16_kernel<<<dim3(2, 32, 4), 1024, 0, stream>>>(coordsB, 512, WT, 512, nullptr,
        nullptr, 0, 512, 0, 0, nullptr, 0, nullptr, 0, P_pa, 32, 0, 0);
    gcomb_kernel<<<1024, 256, 0, stream>>>(P_pa, (size_t)BN*256, 4, 256, nullptr,
        concatB + 256, 512, 0, 1, nullptr, 0, nullptr, 0, nullptr, 0);
    // atom_in = concat @ in_W -> bf16 (split 4)
    transconv_kernel<<<dim3(8, 16), 256, 0, stream>>>(in_W, WT, 512, 512, 256, 0, 0);
    gemm_bf16_kernel<<<dim3(2, 32, 4), 1024, 0, stream>>>(concatB, 512, WT, 512, nullptr,
        nullptr, 0, 512, 0, 0, nullptr, 0, nullptr, 0, P_pa, 32, 0, 0);
    gcomb_kernel<<<1024, 256, 0, stream>>>(P_pa, (size_t)BN*256, 4, 256, nullptr,
        atom_inB, 256, 0, 1, nullptr, 0, nullptr, 0, nullptr, 0);
    // X = LN(atom_in @ tin_W + tin_b) ; Hb = LN(X)*(1+sc1)+sh1  (fused)
    transconv_kernel<<<dim3(24, 8), 256, 0, stream>>>(tin_W, WT, 256, 256, 768, 0, 0);
    gemm_bf16_kernel<<<dim3(6, 32, 2), 1024, 0, stream>>>(atom_inB, 256, WT, 256, nullptr,
        nullptr, 0, 256, 0, 0, nullptr, 0, nullptr, 0, P_tin, 32, 0, 0);
    tinfuse_kernel<<<BN, 256, 0, stream>>>(P_tin, (size_t)BN*768, 2, tin_b,
        tin_ln_g, tin_ln_b, mbuf2 + 768, mbuf2 + 0, X, Hb);

    for (int l = 0; l < NB_; ++l) {
        const float* qkvW = blk_qkv_W + (size_t)l*768*2304;
        const float* qkvB = blk_qkv_b + (size_t)l*2304;
        const float* oW   = blk_o_W   + (size_t)l*768*768;
        const float* oB   = blk_o_b   + (size_t)l*768;
        const float* m1W  = blk_m1_W  + (size_t)l*768*3072;
        const float* m1B  = blk_m1_b  + (size_t)l*3072;
        const float* m2W  = blk_m2_W  + (size_t)l*3072*768;
        const float* m2B  = blk_m2_b  + (size_t)l*768;

        float* mptr = mbuf2 + (size_t)l*9216;        // [b][4608]
        float* sh2 = mptr + 2304, *sc2 = mptr + 3072;
        float* g1  = mptr + 1536, *g2 = mptr + 3840;

        // qkv = h @ qkv_W + b -> bf16
        transconv_kernel<<<dim3(72, 24), 256, 0, stream>>>(qkvW, WT, 768, 768, 2304, 0, 0);
        gemm_bf16_kernel<<<dim3(18, 32, 1), 1024, 0, stream>>>(Hb, 768, WT, 768, qkvB,
            QKVb, 2304, 768, 0, 1, nullptr, 0, nullptr, 0, nullptr, 32, 0, 0);
        // attention
        attn_mfma_kernel<<<B_*H_*64, 64, 0, stream>>>(QKVb, ropeC, ropeS, Ob);
        // x = x + g1*(o @ o_W + o_b)  (split 2) ; fused -> Hb = h2
        transconv_kernel<<<dim3(24, 24), 256, 0, stream>>>(oW, WT, 768, 768, 768, 0, 0);
        gemm_bf16_kernel<<<dim3(6, 32, 2), 1024, 0, stream>>>(Ob, 768, WT, 768, nullptr,
            nullptr, 0, 768, 0, 0, nullptr, 0, nullptr, 0, P_o, 32, 0, 0);
        gcombln_kernel<<<BN, 256, 0, stream>>>(P_o, (size_t)BN*768, 2, oB,
            X, g1, sc2, sh2, Hb);
        // u = gelu(h2 @ m1_W + b) -> bf16
        transconv_kernel<<<dim3(96, 24), 256, 0, stream>>>(m1W, WT, 768, 768, 3072, 0, 0);
        gemm_bf16_kernel<<<dim3(24, 32, 1), 1024, 0, stream>>>(Hb, 768, WT, 768, m1B,
            Ub, 3072, 768, 1, 1, nullptr, 0, nullptr, 0, nullptr, 32, 0, 0);
        // x = x + g2*(u @ m2_W + b)  (split 2)
        transconv_kernel<<<dim3(24, 96), 256, 0, stream>>>(m2W, WT, 3072, 3072, 768, 0, 0);
        gemm_bf16_kernel<<<dim3(6, 32, 2), 1024, 0, stream>>>(Ub, 3072, WT, 3072, nullptr,
            nullptr, 0, 3072, 0, 0, nullptr, 0, nullptr, 0, P_m2, 32, 0, 0);
        if (l < NB_ - 1) {
            float* mnext = mbuf2 + (size_t)(l+1)*9216;
            gcombln_kernel<<<BN, 256, 0, stream>>>(P_m2, (size_t)BN*768, 2, m2B,
                X, g2, mnext + 768, mnext + 0, Hb);
        } else {
            // final layer: X is dead afterward -> write Hb (bf16) directly
            gcomb_kernel<<<3072, 256, 0, stream>>>(P_m2, (size_t)BN*768, 2, 768, m2B,
                Hb, 768, 2, 1, X, 768, g2, 4608, nullptr, 0);
        }
    }

    // atom_latent = LN(x @ tout_W + tout_b)  (split 4, fused combine+LN)
    transconv_kernel<<<dim3(8, 24), 256, 0, stream>>>(tout_W, WT, 768, 768, 256, 0, 0);
    gemm_bf16_kernel<<<dim3(2, 32, 4), 1024, 0, stream>>>(Hb, 768, WT, 768, nullptr,
        nullptr, 0, 768, 0, 0, nullptr, 0, nullptr, 0, P_tout, 32, 0, 0);
    combln256_kernel<<<BN, 256, 0, stream>>>(P_tout, (size_t)BN*256, 4, tout_b,
        tout_ln_g, tout_ln_b, 0, 0, out_lat, 256);

    // ---- residue pooling as MFMA GEMM ----
    a2t_transpose_kernel<<<dim3(8, 64, 2), 256, 0, stream>>>(atom_to_tok, a2tTb);
    rowrecip_kernel<<<512, 256, 0, stream>>>(a2tTb, recip);
    transconv_kernel<<<dim3(8, 64, 2), 256, 0, stream>>>(out_lat, latTb, 2048, 2048, 256,
        (size_t)2048*256, (size_t)256*2048);
    gemm_bf16_kernel<<<dim3(2, 4, 8), 1024, 0, stream>>>(a2tTb, 2048, latTb, 2048, nullptr,
        nullptr, 0, 2048, 0, 0, nullptr, 0, nullptr, 0, P_res,
        2, (size_t)256*2048, (size_t)256*2048);
    gcomb_kernel<<<128, 256, 0, stream>>>(P_res, (size_t)512*256, 8, 256, nullptr,
        out_res, 256, 3, 0, nullptr, 0, recip, 0, nullptr, 0);
}

// Round 16
// 532.956 us; speedup vs baseline: 1.7937x; 1.0390x over previous
//
#include <hip/hip_runtime.h>
#include <hip/hip_bf16.h>
#include <math.h>

// Problem constants
#define B_ 2
#define N_ 2048
#define NR_ 256
#define DA_ 256
#define E_ 768
#define H_ 12
#define DH_ 64
#define NB_ 2

typedef __attribute__((ext_vector_type(8))) __bf16 bf16x8;
typedef __attribute__((ext_vector_type(4))) float f32x4;

union U8 { bf16x8 v; __hip_bfloat16 e[8]; unsigned short u[8]; };
union U4 { __hip_bfloat16 e[4]; uint2 u2; };

__device__ __forceinline__ void gload16(const void* g, void* l) {
    __builtin_amdgcn_global_load_lds(
        (const __attribute__((address_space(1))) void*)g,
        (__attribute__((address_space(3))) void*)l, 16, 0, 0);
}

// 256-thread block sum: wave shuffle + 4-slot LDS combine (2 barriers).
__device__ __forceinline__ float bsum256(float v, float* red4, int tid) {
    #pragma unroll
    for (int m = 32; m > 0; m >>= 1) v += __shfl_xor(v, m, 64);
    __syncthreads();
    if ((tid & 63) == 0) red4[tid >> 6] = v;
    __syncthreads();
    return red4[0] + red4[1] + red4[2] + red4[3];
}

// ---------------------------------------------------------------------------
// build feats[B*N, 1024] (bf16) and coordsF[B*N, 512] (bf16) + rope tables
// ---------------------------------------------------------------------------
__global__ __launch_bounds__(128) void build_feats_kernel(
    const float* __restrict__ atom_coords, const float* __restrict__ ref_pos,
    const int* __restrict__ res_id, const float* __restrict__ res_type,
    const float* __restrict__ charge, const float* __restrict__ atomic_number,
    const float* __restrict__ atom_name, const int* __restrict__ rope_pos,
    __hip_bfloat16* __restrict__ feats, __hip_bfloat16* __restrict__ coordsF,
    float* __restrict__ ropeC, float* __restrict__ ropeS)
{
    int a = blockIdx.x;            // atom index over B*N
    int tid = threadIdx.x;
    __hip_bfloat16* f  = feats   + (size_t)a * 1024;
    __hip_bfloat16* cf = coordsF + (size_t)a * 512;

    float rp[3], cc[3];
    #pragma unroll
    for (int i = 0; i < 3; ++i) { rp[i] = ref_pos[(size_t)a*3 + i]; cc[i] = atom_coords[(size_t)a*3 + i]; }

    if (tid < 3) { f[tid] = __float2bfloat16(rp[tid]); cf[tid] = __float2bfloat16(cc[tid]); }

    if (tid >= 64 && tid < 96) {
        int dd = tid - 64;
        float rpos = (float)rope_pos[a];
        float ang = rpos * expf(-0.28782313662425574f * (float)dd);  // ln(1e4)/32
        float sn, cs; sincosf(ang, &sn, &cs);
        ropeC[a*32 + dd] = cs; ropeS[a*32 + dd] = sn;
    }

    for (int s = tid; s < 192; s += 128) {
        int fi = s / 3, ci = s % 3;
        float freq = exp2f(12.f * (float)fi / 63.f);
        float ar = rp[ci] * freq;
        float ac = cc[ci] * freq;
        float snr, csr, snc, csc_;
        sincosf(ar, &snr, &csr);
        sincosf(ac, &snc, &csc_);
        f[3 + s]    = __float2bfloat16(snr);  f[195 + s]  = __float2bfloat16(csr);
        cf[3 + s]   = __float2bfloat16(snc);  cf[195 + s] = __float2bfloat16(csc_);
    }
    if (tid < 23) f[387 + tid] = __float2bfloat16(res_type[(size_t)a*23 + tid]);

    float pos = (float)res_id[a];
    if (tid == 0) f[410] = __float2bfloat16(pos);
    if (tid < 64) {
        float div = expf(-9.210340371976184f / 128.f * (float)(2 * tid));
        float ang = pos * div;
        float sn, cs; sincosf(ang, &sn, &cs);
        f[411 + tid] = __float2bfloat16(sn);
        f[475 + tid] = __float2bfloat16(cs);
    }
    if (tid == 0) f[539] = __float2bfloat16(charge[a]);
    if (tid < 128) f[540 + tid] = __float2bfloat16(atomic_number[(size_t)a*128 + tid]);
    for (int s = tid; s < 256; s += 128) f[668 + s] = __float2bfloat16(atom_name[(size_t)a*256 + s]);
    if (tid < 100) f[924 + tid] = __float2bfloat16(0.f);
    if (tid < 125) cf[387 + tid] = __float2bfloat16(0.f);
}

// ---------------------------------------------------------------------------
// Transpose + fp32->bf16 + K-pad: W[Ksrc][Nn] -> WT[Nn][Kdst], zeros k>=Ksrc
// ---------------------------------------------------------------------------
__global__ __launch_bounds__(256) void transconv_kernel(
    const float* __restrict__ W, __hip_bfloat16* __restrict__ WT,
    int Ksrc, int Kdst, int Nn, size_t wstride, size_t tstride)
{
    __shared__ float t[32][33];
    W  += (size_t)blockIdx.z * wstride;
    WT += (size_t)blockIdx.z * tstride;
    int n0 = blockIdx.x * 32, k0 = blockIdx.y * 32;
    int tid = threadIdx.x;
    int tx = tid & 31, ty = tid >> 5;           // ty 0..7
    #pragma unroll
    for (int i = 0; i < 4; ++i) {
        int k = k0 + ty + i*8;
        t[ty + i*8][tx] = (k < Ksrc) ? W[(size_t)k * Nn + n0 + tx] : 0.f;
    }
    __syncthreads();
    #pragma unroll
    for (int i = 0; i < 4; ++i) {
        int row = ty + i*8;                      // n within tile
        WT[(size_t)(n0 + row) * Kdst + k0 + tx] = __float2bfloat16(t[tx][row]);
    }
}

// ---------------------------------------------------------------------------
// shared epilogue.  mode 0 none; 1 gelu; 2 X + gate[b][col]*v; 3 v*gate[row]
// ---------------------------------------------------------------------------
__device__ __forceinline__ float epi_apply(float v, int grow, int gcol,
    const float* bias, int mode, const float* X, int ldx,
    const float* gate, int gstride)
{
    if (bias) v += bias[gcol];
    if (mode == 1) {
        float u = 1.5957691216057308f * (v + 0.044715f * v * v * v);
        v = v / (1.f + __expf(-u));
    } else if (mode == 2) {
        int b = grow >> 11;                      // /N_
        v = X[(size_t)grow * ldx + gcol] + gate[(size_t)b * gstride + gcol] * v;
    } else if (mode == 3) {
        v = v * gate[grow];
    }
    return v;
}

// ---------------------------------------------------------------------------
// bf16 MFMA GEMM: tile 128x128, BK=32, 16 waves (1024 thr), 32x32 per wave.
// dbuf-2 LDS (32 KB): barrier -> issue STAGE(next) -> ds_read+MFMA(current).
// Staging: 1 gload16/thread; waves 0-7 stage A, waves 8-15 stage B (uniform).
// XOR-swizzle both sides: key(row)=(row>>1)&3.  Bijective XCD swizzle.
// gridDim.z = nz splits K; nz>1 -> raw fp32 partials to P.
// ---------------------------------------------------------------------------
__global__ __launch_bounds__(1024) void gemm_bf16_kernel(
    const __hip_bfloat16* __restrict__ A, int lda,
    const __hip_bfloat16* __restrict__ BT, int ldb,
    const float* __restrict__ bias,
    void* __restrict__ C, int ldc,
    int K, int mode, int obf,
    const float* __restrict__ X, int ldx,
    const float* __restrict__ gate, int gstride,
    float* __restrict__ P,
    int mtiles, size_t bstrideA, size_t bstrideB)
{
    __shared__ __hip_bfloat16 As[2][128 * 32];
    __shared__ __hip_bfloat16 Bs[2][128 * 32];

    int gx = gridDim.x;
    int nwg = gx * gridDim.y;
    int fo = blockIdx.y * gx + blockIdx.x;
    int ft = (fo & 7) * (nwg >> 3) + (fo >> 3);
    int bx = ft % gx, by = ft / gx;

    int bb  = by / mtiles;
    int m0l = (by % mtiles) * 128;
    int m0g = by * 128;
    int n0 = bx * 128;
    const __hip_bfloat16* Ab  = A  + (size_t)bb * bstrideA;
    const __hip_bfloat16* BTb = BT + (size_t)bb * bstrideB;
    int nz = gridDim.z;
    int Kh = K / nz;
    int kb = blockIdx.z * Kh;
    int tid = threadIdx.x;
    int w = tid >> 6, l = tid & 63;
    int wr = (w >> 2) * 32, wc = (w & 3) * 32;   // 4 wave-rows x 4 wave-cols
    int lr = l & 15, lg = l >> 4;
    int slot = ((lg ^ ((lr >> 1) & 3)) & 3) * 8;

    // staging: 1 seg/thread; low 8 waves -> A, high 8 waves -> B
    int sop  = tid >> 9;                         // 0 = A, 1 = B (wave-uniform)
    int seg  = tid & 511;
    int rowS = seg >> 2;
    int gS   = (seg & 3) ^ ((rowS >> 1) & 3);
    const __hip_bfloat16* srcBase = sop ? (BTb + (size_t)(n0 + rowS) * ldb)
                                        : (Ab  + (size_t)(m0l + rowS) * lda);
    __hip_bfloat16* dst0 = (sop ? Bs[0] : As[0]);
    __hip_bfloat16* dst1 = (sop ? Bs[1] : As[1]);

    f32x4 acc[2][2];
    #pragma unroll
    for (int i = 0; i < 2; ++i)
        #pragma unroll
        for (int j = 0; j < 2; ++j)
            acc[i][j] = f32x4{0.f, 0.f, 0.f, 0.f};

    // prologue: stage first tile into buf 0
    gload16(srcBase + kb + gS * 8, (char*)dst0 + seg * 16);

    int cur = 0;
    for (int k0 = kb; k0 < kb + Kh; k0 += 32) {
        __syncthreads();                         // vmcnt(0): buf[cur] ready
        int kn = k0 + 32;
        if (kn < kb + Kh) {
            gload16(srcBase + kn + gS * 8, (char*)(cur ? dst0 : dst1) + seg * 16);
        }
        bf16x8 af[2], bfr[2];
        #pragma unroll
        for (int i = 0; i < 2; ++i)
            af[i]  = *(bf16x8*)(As[cur] + (wr + i*16 + lr) * 32 + slot);
        #pragma unroll
        for (int j = 0; j < 2; ++j)
            bfr[j] = *(bf16x8*)(Bs[cur] + (wc + j*16 + lr) * 32 + slot);
        #pragma unroll
        for (int i = 0; i < 2; ++i)
            #pragma unroll
            for (int j = 0; j < 2; ++j)
                acc[i][j] = __builtin_amdgcn_mfma_f32_16x16x32_bf16(af[i], bfr[j], acc[i][j], 0, 0, 0);
        cur ^= 1;
    }

    if (nz > 1) {
        int Nw = gridDim.x * 128;
        size_t pstride = (size_t)Nw * (gridDim.y * 128);
        float* Pz = P + (size_t)blockIdx.z * pstride;
        #pragma unroll
        for (int i = 0; i < 2; ++i)
            #pragma unroll
            for (int j = 0; j < 2; ++j)
                #pragma unroll
                for (int r = 0; r < 4; ++r) {
                    int grow = m0g + wr + i*16 + lg*4 + r;
                    int gcol = n0 + wc + j*16 + lr;
                    Pz[(size_t)grow * Nw + gcol] = acc[i][j][r];
                }
        return;
    }

    #pragma unroll
    for (int i = 0; i < 2; ++i)
        #pragma unroll
        for (int j = 0; j < 2; ++j)
            #pragma unroll
            for (int r = 0; r < 4; ++r) {
                int grow = m0g + wr + i*16 + lg*4 + r;
                int gcol = n0 + wc + j*16 + lr;
                float v = epi_apply(acc[i][j][r], grow, gcol, bias, mode, X, ldx, gate, gstride);
                if (obf)
                    ((__hip_bfloat16*)C)[(size_t)grow * ldc + gcol] = __float2bfloat16(v);
                else
                    ((float*)C)[(size_t)grow * ldc + gcol] = v;
            }
}

// ---------------------------------------------------------------------------
// combine split-K partials + epilogue. 4 elems/thread. optional C2 bf16 out.
// ---------------------------------------------------------------------------
__global__ __launch_bounds__(256) void gcomb_kernel(
    const float* __restrict__ P, size_t pstride, int nz, int Nw,
    const float* __restrict__ bias,
    void* __restrict__ C, int ldc, int mode, int obf,
    const float* __restrict__ X, int ldx,
    const float* __restrict__ gate, int gstride,
    __hip_bfloat16* __restrict__ C2, int ldc2)
{
    int idx = blockIdx.x * 256 + threadIdx.x;
    int e0 = idx * 4;
    int grow = e0 / Nw, gc0 = e0 % Nw;
    float4 v = *(const float4*)(P + (size_t)grow * Nw + gc0);
    for (int z = 1; z < nz; ++z) {
        float4 t = *(const float4*)(P + (size_t)z * pstride + (size_t)grow * Nw + gc0);
        v.x += t.x; v.y += t.y; v.z += t.z; v.w += t.w;
    }
    float e[4] = {v.x, v.y, v.z, v.w};
    #pragma unroll
    for (int r = 0; r < 4; ++r)
        e[r] = epi_apply(e[r], grow, gc0 + r, bias, mode, X, ldx, gate, gstride);
    if (obf) {
        U4 o4;
        #pragma unroll
        for (int r = 0; r < 4; ++r) o4.e[r] = __float2bfloat16(e[r]);
        *(uint2*)((__hip_bfloat16*)C + (size_t)grow * ldc + gc0) = o4.u2;
    } else {
        *(float4*)((float*)C + (size_t)grow * ldc + gc0) = make_float4(e[0], e[1], e[2], e[3]);
    }
    if (C2) {
        U4 o4;
        #pragma unroll
        for (int r = 0; r < 4; ++r) o4.e[r] = __float2bfloat16(e[r]);
        *(uint2*)(C2 + (size_t)grow * ldc2 + gc0) = o4.u2;
    }
}

// ---------------------------------------------------------------------------
// fused: combine split-K (nz, D=256) + bias + LayerNorm(g,b) [+silu] -> out
// ---------------------------------------------------------------------------
__global__ __launch_bounds__(256) void combln256_kernel(
    const float* __restrict__ P, size_t pstride, int nz,
    const float* __restrict__ bias,
    const float* __restrict__ g, const float* __restrict__ bv,
    int do_silu, int obf,
    void* __restrict__ out, int ldout)
{
    int row = blockIdx.x, d = threadIdx.x;
    __shared__ float red4[4];
    float v = P[(size_t)row*256 + d];
    for (int z = 1; z < nz; ++z) v += P[(size_t)z*pstride + (size_t)row*256 + d];
    v += bias[d];
    float mu = bsum256(v, red4, d) * (1.f/256.f);
    float dv = v - mu;
    float rstd = rsqrtf(bsum256(dv*dv, red4, d) * (1.f/256.f) + 1e-5f);
    float y = dv * rstd * g[d] + bv[d];
    if (do_silu) y = y / (1.f + __expf(-y));
    if (obf) ((__hip_bfloat16*)out)[(size_t)row * ldout + d] = __float2bfloat16(y);
    else     ((float*)out)[(size_t)row * ldout + d] = y;
}

// ---------------------------------------------------------------------------
// tin-chain fusion: combine split-K (nz, D=768) + bias ->
//   X = LN(t; g,b)  (write fp32) ; Hb = bf16( LN2(X)*(1+scm[b]) + shm[b] )
// ---------------------------------------------------------------------------
__global__ __launch_bounds__(256) void tinfuse_kernel(
    const float* __restrict__ P, size_t pstride, int nz,
    const float* __restrict__ bias,
    const float* __restrict__ g, const float* __restrict__ bb,
    const float* __restrict__ scm, const float* __restrict__ shm,
    float* __restrict__ X, __hip_bfloat16* __restrict__ Hb)
{
    int row = blockIdx.x, tid = threadIdx.x;
    int b = row >> 11;
    __shared__ float red4[4];
    float tv[3];
    float s = 0.f;
    #pragma unroll
    for (int q = 0; q < 3; ++q) {
        int d = tid + q*256;
        float v = P[(size_t)row*768 + d];
        for (int z = 1; z < nz; ++z) v += P[(size_t)z*pstride + (size_t)row*768 + d];
        v += bias[d];
        tv[q] = v; s += v;
    }
    float mu1 = bsum256(s, red4, tid) * (1.f/768.f);
    float s2 = 0.f;
    #pragma unroll
    for (int q = 0; q < 3; ++q) { float dv = tv[q] - mu1; s2 += dv*dv; }
    float rstd1 = rsqrtf(bsum256(s2, red4, tid) * (1.f/768.f) + 1e-5f);
    float xv[3];
    float s3 = 0.f;
    #pragma unroll
    for (int q = 0; q < 3; ++q) {
        int d = tid + q*256;
        float y = (tv[q] - mu1) * rstd1 * g[d] + bb[d];
        X[(size_t)row*768 + d] = y;
        xv[q] = y; s3 += y;
    }
    float mu2 = bsum256(s3, red4, tid) * (1.f/768.f);
    float s4 = 0.f;
    #pragma unroll
    for (int q = 0; q < 3; ++q) { float dv = xv[q] - mu2; s4 += dv*dv; }
    float rstd2 = rsqrtf(bsum256(s4, red4, tid) * (1.f/768.f) + 1e-5f);
    #pragma unroll
    for (int q = 0; q < 3; ++q) {
        int d = tid + q*256;
        float h = (xv[q] - mu2) * rstd2 * (1.f + scm[(size_t)b*4608 + d]) + shm[(size_t)b*4608 + d];
        Hb[(size_t)row*768 + d] = __float2bfloat16(h);
    }
}

// ---------------------------------------------------------------------------
// fused: combine split-K (nz) + bias + residual-gate into X, then
// Hb = bf16( LN(xnew)*(1+scm[b]) + shm[b] ).  block per row, D=768.
// ---------------------------------------------------------------------------
__global__ __launch_bounds__(256) void gcombln_kernel(
    const float* __restrict__ P, size_t pstride, int nz,
    const float* __restrict__ bias,
    float* __restrict__ X,
    const float* __restrict__ gate,
    const float* __restrict__ scm, const float* __restrict__ shm,
    __hip_bfloat16* __restrict__ Hb)
{
    int row = blockIdx.x, tid = threadIdx.x;
    int b = row >> 11;
    __shared__ float red4[4];
    float xv[3];
    float s = 0.f;
    #pragma unroll
    for (int q = 0; q < 3; ++q) {
        int d = tid + q*256;
        float v = P[(size_t)row*768 + d];
        for (int z = 1; z < nz; ++z) v += P[(size_t)z*pstride + (size_t)row*768 + d];
        v += bias[d];
        v = X[(size_t)row*768 + d] + gate[(size_t)b*4608 + d] * v;
        X[(size_t)row*768 + d] = v;
        xv[q] = v; s += v;
    }
    float mu = bsum256(s, red4, tid) * (1.f/768.f);
    float s2 = 0.f;
    #pragma unroll
    for (int q = 0; q < 3; ++q) { float dv = xv[q] - mu; s2 += dv*dv; }
    float rstd = rsqrtf(bsum256(s2, red4, tid) * (1.f/768.f) + 1e-5f);
    #pragma unroll
    for (int q = 0; q < 3; ++q) {
        int d = tid + q*256;
        float y = (xv[q] - mu) * rstd * (1.f + scm[(size_t)b*4608 + d]) + shm[(size_t)b*4608 + d];
        Hb[(size_t)row*768 + d] = __float2bfloat16(y);
    }
}

// ---------------------------------------------------------------------------
// c = LN(adaLN_emb @ ada_W + ada_b; g,b); c_silu = silu(c). 2 blocks.
// ---------------------------------------------------------------------------
__global__ __launch_bounds__(256) void ada_kernel(
    const float* __restrict__ emb, const float* __restrict__ W,
    const float* __restrict__ bias,
    const float* __restrict__ g, const float* __restrict__ bb,
    float* __restrict__ c, float* __restrict__ c_silu)
{
    int b = blockIdx.x, tid = threadIdx.x;
    __shared__ float emb_s[256];
    __shared__ float t[768];
    __shared__ float red[256];
    emb_s[tid] = emb[b*256 + tid];
    __syncthreads();
    for (int q = 0; q < 3; ++q) {
        int e = tid + q*256;
        float acc = bias[e];
        for (int k = 0; k < 256; ++k) acc += emb_s[k] * W[(size_t)k*768 + e];
        t[e] = acc;
    }
    __syncthreads();
    float s = 0.f; for (int q = 0; q < 3; ++q) s += t[tid + q*256];
    red[tid] = s; __syncthreads();
    for (int off = 128; off > 0; off >>= 1) { if (tid < off) red[tid] += red[tid+off]; __syncthreads(); }
    float mu = red[0] / 768.f; __syncthreads();
    float s2 = 0.f; for (int q = 0; q < 3; ++q) { float d = t[tid + q*256] - mu; s2 += d*d; }
    red[tid] = s2; __syncthreads();
    for (int off = 128; off > 0; off >>= 1) { if (tid < off) red[tid] += red[tid+off]; __syncthreads(); }
    float rstd = rsqrtf(red[0] / 768.f + 1e-5f);
    for (int q = 0; q < 3; ++q) {
        int e = tid + q*256;
        float y = (t[e] - mu) * rstd * g[e] + bb[e];
        c[b*768 + e] = y;
        c_silu[b*768 + e] = y / (1.f + expf(-y));
    }
}

// ---------------------------------------------------------------------------
// mod for BOTH layers, K-split 4: part[z][l][b][4608] ; grid (72, 4)
// ---------------------------------------------------------------------------
__global__ __launch_bounds__(256) void mod2_kernel(
    const float* __restrict__ c_silu, const float* __restrict__ mod_W,
    float* __restrict__ part)
{
    int idx = blockIdx.x * 256 + threadIdx.x;   // < 18432
    int z = blockIdx.y;
    int lyr = idx / 9216, b = (idx / 4608) & 1, j = idx % 4608;
    const float* Wl = mod_W + (size_t)lyr * 768 * 4608;
    const float* cs = c_silu + b * 768;
    float acc = 0.f;
    int k0 = z * 192;
    for (int k = k0; k < k0 + 192; ++k) acc += cs[k] * Wl[(size_t)k * 4608 + j];
    part[(size_t)z * 18432 + idx] = acc;
}

__global__ __launch_bounds__(256) void modc_kernel(
    const float* __restrict__ part, const float* __restrict__ mod_b,
    float* __restrict__ m2buf)
{
    int idx = blockIdx.x * 256 + threadIdx.x;
    int lyr = idx / 9216, j = idx % 4608;
    float acc = mod_b[(size_t)lyr * 4608 + j];
    #pragma unroll
    for (int z = 0; z < 4; ++z) acc += part[(size_t)z * 18432 + idx];
    m2buf[idx] = acc;
}

// ---------------------------------------------------------------------------
// MFMA local-window attention. 4 waves/block; block = (b, h, qgroup of 4
// qblocks).  Shared V window staged once: Vl[224][72] covers the union of the
// 4 waves' windows (wave w reads rows [off_w, off_w+128) of Vl).  Per-wave
// P-scratch private.  Single __syncthreads (stage+P-write before, PV after).
// ---------------------------------------------------------------------------
__global__ __launch_bounds__(256) void attn_mfma_kernel(
    const __hip_bfloat16* __restrict__ qkv,   // [B*N, 2304]
    const float* __restrict__ ropeC,          // [B*N, 32]
    const float* __restrict__ ropeS,
    __hip_bfloat16* __restrict__ o)           // [B*N, 768]
{
    int bid = blockIdx.x;
    int qg = bid & 15;                 // q-group (4 qblocks)
    int h  = (bid >> 4) % 12;
    int b  = bid / 192;
    int tid = threadIdx.x;
    int w  = tid >> 6;                 // wave 0..3
    int l  = tid & 63;
    int lr = l & 15, lg = l >> 4;

    int qb = qg * 4 + w;
    int lo_blk = max(0, 128*qg - 48);
    int hi_blk = min(N_, 128*qg + 176);
    int lo = max(0, 32*qb - 48);
    int hi = min(N_, 32*qb + 80);
    int wlen = hi - lo;
    int offv = lo - lo_blk;            // wave's row offset into Vl

    __shared__ __hip_bfloat16 Vl[224 * 72];
    __shared__ __hip_bfloat16 Pl[4 * 32 * 144];
    __hip_bfloat16* Plw = Pl + w * (32 * 144);

    // ---- stage shared V window (all 256 threads), zero-fill past hi_blk ----
    {
        int vr0 = tid >> 3;            // 0..31
        int c0  = (tid & 7) * 8;
        #pragma unroll
        for (int it = 0; it < 7; ++it) {
            int vr = it*32 + vr0;      // 0..223
            int n = lo_blk + vr;
            U8 v;
            if (n < hi_blk) {
                v.v = *(const bf16x8*)(qkv + ((size_t)(b*N_ + n))*2304 + 1536 + h*64 + c0);
            } else {
                #pragma unroll
                for (int j = 0; j < 8; ++j) v.u[j] = 0;
            }
            *(bf16x8*)(Vl + vr*72 + c0) = v.v;
        }
    }

    // ---- Q fragments with rope ----
    bf16x8 aq0[2], aq1[2];
    #pragma unroll
    for (int i = 0; i < 2; ++i) {
        int n = qb*32 + i*16 + lr;
        const __hip_bfloat16* qrow = qkv + ((size_t)(b*N_ + n))*2304 + h*64;
        U8 xlo, xhi;
        xlo.v = *(const bf16x8*)(qrow + lg*8);
        xhi.v = *(const bf16x8*)(qrow + 32 + lg*8);
        const float* pc = ropeC + ((size_t)(b*N_ + n))*32 + lg*8;
        const float* ps = ropeS + ((size_t)(b*N_ + n))*32 + lg*8;
        float4 c0 = *(const float4*)(pc), c1 = *(const float4*)(pc + 4);
        float4 s0 = *(const float4*)(ps), s1 = *(const float4*)(ps + 4);
        float cv[8] = {c0.x,c0.y,c0.z,c0.w,c1.x,c1.y,c1.z,c1.w};
        float sv[8] = {s0.x,s0.y,s0.z,s0.w,s1.x,s1.y,s1.z,s1.w};
        U8 f0, f1;
        #pragma unroll
        for (int j = 0; j < 8; ++j) {
            float x1 = __bfloat162float(xlo.e[j]);
            float x2 = __bfloat162float(xhi.e[j]);
            f0.e[j] = __float2bfloat16(x1*cv[j] - x2*sv[j]);
            f1.e[j] = __float2bfloat16(x1*sv[j] + x2*cv[j]);
        }
        aq0[i] = f0.v; aq1[i] = f1.v;
    }

    // ---- scores ----
    f32x4 S[2][8];
    #pragma unroll
    for (int i = 0; i < 2; ++i)
        #pragma unroll
        for (int jt = 0; jt < 8; ++jt)
            S[i][jt] = f32x4{0.f, 0.f, 0.f, 0.f};

    #pragma unroll
    for (int jt = 0; jt < 8; ++jt) {
        int n = lo + jt*16 + lr;
        U8 f0, f1;
        if (n < hi) {
            const __hip_bfloat16* krow = qkv + ((size_t)(b*N_ + n))*2304 + 768 + h*64;
            U8 xlo, xhi;
            xlo.v = *(const bf16x8*)(krow + lg*8);
            xhi.v = *(const bf16x8*)(krow + 32 + lg*8);
            const float* pc = ropeC + ((size_t)(b*N_ + n))*32 + lg*8;
            const float* ps = ropeS + ((size_t)(b*N_ + n))*32 + lg*8;
            float4 c0 = *(const float4*)(pc), c1 = *(const float4*)(pc + 4);
            float4 s0 = *(const float4*)(ps), s1 = *(const float4*)(ps + 4);
            float cv[8] = {c0.x,c0.y,c0.z,c0.w,c1.x,c1.y,c1.z,c1.w};
            float sv[8] = {s0.x,s0.y,s0.z,s0.w,s1.x,s1.y,s1.z,s1.w};
            #pragma unroll
            for (int j = 0; j < 8; ++j) {
                float x1 = __bfloat162float(xlo.e[j]);
                float x2 = __bfloat162float(xhi.e[j]);
                f0.e[j] = __float2bfloat16(x1*cv[j] - x2*sv[j]);
                f1.e[j] = __float2bfloat16(x1*sv[j] + x2*cv[j]);
            }
        } else {
            #pragma unroll
            for (int j = 0; j < 8; ++j) { f0.u[j] = 0; f1.u[j] = 0; }
        }
        #pragma unroll
        for (int i = 0; i < 2; ++i) {
            S[i][jt] = __builtin_amdgcn_mfma_f32_16x16x32_bf16(aq0[i], f0.v, S[i][jt], 0, 0, 0);
            S[i][jt] = __builtin_amdgcn_mfma_f32_16x16x32_bf16(aq1[i], f1.v, S[i][jt], 0, 0, 0);
        }
    }

    // ---- scale + mask ----
    #pragma unroll
    for (int jt = 0; jt < 8; ++jt) {
        bool oob = (jt*16 + lr) >= wlen;
        #pragma unroll
        for (int i = 0; i < 2; ++i)
            #pragma unroll
            for (int r = 0; r < 4; ++r)
                S[i][jt][r] = oob ? -1e30f : S[i][jt][r] * 0.125f;
    }

    // ---- wave-parallel softmax over 16-lane groups ----
    float rinv[2][4];
    #pragma unroll
    for (int i = 0; i < 2; ++i) {
        #pragma unroll
        for (int r = 0; r < 4; ++r) {
            float m = -1e30f;
            #pragma unroll
            for (int jt = 0; jt < 8; ++jt) m = fmaxf(m, S[i][jt][r]);
            #pragma unroll
            for (int mask = 8; mask > 0; mask >>= 1) m = fmaxf(m, __shfl_xor(m, mask, 16));
            float sum = 0.f;
            #pragma unroll
            for (int jt = 0; jt < 8; ++jt) {
                float e = __expf(S[i][jt][r] - m);
                S[i][jt][r] = e;
                sum += e;
            }
            #pragma unroll
            for (int mask = 8; mask > 0; mask >>= 1) sum += __shfl_xor(sum, mask, 16);
            rinv[i][r] = 1.f / sum;
        }
    }

    // ---- write P (bf16, XOR-swizzled cols) into this wave's region ----
    #pragma unroll
    for (int i = 0; i < 2; ++i)
        #pragma unroll
        for (int jt = 0; jt < 8; ++jt)
            #pragma unroll
            for (int r = 0; r < 4; ++r) {
                int row = i*16 + lg*4 + r;
                int colp = (jt*16 + lr) ^ (lg << 3);
                Plw[row*144 + colp] = __float2bfloat16(S[i][jt][r]);
            }

    __syncthreads();   // Vl staged by all + Plw written before; PV reads after

    // ---- PV ----
    f32x4 O_[2][4];
    #pragma unroll
    for (int i = 0; i < 2; ++i)
        #pragma unroll
        for (int ct = 0; ct < 4; ++ct)
            O_[i][ct] = f32x4{0.f, 0.f, 0.f, 0.f};

    int key = (lr >> 2) & 3;
    #pragma unroll
    for (int kt = 0; kt < 4; ++kt) {
        bf16x8 pa[2];
        #pragma unroll
        for (int i = 0; i < 2; ++i) {
            int row = i*16 + lr;
            int colp = (kt*32 + lg*8) ^ (key << 3);
            pa[i] = *(bf16x8*)(Plw + row*144 + colp);
        }
        #pragma unroll
        for (int ct = 0; ct < 4; ++ct) {
            U8 bv;
            #pragma unroll
            for (int j = 0; j < 8; ++j)
                bv.e[j] = Vl[(offv + kt*32 + lg*8 + j)*72 + ct*16 + lr];
            O_[0][ct] = __builtin_amdgcn_mfma_f32_16x16x32_bf16(pa[0], bv.v, O_[0][ct], 0, 0, 0);
            O_[1][ct] = __builtin_amdgcn_mfma_f32_16x16x32_bf16(pa[1], bv.v, O_[1][ct], 0, 0, 0);
        }
    }

    // ---- store O ----
    #pragma unroll
    for (int i = 0; i < 2; ++i)
        #pragma unroll
        for (int ct = 0; ct < 4; ++ct)
            #pragma unroll
            for (int r = 0; r < 4; ++r) {
                int row = qb*32 + i*16 + lg*4 + r;
                o[((size_t)(b*N_ + row))*768 + h*64 + ct*16 + lr] =
                    __float2bfloat16(O_[i][ct][r] * rinv[i][r]);
            }
}

// ---------------------------------------------------------------------------
// a2t [B,N,NR] fp32 -> a2tTb [B,NR,N] bf16   grid (NR/32, N/32, B)
// ---------------------------------------------------------------------------
__global__ __launch_bounds__(256) void a2t_transpose_kernel(
    const float* __restrict__ a2t, __hip_bfloat16* __restrict__ a2tTb)
{
    __shared__ float t[32][33];
    int r0 = blockIdx.x * 32, n0 = blockIdx.y * 32, b = blockIdx.z;
    int tid = threadIdx.x;
    int tx = tid & 31, ty = tid >> 5;
    #pragma unroll
    for (int i = 0; i < 4; ++i) {
        int row = ty + i*8;
        t[row][tx] = a2t[((size_t)b*N_ + n0 + row) * 256 + r0 + tx];
    }
    __syncthreads();
    #pragma unroll
    for (int i = 0; i < 4; ++i) {
        int row = ty + i*8;
        a2tTb[((size_t)b*256 + r0 + row) * N_ + n0 + tx] = __float2bfloat16(t[tx][row]);
    }
}

// ---------------------------------------------------------------------------
// recip[row] = 1/(sum of a2tTb row + 1e-6).  block per row (512 rows).
// ---------------------------------------------------------------------------
__global__ __launch_bounds__(256) void rowrecip_kernel(
    const __hip_bfloat16* __restrict__ a2tTb, float* __restrict__ recip)
{
    int row = blockIdx.x;
    int tid = threadIdx.x;
    __shared__ float red4[4];
    U8 v; v.v = *(const bf16x8*)(a2tTb + (size_t)row*2048 + tid*8);
    float s = 0.f;
    #pragma unroll
    for (int j = 0; j < 8; ++j) s += __bfloat162float(v.e[j]);
    float tot = bsum256(s, red4, tid);
    if (tid == 0) recip[row] = 1.f / (tot + 1e-6f);
}

// ---------------------------------------------------------------------------
extern "C" void kernel_launch(void* const* d_in, const int* in_sizes, int n_in,
                              void* d_out, int out_size, void* d_ws, size_t ws_size,
                              hipStream_t stream) {
    const float* atom_coords  = (const float*)d_in[0];
    const float* ref_pos      = (const float*)d_in[1];
    const int*   res_id       = (const int*)  d_in[2];
    const float* res_type     = (const float*)d_in[3];
    const float* charge       = (const float*)d_in[4];
    const float* atomic_num   = (const float*)d_in[5];
    const float* atom_name    = (const float*)d_in[6];
    const float* adaLN_emb    = (const float*)d_in[7];
    const int*   rope_pos     = (const int*)  d_in[8];
    const float* atom_to_tok  = (const float*)d_in[9];
    const float* feat_W       = (const float*)d_in[10];
    const float* feat_b       = (const float*)d_in[11];
    const float* feat_ln_g    = (const float*)d_in[12];
    const float* feat_ln_b    = (const float*)d_in[13];
    const float* pos_W        = (const float*)d_in[14];
    const float* in_W         = (const float*)d_in[15];
    const float* tin_W        = (const float*)d_in[16];
    const float* tin_b        = (const float*)d_in[17];
    const float* tin_ln_g     = (const float*)d_in[18];
    const float* tin_ln_b     = (const float*)d_in[19];
    const float* ada_W        = (const float*)d_in[20];
    const float* ada_b        = (const float*)d_in[21];
    const float* ada_ln_g     = (const float*)d_in[22];
    const float* ada_ln_b     = (const float*)d_in[23];
    const float* blk_mod_W    = (const float*)d_in[24];
    const float* blk_mod_b    = (const float*)d_in[25];
    const float* blk_qkv_W    = (const float*)d_in[26];
    const float* blk_qkv_b    = (const float*)d_in[27];
    const float* blk_o_W      = (const float*)d_in[28];
    const float* blk_o_b      = (const float*)d_in[29];
    const float* blk_m1_W     = (const float*)d_in[30];
    const float* blk_m1_b     = (const float*)d_in[31];
    const float* blk_m2_W     = (const float*)d_in[32];
    const float* blk_m2_b     = (const float*)d_in[33];
    const float* tout_W       = (const float*)d_in[34];
    const float* tout_b       = (const float*)d_in[35];
    const float* tout_ln_g    = (const float*)d_in[36];
    const float* tout_ln_b    = (const float*)d_in[37];

    const int BN = B_ * N_;                          // 4096
    float* ws = (float*)d_ws;

    // layout (float units)
    const size_t OFF_X    = 0;                                // fp32 [4096][768]
    const size_t OFF_HB   = OFF_X    + (size_t)BN*768;        // bf16 [4096][768]
    const size_t OFF_QKVB = OFF_HB   + (size_t)BN*768/2;      // bf16 [4096][2304]
    const size_t OFF_OB   = OFF_QKVB + (size_t)BN*2304/2;     // bf16 [4096][768]
    const size_t OFF_UB   = OFF_OB   + (size_t)BN*768/2;      // bf16 [4096][3072]
    const size_t OFF_WT   = OFF_UB   + (size_t)BN*3072/2;     // bf16 up to 3072*768
    const size_t OFF_RC   = OFF_WT   + (size_t)3072*768/2;    // fp32 BN*32
    const size_t OFF_RS   = OFF_RC   + (size_t)BN*32;
    const size_t OFF_SM   = OFF_RS   + (size_t)BN*32;

    float* X = ws + OFF_X;
    __hip_bfloat16* Hb   = (__hip_bfloat16*)(ws + OFF_HB);
    __hip_bfloat16* QKVb = (__hip_bfloat16*)(ws + OFF_QKVB);
    __hip_bfloat16* Ob   = (__hip_bfloat16*)(ws + OFF_OB);
    __hip_bfloat16* Ub   = (__hip_bfloat16*)(ws + OFF_UB);
    __hip_bfloat16* WT   = (__hip_bfloat16*)(ws + OFF_WT);
    float* ropeC  = ws + OFF_RC;
    float* ropeS  = ws + OFF_RS;
    float* cbuf   = ws + OFF_SM;                     // 1536
    float* c_silu = cbuf + 1536;                     // 1536
    float* mbuf2  = c_silu + 1536;                   // 18432  [2][2][4608]
    float* modpart= mbuf2 + 18432;                   // 73728

    // phase-A aliases
    __hip_bfloat16* featsB  = QKVb;                           // [4096][1024] bf16
    __hip_bfloat16* coordsB = QKVb + (size_t)BN*1024;         // [4096][512] bf16
    float* t1               = ws + OFF_UB;                    // scratch
    __hip_bfloat16* concatB = (__hip_bfloat16*)(t1 + (size_t)BN*256);  // [4096][512] bf16
    __hip_bfloat16* atom_inB= Ob;                             // [4096][256] bf16

    // residue-phase aliases (Ob/Ub regions dead by then)
    __hip_bfloat16* a2tTb   = Ob;                             // [2][256][2048] bf16
    __hip_bfloat16* latTb   = Ob + (size_t)2*256*2048;        // [2][256][2048] bf16
    float* recip            = modpart;                        // 512 fp32

    // split-K partial buffers (aliases of dead regions)
    float* P_pa   = ws + OFF_X;       // phase A (feat/pos/in)
    float* P_tin  = ws + OFF_UB;
    float* P_o    = ws + OFF_UB;
    float* P_m2   = ws + OFF_QKVB;
    float* P_tout = ws + OFF_UB;
    float* P_res  = ws + OFF_UB;

    float* out_res = (float*)d_out;                           // B*NR*DA
    float* out_lat = out_res + (size_t)B_*NR_*DA_;            // B*N*DA

    // ---- adaLN + modulation for both layers (input-only; run first) ----
    ada_kernel<<<2, 256, 0, stream>>>(adaLN_emb, ada_W, ada_b, ada_ln_g, ada_ln_b,
        cbuf, c_silu);
    mod2_kernel<<<dim3(72, 4), 256, 0, stream>>>(c_silu, blk_mod_W, modpart);
    modc_kernel<<<72, 256, 0, stream>>>(modpart, blk_mod_b, mbuf2);

    // ---- featurization (bf16) + rope table (fused) ----
    build_feats_kernel<<<BN, 128, 0, stream>>>(atom_coords, ref_pos, res_id,
        res_type, charge, atomic_num, atom_name, rope_pos, featsB, coordsB,
        ropeC, ropeS);

    // t1 = feats @ feat_W + feat_b   (K padded 924->1024, split 4)
    transconv_kernel<<<dim3(8, 32), 256, 0, stream>>>(feat_W, WT, 924, 1024, 256, 0, 0);
    gemm_bf16_kernel<<<dim3(2, 32, 4), 1024, 0, stream>>>(featsB, 1024, WT, 1024, nullptr,
        nullptr, 0, 1024, 0, 0, nullptr, 0, nullptr, 0, P_pa, 32, 0, 0);
    combln256_kernel<<<BN, 256, 0, stream>>>(P_pa, (size_t)BN*256, 4, feat_b,
        feat_ln_g, feat_ln_b, 1, 1, concatB, 512);
    // concat[:,256:512] = coordsF @ pos_W  (K 387->512, split 4)
    transconv_kernel<<<dim3(8, 16), 256, 0, stream>>>(pos_W, WT, 387, 512, 256, 0, 0);
    gemm_bf16_kernel<<<dim3(2, 32, 4), 1024, 0, stream>>>(coordsB, 512, WT, 512, nullptr,
        nullptr, 0, 512, 0, 0, nullptr, 0, nullptr, 0, P_pa, 32, 0, 0);
    gcomb_kernel<<<1024, 256, 0, stream>>>(P_pa, (size_t)BN*256, 4, 256, nullptr,
        concatB + 256, 512, 0, 1, nullptr, 0, nullptr, 0, nullptr, 0);
    // atom_in = concat @ in_W -> bf16 (split 4)
    transconv_kernel<<<dim3(8, 16), 256, 0, stream>>>(in_W, WT, 512, 512, 256, 0, 0);
    gemm_bf16_kernel<<<dim3(2, 32, 4), 1024, 0, stream>>>(concatB, 512, WT, 512, nullptr,
        nullptr, 0, 512, 0, 0, nullptr, 0, nullptr, 0, P_pa, 32, 0, 0);
    gcomb_kernel<<<1024, 256, 0, stream>>>(P_pa, (size_t)BN*256, 4, 256, nullptr,
        atom_inB, 256, 0, 1, nullptr, 0, nullptr, 0, nullptr, 0);
    // X = LN(atom_in @ tin_W + tin_b) ; Hb = LN(X)*(1+sc1)+sh1  (fused)
    transconv_kernel<<<dim3(24, 8), 256, 0, stream>>>(tin_W, WT, 256, 256, 768, 0, 0);
    gemm_bf16_kernel<<<dim3(6, 32, 2), 1024, 0, stream>>>(atom_inB, 256, WT, 256, nullptr,
        nullptr, 0, 256, 0, 0, nullptr, 0, nullptr, 0, P_tin, 32, 0, 0);
    tinfuse_kernel<<<BN, 256, 0, stream>>>(P_tin, (size_t)BN*768, 2, tin_b,
        tin_ln_g, tin_ln_b, mbuf2 + 768, mbuf2 + 0, X, Hb);

    for (int l = 0; l < NB_; ++l) {
        const float* qkvW = blk_qkv_W + (size_t)l*768*2304;
        const float* qkvB = blk_qkv_b + (size_t)l*2304;
        const float* oW   = blk_o_W   + (size_t)l*768*768;
        const float* oB   = blk_o_b   + (size_t)l*768;
        const float* m1W  = blk_m1_W  + (size_t)l*768*3072;
        const float* m1B  = blk_m1_b  + (size_t)l*3072;
        const float* m2W  = blk_m2_W  + (size_t)l*3072*768;
        const float* m2B  = blk_m2_b  + (size_t)l*768;

        float* mptr = mbuf2 + (size_t)l*9216;        // [b][4608]
        float* sh2 = mptr + 2304, *sc2 = mptr + 3072;
        float* g1  = mptr + 1536, *g2 = mptr + 3840;

        // qkv = h @ qkv_W + b -> bf16
        transconv_kernel<<<dim3(72, 24), 256, 0, stream>>>(qkvW, WT, 768, 768, 2304, 0, 0);
        gemm_bf16_kernel<<<dim3(18, 32, 1), 1024, 0, stream>>>(Hb, 768, WT, 768, qkvB,
            QKVb, 2304, 768, 0, 1, nullptr, 0, nullptr, 0, nullptr, 32, 0, 0);
        // attention (4 waves/block, shared V window)
        attn_mfma_kernel<<<B_*H_*16, 256, 0, stream>>>(QKVb, ropeC, ropeS, Ob);
        // x = x + g1*(o @ o_W + o_b)  (split 2) ; fused -> Hb = h2
        transconv_kernel<<<dim3(24, 24), 256, 0, stream>>>(oW, WT, 768, 768, 768, 0, 0);
        gemm_bf16_kernel<<<dim3(6, 32, 2), 1024, 0, stream>>>(Ob, 768, WT, 768, nullptr,
            nullptr, 0, 768, 0, 0, nullptr, 0, nullptr, 0, P_o, 32, 0, 0);
        gcombln_kernel<<<BN, 256, 0, stream>>>(P_o, (size_t)BN*768, 2, oB,
            X, g1, sc2, sh2, Hb);
        // u = gelu(h2 @ m1_W + b) -> bf16
        transconv_kernel<<<dim3(96, 24), 256, 0, stream>>>(m1W, WT, 768, 768, 3072, 0, 0);
        gemm_bf16_kernel<<<dim3(24, 32, 1), 1024, 0, stream>>>(Hb, 768, WT, 768, m1B,
            Ub, 3072, 768, 1, 1, nullptr, 0, nullptr, 0, nullptr, 32, 0, 0);
        // x = x + g2*(u @ m2_W + b)  (split 2)
        transconv_kernel<<<dim3(24, 96), 256, 0, stream>>>(m2W, WT, 3072, 3072, 768, 0, 0);
        gemm_bf16_kernel<<<dim3(6, 32, 2), 1024, 0, stream>>>(Ub, 3072, WT, 3072, nullptr,
            nullptr, 0, 3072, 0, 0, nullptr, 0, nullptr, 0, P_m2, 32, 0, 0);
        if (l < NB_ - 1) {
            float* mnext = mbuf2 + (size_t)(l+1)*9216;
            gcombln_kernel<<<BN, 256, 0, stream>>>(P_m2, (size_t)BN*768, 2, m2B,
                X, g2, mnext + 768, mnext + 0, Hb);
        } else {
            // final layer: X is dead afterward -> write Hb (bf16) directly
            gcomb_kernel<<<3072, 256, 0, stream>>>(P_m2, (size_t)BN*768, 2, 768, m2B,
                Hb, 768, 2, 1, X, 768, g2, 4608, nullptr, 0);
        }
    }

    // atom_latent = LN(x @ tout_W + tout_b)  (split 4, fused combine+LN)
    transconv_kernel<<<dim3(8, 24), 256, 0, stream>>>(tout_W, WT, 768, 768, 256, 0, 0);
    gemm_bf16_kernel<<<dim3(2, 32, 4), 1024, 0, stream>>>(Hb, 768, WT, 768, nullptr,
        nullptr, 0, 768, 0, 0, nullptr, 0, nullptr, 0, P_tout, 32, 0, 0);
    combln256_kernel<<<BN, 256, 0, stream>>>(P_tout, (size_t)BN*256, 4, tout_b,
        tout_ln_g, tout_ln_b, 0, 0, out_lat, 256);

    // ---- residue pooling as MFMA GEMM ----
    a2t_transpose_kernel<<<dim3(8, 64, 2), 256, 0, stream>>>(atom_to_tok, a2tTb);
    rowrecip_kernel<<<512, 256, 0, stream>>>(a2tTb, recip);
    transconv_kernel<<<dim3(8, 64, 2), 256, 0, stream>>>(out_lat, latTb, 2048, 2048, 256,
        (size_t)2048*256, (size_t)256*2048);
    gemm_bf16_kernel<<<dim3(2, 4, 8), 1024, 0, stream>>>(a2tTb, 2048, latTb, 2048, nullptr,
        nullptr, 0, 2048, 0, 0, nullptr, 0, nullptr, 0, P_res,
        2, (size_t)256*2048, (size_t)256*2048);
    gcomb_kernel<<<128, 256, 0, stream>>>(P_res, (size_t)512*256, 8, 256, nullptr,
        out_res, 256, 3, 0, nullptr, 0, recip, 0, nullptr, 0);
}

// Round 17
// 513.972 us; speedup vs baseline: 1.8600x; 1.0369x over previous
//
#include <hip/hip_runtime.h>
#include <hip/hip_bf16.h>
#include <math.h>

// Problem constants
#define B_ 2
#define N_ 2048
#define NR_ 256
#define DA_ 256
#define E_ 768
#define H_ 12
#define DH_ 64
#define NB_ 2

typedef __attribute__((ext_vector_type(8))) __bf16 bf16x8;
typedef __attribute__((ext_vector_type(4))) float f32x4;

union U8 { bf16x8 v; __hip_bfloat16 e[8]; unsigned short u[8]; };
union U4 { __hip_bfloat16 e[4]; uint2 u2; };

__device__ __forceinline__ void gload16(const void* g, void* l) {
    __builtin_amdgcn_global_load_lds(
        (const __attribute__((address_space(1))) void*)g,
        (__attribute__((address_space(3))) void*)l, 16, 0, 0);
}

// 256-thread block sum: wave shuffle + 4-slot LDS combine (2 barriers).
__device__ __forceinline__ float bsum256(float v, float* red4, int tid) {
    #pragma unroll
    for (int m = 32; m > 0; m >>= 1) v += __shfl_xor(v, m, 64);
    __syncthreads();
    if ((tid & 63) == 0) red4[tid >> 6] = v;
    __syncthreads();
    return red4[0] + red4[1] + red4[2] + red4[3];
}

// ---------------------------------------------------------------------------
// build feats[B*N, 1024] (bf16) and coordsF[B*N, 512] (bf16) + rope tables
// ---------------------------------------------------------------------------
__global__ __launch_bounds__(128) void build_feats_kernel(
    const float* __restrict__ atom_coords, const float* __restrict__ ref_pos,
    const int* __restrict__ res_id, const float* __restrict__ res_type,
    const float* __restrict__ charge, const float* __restrict__ atomic_number,
    const float* __restrict__ atom_name, const int* __restrict__ rope_pos,
    __hip_bfloat16* __restrict__ feats, __hip_bfloat16* __restrict__ coordsF,
    float* __restrict__ ropeC, float* __restrict__ ropeS)
{
    int a = blockIdx.x;            // atom index over B*N
    int tid = threadIdx.x;
    __hip_bfloat16* f  = feats   + (size_t)a * 1024;
    __hip_bfloat16* cf = coordsF + (size_t)a * 512;

    float rp[3], cc[3];
    #pragma unroll
    for (int i = 0; i < 3; ++i) { rp[i] = ref_pos[(size_t)a*3 + i]; cc[i] = atom_coords[(size_t)a*3 + i]; }

    if (tid < 3) { f[tid] = __float2bfloat16(rp[tid]); cf[tid] = __float2bfloat16(cc[tid]); }

    if (tid >= 64 && tid < 96) {
        int dd = tid - 64;
        float rpos = (float)rope_pos[a];
        float ang = rpos * expf(-0.28782313662425574f * (float)dd);  // ln(1e4)/32
        float sn, cs; sincosf(ang, &sn, &cs);
        ropeC[a*32 + dd] = cs; ropeS[a*32 + dd] = sn;
    }

    for (int s = tid; s < 192; s += 128) {
        int fi = s / 3, ci = s % 3;
        float freq = exp2f(12.f * (float)fi / 63.f);
        float ar = rp[ci] * freq;
        float ac = cc[ci] * freq;
        float snr, csr, snc, csc_;
        sincosf(ar, &snr, &csr);
        sincosf(ac, &snc, &csc_);
        f[3 + s]    = __float2bfloat16(snr);  f[195 + s]  = __float2bfloat16(csr);
        cf[3 + s]   = __float2bfloat16(snc);  cf[195 + s] = __float2bfloat16(csc_);
    }
    if (tid < 23) f[387 + tid] = __float2bfloat16(res_type[(size_t)a*23 + tid]);

    float pos = (float)res_id[a];
    if (tid == 0) f[410] = __float2bfloat16(pos);
    if (tid < 64) {
        float div = expf(-9.210340371976184f / 128.f * (float)(2 * tid));
        float ang = pos * div;
        float sn, cs; sincosf(ang, &sn, &cs);
        f[411 + tid] = __float2bfloat16(sn);
        f[475 + tid] = __float2bfloat16(cs);
    }
    if (tid == 0) f[539] = __float2bfloat16(charge[a]);
    if (tid < 128) f[540 + tid] = __float2bfloat16(atomic_number[(size_t)a*128 + tid]);
    for (int s = tid; s < 256; s += 128) f[668 + s] = __float2bfloat16(atom_name[(size_t)a*256 + s]);
    if (tid < 100) f[924 + tid] = __float2bfloat16(0.f);
    if (tid < 125) cf[387 + tid] = __float2bfloat16(0.f);
}

// ---------------------------------------------------------------------------
// Transpose + fp32->bf16 + K-pad: W[Ksrc][Nn] -> WT[Nn][Kdst], zeros k>=Ksrc
// ---------------------------------------------------------------------------
__global__ __launch_bounds__(256) void transconv_kernel(
    const float* __restrict__ W, __hip_bfloat16* __restrict__ WT,
    int Ksrc, int Kdst, int Nn, size_t wstride, size_t tstride)
{
    __shared__ float t[32][33];
    W  += (size_t)blockIdx.z * wstride;
    WT += (size_t)blockIdx.z * tstride;
    int n0 = blockIdx.x * 32, k0 = blockIdx.y * 32;
    int tid = threadIdx.x;
    int tx = tid & 31, ty = tid >> 5;           // ty 0..7
    #pragma unroll
    for (int i = 0; i < 4; ++i) {
        int k = k0 + ty + i*8;
        t[ty + i*8][tx] = (k < Ksrc) ? W[(size_t)k * Nn + n0 + tx] : 0.f;
    }
    __syncthreads();
    #pragma unroll
    for (int i = 0; i < 4; ++i) {
        int row = ty + i*8;                      // n within tile
        WT[(size_t)(n0 + row) * Kdst + k0 + tx] = __float2bfloat16(t[tx][row]);
    }
}

// ---------------------------------------------------------------------------
// shared epilogue.  mode 0 none; 1 gelu; 2 X + gate[b][col]*v; 3 v*gate[row]
// ---------------------------------------------------------------------------
__device__ __forceinline__ float epi_apply(float v, int grow, int gcol,
    const float* bias, int mode, const float* X, int ldx,
    const float* gate, int gstride)
{
    if (bias) v += bias[gcol];
    if (mode == 1) {
        float u = 1.5957691216057308f * (v + 0.044715f * v * v * v);
        v = v / (1.f + __expf(-u));
    } else if (mode == 2) {
        int b = grow >> 11;                      // /N_
        v = X[(size_t)grow * ldx + gcol] + gate[(size_t)b * gstride + gcol] * v;
    } else if (mode == 3) {
        v = v * gate[grow];
    }
    return v;
}

// ---------------------------------------------------------------------------
// bf16 MFMA GEMM: tile 128x128, **BK=64**, 16 waves (1024 thr), 32x32/wave.
// dbuf-2 LDS (64 KB; 2 blocks/CU = 32 waves/CU, unchanged residency but
// HALF the barriers of BK=32): barrier -> STAGE(next 64-K tile) ->
// ds_read+MFMA(current, 2 k-steps).
// Staging: 1 seg/thread/operand (1024 segs = 128 rows x 8 chunks).
// XOR-swizzle both sides over 8 chunks: write chunk^=(row&7), read
// p=(ks*4+lg)^(lr&7)  (16 lanes -> 8 distinct chunks = 2-way = free).
// Bijective XCD swizzle.  gridDim.z = nz splits K -> raw fp32 partials to P.
// ---------------------------------------------------------------------------
__global__ __launch_bounds__(1024) void gemm_bf16_kernel(
    const __hip_bfloat16* __restrict__ A, int lda,
    const __hip_bfloat16* __restrict__ BT, int ldb,
    const float* __restrict__ bias,
    void* __restrict__ C, int ldc,
    int K, int mode, int obf,
    const float* __restrict__ X, int ldx,
    const float* __restrict__ gate, int gstride,
    float* __restrict__ P,
    int mtiles, size_t bstrideA, size_t bstrideB)
{
    __shared__ __hip_bfloat16 As[2][128 * 64];
    __shared__ __hip_bfloat16 Bs[2][128 * 64];

    int gx = gridDim.x;
    int nwg = gx * gridDim.y;
    int fo = blockIdx.y * gx + blockIdx.x;
    int ft = (fo & 7) * (nwg >> 3) + (fo >> 3);
    int bx = ft % gx, by = ft / gx;

    int bb  = by / mtiles;
    int m0l = (by % mtiles) * 128;
    int m0g = by * 128;
    int n0 = bx * 128;
    const __hip_bfloat16* Ab  = A  + (size_t)bb * bstrideA;
    const __hip_bfloat16* BTb = BT + (size_t)bb * bstrideB;
    int nz = gridDim.z;
    int Kh = K / nz;
    int kb = blockIdx.z * Kh;
    int tid = threadIdx.x;
    int w = tid >> 6, l = tid & 63;
    int wr = (w >> 2) * 32, wc = (w & 3) * 32;   // 4 wave-rows x 4 wave-cols
    int lr = l & 15, lg = l >> 4;
    int skey = lr & 7;                           // read-side swizzle key

    // staging: seg = tid (0..1023); row = seg>>3, chunk = seg&7 (8B elems)
    int rowS = tid >> 3;
    int gS   = (tid & 7) ^ (rowS & 7);           // pre-swizzled global chunk

    f32x4 acc[2][2];
    #pragma unroll
    for (int i = 0; i < 2; ++i)
        #pragma unroll
        for (int j = 0; j < 2; ++j)
            acc[i][j] = f32x4{0.f, 0.f, 0.f, 0.f};

    // prologue: stage first 64-K tile into buf 0 (2 gload16/thread)
    gload16(Ab  + (size_t)(m0l + rowS) * lda + kb + gS * 8, (char*)As[0] + tid * 16);
    gload16(BTb + (size_t)(n0 + rowS) * ldb + kb + gS * 8, (char*)Bs[0] + tid * 16);

    int cur = 0;
    for (int k0 = kb; k0 < kb + Kh; k0 += 64) {
        __syncthreads();                         // vmcnt(0): buf[cur] ready
        int kn = k0 + 64;
        if (kn < kb + Kh) {
            int nb = cur ^ 1;
            gload16(Ab  + (size_t)(m0l + rowS) * lda + kn + gS * 8, (char*)As[nb] + tid * 16);
            gload16(BTb + (size_t)(n0 + rowS) * ldb + kn + gS * 8, (char*)Bs[nb] + tid * 16);
        }
        #pragma unroll
        for (int ks = 0; ks < 2; ++ks) {
            int pch = ((ks*4 + lg) ^ skey) * 8;  // swizzled chunk offset (elems)
            bf16x8 af[2], bfr[2];
            #pragma unroll
            for (int i = 0; i < 2; ++i)
                af[i]  = *(bf16x8*)(As[cur] + (wr + i*16 + lr) * 64 + pch);
            #pragma unroll
            for (int j = 0; j < 2; ++j)
                bfr[j] = *(bf16x8*)(Bs[cur] + (wc + j*16 + lr) * 64 + pch);
            #pragma unroll
            for (int i = 0; i < 2; ++i)
                #pragma unroll
                for (int j = 0; j < 2; ++j)
                    acc[i][j] = __builtin_amdgcn_mfma_f32_16x16x32_bf16(af[i], bfr[j], acc[i][j], 0, 0, 0);
        }
        cur ^= 1;
    }

    if (nz > 1) {
        int Nw = gridDim.x * 128;
        size_t pstride = (size_t)Nw * (gridDim.y * 128);
        float* Pz = P + (size_t)blockIdx.z * pstride;
        #pragma unroll
        for (int i = 0; i < 2; ++i)
            #pragma unroll
            for (int j = 0; j < 2; ++j)
                #pragma unroll
                for (int r = 0; r < 4; ++r) {
                    int grow = m0g + wr + i*16 + lg*4 + r;
                    int gcol = n0 + wc + j*16 + lr;
                    Pz[(size_t)grow * Nw + gcol] = acc[i][j][r];
                }
        return;
    }

    #pragma unroll
    for (int i = 0; i < 2; ++i)
        #pragma unroll
        for (int j = 0; j < 2; ++j)
            #pragma unroll
            for (int r = 0; r < 4; ++r) {
                int grow = m0g + wr + i*16 + lg*4 + r;
                int gcol = n0 + wc + j*16 + lr;
                float v = epi_apply(acc[i][j][r], grow, gcol, bias, mode, X, ldx, gate, gstride);
                if (obf)
                    ((__hip_bfloat16*)C)[(size_t)grow * ldc + gcol] = __float2bfloat16(v);
                else
                    ((float*)C)[(size_t)grow * ldc + gcol] = v;
            }
}

// ---------------------------------------------------------------------------
// combine split-K partials + epilogue. 4 elems/thread. optional C2 bf16 out.
// ---------------------------------------------------------------------------
__global__ __launch_bounds__(256) void gcomb_kernel(
    const float* __restrict__ P, size_t pstride, int nz, int Nw,
    const float* __restrict__ bias,
    void* __restrict__ C, int ldc, int mode, int obf,
    const float* __restrict__ X, int ldx,
    const float* __restrict__ gate, int gstride,
    __hip_bfloat16* __restrict__ C2, int ldc2)
{
    int idx = blockIdx.x * 256 + threadIdx.x;
    int e0 = idx * 4;
    int grow = e0 / Nw, gc0 = e0 % Nw;
    float4 v = *(const float4*)(P + (size_t)grow * Nw + gc0);
    for (int z = 1; z < nz; ++z) {
        float4 t = *(const float4*)(P + (size_t)z * pstride + (size_t)grow * Nw + gc0);
        v.x += t.x; v.y += t.y; v.z += t.z; v.w += t.w;
    }
    float e[4] = {v.x, v.y, v.z, v.w};
    #pragma unroll
    for (int r = 0; r < 4; ++r)
        e[r] = epi_apply(e[r], grow, gc0 + r, bias, mode, X, ldx, gate, gstride);
    if (obf) {
        U4 o4;
        #pragma unroll
        for (int r = 0; r < 4; ++r) o4.e[r] = __float2bfloat16(e[r]);
        *(uint2*)((__hip_bfloat16*)C + (size_t)grow * ldc + gc0) = o4.u2;
    } else {
        *(float4*)((float*)C + (size_t)grow * ldc + gc0) = make_float4(e[0], e[1], e[2], e[3]);
    }
    if (C2) {
        U4 o4;
        #pragma unroll
        for (int r = 0; r < 4; ++r) o4.e[r] = __float2bfloat16(e[r]);
        *(uint2*)(C2 + (size_t)grow * ldc2 + gc0) = o4.u2;
    }
}

// ---------------------------------------------------------------------------
// fused: combine split-K (nz, D=256) + bias + LayerNorm(g,b) [+silu] -> out
// ---------------------------------------------------------------------------
__global__ __launch_bounds__(256) void combln256_kernel(
    const float* __restrict__ P, size_t pstride, int nz,
    const float* __restrict__ bias,
    const float* __restrict__ g, const float* __restrict__ bv,
    int do_silu, int obf,
    void* __restrict__ out, int ldout)
{
    int row = blockIdx.x, d = threadIdx.x;
    __shared__ float red4[4];
    float v = P[(size_t)row*256 + d];
    for (int z = 1; z < nz; ++z) v += P[(size_t)z*pstride + (size_t)row*256 + d];
    v += bias[d];
    float mu = bsum256(v, red4, d) * (1.f/256.f);
    float dv = v - mu;
    float rstd = rsqrtf(bsum256(dv*dv, red4, d) * (1.f/256.f) + 1e-5f);
    float y = dv * rstd * g[d] + bv[d];
    if (do_silu) y = y / (1.f + __expf(-y));
    if (obf) ((__hip_bfloat16*)out)[(size_t)row * ldout + d] = __float2bfloat16(y);
    else     ((float*)out)[(size_t)row * ldout + d] = y;
}

// ---------------------------------------------------------------------------
// tin-chain fusion: combine split-K (nz, D=768) + bias ->
//   X = LN(t; g,b)  (write fp32) ; Hb = bf16( LN2(X)*(1+scm[b]) + shm[b] )
// ---------------------------------------------------------------------------
__global__ __launch_bounds__(256) void tinfuse_kernel(
    const float* __restrict__ P, size_t pstride, int nz,
    const float* __restrict__ bias,
    const float* __restrict__ g, const float* __restrict__ bb,
    const float* __restrict__ scm, const float* __restrict__ shm,
    float* __restrict__ X, __hip_bfloat16* __restrict__ Hb)
{
    int row = blockIdx.x, tid = threadIdx.x;
    int b = row >> 11;
    __shared__ float red4[4];
    float tv[3];
    float s = 0.f;
    #pragma unroll
    for (int q = 0; q < 3; ++q) {
        int d = tid + q*256;
        float v = P[(size_t)row*768 + d];
        for (int z = 1; z < nz; ++z) v += P[(size_t)z*pstride + (size_t)row*768 + d];
        v += bias[d];
        tv[q] = v; s += v;
    }
    float mu1 = bsum256(s, red4, tid) * (1.f/768.f);
    float s2 = 0.f;
    #pragma unroll
    for (int q = 0; q < 3; ++q) { float dv = tv[q] - mu1; s2 += dv*dv; }
    float rstd1 = rsqrtf(bsum256(s2, red4, tid) * (1.f/768.f) + 1e-5f);
    float xv[3];
    float s3 = 0.f;
    #pragma unroll
    for (int q = 0; q < 3; ++q) {
        int d = tid + q*256;
        float y = (tv[q] - mu1) * rstd1 * g[d] + bb[d];
        X[(size_t)row*768 + d] = y;
        xv[q] = y; s3 += y;
    }
    float mu2 = bsum256(s3, red4, tid) * (1.f/768.f);
    float s4 = 0.f;
    #pragma unroll
    for (int q = 0; q < 3; ++q) { float dv = xv[q] - mu2; s4 += dv*dv; }
    float rstd2 = rsqrtf(bsum256(s4, red4, tid) * (1.f/768.f) + 1e-5f);
    #pragma unroll
    for (int q = 0; q < 3; ++q) {
        int d = tid + q*256;
        float h = (xv[q] - mu2) * rstd2 * (1.f + scm[(size_t)b*4608 + d]) + shm[(size_t)b*4608 + d];
        Hb[(size_t)row*768 + d] = __float2bfloat16(h);
    }
}

// ---------------------------------------------------------------------------
// fused: combine split-K (nz) + bias + residual-gate into X, then
// Hb = bf16( LN(xnew)*(1+scm[b]) + shm[b] ).  block per row, D=768.
// ---------------------------------------------------------------------------
__global__ __launch_bounds__(256) void gcombln_kernel(
    const float* __restrict__ P, size_t pstride, int nz,
    const float* __restrict__ bias,
    float* __restrict__ X,
    const float* __restrict__ gate,
    const float* __restrict__ scm, const float* __restrict__ shm,
    __hip_bfloat16* __restrict__ Hb)
{
    int row = blockIdx.x, tid = threadIdx.x;
    int b = row >> 11;
    __shared__ float red4[4];
    float xv[3];
    float s = 0.f;
    #pragma unroll
    for (int q = 0; q < 3; ++q) {
        int d = tid + q*256;
        float v = P[(size_t)row*768 + d];
        for (int z = 1; z < nz; ++z) v += P[(size_t)z*pstride + (size_t)row*768 + d];
        v += bias[d];
        v = X[(size_t)row*768 + d] + gate[(size_t)b*4608 + d] * v;
        X[(size_t)row*768 + d] = v;
        xv[q] = v; s += v;
    }
    float mu = bsum256(s, red4, tid) * (1.f/768.f);
    float s2 = 0.f;
    #pragma unroll
    for (int q = 0; q < 3; ++q) { float dv = xv[q] - mu; s2 += dv*dv; }
    float rstd = rsqrtf(bsum256(s2, red4, tid) * (1.f/768.f) + 1e-5f);
    #pragma unroll
    for (int q = 0; q < 3; ++q) {
        int d = tid + q*256;
        float y = (xv[q] - mu) * rstd * (1.f + scm[(size_t)b*4608 + d]) + shm[(size_t)b*4608 + d];
        Hb[(size_t)row*768 + d] = __float2bfloat16(y);
    }
}

// ---------------------------------------------------------------------------
// c = LN(adaLN_emb @ ada_W + ada_b; g,b); c_silu = silu(c). 2 blocks.
// ---------------------------------------------------------------------------
__global__ __launch_bounds__(256) void ada_kernel(
    const float* __restrict__ emb, const float* __restrict__ W,
    const float* __restrict__ bias,
    const float* __restrict__ g, const float* __restrict__ bb,
    float* __restrict__ c, float* __restrict__ c_silu)
{
    int b = blockIdx.x, tid = threadIdx.x;
    __shared__ float emb_s[256];
    __shared__ float t[768];
    __shared__ float red[256];
    emb_s[tid] = emb[b*256 + tid];
    __syncthreads();
    for (int q = 0; q < 3; ++q) {
        int e = tid + q*256;
        float acc = bias[e];
        for (int k = 0; k < 256; ++k) acc += emb_s[k] * W[(size_t)k*768 + e];
        t[e] = acc;
    }
    __syncthreads();
    float s = 0.f; for (int q = 0; q < 3; ++q) s += t[tid + q*256];
    red[tid] = s; __syncthreads();
    for (int off = 128; off > 0; off >>= 1) { if (tid < off) red[tid] += red[tid+off]; __syncthreads(); }
    float mu = red[0] / 768.f; __syncthreads();
    float s2 = 0.f; for (int q = 0; q < 3; ++q) { float d = t[tid + q*256] - mu; s2 += d*d; }
    red[tid] = s2; __syncthreads();
    for (int off = 128; off > 0; off >>= 1) { if (tid < off) red[tid] += red[tid+off]; __syncthreads(); }
    float rstd = rsqrtf(red[0] / 768.f + 1e-5f);
    for (int q = 0; q < 3; ++q) {
        int e = tid + q*256;
        float y = (t[e] - mu) * rstd * g[e] + bb[e];
        c[b*768 + e] = y;
        c_silu[b*768 + e] = y / (1.f + expf(-y));
    }
}

// ---------------------------------------------------------------------------
// mod for BOTH layers, K-split 4: part[z][l][b][4608] ; grid (72, 4)
// ---------------------------------------------------------------------------
__global__ __launch_bounds__(256) void mod2_kernel(
    const float* __restrict__ c_silu, const float* __restrict__ mod_W,
    float* __restrict__ part)
{
    int idx = blockIdx.x * 256 + threadIdx.x;   // < 18432
    int z = blockIdx.y;
    int lyr = idx / 9216, b = (idx / 4608) & 1, j = idx % 4608;
    const float* Wl = mod_W + (size_t)lyr * 768 * 4608;
    const float* cs = c_silu + b * 768;
    float acc = 0.f;
    int k0 = z * 192;
    for (int k = k0; k < k0 + 192; ++k) acc += cs[k] * Wl[(size_t)k * 4608 + j];
    part[(size_t)z * 18432 + idx] = acc;
}

__global__ __launch_bounds__(256) void modc_kernel(
    const float* __restrict__ part, const float* __restrict__ mod_b,
    float* __restrict__ m2buf)
{
    int idx = blockIdx.x * 256 + threadIdx.x;
    int lyr = idx / 9216, j = idx % 4608;
    float acc = mod_b[(size_t)lyr * 4608 + j];
    #pragma unroll
    for (int z = 0; z < 4; ++z) acc += part[(size_t)z * 18432 + idx];
    m2buf[idx] = acc;
}

// ---------------------------------------------------------------------------
// MFMA local-window attention. 4 waves/block; block = (b, h, qgroup of 4
// qblocks).  Shared V window staged once: Vl[224][72].  Per-wave P private.
// ---------------------------------------------------------------------------
__global__ __launch_bounds__(256) void attn_mfma_kernel(
    const __hip_bfloat16* __restrict__ qkv,   // [B*N, 2304]
    const float* __restrict__ ropeC,          // [B*N, 32]
    const float* __restrict__ ropeS,
    __hip_bfloat16* __restrict__ o)           // [B*N, 768]
{
    int bid = blockIdx.x;
    int qg = bid & 15;                 // q-group (4 qblocks)
    int h  = (bid >> 4) % 12;
    int b  = bid / 192;
    int tid = threadIdx.x;
    int w  = tid >> 6;                 // wave 0..3
    int l  = tid & 63;
    int lr = l & 15, lg = l >> 4;

    int qb = qg * 4 + w;
    int lo_blk = max(0, 128*qg - 48);
    int hi_blk = min(N_, 128*qg + 176);
    int lo = max(0, 32*qb - 48);
    int hi = min(N_, 32*qb + 80);
    int wlen = hi - lo;
    int offv = lo - lo_blk;            // wave's row offset into Vl

    __shared__ __hip_bfloat16 Vl[224 * 72];
    __shared__ __hip_bfloat16 Pl[4 * 32 * 144];
    __hip_bfloat16* Plw = Pl + w * (32 * 144);

    // ---- stage shared V window (all 256 threads), zero-fill past hi_blk ----
    {
        int vr0 = tid >> 3;            // 0..31
        int c0  = (tid & 7) * 8;
        #pragma unroll
        for (int it = 0; it < 7; ++it) {
            int vr = it*32 + vr0;      // 0..223
            int n = lo_blk + vr;
            U8 v;
            if (n < hi_blk) {
                v.v = *(const bf16x8*)(qkv + ((size_t)(b*N_ + n))*2304 + 1536 + h*64 + c0);
            } else {
                #pragma unroll
                for (int j = 0; j < 8; ++j) v.u[j] = 0;
            }
            *(bf16x8*)(Vl + vr*72 + c0) = v.v;
        }
    }

    // ---- Q fragments with rope ----
    bf16x8 aq0[2], aq1[2];
    #pragma unroll
    for (int i = 0; i < 2; ++i) {
        int n = qb*32 + i*16 + lr;
        const __hip_bfloat16* qrow = qkv + ((size_t)(b*N_ + n))*2304 + h*64;
        U8 xlo, xhi;
        xlo.v = *(const bf16x8*)(qrow + lg*8);
        xhi.v = *(const bf16x8*)(qrow + 32 + lg*8);
        const float* pc = ropeC + ((size_t)(b*N_ + n))*32 + lg*8;
        const float* ps = ropeS + ((size_t)(b*N_ + n))*32 + lg*8;
        float4 c0 = *(const float4*)(pc), c1 = *(const float4*)(pc + 4);
        float4 s0 = *(const float4*)(ps), s1 = *(const float4*)(ps + 4);
        float cv[8] = {c0.x,c0.y,c0.z,c0.w,c1.x,c1.y,c1.z,c1.w};
        float sv[8] = {s0.x,s0.y,s0.z,s0.w,s1.x,s1.y,s1.z,s1.w};
        U8 f0, f1;
        #pragma unroll
        for (int j = 0; j < 8; ++j) {
            float x1 = __bfloat162float(xlo.e[j]);
            float x2 = __bfloat162float(xhi.e[j]);
            f0.e[j] = __float2bfloat16(x1*cv[j] - x2*sv[j]);
            f1.e[j] = __float2bfloat16(x1*sv[j] + x2*cv[j]);
        }
        aq0[i] = f0.v; aq1[i] = f1.v;
    }

    // ---- scores ----
    f32x4 S[2][8];
    #pragma unroll
    for (int i = 0; i < 2; ++i)
        #pragma unroll
        for (int jt = 0; jt < 8; ++jt)
            S[i][jt] = f32x4{0.f, 0.f, 0.f, 0.f};

    #pragma unroll
    for (int jt = 0; jt < 8; ++jt) {
        int n = lo + jt*16 + lr;
        U8 f0, f1;
        if (n < hi) {
            const __hip_bfloat16* krow = qkv + ((size_t)(b*N_ + n))*2304 + 768 + h*64;
            U8 xlo, xhi;
            xlo.v = *(const bf16x8*)(krow + lg*8);
            xhi.v = *(const bf16x8*)(krow + 32 + lg*8);
            const float* pc = ropeC + ((size_t)(b*N_ + n))*32 + lg*8;
            const float* ps = ropeS + ((size_t)(b*N_ + n))*32 + lg*8;
            float4 c0 = *(const float4*)(pc), c1 = *(const float4*)(pc + 4);
            float4 s0 = *(const float4*)(ps), s1 = *(const float4*)(ps + 4);
            float cv[8] = {c0.x,c0.y,c0.z,c0.w,c1.x,c1.y,c1.z,c1.w};
            float sv[8] = {s0.x,s0.y,s0.z,s0.w,s1.x,s1.y,s1.z,s1.w};
            #pragma unroll
            for (int j = 0; j < 8; ++j) {
                float x1 = __bfloat162float(xlo.e[j]);
                float x2 = __bfloat162float(xhi.e[j]);
                f0.e[j] = __float2bfloat16(x1*cv[j] - x2*sv[j]);
                f1.e[j] = __float2bfloat16(x1*sv[j] + x2*cv[j]);
            }
        } else {
            #pragma unroll
            for (int j = 0; j < 8; ++j) { f0.u[j] = 0; f1.u[j] = 0; }
        }
        #pragma unroll
        for (int i = 0; i < 2; ++i) {
            S[i][jt] = __builtin_amdgcn_mfma_f32_16x16x32_bf16(aq0[i], f0.v, S[i][jt], 0, 0, 0);
            S[i][jt] = __builtin_amdgcn_mfma_f32_16x16x32_bf16(aq1[i], f1.v, S[i][jt], 0, 0, 0);
        }
    }

    // ---- scale + mask ----
    #pragma unroll
    for (int jt = 0; jt < 8; ++jt) {
        bool oob = (jt*16 + lr) >= wlen;
        #pragma unroll
        for (int i = 0; i < 2; ++i)
            #pragma unroll
            for (int r = 0; r < 4; ++r)
                S[i][jt][r] = oob ? -1e30f : S[i][jt][r] * 0.125f;
    }

    // ---- wave-parallel softmax over 16-lane groups ----
    float rinv[2][4];
    #pragma unroll
    for (int i = 0; i < 2; ++i) {
        #pragma unroll
        for (int r = 0; r < 4; ++r) {
            float m = -1e30f;
            #pragma unroll
            for (int jt = 0; jt < 8; ++jt) m = fmaxf(m, S[i][jt][r]);
            #pragma unroll
            for (int mask = 8; mask > 0; mask >>= 1) m = fmaxf(m, __shfl_xor(m, mask, 16));
            float sum = 0.f;
            #pragma unroll
            for (int jt = 0; jt < 8; ++jt) {
                float e = __expf(S[i][jt][r] - m);
                S[i][jt][r] = e;
                sum += e;
            }
            #pragma unroll
            for (int mask = 8; mask > 0; mask >>= 1) sum += __shfl_xor(sum, mask, 16);
            rinv[i][r] = 1.f / sum;
        }
    }

    // ---- write P (bf16, XOR-swizzled cols) into this wave's region ----
    #pragma unroll
    for (int i = 0; i < 2; ++i)
        #pragma unroll
        for (int jt = 0; jt < 8; ++jt)
            #pragma unroll
            for (int r = 0; r < 4; ++r) {
                int row = i*16 + lg*4 + r;
                int colp = (jt*16 + lr) ^ (lg << 3);
                Plw[row*144 + colp] = __float2bfloat16(S[i][jt][r]);
            }

    __syncthreads();   // Vl staged by all + Plw written before; PV reads after

    // ---- PV ----
    f32x4 O_[2][4];
    #pragma unroll
    for (int i = 0; i < 2; ++i)
        #pragma unroll
        for (int ct = 0; ct < 4; ++ct)
            O_[i][ct] = f32x4{0.f, 0.f, 0.f, 0.f};

    int key = (lr >> 2) & 3;
    #pragma unroll
    for (int kt = 0; kt < 4; ++kt) {
        bf16x8 pa[2];
        #pragma unroll
        for (int i = 0; i < 2; ++i) {
            int row = i*16 + lr;
            int colp = (kt*32 + lg*8) ^ (key << 3);
            pa[i] = *(bf16x8*)(Plw + row*144 + colp);
        }
        #pragma unroll
        for (int ct = 0; ct < 4; ++ct) {
            U8 bv;
            #pragma unroll
            for (int j = 0; j < 8; ++j)
                bv.e[j] = Vl[(offv + kt*32 + lg*8 + j)*72 + ct*16 + lr];
            O_[0][ct] = __builtin_amdgcn_mfma_f32_16x16x32_bf16(pa[0], bv.v, O_[0][ct], 0, 0, 0);
            O_[1][ct] = __builtin_amdgcn_mfma_f32_16x16x32_bf16(pa[1], bv.v, O_[1][ct], 0, 0, 0);
        }
    }

    // ---- store O ----
    #pragma unroll
    for (int i = 0; i < 2; ++i)
        #pragma unroll
        for (int ct = 0; ct < 4; ++ct)
            #pragma unroll
            for (int r = 0; r < 4; ++r) {
                int row = qb*32 + i*16 + lg*4 + r;
                o[((size_t)(b*N_ + row))*768 + h*64 + ct*16 + lr] =
                    __float2bfloat16(O_[i][ct][r] * rinv[i][r]);
            }
}

// ---------------------------------------------------------------------------
// a2t [B,N,NR] fp32 -> a2tTb [B,NR,N] bf16   grid (NR/32, N/32, B)
// ---------------------------------------------------------------------------
__global__ __launch_bounds__(256) void a2t_transpose_kernel(
    const float* __restrict__ a2t, __hip_bfloat16* __restrict__ a2tTb)
{
    __shared__ float t[32][33];
    int r0 = blockIdx.x * 32, n0 = blockIdx.y * 32, b = blockIdx.z;
    int tid = threadIdx.x;
    int tx = tid & 31, ty = tid >> 5;
    #pragma unroll
    for (int i = 0; i < 4; ++i) {
        int row = ty + i*8;
        t[row][tx] = a2t[((size_t)b*N_ + n0 + row) * 256 + r0 + tx];
    }
    __syncthreads();
    #pragma unroll
    for (int i = 0; i < 4; ++i) {
        int row = ty + i*8;
        a2tTb[((size_t)b*256 + r0 + row) * N_ + n0 + tx] = __float2bfloat16(t[tx][row]);
    }
}

// ---------------------------------------------------------------------------
// recip[row] = 1/(sum of a2tTb row + 1e-6).  block per row (512 rows).
// ---------------------------------------------------------------------------
__global__ __launch_bounds__(256) void rowrecip_kernel(
    const __hip_bfloat16* __restrict__ a2tTb, float* __restrict__ recip)
{
    int row = blockIdx.x;
    int tid = threadIdx.x;
    __shared__ float red4[4];
    U8 v; v.v = *(const bf16x8*)(a2tTb + (size_t)row*2048 + tid*8);
    float s = 0.f;
    #pragma unroll
    for (int j = 0; j < 8; ++j) s += __bfloat162float(v.e[j]);
    float tot = bsum256(s, red4, tid);
    if (tid == 0) recip[row] = 1.f / (tot + 1e-6f);
}

// ---------------------------------------------------------------------------
extern "C" void kernel_launch(void* const* d_in, const int* in_sizes, int n_in,
                              void* d_out, int out_size, void* d_ws, size_t ws_size,
                              hipStream_t stream) {
    const float* atom_coords  = (const float*)d_in[0];
    const float* ref_pos      = (const float*)d_in[1];
    const int*   res_id       = (const int*)  d_in[2];
    const float* res_type     = (const float*)d_in[3];
    const float* charge       = (const float*)d_in[4];
    const float* atomic_num   = (const float*)d_in[5];
    const float* atom_name    = (const float*)d_in[6];
    const float* adaLN_emb    = (const float*)d_in[7];
    const int*   rope_pos     = (const int*)  d_in[8];
    const float* atom_to_tok  = (const float*)d_in[9];
    const float* feat_W       = (const float*)d_in[10];
    const float* feat_b       = (const float*)d_in[11];
    const float* feat_ln_g    = (const float*)d_in[12];
    const float* feat_ln_b    = (const float*)d_in[13];
    const float* pos_W        = (const float*)d_in[14];
    const float* in_W         = (const float*)d_in[15];
    const float* tin_W        = (const float*)d_in[16];
    const float* tin_b        = (const float*)d_in[17];
    const float* tin_ln_g     = (const float*)d_in[18];
    const float* tin_ln_b     = (const float*)d_in[19];
    const float* ada_W        = (const float*)d_in[20];
    const float* ada_b        = (const float*)d_in[21];
    const float* ada_ln_g     = (const float*)d_in[22];
    const float* ada_ln_b     = (const float*)d_in[23];
    const float* blk_mod_W    = (const float*)d_in[24];
    const float* blk_mod_b    = (const float*)d_in[25];
    const float* blk_qkv_W    = (const float*)d_in[26];
    const float* blk_qkv_b    = (const float*)d_in[27];
    const float* blk_o_W      = (const float*)d_in[28];
    const float* blk_o_b      = (const float*)d_in[29];
    const float* blk_m1_W     = (const float*)d_in[30];
    const float* blk_m1_b     = (const float*)d_in[31];
    const float* blk_m2_W     = (const float*)d_in[32];
    const float* blk_m2_b     = (const float*)d_in[33];
    const float* tout_W       = (const float*)d_in[34];
    const float* tout_b       = (const float*)d_in[35];
    const float* tout_ln_g    = (const float*)d_in[36];
    const float* tout_ln_b    = (const float*)d_in[37];

    const int BN = B_ * N_;                          // 4096
    float* ws = (float*)d_ws;

    // layout (float units)
    const size_t OFF_X    = 0;                                // fp32 [4096][768]
    const size_t OFF_HB   = OFF_X    + (size_t)BN*768;        // bf16 [4096][768]
    const size_t OFF_QKVB = OFF_HB   + (size_t)BN*768/2;      // bf16 [4096][2304]
    const size_t OFF_OB   = OFF_QKVB + (size_t)BN*2304/2;     // bf16 [4096][768]
    const size_t OFF_UB   = OFF_OB   + (size_t)BN*768/2;      // bf16 [4096][3072]
    const size_t OFF_WT   = OFF_UB   + (size_t)BN*3072/2;     // bf16 up to 3072*768
    const size_t OFF_RC   = OFF_WT   + (size_t)3072*768/2;    // fp32 BN*32
    const size_t OFF_RS   = OFF_RC   + (size_t)BN*32;
    const size_t OFF_SM   = OFF_RS   + (size_t)BN*32;

    float* X = ws + OFF_X;
    __hip_bfloat16* Hb   = (__hip_bfloat16*)(ws + OFF_HB);
    __hip_bfloat16* QKVb = (__hip_bfloat16*)(ws + OFF_QKVB);
    __hip_bfloat16* Ob   = (__hip_bfloat16*)(ws + OFF_OB);
    __hip_bfloat16* Ub   = (__hip_bfloat16*)(ws + OFF_UB);
    __hip_bfloat16* WT   = (__hip_bfloat16*)(ws + OFF_WT);
    float* ropeC  = ws + OFF_RC;
    float* ropeS  = ws + OFF_RS;
    float* cbuf   = ws + OFF_SM;                     // 1536
    float* c_silu = cbuf + 1536;                     // 1536
    float* mbuf2  = c_silu + 1536;                   // 18432  [2][2][4608]
    float* modpart= mbuf2 + 18432;                   // 73728

    // phase-A aliases
    __hip_bfloat16* featsB  = QKVb;                           // [4096][1024] bf16
    __hip_bfloat16* coordsB = QKVb + (size_t)BN*1024;         // [4096][512] bf16
    float* t1               = ws + OFF_UB;                    // scratch
    __hip_bfloat16* concatB = (__hip_bfloat16*)(t1 + (size_t)BN*256);  // [4096][512] bf16
    __hip_bfloat16* atom_inB= Ob;                             // [4096][256] bf16

    // residue-phase aliases (Ob/Ub regions dead by then)
    __hip_bfloat16* a2tTb   = Ob;                             // [2][256][2048] bf16
    __hip_bfloat16* latTb   = Ob + (size_t)2*256*2048;        // [2][256][2048] bf16
    float* recip            = modpart;                        // 512 fp32

    // split-K partial buffers (aliases of dead regions)
    float* P_pa   = ws + OFF_X;       // phase A (feat/pos/in)
    float* P_tin  = ws + OFF_UB;
    float* P_o    = ws + OFF_UB;
    float* P_m2   = ws + OFF_QKVB;
    float* P_tout = ws + OFF_UB;
    float* P_res  = ws + OFF_UB;

    float* out_res = (float*)d_out;                           // B*NR*DA
    float* out_lat = out_res + (size_t)B_*NR_*DA_;            // B*N*DA

    // ---- adaLN + modulation for both layers (input-only; run first) ----
    ada_kernel<<<2, 256, 0, stream>>>(adaLN_emb, ada_W, ada_b, ada_ln_g, ada_ln_b,
        cbuf, c_silu);
    mod2_kernel<<<dim3(72, 4), 256, 0, stream>>>(c_silu, blk_mod_W, modpart);
    modc_kernel<<<72, 256, 0, stream>>>(modpart, blk_mod_b, mbuf2);

    // ---- featurization (bf16) + rope table (fused) ----
    build_feats_kernel<<<BN, 128, 0, stream>>>(atom_coords, ref_pos, res_id,
        res_type, charge, atomic_num, atom_name, rope_pos, featsB, coordsB,
        ropeC, ropeS);

    // t1 = feats @ feat_W + feat_b   (K padded 924->1024, split 4)
    transconv_kernel<<<dim3(8, 32), 256, 0, stream>>>(feat_W, WT, 924, 1024, 256, 0, 0);
    gemm_bf16_kernel<<<dim3(2, 32, 4), 1024, 0, stream>>>(featsB, 1024, WT, 1024, nullptr,
        nullptr, 0, 1024, 0, 0, nullptr, 0, nullptr, 0, P_pa, 32, 0, 0);
    combln256_kernel<<<BN, 256, 0, stream>>>(P_pa, (size_t)BN*256, 4, feat_b,
        feat_ln_g, feat_ln_b, 1, 1, concatB, 512);
    // concat[:,256:512] = coordsF @ pos_W  (K 387->512, split 4)
    transconv_kernel<<<dim3(8, 16), 256, 0, stream>>>(pos_W, WT, 387, 512, 256, 0, 0);
    gemm_bf16_kernel<<<dim3(2, 32, 4), 1024, 0, stream>>>(coordsB, 512, WT, 512, nullptr,
        nullptr, 0, 512, 0, 0, nullptr, 0, nullptr, 0, P_pa, 32, 0, 0);
    gcomb_kernel<<<1024, 256, 0, stream>>>(P_pa, (size_t)BN*256, 4, 256, nullptr,
        concatB + 256, 512, 0, 1, nullptr, 0, nullptr, 0, nullptr, 0);
    // atom_in = concat @ in_W -> bf16 (split 4)
    transconv_kernel<<<dim3(8, 16), 256, 0, stream>>>(in_W, WT, 512, 512, 256, 0, 0);
    gemm_bf16_kernel<<<dim3(2, 32, 4), 1024, 0, stream>>>(concatB, 512, WT, 512, nullptr,
        nullptr, 0, 512, 0, 0, nullptr, 0, nullptr, 0, P_pa, 32, 0, 0);
    gcomb_kernel<<<1024, 256, 0, stream>>>(P_pa, (size_t)BN*256, 4, 256, nullptr,
        atom_inB, 256, 0, 1, nullptr, 0, nullptr, 0, nullptr, 0);
    // X = LN(atom_in @ tin_W + tin_b) ; Hb = LN(X)*(1+sc1)+sh1  (fused)
    transconv_kernel<<<dim3(24, 8), 256, 0, stream>>>(tin_W, WT, 256, 256, 768, 0, 0);
    gemm_bf16_kernel<<<dim3(6, 32, 2), 1024, 0, stream>>>(atom_inB, 256, WT, 256, nullptr,
        nullptr, 0, 256, 0, 0, nullptr, 0, nullptr, 0, P_tin, 32, 0, 0);
    tinfuse_kernel<<<BN, 256, 0, stream>>>(P_tin, (size_t)BN*768, 2, tin_b,
        tin_ln_g, tin_ln_b, mbuf2 + 768, mbuf2 + 0, X, Hb);

    for (int l = 0; l < NB_; ++l) {
        const float* qkvW = blk_qkv_W + (size_t)l*768*2304;
        const float* qkvB = blk_qkv_b + (size_t)l*2304;
        const float* oW   = blk_o_W   + (size_t)l*768*768;
        const float* oB   = blk_o_b   + (size_t)l*768;
        const float* m1W  = blk_m1_W  + (size_t)l*768*3072;
        const float* m1B  = blk_m1_b  + (size_t)l*3072;
        const float* m2W  = blk_m2_W  + (size_t)l*3072*768;
        const float* m2B  = blk_m2_b  + (size_t)l*768;

        float* mptr = mbuf2 + (size_t)l*9216;        // [b][4608]
        float* sh2 = mptr + 2304, *sc2 = mptr + 3072;
        float* g1  = mptr + 1536, *g2 = mptr + 3840;

        // qkv = h @ qkv_W + b -> bf16
        transconv_kernel<<<dim3(72, 24), 256, 0, stream>>>(qkvW, WT, 768, 768, 2304, 0, 0);
        gemm_bf16_kernel<<<dim3(18, 32, 1), 1024, 0, stream>>>(Hb, 768, WT, 768, qkvB,
            QKVb, 2304, 768, 0, 1, nullptr, 0, nullptr, 0, nullptr, 32, 0, 0);
        // attention (4 waves/block, shared V window)
        attn_mfma_kernel<<<B_*H_*16, 256, 0, stream>>>(QKVb, ropeC, ropeS, Ob);
        // x = x + g1*(o @ o_W + o_b)  (split 2) ; fused -> Hb = h2
        transconv_kernel<<<dim3(24, 24), 256, 0, stream>>>(oW, WT, 768, 768, 768, 0, 0);
        gemm_bf16_kernel<<<dim3(6, 32, 2), 1024, 0, stream>>>(Ob, 768, WT, 768, nullptr,
            nullptr, 0, 768, 0, 0, nullptr, 0, nullptr, 0, P_o, 32, 0, 0);
        gcombln_kernel<<<BN, 256, 0, stream>>>(P_o, (size_t)BN*768, 2, oB,
            X, g1, sc2, sh2, Hb);
        // u = gelu(h2 @ m1_W + b) -> bf16
        transconv_kernel<<<dim3(96, 24), 256, 0, stream>>>(m1W, WT, 768, 768, 3072, 0, 0);
        gemm_bf16_kernel<<<dim3(24, 32, 1), 1024, 0, stream>>>(Hb, 768, WT, 768, m1B,
            Ub, 3072, 768, 1, 1, nullptr, 0, nullptr, 0, nullptr, 32, 0, 0);
        // x = x + g2*(u @ m2_W + b)  (split 2)
        transconv_kernel<<<dim3(24, 96), 256, 0, stream>>>(m2W, WT, 3072, 3072, 768, 0, 0);
        gemm_bf16_kernel<<<dim3(6, 32, 2), 1024, 0, stream>>>(Ub, 3072, WT, 3072, nullptr,
            nullptr, 0, 3072, 0, 0, nullptr, 0, nullptr, 0, P_m2, 32, 0, 0);
        if (l < NB_ - 1) {
            float* mnext = mbuf2 + (size_t)(l+1)*9216;
            gcombln_kernel<<<BN, 256, 0, stream>>>(P_m2, (size_t)BN*768, 2, m2B,
                X, g2, mnext + 768, mnext + 0, Hb);
        } else {
            // final layer: X is dead afterward -> write Hb (bf16) directly
            gcomb_kernel<<<3072, 256, 0, stream>>>(P_m2, (size_t)BN*768, 2, 768, m2B,
                Hb, 768, 2, 1, X, 768, g2, 4608, nullptr, 0);
        }
    }

    // atom_latent = LN(x @ tout_W + tout_b)  (split 4, fused combine+LN)
    transconv_kernel<<<dim3(8, 24), 256, 0, stream>>>(tout_W, WT, 768, 768, 256, 0, 0);
    gemm_bf16_kernel<<<dim3(2, 32, 4), 1024, 0, stream>>>(Hb, 768, WT, 768, nullptr,
        nullptr, 0, 768, 0, 0, nullptr, 0, nullptr, 0, P_tout, 32, 0, 0);
    combln256_kernel<<<BN, 256, 0, stream>>>(P_tout, (size_t)BN*256, 4, tout_b,
        tout_ln_g, tout_ln_b, 0, 0, out_lat, 256);

    // ---- residue pooling as MFMA GEMM ----
    a2t_transpose_kernel<<<dim3(8, 64, 2), 256, 0, stream>>>(atom_to_tok, a2tTb);
    rowrecip_kernel<<<512, 256, 0, stream>>>(a2tTb, recip);
    transconv_kernel<<<dim3(8, 64, 2), 256, 0, stream>>>(out_lat, latTb, 2048, 2048, 256,
        (size_t)2048*256, (size_t)256*2048);
    gemm_bf16_kernel<<<dim3(2, 4, 8), 1024, 0, stream>>>(a2tTb, 2048, latTb, 2048, nullptr,
        nullptr, 0, 2048, 0, 0, nullptr, 0, nullptr, 0, P_res,
        2, (size_t)256*2048, (size_t)256*2048);
    gcomb_kernel<<<128, 256, 0, stream>>>(P_res, (size_t)512*256, 8, 256, nullptr,
        out_res, 256, 3, 0, nullptr, 0, recip, 0, nullptr, 0);
}

// Round 18
// 499.640 us; speedup vs baseline: 1.9133x; 1.0287x over previous
//
#include <hip/hip_runtime.h>
#include <hip/hip_bf16.h>
#include <math.h>

// Problem constants
#define B_ 2
#define N_ 2048
#define NR_ 256
#define DA_ 256
#define E_ 768
#define H_ 12
#define DH_ 64
#define NB_ 2

typedef __attribute__((ext_vector_type(8))) __bf16 bf16x8;
typedef __attribute__((ext_vector_type(4))) float f32x4;

union U8 { bf16x8 v; __hip_bfloat16 e[8]; unsigned short u[8]; };
union U4 { __hip_bfloat16 e[4]; uint2 u2; };

__device__ __forceinline__ void gload16(const void* g, void* l) {
    __builtin_amdgcn_global_load_lds(
        (const __attribute__((address_space(1))) void*)g,
        (__attribute__((address_space(3))) void*)l, 16, 0, 0);
}

// 256-thread block sum: wave shuffle + 4-slot LDS combine (2 barriers).
__device__ __forceinline__ float bsum256(float v, float* red4, int tid) {
    #pragma unroll
    for (int m = 32; m > 0; m >>= 1) v += __shfl_xor(v, m, 64);
    __syncthreads();
    if ((tid & 63) == 0) red4[tid >> 6] = v;
    __syncthreads();
    return red4[0] + red4[1] + red4[2] + red4[3];
}

// ---------------------------------------------------------------------------
// build feats[B*N, 1024] (bf16) and coordsF[B*N, 512] (bf16) + rope tables
// ---------------------------------------------------------------------------
__global__ __launch_bounds__(128) void build_feats_kernel(
    const float* __restrict__ atom_coords, const float* __restrict__ ref_pos,
    const int* __restrict__ res_id, const float* __restrict__ res_type,
    const float* __restrict__ charge, const float* __restrict__ atomic_number,
    const float* __restrict__ atom_name, const int* __restrict__ rope_pos,
    __hip_bfloat16* __restrict__ feats, __hip_bfloat16* __restrict__ coordsF,
    float* __restrict__ ropeC, float* __restrict__ ropeS)
{
    int a = blockIdx.x;            // atom index over B*N
    int tid = threadIdx.x;
    __hip_bfloat16* f  = feats   + (size_t)a * 1024;
    __hip_bfloat16* cf = coordsF + (size_t)a * 512;

    float rp[3], cc[3];
    #pragma unroll
    for (int i = 0; i < 3; ++i) { rp[i] = ref_pos[(size_t)a*3 + i]; cc[i] = atom_coords[(size_t)a*3 + i]; }

    if (tid < 3) { f[tid] = __float2bfloat16(rp[tid]); cf[tid] = __float2bfloat16(cc[tid]); }

    if (tid >= 64 && tid < 96) {
        int dd = tid - 64;
        float rpos = (float)rope_pos[a];
        float ang = rpos * expf(-0.28782313662425574f * (float)dd);  // ln(1e4)/32
        float sn, cs; sincosf(ang, &sn, &cs);
        ropeC[a*32 + dd] = cs; ropeS[a*32 + dd] = sn;
    }

    for (int s = tid; s < 192; s += 128) {
        int fi = s / 3, ci = s % 3;
        float freq = exp2f(12.f * (float)fi / 63.f);
        float ar = rp[ci] * freq;
        float ac = cc[ci] * freq;
        float snr, csr, snc, csc_;
        sincosf(ar, &snr, &csr);
        sincosf(ac, &snc, &csc_);
        f[3 + s]    = __float2bfloat16(snr);  f[195 + s]  = __float2bfloat16(csr);
        cf[3 + s]   = __float2bfloat16(snc);  cf[195 + s] = __float2bfloat16(csc_);
    }
    if (tid < 23) f[387 + tid] = __float2bfloat16(res_type[(size_t)a*23 + tid]);

    float pos = (float)res_id[a];
    if (tid == 0) f[410] = __float2bfloat16(pos);
    if (tid < 64) {
        float div = expf(-9.210340371976184f / 128.f * (float)(2 * tid));
        float ang = pos * div;
        float sn, cs; sincosf(ang, &sn, &cs);
        f[411 + tid] = __float2bfloat16(sn);
        f[475 + tid] = __float2bfloat16(cs);
    }
    if (tid == 0) f[539] = __float2bfloat16(charge[a]);
    if (tid < 128) f[540 + tid] = __float2bfloat16(atomic_number[(size_t)a*128 + tid]);
    for (int s = tid; s < 256; s += 128) f[668 + s] = __float2bfloat16(atom_name[(size_t)a*256 + s]);
    if (tid < 100) f[924 + tid] = __float2bfloat16(0.f);
    if (tid < 125) cf[387 + tid] = __float2bfloat16(0.f);
}

// ---------------------------------------------------------------------------
// Transpose + fp32->bf16 + K-pad: W[Ksrc][Nn] -> WT[Nn][Kdst], zeros k>=Ksrc
// grid (Nn/32, Kdst/32, nbatch); strides advance per batch (z).
// ---------------------------------------------------------------------------
__global__ __launch_bounds__(256) void transconv_kernel(
    const float* __restrict__ W, __hip_bfloat16* __restrict__ WT,
    int Ksrc, int Kdst, int Nn, size_t wstride, size_t tstride)
{
    __shared__ float t[32][33];
    W  += (size_t)blockIdx.z * wstride;
    WT += (size_t)blockIdx.z * tstride;
    int n0 = blockIdx.x * 32, k0 = blockIdx.y * 32;
    int tid = threadIdx.x;
    int tx = tid & 31, ty = tid >> 5;           // ty 0..7
    #pragma unroll
    for (int i = 0; i < 4; ++i) {
        int k = k0 + ty + i*8;
        t[ty + i*8][tx] = (k < Ksrc) ? W[(size_t)k * Nn + n0 + tx] : 0.f;
    }
    __syncthreads();
    #pragma unroll
    for (int i = 0; i < 4; ++i) {
        int row = ty + i*8;                      // n within tile
        WT[(size_t)(n0 + row) * Kdst + k0 + tx] = __float2bfloat16(t[tx][row]);
    }
}

// ---------------------------------------------------------------------------
// shared epilogue.  mode 0 none; 1 gelu; 2 X + gate[b][col]*v; 3 v*gate[row]
// ---------------------------------------------------------------------------
__device__ __forceinline__ float epi_apply(float v, int grow, int gcol,
    const float* bias, int mode, const float* X, int ldx,
    const float* gate, int gstride)
{
    if (bias) v += bias[gcol];
    if (mode == 1) {
        float u = 1.5957691216057308f * (v + 0.044715f * v * v * v);
        v = v / (1.f + __expf(-u));
    } else if (mode == 2) {
        int b = grow >> 11;                      // /N_
        v = X[(size_t)grow * ldx + gcol] + gate[(size_t)b * gstride + gcol] * v;
    } else if (mode == 3) {
        v = v * gate[grow];
    }
    return v;
}

// ---------------------------------------------------------------------------
// bf16 MFMA GEMM: tile 128x128, BK=64, 16 waves (1024 thr), 32x32/wave.
// dbuf-2 LDS (64 KB; 2 blocks/CU): barrier -> STAGE(next 64-K tile) ->
// ds_read+MFMA(current, 2 k-steps).  (round-17 proven)
// Staging: 1 seg/thread/operand.  XOR-swizzle both sides over 8 chunks.
// Bijective XCD swizzle.  gridDim.z = nz splits K -> raw fp32 partials to P.
// ---------------------------------------------------------------------------
__global__ __launch_bounds__(1024) void gemm_bf16_kernel(
    const __hip_bfloat16* __restrict__ A, int lda,
    const __hip_bfloat16* __restrict__ BT, int ldb,
    const float* __restrict__ bias,
    void* __restrict__ C, int ldc,
    int K, int mode, int obf,
    const float* __restrict__ X, int ldx,
    const float* __restrict__ gate, int gstride,
    float* __restrict__ P,
    int mtiles, size_t bstrideA, size_t bstrideB)
{
    __shared__ __hip_bfloat16 As[2][128 * 64];
    __shared__ __hip_bfloat16 Bs[2][128 * 64];

    int gx = gridDim.x;
    int nwg = gx * gridDim.y;
    int fo = blockIdx.y * gx + blockIdx.x;
    int ft = (fo & 7) * (nwg >> 3) + (fo >> 3);
    int bx = ft % gx, by = ft / gx;

    int bb  = by / mtiles;
    int m0l = (by % mtiles) * 128;
    int m0g = by * 128;
    int n0 = bx * 128;
    const __hip_bfloat16* Ab  = A  + (size_t)bb * bstrideA;
    const __hip_bfloat16* BTb = BT + (size_t)bb * bstrideB;
    int nz = gridDim.z;
    int Kh = K / nz;
    int kb = blockIdx.z * Kh;
    int tid = threadIdx.x;
    int w = tid >> 6, l = tid & 63;
    int wr = (w >> 2) * 32, wc = (w & 3) * 32;   // 4 wave-rows x 4 wave-cols
    int lr = l & 15, lg = l >> 4;
    int skey = lr & 7;                           // read-side swizzle key

    // staging: seg = tid (0..1023); row = seg>>3, chunk = seg&7 (8B elems)
    int rowS = tid >> 3;
    int gS   = (tid & 7) ^ (rowS & 7);           // pre-swizzled global chunk

    f32x4 acc[2][2];
    #pragma unroll
    for (int i = 0; i < 2; ++i)
        #pragma unroll
        for (int j = 0; j < 2; ++j)
            acc[i][j] = f32x4{0.f, 0.f, 0.f, 0.f};

    // prologue: stage first 64-K tile into buf 0 (2 gload16/thread)
    gload16(Ab  + (size_t)(m0l + rowS) * lda + kb + gS * 8, (char*)As[0] + tid * 16);
    gload16(BTb + (size_t)(n0 + rowS) * ldb + kb + gS * 8, (char*)Bs[0] + tid * 16);

    int cur = 0;
    for (int k0 = kb; k0 < kb + Kh; k0 += 64) {
        __syncthreads();                         // vmcnt(0): buf[cur] ready
        int kn = k0 + 64;
        if (kn < kb + Kh) {
            int nb = cur ^ 1;
            gload16(Ab  + (size_t)(m0l + rowS) * lda + kn + gS * 8, (char*)As[nb] + tid * 16);
            gload16(BTb + (size_t)(n0 + rowS) * ldb + kn + gS * 8, (char*)Bs[nb] + tid * 16);
        }
        #pragma unroll
        for (int ks = 0; ks < 2; ++ks) {
            int pch = ((ks*4 + lg) ^ skey) * 8;  // swizzled chunk offset (elems)
            bf16x8 af[2], bfr[2];
            #pragma unroll
            for (int i = 0; i < 2; ++i)
                af[i]  = *(bf16x8*)(As[cur] + (wr + i*16 + lr) * 64 + pch);
            #pragma unroll
            for (int j = 0; j < 2; ++j)
                bfr[j] = *(bf16x8*)(Bs[cur] + (wc + j*16 + lr) * 64 + pch);
            #pragma unroll
            for (int i = 0; i < 2; ++i)
                #pragma unroll
                for (int j = 0; j < 2; ++j)
                    acc[i][j] = __builtin_amdgcn_mfma_f32_16x16x32_bf16(af[i], bfr[j], acc[i][j], 0, 0, 0);
        }
        cur ^= 1;
    }

    if (nz > 1) {
        int Nw = gridDim.x * 128;
        size_t pstride = (size_t)Nw * (gridDim.y * 128);
        float* Pz = P + (size_t)blockIdx.z * pstride;
        #pragma unroll
        for (int i = 0; i < 2; ++i)
            #pragma unroll
            for (int j = 0; j < 2; ++j)
                #pragma unroll
                for (int r = 0; r < 4; ++r) {
                    int grow = m0g + wr + i*16 + lg*4 + r;
                    int gcol = n0 + wc + j*16 + lr;
                    Pz[(size_t)grow * Nw + gcol] = acc[i][j][r];
                }
        return;
    }

    #pragma unroll
    for (int i = 0; i < 2; ++i)
        #pragma unroll
        for (int j = 0; j < 2; ++j)
            #pragma unroll
            for (int r = 0; r < 4; ++r) {
                int grow = m0g + wr + i*16 + lg*4 + r;
                int gcol = n0 + wc + j*16 + lr;
                float v = epi_apply(acc[i][j][r], grow, gcol, bias, mode, X, ldx, gate, gstride);
                if (obf)
                    ((__hip_bfloat16*)C)[(size_t)grow * ldc + gcol] = __float2bfloat16(v);
                else
                    ((float*)C)[(size_t)grow * ldc + gcol] = v;
            }
}

// ---------------------------------------------------------------------------
// combine split-K partials + epilogue. 4 elems/thread. optional C2 bf16 out.
// ---------------------------------------------------------------------------
__global__ __launch_bounds__(256) void gcomb_kernel(
    const float* __restrict__ P, size_t pstride, int nz, int Nw,
    const float* __restrict__ bias,
    void* __restrict__ C, int ldc, int mode, int obf,
    const float* __restrict__ X, int ldx,
    const float* __restrict__ gate, int gstride,
    __hip_bfloat16* __restrict__ C2, int ldc2)
{
    int idx = blockIdx.x * 256 + threadIdx.x;
    int e0 = idx * 4;
    int grow = e0 / Nw, gc0 = e0 % Nw;
    float4 v = *(const float4*)(P + (size_t)grow * Nw + gc0);
    for (int z = 1; z < nz; ++z) {
        float4 t = *(const float4*)(P + (size_t)z * pstride + (size_t)grow * Nw + gc0);
        v.x += t.x; v.y += t.y; v.z += t.z; v.w += t.w;
    }
    float e[4] = {v.x, v.y, v.z, v.w};
    #pragma unroll
    for (int r = 0; r < 4; ++r)
        e[r] = epi_apply(e[r], grow, gc0 + r, bias, mode, X, ldx, gate, gstride);
    if (obf) {
        U4 o4;
        #pragma unroll
        for (int r = 0; r < 4; ++r) o4.e[r] = __float2bfloat16(e[r]);
        *(uint2*)((__hip_bfloat16*)C + (size_t)grow * ldc + gc0) = o4.u2;
    } else {
        *(float4*)((float*)C + (size_t)grow * ldc + gc0) = make_float4(e[0], e[1], e[2], e[3]);
    }
    if (C2) {
        U4 o4;
        #pragma unroll
        for (int r = 0; r < 4; ++r) o4.e[r] = __float2bfloat16(e[r]);
        *(uint2*)(C2 + (size_t)grow * ldc2 + gc0) = o4.u2;
    }
}

// ---------------------------------------------------------------------------
// fused: combine split-K (nz, D=256) + bias + LayerNorm(g,b) [+silu] -> out
// ---------------------------------------------------------------------------
__global__ __launch_bounds__(256) void combln256_kernel(
    const float* __restrict__ P, size_t pstride, int nz,
    const float* __restrict__ bias,
    const float* __restrict__ g, const float* __restrict__ bv,
    int do_silu, int obf,
    void* __restrict__ out, int ldout)
{
    int row = blockIdx.x, d = threadIdx.x;
    __shared__ float red4[4];
    float v = P[(size_t)row*256 + d];
    for (int z = 1; z < nz; ++z) v += P[(size_t)z*pstride + (size_t)row*256 + d];
    v += bias[d];
    float mu = bsum256(v, red4, d) * (1.f/256.f);
    float dv = v - mu;
    float rstd = rsqrtf(bsum256(dv*dv, red4, d) * (1.f/256.f) + 1e-5f);
    float y = dv * rstd * g[d] + bv[d];
    if (do_silu) y = y / (1.f + __expf(-y));
    if (obf) ((__hip_bfloat16*)out)[(size_t)row * ldout + d] = __float2bfloat16(y);
    else     ((float*)out)[(size_t)row * ldout + d] = y;
}

// ---------------------------------------------------------------------------
// tin-chain fusion: combine split-K (nz, D=768) + bias ->
//   X = LN(t; g,b)  (write fp32) ; Hb = bf16( LN2(X)*(1+scm[b]) + shm[b] )
// ---------------------------------------------------------------------------
__global__ __launch_bounds__(256) void tinfuse_kernel(
    const float* __restrict__ P, size_t pstride, int nz,
    const float* __restrict__ bias,
    const float* __restrict__ g, const float* __restrict__ bb,
    const float* __restrict__ scm, const float* __restrict__ shm,
    float* __restrict__ X, __hip_bfloat16* __restrict__ Hb)
{
    int row = blockIdx.x, tid = threadIdx.x;
    int b = row >> 11;
    __shared__ float red4[4];
    float tv[3];
    float s = 0.f;
    #pragma unroll
    for (int q = 0; q < 3; ++q) {
        int d = tid + q*256;
        float v = P[(size_t)row*768 + d];
        for (int z = 1; z < nz; ++z) v += P[(size_t)z*pstride + (size_t)row*768 + d];
        v += bias[d];
        tv[q] = v; s += v;
    }
    float mu1 = bsum256(s, red4, tid) * (1.f/768.f);
    float s2 = 0.f;
    #pragma unroll
    for (int q = 0; q < 3; ++q) { float dv = tv[q] - mu1; s2 += dv*dv; }
    float rstd1 = rsqrtf(bsum256(s2, red4, tid) * (1.f/768.f) + 1e-5f);
    float xv[3];
    float s3 = 0.f;
    #pragma unroll
    for (int q = 0; q < 3; ++q) {
        int d = tid + q*256;
        float y = (tv[q] - mu1) * rstd1 * g[d] + bb[d];
        X[(size_t)row*768 + d] = y;
        xv[q] = y; s3 += y;
    }
    float mu2 = bsum256(s3, red4, tid) * (1.f/768.f);
    float s4 = 0.f;
    #pragma unroll
    for (int q = 0; q < 3; ++q) { float dv = xv[q] - mu2; s4 += dv*dv; }
    float rstd2 = rsqrtf(bsum256(s4, red4, tid) * (1.f/768.f) + 1e-5f);
    #pragma unroll
    for (int q = 0; q < 3; ++q) {
        int d = tid + q*256;
        float h = (xv[q] - mu2) * rstd2 * (1.f + scm[(size_t)b*4608 + d]) + shm[(size_t)b*4608 + d];
        Hb[(size_t)row*768 + d] = __float2bfloat16(h);
    }
}

// ---------------------------------------------------------------------------
// fused: combine split-K (nz) + bias + residual-gate into X, then
// Hb = bf16( LN(xnew)*(1+scm[b]) + shm[b] ).  block per row, D=768.
// ---------------------------------------------------------------------------
__global__ __launch_bounds__(256) void gcombln_kernel(
    const float* __restrict__ P, size_t pstride, int nz,
    const float* __restrict__ bias,
    float* __restrict__ X,
    const float* __restrict__ gate,
    const float* __restrict__ scm, const float* __restrict__ shm,
    __hip_bfloat16* __restrict__ Hb)
{
    int row = blockIdx.x, tid = threadIdx.x;
    int b = row >> 11;
    __shared__ float red4[4];
    float xv[3];
    float s = 0.f;
    #pragma unroll
    for (int q = 0; q < 3; ++q) {
        int d = tid + q*256;
        float v = P[(size_t)row*768 + d];
        for (int z = 1; z < nz; ++z) v += P[(size_t)z*pstride + (size_t)row*768 + d];
        v += bias[d];
        v = X[(size_t)row*768 + d] + gate[(size_t)b*4608 + d] * v;
        X[(size_t)row*768 + d] = v;
        xv[q] = v; s += v;
    }
    float mu = bsum256(s, red4, tid) * (1.f/768.f);
    float s2 = 0.f;
    #pragma unroll
    for (int q = 0; q < 3; ++q) { float dv = xv[q] - mu; s2 += dv*dv; }
    float rstd = rsqrtf(bsum256(s2, red4, tid) * (1.f/768.f) + 1e-5f);
    #pragma unroll
    for (int q = 0; q < 3; ++q) {
        int d = tid + q*256;
        float y = (xv[q] - mu) * rstd * (1.f + scm[(size_t)b*4608 + d]) + shm[(size_t)b*4608 + d];
        Hb[(size_t)row*768 + d] = __float2bfloat16(y);
    }
}

// ---------------------------------------------------------------------------
// c = LN(adaLN_emb @ ada_W + ada_b; g,b); c_silu = silu(c). 2 blocks.
// ---------------------------------------------------------------------------
__global__ __launch_bounds__(256) void ada_kernel(
    const float* __restrict__ emb, const float* __restrict__ W,
    const float* __restrict__ bias,
    const float* __restrict__ g, const float* __restrict__ bb,
    float* __restrict__ c, float* __restrict__ c_silu)
{
    int b = blockIdx.x, tid = threadIdx.x;
    __shared__ float emb_s[256];
    __shared__ float t[768];
    __shared__ float red[256];
    emb_s[tid] = emb[b*256 + tid];
    __syncthreads();
    for (int q = 0; q < 3; ++q) {
        int e = tid + q*256;
        float acc = bias[e];
        for (int k = 0; k < 256; ++k) acc += emb_s[k] * W[(size_t)k*768 + e];
        t[e] = acc;
    }
    __syncthreads();
    float s = 0.f; for (int q = 0; q < 3; ++q) s += t[tid + q*256];
    red[tid] = s; __syncthreads();
    for (int off = 128; off > 0; off >>= 1) { if (tid < off) red[tid] += red[tid+off]; __syncthreads(); }
    float mu = red[0] / 768.f; __syncthreads();
    float s2 = 0.f; for (int q = 0; q < 3; ++q) { float d = t[tid + q*256] - mu; s2 += d*d; }
    red[tid] = s2; __syncthreads();
    for (int off = 128; off > 0; off >>= 1) { if (tid < off) red[tid] += red[tid+off]; __syncthreads(); }
    float rstd = rsqrtf(red[0] / 768.f + 1e-5f);
    for (int q = 0; q < 3; ++q) {
        int e = tid + q*256;
        float y = (t[e] - mu) * rstd * g[e] + bb[e];
        c[b*768 + e] = y;
        c_silu[b*768 + e] = y / (1.f + expf(-y));
    }
}

// ---------------------------------------------------------------------------
// mod for BOTH layers, K-split 4: part[z][l][b][4608] ; grid (72, 4)
// ---------------------------------------------------------------------------
__global__ __launch_bounds__(256) void mod2_kernel(
    const float* __restrict__ c_silu, const float* __restrict__ mod_W,
    float* __restrict__ part)
{
    int idx = blockIdx.x * 256 + threadIdx.x;   // < 18432
    int z = blockIdx.y;
    int lyr = idx / 9216, b = (idx / 4608) & 1, j = idx % 4608;
    const float* Wl = mod_W + (size_t)lyr * 768 * 4608;
    const float* cs = c_silu + b * 768;
    float acc = 0.f;
    int k0 = z * 192;
    for (int k = k0; k < k0 + 192; ++k) acc += cs[k] * Wl[(size_t)k * 4608 + j];
    part[(size_t)z * 18432 + idx] = acc;
}

__global__ __launch_bounds__(256) void modc_kernel(
    const float* __restrict__ part, const float* __restrict__ mod_b,
    float* __restrict__ m2buf)
{
    int idx = blockIdx.x * 256 + threadIdx.x;
    int lyr = idx / 9216, j = idx % 4608;
    float acc = mod_b[(size_t)lyr * 4608 + j];
    #pragma unroll
    for (int z = 0; z < 4; ++z) acc += part[(size_t)z * 18432 + idx];
    m2buf[idx] = acc;
}

// ---------------------------------------------------------------------------
// MFMA local-window attention. 4 waves/block; block = (b, h, qgroup of 4
// qblocks).  Shared V window staged once: Vl[224][72].  Per-wave P private.
// ---------------------------------------------------------------------------
__global__ __launch_bounds__(256) void attn_mfma_kernel(
    const __hip_bfloat16* __restrict__ qkv,   // [B*N, 2304]
    const float* __restrict__ ropeC,          // [B*N, 32]
    const float* __restrict__ ropeS,
    __hip_bfloat16* __restrict__ o)           // [B*N, 768]
{
    int bid = blockIdx.x;
    int qg = bid & 15;                 // q-group (4 qblocks)
    int h  = (bid >> 4) % 12;
    int b  = bid / 192;
    int tid = threadIdx.x;
    int w  = tid >> 6;                 // wave 0..3
    int l  = tid & 63;
    int lr = l & 15, lg = l >> 4;

    int qb = qg * 4 + w;
    int lo_blk = max(0, 128*qg - 48);
    int hi_blk = min(N_, 128*qg + 176);
    int lo = max(0, 32*qb - 48);
    int hi = min(N_, 32*qb + 80);
    int wlen = hi - lo;
    int offv = lo - lo_blk;            // wave's row offset into Vl

    __shared__ __hip_bfloat16 Vl[224 * 72];
    __shared__ __hip_bfloat16 Pl[4 * 32 * 144];
    __hip_bfloat16* Plw = Pl + w * (32 * 144);

    // ---- stage shared V window (all 256 threads), zero-fill past hi_blk ----
    {
        int vr0 = tid >> 3;            // 0..31
        int c0  = (tid & 7) * 8;
        #pragma unroll
        for (int it = 0; it < 7; ++it) {
            int vr = it*32 + vr0;      // 0..223
            int n = lo_blk + vr;
            U8 v;
            if (n < hi_blk) {
                v.v = *(const bf16x8*)(qkv + ((size_t)(b*N_ + n))*2304 + 1536 + h*64 + c0);
            } else {
                #pragma unroll
                for (int j = 0; j < 8; ++j) v.u[j] = 0;
            }
            *(bf16x8*)(Vl + vr*72 + c0) = v.v;
        }
    }

    // ---- Q fragments with rope ----
    bf16x8 aq0[2], aq1[2];
    #pragma unroll
    for (int i = 0; i < 2; ++i) {
        int n = qb*32 + i*16 + lr;
        const __hip_bfloat16* qrow = qkv + ((size_t)(b*N_ + n))*2304 + h*64;
        U8 xlo, xhi;
        xlo.v = *(const bf16x8*)(qrow + lg*8);
        xhi.v = *(const bf16x8*)(qrow + 32 + lg*8);
        const float* pc = ropeC + ((size_t)(b*N_ + n))*32 + lg*8;
        const float* ps = ropeS + ((size_t)(b*N_ + n))*32 + lg*8;
        float4 c0 = *(const float4*)(pc), c1 = *(const float4*)(pc + 4);
        float4 s0 = *(const float4*)(ps), s1 = *(const float4*)(ps + 4);
        float cv[8] = {c0.x,c0.y,c0.z,c0.w,c1.x,c1.y,c1.z,c1.w};
        float sv[8] = {s0.x,s0.y,s0.z,s0.w,s1.x,s1.y,s1.z,s1.w};
        U8 f0, f1;
        #pragma unroll
        for (int j = 0; j < 8; ++j) {
            float x1 = __bfloat162float(xlo.e[j]);
            float x2 = __bfloat162float(xhi.e[j]);
            f0.e[j] = __float2bfloat16(x1*cv[j] - x2*sv[j]);
            f1.e[j] = __float2bfloat16(x1*sv[j] + x2*cv[j]);
        }
        aq0[i] = f0.v; aq1[i] = f1.v;
    }

    // ---- scores ----
    f32x4 S[2][8];
    #pragma unroll
    for (int i = 0; i < 2; ++i)
        #pragma unroll
        for (int jt = 0; jt < 8; ++jt)
            S[i][jt] = f32x4{0.f, 0.f, 0.f, 0.f};

    #pragma unroll
    for (int jt = 0; jt < 8; ++jt) {
        int n = lo + jt*16 + lr;
        U8 f0, f1;
        if (n < hi) {
            const __hip_bfloat16* krow = qkv + ((size_t)(b*N_ + n))*2304 + 768 + h*64;
            U8 xlo, xhi;
            xlo.v = *(const bf16x8*)(krow + lg*8);
            xhi.v = *(const bf16x8*)(krow + 32 + lg*8);
            const float* pc = ropeC + ((size_t)(b*N_ + n))*32 + lg*8;
            const float* ps = ropeS + ((size_t)(b*N_ + n))*32 + lg*8;
            float4 c0 = *(const float4*)(pc), c1 = *(const float4*)(pc + 4);
            float4 s0 = *(const float4*)(ps), s1 = *(const float4*)(ps + 4);
            float cv[8] = {c0.x,c0.y,c0.z,c0.w,c1.x,c1.y,c1.z,c1.w};
            float sv[8] = {s0.x,s0.y,s0.z,s0.w,s1.x,s1.y,s1.z,s1.w};
            #pragma unroll
            for (int j = 0; j < 8; ++j) {
                float x1 = __bfloat162float(xlo.e[j]);
                float x2 = __bfloat162float(xhi.e[j]);
                f0.e[j] = __float2bfloat16(x1*cv[j] - x2*sv[j]);
                f1.e[j] = __float2bfloat16(x1*sv[j] + x2*cv[j]);
            }
        } else {
            #pragma unroll
            for (int j = 0; j < 8; ++j) { f0.u[j] = 0; f1.u[j] = 0; }
        }
        #pragma unroll
        for (int i = 0; i < 2; ++i) {
            S[i][jt] = __builtin_amdgcn_mfma_f32_16x16x32_bf16(aq0[i], f0.v, S[i][jt], 0, 0, 0);
            S[i][jt] = __builtin_amdgcn_mfma_f32_16x16x32_bf16(aq1[i], f1.v, S[i][jt], 0, 0, 0);
        }
    }

    // ---- scale + mask ----
    #pragma unroll
    for (int jt = 0; jt < 8; ++jt) {
        bool oob = (jt*16 + lr) >= wlen;
        #pragma unroll
        for (int i = 0; i < 2; ++i)
            #pragma unroll
            for (int r = 0; r < 4; ++r)
                S[i][jt][r] = oob ? -1e30f : S[i][jt][r] * 0.125f;
    }

    // ---- wave-parallel softmax over 16-lane groups ----
    float rinv[2][4];
    #pragma unroll
    for (int i = 0; i < 2; ++i) {
        #pragma unroll
        for (int r = 0; r < 4; ++r) {
            float m = -1e30f;
            #pragma unroll
            for (int jt = 0; jt < 8; ++jt) m = fmaxf(m, S[i][jt][r]);
            #pragma unroll
            for (int mask = 8; mask > 0; mask >>= 1) m = fmaxf(m, __shfl_xor(m, mask, 16));
            float sum = 0.f;
            #pragma unroll
            for (int jt = 0; jt < 8; ++jt) {
                float e = __expf(S[i][jt][r] - m);
                S[i][jt][r] = e;
                sum += e;
            }
            #pragma unroll
            for (int mask = 8; mask > 0; mask >>= 1) sum += __shfl_xor(sum, mask, 16);
            rinv[i][r] = 1.f / sum;
        }
    }

    // ---- write P (bf16, XOR-swizzled cols) into this wave's region ----
    #pragma unroll
    for (int i = 0; i < 2; ++i)
        #pragma unroll
        for (int jt = 0; jt < 8; ++jt)
            #pragma unroll
            for (int r = 0; r < 4; ++r) {
                int row = i*16 + lg*4 + r;
                int colp = (jt*16 + lr) ^ (lg << 3);
                Plw[row*144 + colp] = __float2bfloat16(S[i][jt][r]);
            }

    __syncthreads();   // Vl staged by all + Plw written before; PV reads after

    // ---- PV ----
    f32x4 O_[2][4];
    #pragma unroll
    for (int i = 0; i < 2; ++i)
        #pragma unroll
        for (int ct = 0; ct < 4; ++ct)
            O_[i][ct] = f32x4{0.f, 0.f, 0.f, 0.f};

    int key = (lr >> 2) & 3;
    #pragma unroll
    for (int kt = 0; kt < 4; ++kt) {
        bf16x8 pa[2];
        #pragma unroll
        for (int i = 0; i < 2; ++i) {
            int row = i*16 + lr;
            int colp = (kt*32 + lg*8) ^ (key << 3);
            pa[i] = *(bf16x8*)(Plw + row*144 + colp);
        }
        #pragma unroll
        for (int ct = 0; ct < 4; ++ct) {
            U8 bv;
            #pragma unroll
            for (int j = 0; j < 8; ++j)
                bv.e[j] = Vl[(offv + kt*32 + lg*8 + j)*72 + ct*16 + lr];
            O_[0][ct] = __builtin_amdgcn_mfma_f32_16x16x32_bf16(pa[0], bv.v, O_[0][ct], 0, 0, 0);
            O_[1][ct] = __builtin_amdgcn_mfma_f32_16x16x32_bf16(pa[1], bv.v, O_[1][ct], 0, 0, 0);
        }
    }

    // ---- store O ----
    #pragma unroll
    for (int i = 0; i < 2; ++i)
        #pragma unroll
        for (int ct = 0; ct < 4; ++ct)
            #pragma unroll
            for (int r = 0; r < 4; ++r) {
                int row = qb*32 + i*16 + lg*4 + r;
                o[((size_t)(b*N_ + row))*768 + h*64 + ct*16 + lr] =
                    __float2bfloat16(O_[i][ct][r] * rinv[i][r]);
            }
}

// ---------------------------------------------------------------------------
// a2t [B,N,NR] fp32 -> a2tTb [B,NR,N] bf16   grid (NR/32, N/32, B)
// ---------------------------------------------------------------------------
__global__ __launch_bounds__(256) void a2t_transpose_kernel(
    const float* __restrict__ a2t, __hip_bfloat16* __restrict__ a2tTb)
{
    __shared__ float t[32][33];
    int r0 = blockIdx.x * 32, n0 = blockIdx.y * 32, b = blockIdx.z;
    int tid = threadIdx.x;
    int tx = tid & 31, ty = tid >> 5;
    #pragma unroll
    for (int i = 0; i < 4; ++i) {
        int row = ty + i*8;
        t[row][tx] = a2t[((size_t)b*N_ + n0 + row) * 256 + r0 + tx];
    }
    __syncthreads();
    #pragma unroll
    for (int i = 0; i < 4; ++i) {
        int row = ty + i*8;
        a2tTb[((size_t)b*256 + r0 + row) * N_ + n0 + tx] = __float2bfloat16(t[tx][row]);
    }
}

// ---------------------------------------------------------------------------
// recip[row] = 1/(sum of a2tTb row + 1e-6).  block per row (512 rows).
// ---------------------------------------------------------------------------
__global__ __launch_bounds__(256) void rowrecip_kernel(
    const __hip_bfloat16* __restrict__ a2tTb, float* __restrict__ recip)
{
    int row = blockIdx.x;
    int tid = threadIdx.x;
    __shared__ float red4[4];
    U8 v; v.v = *(const bf16x8*)(a2tTb + (size_t)row*2048 + tid*8);
    float s = 0.f;
    #pragma unroll
    for (int j = 0; j < 8; ++j) s += __bfloat162float(v.e[j]);
    float tot = bsum256(s, red4, tid);
    if (tid == 0) recip[row] = 1.f / (tot + 1e-6f);
}

// ---------------------------------------------------------------------------
extern "C" void kernel_launch(void* const* d_in, const int* in_sizes, int n_in,
                              void* d_out, int out_size, void* d_ws, size_t ws_size,
                              hipStream_t stream) {
    const float* atom_coords  = (const float*)d_in[0];
    const float* ref_pos      = (const float*)d_in[1];
    const int*   res_id       = (const int*)  d_in[2];
    const float* res_type     = (const float*)d_in[3];
    const float* charge       = (const float*)d_in[4];
    const float* atomic_num   = (const float*)d_in[5];
    const float* atom_name    = (const float*)d_in[6];
    const float* adaLN_emb    = (const float*)d_in[7];
    const int*   rope_pos     = (const int*)  d_in[8];
    const float* atom_to_tok  = (const float*)d_in[9];
    const float* feat_W       = (const float*)d_in[10];
    const float* feat_b       = (const float*)d_in[11];
    const float* feat_ln_g    = (const float*)d_in[12];
    const float* feat_ln_b    = (const float*)d_in[13];
    const float* pos_W        = (const float*)d_in[14];
    const float* in_W         = (const float*)d_in[15];
    const float* tin_W        = (const float*)d_in[16];
    const float* tin_b        = (const float*)d_in[17];
    const float* tin_ln_g     = (const float*)d_in[18];
    const float* tin_ln_b     = (const float*)d_in[19];
    const float* ada_W        = (const float*)d_in[20];
    const float* ada_b        = (const float*)d_in[21];
    const float* ada_ln_g     = (const float*)d_in[22];
    const float* ada_ln_b     = (const float*)d_in[23];
    const float* blk_mod_W    = (const float*)d_in[24];
    const float* blk_mod_b    = (const float*)d_in[25];
    const float* blk_qkv_W    = (const float*)d_in[26];
    const float* blk_qkv_b    = (const float*)d_in[27];
    const float* blk_o_W      = (const float*)d_in[28];
    const float* blk_o_b      = (const float*)d_in[29];
    const float* blk_m1_W     = (const float*)d_in[30];
    const float* blk_m1_b     = (const float*)d_in[31];
    const float* blk_m2_W     = (const float*)d_in[32];
    const float* blk_m2_b     = (const float*)d_in[33];
    const float* tout_W       = (const float*)d_in[34];
    const float* tout_b       = (const float*)d_in[35];
    const float* tout_ln_g    = (const float*)d_in[36];
    const float* tout_ln_b    = (const float*)d_in[37];

    const int BN = B_ * N_;                          // 4096
    float* ws = (float*)d_ws;

    // layout (float units)
    const size_t OFF_X    = 0;                                // fp32 [4096][768]
    const size_t OFF_HB   = OFF_X    + (size_t)BN*768;        // bf16 [4096][768]
    const size_t OFF_QKVB = OFF_HB   + (size_t)BN*768/2;      // bf16 [4096][2304]
    const size_t OFF_OB   = OFF_QKVB + (size_t)BN*2304/2;     // bf16 [4096][768]
    const size_t OFF_UB   = OFF_OB   + (size_t)BN*768/2;      // bf16 [4096][3072]
    const size_t OFF_WTL  = OFF_UB   + (size_t)BN*3072/2;     // bf16 layer weights (persistent)
    const size_t WTL_FLTS = (size_t)(2*768*2304 + 2*768*768 + 2*768*3072 + 2*3072*768) / 2;
    const size_t OFF_WTS  = OFF_WTL  + WTL_FLTS;              // bf16 phase-A scratch
    const size_t OFF_RC   = OFF_WTS  + 524288;                // fp32 BN*32
    const size_t OFF_RS   = OFF_RC   + (size_t)BN*32;
    const size_t OFF_SM   = OFF_RS   + (size_t)BN*32;

    float* X = ws + OFF_X;
    __hip_bfloat16* Hb   = (__hip_bfloat16*)(ws + OFF_HB);
    __hip_bfloat16* QKVb = (__hip_bfloat16*)(ws + OFF_QKVB);
    __hip_bfloat16* Ob   = (__hip_bfloat16*)(ws + OFF_OB);
    __hip_bfloat16* Ub   = (__hip_bfloat16*)(ws + OFF_UB);
    __hip_bfloat16* WTL  = (__hip_bfloat16*)(ws + OFF_WTL);
    __hip_bfloat16* WTs  = (__hip_bfloat16*)(ws + OFF_WTS);
    float* ropeC  = ws + OFF_RC;
    float* ropeS  = ws + OFF_RS;
    float* cbuf   = ws + OFF_SM;                     // 1536
    float* c_silu = cbuf + 1536;                     // 1536
    float* mbuf2  = c_silu + 1536;                   // 18432  [2][2][4608]
    float* modpart= mbuf2 + 18432;                   // 73728

    // persistent per-layer transposed weights (bf16 elem offsets)
    __hip_bfloat16* WTqkv = WTL;                                  // 2 x 768*2304
    __hip_bfloat16* WTo   = WTqkv + (size_t)2*768*2304;           // 2 x 768*768
    __hip_bfloat16* WTm1  = WTo   + (size_t)2*768*768;            // 2 x 768*3072
    __hip_bfloat16* WTm2  = WTm1  + (size_t)2*768*3072;           // 2 x 3072*768

    // phase-A aliases
    __hip_bfloat16* featsB  = QKVb;                           // [4096][1024] bf16
    __hip_bfloat16* coordsB = QKVb + (size_t)BN*1024;         // [4096][512] bf16
    float* t1               = ws + OFF_UB;                    // scratch
    __hip_bfloat16* concatB = (__hip_bfloat16*)(t1 + (size_t)BN*256);  // [4096][512] bf16
    __hip_bfloat16* atom_inB= Ob;                             // [4096][256] bf16

    // residue-phase aliases (Ob/Ub regions dead by then)
    __hip_bfloat16* a2tTb   = Ob;                             // [2][256][2048] bf16
    __hip_bfloat16* latTb   = Ob + (size_t)2*256*2048;        // [2][256][2048] bf16
    float* recip            = modpart;                        // 512 fp32

    // split-K partial buffers (aliases of dead regions)
    float* P_pa   = ws + OFF_X;       // phase A (feat/pos/in)
    float* P_tin  = ws + OFF_UB;
    float* P_o    = ws + OFF_UB;
    float* P_m2   = ws + OFF_QKVB;
    float* P_tout = ws + OFF_UB;
    float* P_res  = ws + OFF_UB;

    float* out_res = (float*)d_out;                           // B*NR*DA
    float* out_lat = out_res + (size_t)B_*NR_*DA_;            // B*N*DA

    // ---- adaLN + modulation for both layers (input-only; run first) ----
    ada_kernel<<<2, 256, 0, stream>>>(adaLN_emb, ada_W, ada_b, ada_ln_g, ada_ln_b,
        cbuf, c_silu);
    mod2_kernel<<<dim3(72, 4), 256, 0, stream>>>(c_silu, blk_mod_W, modpart);
    modc_kernel<<<72, 256, 0, stream>>>(modpart, blk_mod_b, mbuf2);

    // ---- pre-transpose ALL layer weights (batched across layers, z=2) ----
    transconv_kernel<<<dim3(72, 24, 2), 256, 0, stream>>>(blk_qkv_W, WTqkv,
        768, 768, 2304, (size_t)768*2304, (size_t)768*2304);
    transconv_kernel<<<dim3(24, 24, 2), 256, 0, stream>>>(blk_o_W, WTo,
        768, 768, 768, (size_t)768*768, (size_t)768*768);
    transconv_kernel<<<dim3(96, 24, 2), 256, 0, stream>>>(blk_m1_W, WTm1,
        768, 768, 3072, (size_t)768*3072, (size_t)768*3072);
    transconv_kernel<<<dim3(24, 96, 2), 256, 0, stream>>>(blk_m2_W, WTm2,
        3072, 3072, 768, (size_t)3072*768, (size_t)3072*768);

    // ---- featurization (bf16) + rope table (fused) ----
    build_feats_kernel<<<BN, 128, 0, stream>>>(atom_coords, ref_pos, res_id,
        res_type, charge, atomic_num, atom_name, rope_pos, featsB, coordsB,
        ropeC, ropeS);

    // t1 = feats @ feat_W + feat_b   (K padded 924->1024, split 4)
    transconv_kernel<<<dim3(8, 32), 256, 0, stream>>>(feat_W, WTs, 924, 1024, 256, 0, 0);
    gemm_bf16_kernel<<<dim3(2, 32, 4), 1024, 0, stream>>>(featsB, 1024, WTs, 1024, nullptr,
        nullptr, 0, 1024, 0, 0, nullptr, 0, nullptr, 0, P_pa, 32, 0, 0);
    combln256_kernel<<<BN, 256, 0, stream>>>(P_pa, (size_t)BN*256, 4, feat_b,
        feat_ln_g, feat_ln_b, 1, 1, concatB, 512);
    // concat[:,256:512] = coordsF @ pos_W  (K 387->512, split 4)
    transconv_kernel<<<dim3(8, 16), 256, 0, stream>>>(pos_W, WTs, 387, 512, 256, 0, 0);
    gemm_bf16_kernel<<<dim3(2, 32, 4), 1024, 0, stream>>>(coordsB, 512, WTs, 512, nullptr,
        nullptr, 0, 512, 0, 0, nullptr, 0, nullptr, 0, P_pa, 32, 0, 0);
    gcomb_kernel<<<1024, 256, 0, stream>>>(P_pa, (size_t)BN*256, 4, 256, nullptr,
        concatB + 256, 512, 0, 1, nullptr, 0, nullptr, 0, nullptr, 0);
    // atom_in = concat @ in_W -> bf16 (split 4)
    transconv_kernel<<<dim3(8, 16), 256, 0, stream>>>(in_W, WTs, 512, 512, 256, 0, 0);
    gemm_bf16_kernel<<<dim3(2, 32, 4), 1024, 0, stream>>>(concatB, 512, WTs, 512, nullptr,
        nullptr, 0, 512, 0, 0, nullptr, 0, nullptr, 0, P_pa, 32, 0, 0);
    gcomb_kernel<<<1024, 256, 0, stream>>>(P_pa, (size_t)BN*256, 4, 256, nullptr,
        atom_inB, 256, 0, 1, nullptr, 0, nullptr, 0, nullptr, 0);
    // X = LN(atom_in @ tin_W + tin_b) ; Hb = LN(X)*(1+sc1)+sh1  (fused)
    transconv_kernel<<<dim3(24, 8), 256, 0, stream>>>(tin_W, WTs, 256, 256, 768, 0, 0);
    gemm_bf16_kernel<<<dim3(6, 32, 2), 1024, 0, stream>>>(atom_inB, 256, WTs, 256, nullptr,
        nullptr, 0, 256, 0, 0, nullptr, 0, nullptr, 0, P_tin, 32, 0, 0);
    tinfuse_kernel<<<BN, 256, 0, stream>>>(P_tin, (size_t)BN*768, 2, tin_b,
        tin_ln_g, tin_ln_b, mbuf2 + 768, mbuf2 + 0, X, Hb);

    for (int l = 0; l < NB_; ++l) {
        const float* qkvB = blk_qkv_b + (size_t)l*2304;
        const float* oB   = blk_o_b   + (size_t)l*768;
        const float* m1B  = blk_m1_b  + (size_t)l*3072;
        const float* m2B  = blk_m2_b  + (size_t)l*768;
        __hip_bfloat16* Wq = WTqkv + (size_t)l*768*2304;
        __hip_bfloat16* Wo = WTo   + (size_t)l*768*768;
        __hip_bfloat16* W1 = WTm1  + (size_t)l*768*3072;
        __hip_bfloat16* W2 = WTm2  + (size_t)l*3072*768;

        float* mptr = mbuf2 + (size_t)l*9216;        // [b][4608]
        float* sh2 = mptr + 2304, *sc2 = mptr + 3072;
        float* g1  = mptr + 1536, *g2 = mptr + 3840;

        // qkv = h @ qkv_W + b -> bf16
        gemm_bf16_kernel<<<dim3(18, 32, 1), 1024, 0, stream>>>(Hb, 768, Wq, 768, qkvB,
            QKVb, 2304, 768, 0, 1, nullptr, 0, nullptr, 0, nullptr, 32, 0, 0);
        // attention (4 waves/block, shared V window)
        attn_mfma_kernel<<<B_*H_*16, 256, 0, stream>>>(QKVb, ropeC, ropeS, Ob);
        // x = x + g1*(o @ o_W + o_b)  (split 2) ; fused -> Hb = h2
        gemm_bf16_kernel<<<dim3(6, 32, 2), 1024, 0, stream>>>(Ob, 768, Wo, 768, nullptr,
            nullptr, 0, 768, 0, 0, nullptr, 0, nullptr, 0, P_o, 32, 0, 0);
        gcombln_kernel<<<BN, 256, 0, stream>>>(P_o, (size_t)BN*768, 2, oB,
            X, g1, sc2, sh2, Hb);
        // u = gelu(h2 @ m1_W + b) -> bf16
        gemm_bf16_kernel<<<dim3(24, 32, 1), 1024, 0, stream>>>(Hb, 768, W1, 768, m1B,
            Ub, 3072, 768, 1, 1, nullptr, 0, nullptr, 0, nullptr, 32, 0, 0);
        // x = x + g2*(u @ m2_W + b)  (split 2)
        gemm_bf16_kernel<<<dim3(6, 32, 2), 1024, 0, stream>>>(Ub, 3072, W2, 3072, nullptr,
            nullptr, 0, 3072, 0, 0, nullptr, 0, nullptr, 0, P_m2, 32, 0, 0);
        if (l < NB_ - 1) {
            float* mnext = mbuf2 + (size_t)(l+1)*9216;
            gcombln_kernel<<<BN, 256, 0, stream>>>(P_m2, (size_t)BN*768, 2, m2B,
                X, g2, mnext + 768, mnext + 0, Hb);
        } else {
            // final layer: X is dead afterward -> write Hb (bf16) directly
            gcomb_kernel<<<3072, 256, 0, stream>>>(P_m2, (size_t)BN*768, 2, 768, m2B,
                Hb, 768, 2, 1, X, 768, g2, 4608, nullptr, 0);
        }
    }

    // atom_latent = LN(x @ tout_W + tout_b)  (split 4, fused combine+LN)
    transconv_kernel<<<dim3(8, 24), 256, 0, stream>>>(tout_W, WTs, 768, 768, 256, 0, 0);
    gemm_bf16_kernel<<<dim3(2, 32, 4), 1024, 0, stream>>>(Hb, 768, WTs, 768, nullptr,
        nullptr, 0, 768, 0, 0, nullptr, 0, nullptr, 0, P_tout, 32, 0, 0);
    combln256_kernel<<<BN, 256, 0, stream>>>(P_tout, (size_t)BN*256, 4, tout_b,
        tout_ln_g, tout_ln_b, 0, 0, out_lat, 256);

    // ---- residue pooling as MFMA GEMM ----
    a2t_transpose_kernel<<<dim3(8, 64, 2), 256, 0, stream>>>(atom_to_tok, a2tTb);
    rowrecip_kernel<<<512, 256, 0, stream>>>(a2tTb, recip);
    transconv_kernel<<<dim3(8, 64, 2), 256, 0, stream>>>(out_lat, latTb, 2048, 2048, 256,
        (size_t)2048*256, (size_t)256*2048);
    gemm_bf16_kernel<<<dim3(2, 4, 8), 1024, 0, stream>>>(a2tTb, 2048, latTb, 2048, nullptr,
        nullptr, 0, 2048, 0, 0, nullptr, 0, nullptr, 0, P_res,
        2, (size_t)256*2048, (size_t)256*2048);
    gcomb_kernel<<<128, 256, 0, stream>>>(P_res, (size_t)512*256, 8, 256, nullptr,
        out_res, 256, 3, 0, nullptr, 0, recip, 0, nullptr, 0);
}

// Round 19
// 497.019 us; speedup vs baseline: 1.9234x; 1.0053x over previous
//
#include <hip/hip_runtime.h>
#include <hip/hip_bf16.h>
#include <math.h>

// Problem constants
#define B_ 2
#define N_ 2048
#define NR_ 256
#define DA_ 256
#define E_ 768
#define H_ 12
#define DH_ 64
#define NB_ 2

typedef __attribute__((ext_vector_type(8))) __bf16 bf16x8;
typedef __attribute__((ext_vector_type(4))) float f32x4;

union U8 { bf16x8 v; __hip_bfloat16 e[8]; unsigned short u[8]; };
union U4 { __hip_bfloat16 e[4]; uint2 u2; };

__device__ __forceinline__ void gload16(const void* g, void* l) {
    __builtin_amdgcn_global_load_lds(
        (const __attribute__((address_space(1))) void*)g,
        (__attribute__((address_space(3))) void*)l, 16, 0, 0);
}

// 256-thread block sum: wave shuffle + 4-slot LDS combine (2 barriers).
__device__ __forceinline__ float bsum256(float v, float* red4, int tid) {
    #pragma unroll
    for (int m = 32; m > 0; m >>= 1) v += __shfl_xor(v, m, 64);
    __syncthreads();
    if ((tid & 63) == 0) red4[tid >> 6] = v;
    __syncthreads();
    return red4[0] + red4[1] + red4[2] + red4[3];
}

// ---------------------------------------------------------------------------
// build feats[B*N, 1024] (bf16) and coordsF[B*N, 512] (bf16) + rope tables
// ---------------------------------------------------------------------------
__global__ __launch_bounds__(128) void build_feats_kernel(
    const float* __restrict__ atom_coords, const float* __restrict__ ref_pos,
    const int* __restrict__ res_id, const float* __restrict__ res_type,
    const float* __restrict__ charge, const float* __restrict__ atomic_number,
    const float* __restrict__ atom_name, const int* __restrict__ rope_pos,
    __hip_bfloat16* __restrict__ feats, __hip_bfloat16* __restrict__ coordsF,
    float* __restrict__ ropeC, float* __restrict__ ropeS)
{
    int a = blockIdx.x;            // atom index over B*N
    int tid = threadIdx.x;
    __hip_bfloat16* f  = feats   + (size_t)a * 1024;
    __hip_bfloat16* cf = coordsF + (size_t)a * 512;

    float rp[3], cc[3];
    #pragma unroll
    for (int i = 0; i < 3; ++i) { rp[i] = ref_pos[(size_t)a*3 + i]; cc[i] = atom_coords[(size_t)a*3 + i]; }

    if (tid < 3) { f[tid] = __float2bfloat16(rp[tid]); cf[tid] = __float2bfloat16(cc[tid]); }

    if (tid >= 64 && tid < 96) {
        int dd = tid - 64;
        float rpos = (float)rope_pos[a];
        float ang = rpos * expf(-0.28782313662425574f * (float)dd);  // ln(1e4)/32
        float sn, cs; sincosf(ang, &sn, &cs);
        ropeC[a*32 + dd] = cs; ropeS[a*32 + dd] = sn;
    }

    for (int s = tid; s < 192; s += 128) {
        int fi = s / 3, ci = s % 3;
        float freq = exp2f(12.f * (float)fi / 63.f);
        float ar = rp[ci] * freq;
        float ac = cc[ci] * freq;
        float snr, csr, snc, csc_;
        sincosf(ar, &snr, &csr);
        sincosf(ac, &snc, &csc_);
        f[3 + s]    = __float2bfloat16(snr);  f[195 + s]  = __float2bfloat16(csr);
        cf[3 + s]   = __float2bfloat16(snc);  cf[195 + s] = __float2bfloat16(csc_);
    }
    if (tid < 23) f[387 + tid] = __float2bfloat16(res_type[(size_t)a*23 + tid]);

    float pos = (float)res_id[a];
    if (tid == 0) f[410] = __float2bfloat16(pos);
    if (tid < 64) {
        float div = expf(-9.210340371976184f / 128.f * (float)(2 * tid));
        float ang = pos * div;
        float sn, cs; sincosf(ang, &sn, &cs);
        f[411 + tid] = __float2bfloat16(sn);
        f[475 + tid] = __float2bfloat16(cs);
    }
    if (tid == 0) f[539] = __float2bfloat16(charge[a]);
    if (tid < 128) f[540 + tid] = __float2bfloat16(atomic_number[(size_t)a*128 + tid]);
    for (int s = tid; s < 256; s += 128) f[668 + s] = __float2bfloat16(atom_name[(size_t)a*256 + s]);
    if (tid < 100) f[924 + tid] = __float2bfloat16(0.f);
    if (tid < 125) cf[387 + tid] = __float2bfloat16(0.f);
}

// ---------------------------------------------------------------------------
// Transpose + fp32->bf16 + K-pad: W[Ksrc][Nn] -> WT[Nn][Kdst], zeros k>=Ksrc
// grid (Nn/32, Kdst/32, nbatch); strides advance per batch (z).
// ---------------------------------------------------------------------------
__global__ __launch_bounds__(256) void transconv_kernel(
    const float* __restrict__ W, __hip_bfloat16* __restrict__ WT,
    int Ksrc, int Kdst, int Nn, size_t wstride, size_t tstride)
{
    __shared__ float t[32][33];
    W  += (size_t)blockIdx.z * wstride;
    WT += (size_t)blockIdx.z * tstride;
    int n0 = blockIdx.x * 32, k0 = blockIdx.y * 32;
    int tid = threadIdx.x;
    int tx = tid & 31, ty = tid >> 5;           // ty 0..7
    #pragma unroll
    for (int i = 0; i < 4; ++i) {
        int k = k0 + ty + i*8;
        t[ty + i*8][tx] = (k < Ksrc) ? W[(size_t)k * Nn + n0 + tx] : 0.f;
    }
    __syncthreads();
    #pragma unroll
    for (int i = 0; i < 4; ++i) {
        int row = ty + i*8;                      // n within tile
        WT[(size_t)(n0 + row) * Kdst + k0 + tx] = __float2bfloat16(t[tx][row]);
    }
}

// ---------------------------------------------------------------------------
// shared epilogue.  mode 0 none; 1 gelu; 2 X + gate[b][col]*v; 3 v*gate[row]
// ---------------------------------------------------------------------------
__device__ __forceinline__ float epi_apply(float v, int grow, int gcol,
    const float* bias, int mode, const float* X, int ldx,
    const float* gate, int gstride)
{
    if (bias) v += bias[gcol];
    if (mode == 1) {
        float u = 1.5957691216057308f * (v + 0.044715f * v * v * v);
        v = v / (1.f + __expf(-u));
    } else if (mode == 2) {
        int b = grow >> 11;                      // /N_
        v = X[(size_t)grow * ldx + gcol] + gate[(size_t)b * gstride + gcol] * v;
    } else if (mode == 3) {
        v = v * gate[grow];
    }
    return v;
}

// ---------------------------------------------------------------------------
// bf16 MFMA GEMM: tile 128x128, BK=64, 16 waves (1024 thr), 32x32/wave.
// dbuf-2 LDS (64 KB; 2 blocks/CU): barrier -> STAGE(next 64-K tile) ->
// ds_read+MFMA(current, 2 k-steps).
// Staging: 1 seg/thread/operand.  XOR-swizzle both sides over 8 chunks.
// Bijective XCD swizzle.  gridDim.z = nz splits K -> raw fp32 partials to P.
// ---------------------------------------------------------------------------
__global__ __launch_bounds__(1024) void gemm_bf16_kernel(
    const __hip_bfloat16* __restrict__ A, int lda,
    const __hip_bfloat16* __restrict__ BT, int ldb,
    const float* __restrict__ bias,
    void* __restrict__ C, int ldc,
    int K, int mode, int obf,
    const float* __restrict__ X, int ldx,
    const float* __restrict__ gate, int gstride,
    float* __restrict__ P,
    int mtiles, size_t bstrideA, size_t bstrideB)
{
    __shared__ __hip_bfloat16 As[2][128 * 64];
    __shared__ __hip_bfloat16 Bs[2][128 * 64];

    int gx = gridDim.x;
    int nwg = gx * gridDim.y;
    int fo = blockIdx.y * gx + blockIdx.x;
    int ft = (fo & 7) * (nwg >> 3) + (fo >> 3);
    int bx = ft % gx, by = ft / gx;

    int bb  = by / mtiles;
    int m0l = (by % mtiles) * 128;
    int m0g = by * 128;
    int n0 = bx * 128;
    const __hip_bfloat16* Ab  = A  + (size_t)bb * bstrideA;
    const __hip_bfloat16* BTb = BT + (size_t)bb * bstrideB;
    int nz = gridDim.z;
    int Kh = K / nz;
    int kb = blockIdx.z * Kh;
    int tid = threadIdx.x;
    int w = tid >> 6, l = tid & 63;
    int wr = (w >> 2) * 32, wc = (w & 3) * 32;   // 4 wave-rows x 4 wave-cols
    int lr = l & 15, lg = l >> 4;
    int skey = lr & 7;                           // read-side swizzle key

    // staging: seg = tid (0..1023); row = seg>>3, chunk = seg&7 (8B elems)
    int rowS = tid >> 3;
    int gS   = (tid & 7) ^ (rowS & 7);           // pre-swizzled global chunk

    f32x4 acc[2][2];
    #pragma unroll
    for (int i = 0; i < 2; ++i)
        #pragma unroll
        for (int j = 0; j < 2; ++j)
            acc[i][j] = f32x4{0.f, 0.f, 0.f, 0.f};

    // prologue: stage first 64-K tile into buf 0 (2 gload16/thread)
    gload16(Ab  + (size_t)(m0l + rowS) * lda + kb + gS * 8, (char*)As[0] + tid * 16);
    gload16(BTb + (size_t)(n0 + rowS) * ldb + kb + gS * 8, (char*)Bs[0] + tid * 16);

    int cur = 0;
    for (int k0 = kb; k0 < kb + Kh; k0 += 64) {
        __syncthreads();                         // vmcnt(0): buf[cur] ready
        int kn = k0 + 64;
        if (kn < kb + Kh) {
            int nb = cur ^ 1;
            gload16(Ab  + (size_t)(m0l + rowS) * lda + kn + gS * 8, (char*)As[nb] + tid * 16);
            gload16(BTb + (size_t)(n0 + rowS) * ldb + kn + gS * 8, (char*)Bs[nb] + tid * 16);
        }
        #pragma unroll
        for (int ks = 0; ks < 2; ++ks) {
            int pch = ((ks*4 + lg) ^ skey) * 8;  // swizzled chunk offset (elems)
            bf16x8 af[2], bfr[2];
            #pragma unroll
            for (int i = 0; i < 2; ++i)
                af[i]  = *(bf16x8*)(As[cur] + (wr + i*16 + lr) * 64 + pch);
            #pragma unroll
            for (int j = 0; j < 2; ++j)
                bfr[j] = *(bf16x8*)(Bs[cur] + (wc + j*16 + lr) * 64 + pch);
            #pragma unroll
            for (int i = 0; i < 2; ++i)
                #pragma unroll
                for (int j = 0; j < 2; ++j)
                    acc[i][j] = __builtin_amdgcn_mfma_f32_16x16x32_bf16(af[i], bfr[j], acc[i][j], 0, 0, 0);
        }
        cur ^= 1;
    }

    if (nz > 1) {
        int Nw = gridDim.x * 128;
        size_t pstride = (size_t)Nw * (gridDim.y * 128);
        float* Pz = P + (size_t)blockIdx.z * pstride;
        #pragma unroll
        for (int i = 0; i < 2; ++i)
            #pragma unroll
            for (int j = 0; j < 2; ++j)
                #pragma unroll
                for (int r = 0; r < 4; ++r) {
                    int grow = m0g + wr + i*16 + lg*4 + r;
                    int gcol = n0 + wc + j*16 + lr;
                    Pz[(size_t)grow * Nw + gcol] = acc[i][j][r];
                }
        return;
    }

    #pragma unroll
    for (int i = 0; i < 2; ++i)
        #pragma unroll
        for (int j = 0; j < 2; ++j)
            #pragma unroll
            for (int r = 0; r < 4; ++r) {
                int grow = m0g + wr + i*16 + lg*4 + r;
                int gcol = n0 + wc + j*16 + lr;
                float v = epi_apply(acc[i][j][r], grow, gcol, bias, mode, X, ldx, gate, gstride);
                if (obf)
                    ((__hip_bfloat16*)C)[(size_t)grow * ldc + gcol] = __float2bfloat16(v);
                else
                    ((float*)C)[(size_t)grow * ldc + gcol] = v;
            }
}

// ---------------------------------------------------------------------------
// combine split-K partials + epilogue. 4 elems/thread. optional C2 bf16 out.
// ---------------------------------------------------------------------------
__global__ __launch_bounds__(256) void gcomb_kernel(
    const float* __restrict__ P, size_t pstride, int nz, int Nw,
    const float* __restrict__ bias,
    void* __restrict__ C, int ldc, int mode, int obf,
    const float* __restrict__ X, int ldx,
    const float* __restrict__ gate, int gstride,
    __hip_bfloat16* __restrict__ C2, int ldc2)
{
    int idx = blockIdx.x * 256 + threadIdx.x;
    int e0 = idx * 4;
    int grow = e0 / Nw, gc0 = e0 % Nw;
    float4 v = *(const float4*)(P + (size_t)grow * Nw + gc0);
    for (int z = 1; z < nz; ++z) {
        float4 t = *(const float4*)(P + (size_t)z * pstride + (size_t)grow * Nw + gc0);
        v.x += t.x; v.y += t.y; v.z += t.z; v.w += t.w;
    }
    float e[4] = {v.x, v.y, v.z, v.w};
    #pragma unroll
    for (int r = 0; r < 4; ++r)
        e[r] = epi_apply(e[r], grow, gc0 + r, bias, mode, X, ldx, gate, gstride);
    if (obf) {
        U4 o4;
        #pragma unroll
        for (int r = 0; r < 4; ++r) o4.e[r] = __float2bfloat16(e[r]);
        *(uint2*)((__hip_bfloat16*)C + (size_t)grow * ldc + gc0) = o4.u2;
    } else {
        *(float4*)((float*)C + (size_t)grow * ldc + gc0) = make_float4(e[0], e[1], e[2], e[3]);
    }
    if (C2) {
        U4 o4;
        #pragma unroll
        for (int r = 0; r < 4; ++r) o4.e[r] = __float2bfloat16(e[r]);
        *(uint2*)(C2 + (size_t)grow * ldc2 + gc0) = o4.u2;
    }
}

// ---------------------------------------------------------------------------
// fused: combine split-K (nz, D=256) + bias + LayerNorm(g,b) [+silu] -> out
// ---------------------------------------------------------------------------
__global__ __launch_bounds__(256) void combln256_kernel(
    const float* __restrict__ P, size_t pstride, int nz,
    const float* __restrict__ bias,
    const float* __restrict__ g, const float* __restrict__ bv,
    int do_silu, int obf,
    void* __restrict__ out, int ldout)
{
    int row = blockIdx.x, d = threadIdx.x;
    __shared__ float red4[4];
    float v = P[(size_t)row*256 + d];
    for (int z = 1; z < nz; ++z) v += P[(size_t)z*pstride + (size_t)row*256 + d];
    v += bias[d];
    float mu = bsum256(v, red4, d) * (1.f/256.f);
    float dv = v - mu;
    float rstd = rsqrtf(bsum256(dv*dv, red4, d) * (1.f/256.f) + 1e-5f);
    float y = dv * rstd * g[d] + bv[d];
    if (do_silu) y = y / (1.f + __expf(-y));
    if (obf) ((__hip_bfloat16*)out)[(size_t)row * ldout + d] = __float2bfloat16(y);
    else     ((float*)out)[(size_t)row * ldout + d] = y;
}

// ---------------------------------------------------------------------------
// tin-chain fusion: combine split-K (nz, D=768) + bias ->
//   X = LN(t; g,b)  (write fp32) ; Hb = bf16( LN2(X)*(1+scm[b]) + shm[b] )
// ---------------------------------------------------------------------------
__global__ __launch_bounds__(256) void tinfuse_kernel(
    const float* __restrict__ P, size_t pstride, int nz,
    const float* __restrict__ bias,
    const float* __restrict__ g, const float* __restrict__ bb,
    const float* __restrict__ scm, const float* __restrict__ shm,
    float* __restrict__ X, __hip_bfloat16* __restrict__ Hb)
{
    int row = blockIdx.x, tid = threadIdx.x;
    int b = row >> 11;
    __shared__ float red4[4];
    float tv[3];
    float s = 0.f;
    #pragma unroll
    for (int q = 0; q < 3; ++q) {
        int d = tid + q*256;
        float v = P[(size_t)row*768 + d];
        for (int z = 1; z < nz; ++z) v += P[(size_t)z*pstride + (size_t)row*768 + d];
        v += bias[d];
        tv[q] = v; s += v;
    }
    float mu1 = bsum256(s, red4, tid) * (1.f/768.f);
    float s2 = 0.f;
    #pragma unroll
    for (int q = 0; q < 3; ++q) { float dv = tv[q] - mu1; s2 += dv*dv; }
    float rstd1 = rsqrtf(bsum256(s2, red4, tid) * (1.f/768.f) + 1e-5f);
    float xv[3];
    float s3 = 0.f;
    #pragma unroll
    for (int q = 0; q < 3; ++q) {
        int d = tid + q*256;
        float y = (tv[q] - mu1) * rstd1 * g[d] + bb[d];
        X[(size_t)row*768 + d] = y;
        xv[q] = y; s3 += y;
    }
    float mu2 = bsum256(s3, red4, tid) * (1.f/768.f);
    float s4 = 0.f;
    #pragma unroll
    for (int q = 0; q < 3; ++q) { float dv = xv[q] - mu2; s4 += dv*dv; }
    float rstd2 = rsqrtf(bsum256(s4, red4, tid) * (1.f/768.f) + 1e-5f);
    #pragma unroll
    for (int q = 0; q < 3; ++q) {
        int d = tid + q*256;
        float h = (xv[q] - mu2) * rstd2 * (1.f + scm[(size_t)b*4608 + d]) + shm[(size_t)b*4608 + d];
        Hb[(size_t)row*768 + d] = __float2bfloat16(h);
    }
}

// ---------------------------------------------------------------------------
// fused: combine split-K (nz) + bias + residual-gate into X, then
// Hb = bf16( LN(xnew)*(1+scm[b]) + shm[b] ).  block per row, D=768.
// ---------------------------------------------------------------------------
__global__ __launch_bounds__(256) void gcombln_kernel(
    const float* __restrict__ P, size_t pstride, int nz,
    const float* __restrict__ bias,
    float* __restrict__ X,
    const float* __restrict__ gate,
    const float* __restrict__ scm, const float* __restrict__ shm,
    __hip_bfloat16* __restrict__ Hb)
{
    int row = blockIdx.x, tid = threadIdx.x;
    int b = row >> 11;
    __shared__ float red4[4];
    float xv[3];
    float s = 0.f;
    #pragma unroll
    for (int q = 0; q < 3; ++q) {
        int d = tid + q*256;
        float v = P[(size_t)row*768 + d];
        for (int z = 1; z < nz; ++z) v += P[(size_t)z*pstride + (size_t)row*768 + d];
        v += bias[d];
        v = X[(size_t)row*768 + d] + gate[(size_t)b*4608 + d] * v;
        X[(size_t)row*768 + d] = v;
        xv[q] = v; s += v;
    }
    float mu = bsum256(s, red4, tid) * (1.f/768.f);
    float s2 = 0.f;
    #pragma unroll
    for (int q = 0; q < 3; ++q) { float dv = xv[q] - mu; s2 += dv*dv; }
    float rstd = rsqrtf(bsum256(s2, red4, tid) * (1.f/768.f) + 1e-5f);
    #pragma unroll
    for (int q = 0; q < 3; ++q) {
        int d = tid + q*256;
        float y = (xv[q] - mu) * rstd * (1.f + scm[(size_t)b*4608 + d]) + shm[(size_t)b*4608 + d];
        Hb[(size_t)row*768 + d] = __float2bfloat16(y);
    }
}

// ---------------------------------------------------------------------------
// c = LN(adaLN_emb @ ada_W + ada_b; g,b); c_silu = silu(c). 2 blocks.
// ---------------------------------------------------------------------------
__global__ __launch_bounds__(256) void ada_kernel(
    const float* __restrict__ emb, const float* __restrict__ W,
    const float* __restrict__ bias,
    const float* __restrict__ g, const float* __restrict__ bb,
    float* __restrict__ c, float* __restrict__ c_silu)
{
    int b = blockIdx.x, tid = threadIdx.x;
    __shared__ float emb_s[256];
    __shared__ float t[768];
    __shared__ float red[256];
    emb_s[tid] = emb[b*256 + tid];
    __syncthreads();
    for (int q = 0; q < 3; ++q) {
        int e = tid + q*256;
        float acc = bias[e];
        for (int k = 0; k < 256; ++k) acc += emb_s[k] * W[(size_t)k*768 + e];
        t[e] = acc;
    }
    __syncthreads();
    float s = 0.f; for (int q = 0; q < 3; ++q) s += t[tid + q*256];
    red[tid] = s; __syncthreads();
    for (int off = 128; off > 0; off >>= 1) { if (tid < off) red[tid] += red[tid+off]; __syncthreads(); }
    float mu = red[0] / 768.f; __syncthreads();
    float s2 = 0.f; for (int q = 0; q < 3; ++q) { float d = t[tid + q*256] - mu; s2 += d*d; }
    red[tid] = s2; __syncthreads();
    for (int off = 128; off > 0; off >>= 1) { if (tid < off) red[tid] += red[tid+off]; __syncthreads(); }
    float rstd = rsqrtf(red[0] / 768.f + 1e-5f);
    for (int q = 0; q < 3; ++q) {
        int e = tid + q*256;
        float y = (t[e] - mu) * rstd * g[e] + bb[e];
        c[b*768 + e] = y;
        c_silu[b*768 + e] = y / (1.f + expf(-y));
    }
}

// ---------------------------------------------------------------------------
// mod for BOTH layers, K-split 4: part[z][l][b][4608] ; grid (72, 4)
// ---------------------------------------------------------------------------
__global__ __launch_bounds__(256) void mod2_kernel(
    const float* __restrict__ c_silu, const float* __restrict__ mod_W,
    float* __restrict__ part)
{
    int idx = blockIdx.x * 256 + threadIdx.x;   // < 18432
    int z = blockIdx.y;
    int lyr = idx / 9216, b = (idx / 4608) & 1, j = idx % 4608;
    const float* Wl = mod_W + (size_t)lyr * 768 * 4608;
    const float* cs = c_silu + b * 768;
    float acc = 0.f;
    int k0 = z * 192;
    for (int k = k0; k < k0 + 192; ++k) acc += cs[k] * Wl[(size_t)k * 4608 + j];
    part[(size_t)z * 18432 + idx] = acc;
}

__global__ __launch_bounds__(256) void modc_kernel(
    const float* __restrict__ part, const float* __restrict__ mod_b,
    float* __restrict__ m2buf)
{
    int idx = blockIdx.x * 256 + threadIdx.x;
    int lyr = idx / 9216, j = idx % 4608;
    float acc = mod_b[(size_t)lyr * 4608 + j];
    #pragma unroll
    for (int z = 0; z < 4; ++z) acc += part[(size_t)z * 18432 + idx];
    m2buf[idx] = acc;
}

// ---------------------------------------------------------------------------
// MFMA local-window attention. 4 waves/block; block = (b, h, qgroup of 4
// qblocks).  Shared V window staged once: Vl[224][72].  Per-wave P private.
// ---------------------------------------------------------------------------
__global__ __launch_bounds__(256) void attn_mfma_kernel(
    const __hip_bfloat16* __restrict__ qkv,   // [B*N, 2304]
    const float* __restrict__ ropeC,          // [B*N, 32]
    const float* __restrict__ ropeS,
    __hip_bfloat16* __restrict__ o)           // [B*N, 768]
{
    int bid = blockIdx.x;
    int qg = bid & 15;                 // q-group (4 qblocks)
    int h  = (bid >> 4) % 12;
    int b  = bid / 192;
    int tid = threadIdx.x;
    int w  = tid >> 6;                 // wave 0..3
    int l  = tid & 63;
    int lr = l & 15, lg = l >> 4;

    int qb = qg * 4 + w;
    int lo_blk = max(0, 128*qg - 48);
    int hi_blk = min(N_, 128*qg + 176);
    int lo = max(0, 32*qb - 48);
    int hi = min(N_, 32*qb + 80);
    int wlen = hi - lo;
    int offv = lo - lo_blk;            // wave's row offset into Vl

    __shared__ __hip_bfloat16 Vl[224 * 72];
    __shared__ __hip_bfloat16 Pl[4 * 32 * 144];
    __hip_bfloat16* Plw = Pl + w * (32 * 144);

    // ---- stage shared V window (all 256 threads), zero-fill past hi_blk ----
    {
        int vr0 = tid >> 3;            // 0..31
        int c0  = (tid & 7) * 8;
        #pragma unroll
        for (int it = 0; it < 7; ++it) {
            int vr = it*32 + vr0;      // 0..223
            int n = lo_blk + vr;
            U8 v;
            if (n < hi_blk) {
                v.v = *(const bf16x8*)(qkv + ((size_t)(b*N_ + n))*2304 + 1536 + h*64 + c0);
            } else {
                #pragma unroll
                for (int j = 0; j < 8; ++j) v.u[j] = 0;
            }
            *(bf16x8*)(Vl + vr*72 + c0) = v.v;
        }
    }

    // ---- Q fragments with rope ----
    bf16x8 aq0[2], aq1[2];
    #pragma unroll
    for (int i = 0; i < 2; ++i) {
        int n = qb*32 + i*16 + lr;
        const __hip_bfloat16* qrow = qkv + ((size_t)(b*N_ + n))*2304 + h*64;
        U8 xlo, xhi;
        xlo.v = *(const bf16x8*)(qrow + lg*8);
        xhi.v = *(const bf16x8*)(qrow + 32 + lg*8);
        const float* pc = ropeC + ((size_t)(b*N_ + n))*32 + lg*8;
        const float* ps = ropeS + ((size_t)(b*N_ + n))*32 + lg*8;
        float4 c0 = *(const float4*)(pc), c1 = *(const float4*)(pc + 4);
        float4 s0 = *(const float4*)(ps), s1 = *(const float4*)(ps + 4);
        float cv[8] = {c0.x,c0.y,c0.z,c0.w,c1.x,c1.y,c1.z,c1.w};
        float sv[8] = {s0.x,s0.y,s0.z,s0.w,s1.x,s1.y,s1.z,s1.w};
        U8 f0, f1;
        #pragma unroll
        for (int j = 0; j < 8; ++j) {
            float x1 = __bfloat162float(xlo.e[j]);
            float x2 = __bfloat162float(xhi.e[j]);
            f0.e[j] = __float2bfloat16(x1*cv[j] - x2*sv[j]);
            f1.e[j] = __float2bfloat16(x1*sv[j] + x2*cv[j]);
        }
        aq0[i] = f0.v; aq1[i] = f1.v;
    }

    // ---- scores ----
    f32x4 S[2][8];
    #pragma unroll
    for (int i = 0; i < 2; ++i)
        #pragma unroll
        for (int jt = 0; jt < 8; ++jt)
            S[i][jt] = f32x4{0.f, 0.f, 0.f, 0.f};

    #pragma unroll
    for (int jt = 0; jt < 8; ++jt) {
        int n = lo + jt*16 + lr;
        U8 f0, f1;
        if (n < hi) {
            const __hip_bfloat16* krow = qkv + ((size_t)(b*N_ + n))*2304 + 768 + h*64;
            U8 xlo, xhi;
            xlo.v = *(const bf16x8*)(krow + lg*8);
            xhi.v = *(const bf16x8*)(krow + 32 + lg*8);
            const float* pc = ropeC + ((size_t)(b*N_ + n))*32 + lg*8;
            const float* ps = ropeS + ((size_t)(b*N_ + n))*32 + lg*8;
            float4 c0 = *(const float4*)(pc), c1 = *(const float4*)(pc + 4);
            float4 s0 = *(const float4*)(ps), s1 = *(const float4*)(ps + 4);
            float cv[8] = {c0.x,c0.y,c0.z,c0.w,c1.x,c1.y,c1.z,c1.w};
            float sv[8] = {s0.x,s0.y,s0.z,s0.w,s1.x,s1.y,s1.z,s1.w};
            #pragma unroll
            for (int j = 0; j < 8; ++j) {
                float x1 = __bfloat162float(xlo.e[j]);
                float x2 = __bfloat162float(xhi.e[j]);
                f0.e[j] = __float2bfloat16(x1*cv[j] - x2*sv[j]);
                f1.e[j] = __float2bfloat16(x1*sv[j] + x2*cv[j]);
            }
        } else {
            #pragma unroll
            for (int j = 0; j < 8; ++j) { f0.u[j] = 0; f1.u[j] = 0; }
        }
        #pragma unroll
        for (int i = 0; i < 2; ++i) {
            S[i][jt] = __builtin_amdgcn_mfma_f32_16x16x32_bf16(aq0[i], f0.v, S[i][jt], 0, 0, 0);
            S[i][jt] = __builtin_amdgcn_mfma_f32_16x16x32_bf16(aq1[i], f1.v, S[i][jt], 0, 0, 0);
        }
    }

    // ---- scale + mask ----
    #pragma unroll
    for (int jt = 0; jt < 8; ++jt) {
        bool oob = (jt*16 + lr) >= wlen;
        #pragma unroll
        for (int i = 0; i < 2; ++i)
            #pragma unroll
            for (int r = 0; r < 4; ++r)
                S[i][jt][r] = oob ? -1e30f : S[i][jt][r] * 0.125f;
    }

    // ---- wave-parallel softmax over 16-lane groups ----
    float rinv[2][4];
    #pragma unroll
    for (int i = 0; i < 2; ++i) {
        #pragma unroll
        for (int r = 0; r < 4; ++r) {
            float m = -1e30f;
            #pragma unroll
            for (int jt = 0; jt < 8; ++jt) m = fmaxf(m, S[i][jt][r]);
            #pragma unroll
            for (int mask = 8; mask > 0; mask >>= 1) m = fmaxf(m, __shfl_xor(m, mask, 16));
            float sum = 0.f;
            #pragma unroll
            for (int jt = 0; jt < 8; ++jt) {
                float e = __expf(S[i][jt][r] - m);
                S[i][jt][r] = e;
                sum += e;
            }
            #pragma unroll
            for (int mask = 8; mask > 0; mask >>= 1) sum += __shfl_xor(sum, mask, 16);
            rinv[i][r] = 1.f / sum;
        }
    }

    // ---- write P (bf16, XOR-swizzled cols) into this wave's region ----
    #pragma unroll
    for (int i = 0; i < 2; ++i)
        #pragma unroll
        for (int jt = 0; jt < 8; ++jt)
            #pragma unroll
            for (int r = 0; r < 4; ++r) {
                int row = i*16 + lg*4 + r;
                int colp = (jt*16 + lr) ^ (lg << 3);
                Plw[row*144 + colp] = __float2bfloat16(S[i][jt][r]);
            }

    __syncthreads();   // Vl staged by all + Plw written before; PV reads after

    // ---- PV ----
    f32x4 O_[2][4];
    #pragma unroll
    for (int i = 0; i < 2; ++i)
        #pragma unroll
        for (int ct = 0; ct < 4; ++ct)
            O_[i][ct] = f32x4{0.f, 0.f, 0.f, 0.f};

    int key = (lr >> 2) & 3;
    #pragma unroll
    for (int kt = 0; kt < 4; ++kt) {
        bf16x8 pa[2];
        #pragma unroll
        for (int i = 0; i < 2; ++i) {
            int row = i*16 + lr;
            int colp = (kt*32 + lg*8) ^ (key << 3);
            pa[i] = *(bf16x8*)(Plw + row*144 + colp);
        }
        #pragma unroll
        for (int ct = 0; ct < 4; ++ct) {
            U8 bv;
            #pragma unroll
            for (int j = 0; j < 8; ++j)
                bv.e[j] = Vl[(offv + kt*32 + lg*8 + j)*72 + ct*16 + lr];
            O_[0][ct] = __builtin_amdgcn_mfma_f32_16x16x32_bf16(pa[0], bv.v, O_[0][ct], 0, 0, 0);
            O_[1][ct] = __builtin_amdgcn_mfma_f32_16x16x32_bf16(pa[1], bv.v, O_[1][ct], 0, 0, 0);
        }
    }

    // ---- store O ----
    #pragma unroll
    for (int i = 0; i < 2; ++i)
        #pragma unroll
        for (int ct = 0; ct < 4; ++ct)
            #pragma unroll
            for (int r = 0; r < 4; ++r) {
                int row = qb*32 + i*16 + lg*4 + r;
                o[((size_t)(b*N_ + row))*768 + h*64 + ct*16 + lr] =
                    __float2bfloat16(O_[i][ct][r] * rinv[i][r]);
            }
}

// ---------------------------------------------------------------------------
// a2t [B,N,NR] fp32 -> a2tTb [B,NR,N] bf16   grid (NR/32, N/32, B)
// ---------------------------------------------------------------------------
__global__ __launch_bounds__(256) void a2t_transpose_kernel(
    const float* __restrict__ a2t, __hip_bfloat16* __restrict__ a2tTb)
{
    __shared__ float t[32][33];
    int r0 = blockIdx.x * 32, n0 = blockIdx.y * 32, b = blockIdx.z;
    int tid = threadIdx.x;
    int tx = tid & 31, ty = tid >> 5;
    #pragma unroll
    for (int i = 0; i < 4; ++i) {
        int row = ty + i*8;
        t[row][tx] = a2t[((size_t)b*N_ + n0 + row) * 256 + r0 + tx];
    }
    __syncthreads();
    #pragma unroll
    for (int i = 0; i < 4; ++i) {
        int row = ty + i*8;
        a2tTb[((size_t)b*256 + r0 + row) * N_ + n0 + tx] = __float2bfloat16(t[tx][row]);
    }
}

// ---------------------------------------------------------------------------
// recip[row] = 1/(sum of a2tTb row + 1e-6).  block per row (512 rows).
// ---------------------------------------------------------------------------
__global__ __launch_bounds__(256) void rowrecip_kernel(
    const __hip_bfloat16* __restrict__ a2tTb, float* __restrict__ recip)
{
    int row = blockIdx.x;
    int tid = threadIdx.x;
    __shared__ float red4[4];
    U8 v; v.v = *(const bf16x8*)(a2tTb + (size_t)row*2048 + tid*8);
    float s = 0.f;
    #pragma unroll
    for (int j = 0; j < 8; ++j) s += __bfloat162float(v.e[j]);
    float tot = bsum256(s, red4, tid);
    if (tid == 0) recip[row] = 1.f / (tot + 1e-6f);
}

// ---------------------------------------------------------------------------
extern "C" void kernel_launch(void* const* d_in, const int* in_sizes, int n_in,
                              void* d_out, int out_size, void* d_ws, size_t ws_size,
                              hipStream_t stream) {
    const float* atom_coords  = (const float*)d_in[0];
    const float* ref_pos      = (const float*)d_in[1];
    const int*   res_id       = (const int*)  d_in[2];
    const float* res_type     = (const float*)d_in[3];
    const float* charge       = (const float*)d_in[4];
    const float* atomic_num   = (const float*)d_in[5];
    const float* atom_name    = (const float*)d_in[6];
    const float* adaLN_emb    = (const float*)d_in[7];
    const int*   rope_pos     = (const int*)  d_in[8];
    const float* atom_to_tok  = (const float*)d_in[9];
    const float* feat_W       = (const float*)d_in[10];
    const float* feat_b       = (const float*)d_in[11];
    const float* feat_ln_g    = (const float*)d_in[12];
    const float* feat_ln_b    = (const float*)d_in[13];
    const float* pos_W        = (const float*)d_in[14];
    const float* in_W         = (const float*)d_in[15];
    const float* tin_W        = (const float*)d_in[16];
    const float* tin_b        = (const float*)d_in[17];
    const float* tin_ln_g     = (const float*)d_in[18];
    const float* tin_ln_b     = (const float*)d_in[19];
    const float* ada_W        = (const float*)d_in[20];
    const float* ada_b        = (const float*)d_in[21];
    const float* ada_ln_g     = (const float*)d_in[22];
    const float* ada_ln_b     = (const float*)d_in[23];
    const float* blk_mod_W    = (const float*)d_in[24];
    const float* blk_mod_b    = (const float*)d_in[25];
    const float* blk_qkv_W    = (const float*)d_in[26];
    const float* blk_qkv_b    = (const float*)d_in[27];
    const float* blk_o_W      = (const float*)d_in[28];
    const float* blk_o_b      = (const float*)d_in[29];
    const float* blk_m1_W     = (const float*)d_in[30];
    const float* blk_m1_b     = (const float*)d_in[31];
    const float* blk_m2_W     = (const float*)d_in[32];
    const float* blk_m2_b     = (const float*)d_in[33];
    const float* tout_W       = (const float*)d_in[34];
    const float* tout_b       = (const float*)d_in[35];
    const float* tout_ln_g    = (const float*)d_in[36];
    const float* tout_ln_b    = (const float*)d_in[37];

    const int BN = B_ * N_;                          // 4096
    float* ws = (float*)d_ws;

    // layout (float units)
    const size_t OFF_X    = 0;                                // fp32 [4096][768]
    const size_t OFF_HB   = OFF_X    + (size_t)BN*768;        // bf16 [4096][768]
    const size_t OFF_QKVB = OFF_HB   + (size_t)BN*768/2;      // bf16 [4096][2304]
    const size_t OFF_OB   = OFF_QKVB + (size_t)BN*2304/2;     // bf16 [4096][768]
    const size_t OFF_UB   = OFF_OB   + (size_t)BN*768/2;      // bf16 [4096][3072]
    const size_t OFF_WTL  = OFF_UB   + (size_t)BN*3072/2;     // bf16 layer weights (persistent)
    const size_t WTL_FLTS = (size_t)(2*768*2304 + 2*768*768 + 2*768*3072 + 2*3072*768) / 2;
    const size_t OFF_WTS  = OFF_WTL  + WTL_FLTS;              // bf16 phase-A scratch (5 regions)
    const size_t OFF_RC   = OFF_WTS  + 524288;                // fp32 BN*32
    const size_t OFF_RS   = OFF_RC   + (size_t)BN*32;
    const size_t OFF_SM   = OFF_RS   + (size_t)BN*32;

    float* X = ws + OFF_X;
    __hip_bfloat16* Hb   = (__hip_bfloat16*)(ws + OFF_HB);
    __hip_bfloat16* QKVb = (__hip_bfloat16*)(ws + OFF_QKVB);
    __hip_bfloat16* Ob   = (__hip_bfloat16*)(ws + OFF_OB);
    __hip_bfloat16* Ub   = (__hip_bfloat16*)(ws + OFF_UB);
    __hip_bfloat16* WTL  = (__hip_bfloat16*)(ws + OFF_WTL);
    __hip_bfloat16* WTs  = (__hip_bfloat16*)(ws + OFF_WTS);
    float* ropeC  = ws + OFF_RC;
    float* ropeS  = ws + OFF_RS;
    float* cbuf   = ws + OFF_SM;                     // 1536
    float* c_silu = cbuf + 1536;                     // 1536
    float* mbuf2  = c_silu + 1536;                   // 18432  [2][2][4608]
    float* modpart= mbuf2 + 18432;                   // 73728

    // persistent per-layer transposed weights (bf16 elem offsets)
    __hip_bfloat16* WTqkv = WTL;                                  // 2 x 768*2304
    __hip_bfloat16* WTo   = WTqkv + (size_t)2*768*2304;           // 2 x 768*768
    __hip_bfloat16* WTm1  = WTo   + (size_t)2*768*768;            // 2 x 768*3072
    __hip_bfloat16* WTm2  = WTm1  + (size_t)2*768*3072;           // 2 x 3072*768

    // phase-A scratch sub-regions (independent -> no WAR serialization)
    __hip_bfloat16* WTfeat = WTs;                                 // 1024*256
    __hip_bfloat16* WTpos  = WTfeat + (size_t)1024*256;           // 512*256
    __hip_bfloat16* WTin   = WTpos  + (size_t)512*256;            // 512*256
    __hip_bfloat16* WTtin  = WTin   + (size_t)512*256;            // 256*768
    __hip_bfloat16* WTtout = WTtin  + (size_t)256*768;            // 768*256

    // phase-A aliases
    __hip_bfloat16* featsB  = QKVb;                           // [4096][1024] bf16
    __hip_bfloat16* coordsB = QKVb + (size_t)BN*1024;         // [4096][512] bf16
    float* t1               = ws + OFF_UB;                    // scratch
    __hip_bfloat16* concatB = (__hip_bfloat16*)(t1 + (size_t)BN*256);  // [4096][512] bf16
    __hip_bfloat16* atom_inB= Ob;                             // [4096][256] bf16

    // residue-phase aliases (Ob/Ub regions dead by then)
    __hip_bfloat16* a2tTb   = Ob;                             // [2][256][2048] bf16
    __hip_bfloat16* latTb   = Ob + (size_t)2*256*2048;        // [2][256][2048] bf16
    float* recip            = modpart;                        // 512 fp32

    // split-K partial buffers (aliases of dead regions)
    float* P_pa   = ws + OFF_X;       // phase A (feat/pos/in)
    float* P_tin  = ws + OFF_UB;
    float* P_o    = ws + OFF_UB;
    float* P_m2   = ws + OFF_QKVB;
    float* P_tout = ws + OFF_UB;
    float* P_res  = ws + OFF_UB;

    float* out_res = (float*)d_out;                           // B*NR*DA
    float* out_lat = out_res + (size_t)B_*NR_*DA_;            // B*N*DA

    // ---- adaLN + modulation for both layers (input-only; run first) ----
    ada_kernel<<<2, 256, 0, stream>>>(adaLN_emb, ada_W, ada_b, ada_ln_g, ada_ln_b,
        cbuf, c_silu);
    mod2_kernel<<<dim3(72, 4), 256, 0, stream>>>(c_silu, blk_mod_W, modpart);
    modc_kernel<<<72, 256, 0, stream>>>(modpart, blk_mod_b, mbuf2);

    // ---- pre-transpose ALL weights upfront (no WAR serialization) ----
    transconv_kernel<<<dim3(72, 24, 2), 256, 0, stream>>>(blk_qkv_W, WTqkv,
        768, 768, 2304, (size_t)768*2304, (size_t)768*2304);
    transconv_kernel<<<dim3(24, 24, 2), 256, 0, stream>>>(blk_o_W, WTo,
        768, 768, 768, (size_t)768*768, (size_t)768*768);
    transconv_kernel<<<dim3(96, 24, 2), 256, 0, stream>>>(blk_m1_W, WTm1,
        768, 768, 3072, (size_t)768*3072, (size_t)768*3072);
    transconv_kernel<<<dim3(24, 96, 2), 256, 0, stream>>>(blk_m2_W, WTm2,
        3072, 3072, 768, (size_t)3072*768, (size_t)3072*768);
    transconv_kernel<<<dim3(8, 32), 256, 0, stream>>>(feat_W, WTfeat, 924, 1024, 256, 0, 0);
    transconv_kernel<<<dim3(8, 16), 256, 0, stream>>>(pos_W,  WTpos,  387, 512, 256, 0, 0);
    transconv_kernel<<<dim3(8, 16), 256, 0, stream>>>(in_W,   WTin,   512, 512, 256, 0, 0);
    transconv_kernel<<<dim3(24, 8), 256, 0, stream>>>(tin_W,  WTtin,  256, 256, 768, 0, 0);
    transconv_kernel<<<dim3(8, 24), 256, 0, stream>>>(tout_W, WTtout, 768, 768, 256, 0, 0);

    // ---- featurization (bf16) + rope table (fused) ----
    build_feats_kernel<<<BN, 128, 0, stream>>>(atom_coords, ref_pos, res_id,
        res_type, charge, atomic_num, atom_name, rope_pos, featsB, coordsB,
        ropeC, ropeS);

    // t1 = feats @ feat_W + feat_b   (K padded 924->1024, split 4)
    gemm_bf16_kernel<<<dim3(2, 32, 4), 1024, 0, stream>>>(featsB, 1024, WTfeat, 1024, nullptr,
        nullptr, 0, 1024, 0, 0, nullptr, 0, nullptr, 0, P_pa, 32, 0, 0);
    combln256_kernel<<<BN, 256, 0, stream>>>(P_pa, (size_t)BN*256, 4, feat_b,
        feat_ln_g, feat_ln_b, 1, 1, concatB, 512);
    // concat[:,256:512] = coordsF @ pos_W  (K 387->512, split 4)
    gemm_bf16_kernel<<<dim3(2, 32, 4), 1024, 0, stream>>>(coordsB, 512, WTpos, 512, nullptr,
        nullptr, 0, 512, 0, 0, nullptr, 0, nullptr, 0, P_pa, 32, 0, 0);
    gcomb_kernel<<<1024, 256, 0, stream>>>(P_pa, (size_t)BN*256, 4, 256, nullptr,
        concatB + 256, 512, 0, 1, nullptr, 0, nullptr, 0, nullptr, 0);
    // atom_in = concat @ in_W -> bf16 (split 4)
    gemm_bf16_kernel<<<dim3(2, 32, 4), 1024, 0, stream>>>(concatB, 512, WTin, 512, nullptr,
        nullptr, 0, 512, 0, 0, nullptr, 0, nullptr, 0, P_pa, 32, 0, 0);
    gcomb_kernel<<<1024, 256, 0, stream>>>(P_pa, (size_t)BN*256, 4, 256, nullptr,
        atom_inB, 256, 0, 1, nullptr, 0, nullptr, 0, nullptr, 0);
    // X = LN(atom_in @ tin_W + tin_b) ; Hb = LN(X)*(1+sc1)+sh1  (fused)
    gemm_bf16_kernel<<<dim3(6, 32, 2), 1024, 0, stream>>>(atom_inB, 256, WTtin, 256, nullptr,
        nullptr, 0, 256, 0, 0, nullptr, 0, nullptr, 0, P_tin, 32, 0, 0);
    tinfuse_kernel<<<BN, 256, 0, stream>>>(P_tin, (size_t)BN*768, 2, tin_b,
        tin_ln_g, tin_ln_b, mbuf2 + 768, mbuf2 + 0, X, Hb);

    for (int l = 0; l < NB_; ++l) {
        const float* qkvB = blk_qkv_b + (size_t)l*2304;
        const float* oB   = blk_o_b   + (size_t)l*768;
        const float* m1B  = blk_m1_b  + (size_t)l*3072;
        const float* m2B  = blk_m2_b  + (size_t)l*768;
        __hip_bfloat16* Wq = WTqkv + (size_t)l*768*2304;
        __hip_bfloat16* Wo = WTo   + (size_t)l*768*768;
        __hip_bfloat16* W1 = WTm1  + (size_t)l*768*3072;
        __hip_bfloat16* W2 = WTm2  + (size_t)l*3072*768;

        float* mptr = mbuf2 + (size_t)l*9216;        // [b][4608]
        float* sh2 = mptr + 2304, *sc2 = mptr + 3072;
        float* g1  = mptr + 1536, *g2 = mptr + 3840;

        // qkv = h @ qkv_W + b -> bf16
        gemm_bf16_kernel<<<dim3(18, 32, 1), 1024, 0, stream>>>(Hb, 768, Wq, 768, qkvB,
            QKVb, 2304, 768, 0, 1, nullptr, 0, nullptr, 0, nullptr, 32, 0, 0);
        // attention (4 waves/block, shared V window)
        attn_mfma_kernel<<<B_*H_*16, 256, 0, stream>>>(QKVb, ropeC, ropeS, Ob);
        // x = x + g1*(o @ o_W + o_b)  (split 2) ; fused -> Hb = h2
        gemm_bf16_kernel<<<dim3(6, 32, 2), 1024, 0, stream>>>(Ob, 768, Wo, 768, nullptr,
            nullptr, 0, 768, 0, 0, nullptr, 0, nullptr, 0, P_o, 32, 0, 0);
        gcombln_kernel<<<BN, 256, 0, stream>>>(P_o, (size_t)BN*768, 2, oB,
            X, g1, sc2, sh2, Hb);
        // u = gelu(h2 @ m1_W + b) -> bf16
        gemm_bf16_kernel<<<dim3(24, 32, 1), 1024, 0, stream>>>(Hb, 768, W1, 768, m1B,
            Ub, 3072, 768, 1, 1, nullptr, 0, nullptr, 0, nullptr, 32, 0, 0);
        // x = x + g2*(u @ m2_W + b)  (split 2)
        gemm_bf16_kernel<<<dim3(6, 32, 2), 1024, 0, stream>>>(Ub, 3072, W2, 3072, nullptr,
            nullptr, 0, 3072, 0, 0, nullptr, 0, nullptr, 0, P_m2, 32, 0, 0);
        if (l < NB_ - 1) {
            float* mnext = mbuf2 + (size_t)(l+1)*9216;
            gcombln_kernel<<<BN, 256, 0, stream>>>(P_m2, (size_t)BN*768, 2, m2B,
                X, g2, mnext + 768, mnext + 0, Hb);
        } else {
            // final layer: X is dead afterward -> write Hb (bf16) directly
            gcomb_kernel<<<3072, 256, 0, stream>>>(P_m2, (size_t)BN*768, 2, 768, m2B,
                Hb, 768, 2, 1, X, 768, g2, 4608, nullptr, 0);
        }
    }

    // atom_latent = LN(x @ tout_W + tout_b)  (split 4, fused combine+LN)
    gemm_bf16_kernel<<<dim3(2, 32, 4), 1024, 0, stream>>>(Hb, 768, WTtout, 768, nullptr,
        nullptr, 0, 768, 0, 0, nullptr, 0, nullptr, 0, P_tout, 32, 0, 0);
    combln256_kernel<<<BN, 256, 0, stream>>>(P_tout, (size_t)BN*256, 4, tout_b,
        tout_ln_g, tout_ln_b, 0, 0, out_lat, 256);

    // ---- residue pooling as MFMA GEMM ----
    a2t_transpose_kernel<<<dim3(8, 64, 2), 256, 0, stream>>>(atom_to_tok, a2tTb);
    rowrecip_kernel<<<512, 256, 0, stream>>>(a2tTb, recip);
    transconv_kernel<<<dim3(8, 64, 2), 256, 0, stream>>>(out_lat, latTb, 2048, 2048, 256,
        (size_t)2048*256, (size_t)256*2048);
    gemm_bf16_kernel<<<dim3(2, 4, 8), 1024, 0, stream>>>(a2tTb, 2048, latTb, 2048, nullptr,
        nullptr, 0, 2048, 0, 0, nullptr, 0, nullptr, 0, P_res,
        2, (size_t)256*2048, (size_t)256*2048);
    gcomb_kernel<<<128, 256, 0, stream>>>(P_res, (size_t)512*256, 8, 256, nullptr,
        out_res, 256, 3, 0, nullptr, 0, recip, 0, nullptr, 0);
}